// Round 2
// baseline (2647.644 us; speedup 1.0000x reference)
//
#include <hip/hip_runtime.h>
#include <cstdint>
#include <cstddef>
#include <type_traits>

// Problem constants
#define B_ 8
#define V_ 16
#define T_ 64
#define E_ 240          // V*(V-1)
#define H_ 256
#define RH_ 64
#define K_ 2
#define DIN_ 6
#define BET_ (B_*E_*T_)   // 122880
#define BVT_ (B_*V_*T_)   // 8192
#define BE_ (B_*E_)       // 1920

typedef unsigned short ushort_t;

__device__ __forceinline__ float eluf(float x) { return x > 0.f ? x : __expf(x) - 1.f; }
__device__ __forceinline__ float fsig(float x) { return 1.f / (1.f + __expf(-x)); }
__device__ __forceinline__ float ftanh_(float x) {
    float y = fminf(fmaxf(x, -8.f), 8.f);
    float e = __expf(2.f * y);
    return (e - 1.f) / (e + 1.f);
}
__device__ __forceinline__ float b2f(ushort_t u) {
    union { float f; uint32_t i; } v; v.i = ((uint32_t)u) << 16; return v.f;
}
__device__ __forceinline__ ushort_t f2b(float f) {
    union { float f; uint32_t i; } v; v.f = f;
    uint32_t r = (v.i + 0x7FFFu + ((v.i >> 16) & 1u)) >> 16;
    return (ushort_t)r;
}

// ---------------------------------------------------------------------------
// Generic tiled GEMM: C[m,n] = act( sum_k A[m,k]*W[n,k] + b1[n] (+ b2[n]) )
// A: [M,Kd] (TA = float or bf16/ushort), W: [N,Kd] f32 row-major.
// M%64==0, N%64==0, Kd%16==0. TO = float or bf16.
// ---------------------------------------------------------------------------
template<typename TA, typename TO>
__global__ __launch_bounds__(256) void gemm_t(
    const TA* __restrict__ A, const float* __restrict__ W,
    const float* __restrict__ b1, const float* __restrict__ b2,
    TO* __restrict__ C, int M, int Kd, int N, int act)
{
    __shared__ float As[16][64];
    __shared__ float Ws[16][64];
    const int m0 = blockIdx.x * 64, n0 = blockIdx.y * 64;
    const int tid = threadIdx.x;
    const int tm = tid >> 4, tn = tid & 15;   // compute coords
    const int lm = tid >> 2, lq = tid & 3;    // loader coords
    float acc[4][4] = {};
    const TA* Arow = A + (size_t)(m0 + lm) * Kd + lq * 4;
    const float* Wrow = W + (size_t)(n0 + lm) * Kd + lq * 4;
    for (int k0 = 0; k0 < Kd; k0 += 16) {
        float4 av, wv;
        if constexpr (std::is_same<TA, ushort_t>::value) {
            ushort4 u = *(const ushort4*)(Arow + k0);
            av.x = b2f(u.x); av.y = b2f(u.y); av.z = b2f(u.z); av.w = b2f(u.w);
        } else {
            av = *(const float4*)(Arow + k0);
        }
        wv = *(const float4*)(Wrow + k0);
        __syncthreads();
        As[lq*4+0][lm] = av.x; As[lq*4+1][lm] = av.y; As[lq*4+2][lm] = av.z; As[lq*4+3][lm] = av.w;
        Ws[lq*4+0][lm] = wv.x; Ws[lq*4+1][lm] = wv.y; Ws[lq*4+2][lm] = wv.z; Ws[lq*4+3][lm] = wv.w;
        __syncthreads();
        #pragma unroll
        for (int k = 0; k < 16; ++k) {
            float4 a = *(const float4*)&As[k][tm * 4];
            float4 w = *(const float4*)&Ws[k][tn * 4];
            float a_[4] = {a.x, a.y, a.z, a.w};
            float w_[4] = {w.x, w.y, w.z, w.w};
            #pragma unroll
            for (int i = 0; i < 4; ++i)
                #pragma unroll
                for (int j = 0; j < 4; ++j)
                    acc[i][j] += a_[i] * w_[j];
        }
    }
    float bb[4];
    #pragma unroll
    for (int j = 0; j < 4; ++j) {
        int n = n0 + tn * 4 + j;
        bb[j] = b1[n] + (b2 ? b2[n] : 0.f);
    }
    #pragma unroll
    for (int i = 0; i < 4; ++i) {
        float v0 = acc[i][0] + bb[0], v1 = acc[i][1] + bb[1];
        float v2 = acc[i][2] + bb[2], v3 = acc[i][3] + bb[3];
        if (act) { v0 = eluf(v0); v1 = eluf(v1); v2 = eluf(v2); v3 = eluf(v3); }
        TO* dst = C + (size_t)(m0 + tm * 4 + i) * N + (n0 + tn * 4);
        if constexpr (std::is_same<TO, ushort_t>::value) {
            ushort4 o; o.x = f2b(v0); o.y = f2b(v1); o.z = f2b(v2); o.w = f2b(v3);
            *(ushort4*)dst = o;
        } else {
            float4 o; o.x = v0; o.y = v1; o.z = v2; o.w = v3;
            *(float4*)dst = o;
        }
    }
}

// ---------------------------------------------------------------------------
// First GEMM with fused concat: A[m,c] = c<13 ? ear[m,c] : epos[m,c-13], Kd=16.
// Output bf16, ELU.
// ---------------------------------------------------------------------------
__global__ __launch_bounds__(256) void gemm_ein_k(
    const float* __restrict__ ear, const float* __restrict__ epos,
    const float* __restrict__ W, const float* __restrict__ b1,
    ushort_t* __restrict__ C)
{
    __shared__ float As[16][64];
    __shared__ float Ws[16][64];
    const int m0 = blockIdx.x * 64, n0 = blockIdx.y * 64;
    const int tid = threadIdx.x;
    const int tm = tid >> 4, tn = tid & 15;
    const int lm = tid >> 2, lq = tid & 3;
    const int m = m0 + lm;
    float a_[4];
    #pragma unroll
    for (int q = 0; q < 4; ++q) {
        int c = lq * 4 + q;
        a_[q] = (c < 13) ? ear[(size_t)m * 13 + c] : epos[(size_t)m * 3 + (c - 13)];
    }
    float4 wv = *(const float4*)(W + (size_t)(n0 + lm) * 16 + lq * 4);
    As[lq*4+0][lm] = a_[0]; As[lq*4+1][lm] = a_[1]; As[lq*4+2][lm] = a_[2]; As[lq*4+3][lm] = a_[3];
    Ws[lq*4+0][lm] = wv.x; Ws[lq*4+1][lm] = wv.y; Ws[lq*4+2][lm] = wv.z; Ws[lq*4+3][lm] = wv.w;
    __syncthreads();
    float acc[4][4] = {};
    #pragma unroll
    for (int k = 0; k < 16; ++k) {
        float4 a = *(const float4*)&As[k][tm * 4];
        float4 w = *(const float4*)&Ws[k][tn * 4];
        float aa[4] = {a.x, a.y, a.z, a.w};
        float ww[4] = {w.x, w.y, w.z, w.w};
        #pragma unroll
        for (int i = 0; i < 4; ++i)
            #pragma unroll
            for (int j = 0; j < 4; ++j)
                acc[i][j] += aa[i] * ww[j];
    }
    #pragma unroll
    for (int i = 0; i < 4; ++i) {
        ushort4 o;
        o.x = f2b(eluf(acc[i][0] + b1[n0 + tn*4 + 0]));
        o.y = f2b(eluf(acc[i][1] + b1[n0 + tn*4 + 1]));
        o.z = f2b(eluf(acc[i][2] + b1[n0 + tn*4 + 2]));
        o.w = f2b(eluf(acc[i][3] + b1[n0 + tn*4 + 3]));
        *(ushort4*)(C + (size_t)(m0 + tm * 4 + i) * H_ + (n0 + tn * 4)) = o;
    }
}

// ---------------------------------------------------------------------------
// mlp4 layer1 GEMM with on-the-fly gather. One block tile = one (b,e). Kd=768.
// k<256 -> X2[b,SEND[e],t,k] (f32); k<512 -> X2[b,RECV[e],t,·] (f32);
// else EA[b,e,t,·] (bf16). Output bf16, ELU.
// ---------------------------------------------------------------------------
__global__ __launch_bounds__(256) void gemm_mlp4_k(
    const float* __restrict__ X2, const ushort_t* __restrict__ EA,
    const float* __restrict__ W, const float* __restrict__ b1,
    ushort_t* __restrict__ C)
{
    __shared__ float As[16][64];
    __shared__ float Ws[16][64];
    const int be = blockIdx.x;             // 0..1919
    const int n0 = blockIdx.y * 64;
    const int b = be / E_, e = be % E_;
    const int s = e / (V_ - 1);
    const int r0 = e % (V_ - 1);
    const int r = r0 + (r0 >= s ? 1 : 0);
    const float* baseS = X2 + ((size_t)(b * V_ + s) * T_) * H_;
    const float* baseR = X2 + ((size_t)(b * V_ + r) * T_) * H_;
    const ushort_t* baseE = EA + ((size_t)be * T_) * H_;
    const int tid = threadIdx.x;
    const int tm = tid >> 4, tn = tid & 15;
    const int lm = tid >> 2, lq = tid & 3;
    float acc[4][4] = {};
    const float* Wrow = W + (size_t)(n0 + lm) * 768 + lq * 4;
    for (int k0 = 0; k0 < 768; k0 += 16) {
        float4 av;
        if (k0 < 512) {
            const float* src = (k0 < 256) ? baseS : baseR;
            int ko = k0 & 255;
            av = *(const float4*)(src + (size_t)lm * H_ + ko + lq * 4);
        } else {
            ushort4 u = *(const ushort4*)(baseE + (size_t)lm * H_ + (k0 - 512) + lq * 4);
            av.x = b2f(u.x); av.y = b2f(u.y); av.z = b2f(u.z); av.w = b2f(u.w);
        }
        float4 wv = *(const float4*)(Wrow + k0);
        __syncthreads();
        As[lq*4+0][lm] = av.x; As[lq*4+1][lm] = av.y; As[lq*4+2][lm] = av.z; As[lq*4+3][lm] = av.w;
        Ws[lq*4+0][lm] = wv.x; Ws[lq*4+1][lm] = wv.y; Ws[lq*4+2][lm] = wv.z; Ws[lq*4+3][lm] = wv.w;
        __syncthreads();
        #pragma unroll
        for (int k = 0; k < 16; ++k) {
            float4 a = *(const float4*)&As[k][tm * 4];
            float4 w = *(const float4*)&Ws[k][tn * 4];
            float a_[4] = {a.x, a.y, a.z, a.w};
            float w_[4] = {w.x, w.y, w.z, w.w};
            #pragma unroll
            for (int i = 0; i < 4; ++i)
                #pragma unroll
                for (int j = 0; j < 4; ++j)
                    acc[i][j] += a_[i] * w_[j];
        }
    }
    const int m0 = be * T_;
    #pragma unroll
    for (int i = 0; i < 4; ++i) {
        ushort4 o;
        o.x = f2b(eluf(acc[i][0] + b1[n0 + tn*4 + 0]));
        o.y = f2b(eluf(acc[i][1] + b1[n0 + tn*4 + 1]));
        o.z = f2b(eluf(acc[i][2] + b1[n0 + tn*4 + 2]));
        o.w = f2b(eluf(acc[i][3] + b1[n0 + tn*4 + 3]));
        *(ushort4*)(C + (size_t)(m0 + tm * 4 + i) * H_ + (n0 + tn * 4)) = o;
    }
}

// ---------------------------------------------------------------------------
// enc layer1 GEMM with fused concat: A[m,k] = k<64 ? HF[m,k] : HR[m,k-64]. Kd=128.
// bf16 in, bf16 out, ELU.
// ---------------------------------------------------------------------------
__global__ __launch_bounds__(256) void gemm_enc1_k(
    const ushort_t* __restrict__ HF, const ushort_t* __restrict__ HR,
    const float* __restrict__ W, const float* __restrict__ b1,
    ushort_t* __restrict__ C)
{
    __shared__ float As[16][64];
    __shared__ float Ws[16][64];
    const int m0 = blockIdx.x * 64, n0 = blockIdx.y * 64;
    const int tid = threadIdx.x;
    const int tm = tid >> 4, tn = tid & 15;
    const int lm = tid >> 2, lq = tid & 3;
    float acc[4][4] = {};
    const float* Wrow = W + (size_t)(n0 + lm) * 128 + lq * 4;
    for (int k0 = 0; k0 < 128; k0 += 16) {
        const ushort_t* src = (k0 < 64) ? HF : HR;
        int ko = k0 & 63;
        ushort4 u = *(const ushort4*)(src + (size_t)(m0 + lm) * 64 + ko + lq * 4);
        float4 av; av.x = b2f(u.x); av.y = b2f(u.y); av.z = b2f(u.z); av.w = b2f(u.w);
        float4 wv = *(const float4*)(Wrow + k0);
        __syncthreads();
        As[lq*4+0][lm] = av.x; As[lq*4+1][lm] = av.y; As[lq*4+2][lm] = av.z; As[lq*4+3][lm] = av.w;
        Ws[lq*4+0][lm] = wv.x; Ws[lq*4+1][lm] = wv.y; Ws[lq*4+2][lm] = wv.z; Ws[lq*4+3][lm] = wv.w;
        __syncthreads();
        #pragma unroll
        for (int k = 0; k < 16; ++k) {
            float4 a = *(const float4*)&As[k][tm * 4];
            float4 w = *(const float4*)&Ws[k][tn * 4];
            float a_[4] = {a.x, a.y, a.z, a.w};
            float w_[4] = {w.x, w.y, w.z, w.w};
            #pragma unroll
            for (int i = 0; i < 4; ++i)
                #pragma unroll
                for (int j = 0; j < 4; ++j)
                    acc[i][j] += a_[i] * w_[j];
        }
    }
    #pragma unroll
    for (int i = 0; i < 4; ++i) {
        ushort4 o;
        o.x = f2b(eluf(acc[i][0] + b1[n0 + tn*4 + 0]));
        o.y = f2b(eluf(acc[i][1] + b1[n0 + tn*4 + 1]));
        o.z = f2b(eluf(acc[i][2] + b1[n0 + tn*4 + 2]));
        o.w = f2b(eluf(acc[i][3] + b1[n0 + tn*4 + 3]));
        *(ushort4*)(C + (size_t)(m0 + tm * 4 + i) * H_ + (n0 + tn * 4)) = o;
    }
}

// ---------------------------------------------------------------------------
// edge2node: X[b,v,t,h] = (1/15)*sum_{e:RECV==v} EA[b,e,t,h] + rel@res_w.T + res_b
// grid = BVT blocks, 256 threads = h. EA bf16, X f32.
// ---------------------------------------------------------------------------
__global__ __launch_bounds__(256) void e2n_k(
    const ushort_t* __restrict__ EA, const float* __restrict__ rel,
    const float* __restrict__ res_w, const float* __restrict__ res_b,
    float* __restrict__ X)
{
    const int idx = blockIdx.x;            // (b*V+v)*T + t
    const int t = idx & (T_ - 1);
    const int bv = idx >> 6;
    const int v = bv & (V_ - 1);
    const int b = bv >> 4;
    const int h = threadIdx.x;
    float sum = 0.f;
    #pragma unroll
    for (int i = 0; i < V_; ++i) {
        if (i == v) continue;
        int jj = (v < i) ? v : v - 1;
        int e = i * (V_ - 1) + jj;
        sum += b2f(EA[(((size_t)(b * E_ + e)) * T_ + t) * H_ + h]);
    }
    const float* rp = rel + ((size_t)bv * T_ + t) * DIN_;
    float res = res_b[h];
    #pragma unroll
    for (int d = 0; d < DIN_; ++d) res += rp[d] * res_w[h * DIN_ + d];
    X[((size_t)bv * T_ + t) * H_ + h] = sum * (1.f / 15.f) + res;
}

// ---------------------------------------------------------------------------
// LSTM scan, one direction per launch. 4 sequences / block (1 wave each).
// whh staged transposed in LDS (f32). h in lane j, broadcast via __shfl.
// Gates G bf16 [BE*T, 256] in torch order i,f,g,o; output H bf16 [BE*T, 64].
// ---------------------------------------------------------------------------
__global__ __launch_bounds__(256) void lstm_k(
    const ushort_t* __restrict__ G, const float* __restrict__ whh,
    ushort_t* __restrict__ Hh, int dir)
{
    __shared__ float4 wt[64 * 64];   // wt[k*64+j] = {whh[j,k], whh[64+j,k], whh[128+j,k], whh[192+j,k]}
    const int tid = threadIdx.x;
    const int seq = tid >> 6, j = tid & 63;
    const int n = blockIdx.x * 4 + seq;
    #pragma unroll
    for (int ii = 0; ii < 16; ++ii) {
        int pos = tid + ii * 256;
        int k = pos >> 6, jj = pos & 63;
        float4 w;
        w.x = whh[(size_t)(jj) * 64 + k];
        w.y = whh[(size_t)(64 + jj) * 64 + k];
        w.z = whh[(size_t)(128 + jj) * 64 + k];
        w.w = whh[(size_t)(192 + jj) * 64 + k];
        wt[pos] = w;
    }
    __syncthreads();
    const ushort_t* gbase = G + (size_t)n * T_ * 256;
    ushort_t* hbase = Hh + (size_t)n * T_ * RH_;
    float h = 0.f, c = 0.f;
    for (int s = 0; s < T_; ++s) {
        int t = dir ? (T_ - 1 - s) : s;
        const ushort_t* g = gbase + (size_t)t * 256;
        float zi = b2f(g[j]), zf = b2f(g[64 + j]), zg = b2f(g[128 + j]), zo = b2f(g[192 + j]);
        #pragma unroll
        for (int k = 0; k < 64; ++k) {
            float hk = __shfl(h, k, 64);
            float4 w = wt[k * 64 + j];
            zi += hk * w.x; zf += hk * w.y; zg += hk * w.z; zo += hk * w.w;
        }
        c = fsig(zf) * c + fsig(zi) * ftanh_(zg);
        h = fsig(zo) * ftanh_(c);
        hbase[(size_t)t * RH_ + j] = f2b(h);
    }
}

// ---------------------------------------------------------------------------
// prior head: out[b,t,e,k] = HF[row,:] . p_w[k,:] + p_b[k]   (row = (b*E+e)*T+t)
// ---------------------------------------------------------------------------
__global__ __launch_bounds__(256) void prior_k(
    const ushort_t* __restrict__ HF, const float* __restrict__ p_w,
    const float* __restrict__ p_b, float* __restrict__ out)
{
    const int row = blockIdx.x * 4 + (threadIdx.x >> 6);  // [0, BET)
    const int lane = threadIdx.x & 63;
    float hf = b2f(HF[(size_t)row * RH_ + lane]);
    float v0 = hf * p_w[lane];
    float v1 = hf * p_w[64 + lane];
    #pragma unroll
    for (int off = 32; off > 0; off >>= 1) {
        v0 += __shfl_down(v0, off, 64);
        v1 += __shfl_down(v1, off, 64);
    }
    if (lane == 0) {
        int t = row & (T_ - 1);
        int be = row >> 6;
        int e = be % E_, b = be / E_;
        size_t o = (((size_t)b * T_ + t) * E_ + e) * K_;
        out[o] = v0 + p_b[0];
        out[o + 1] = v1 + p_b[1];
    }
}

// ---------------------------------------------------------------------------
// enc head: out[b,t,e,k] = ENCH[row,:] . e_w2[k,:] + e_b2[k]. ENCH bf16 [BET,256].
// ---------------------------------------------------------------------------
__global__ __launch_bounds__(256) void encout_k(
    const ushort_t* __restrict__ ENCH, const float* __restrict__ e_w2,
    const float* __restrict__ e_b2, float* __restrict__ out)
{
    const int row = blockIdx.x * 4 + (threadIdx.x >> 6);
    const int lane = threadIdx.x & 63;
    ushort4 u = *(const ushort4*)(ENCH + (size_t)row * 256 + lane * 4);
    float4 v; v.x = b2f(u.x); v.y = b2f(u.y); v.z = b2f(u.z); v.w = b2f(u.w);
    float4 w0 = *(const float4*)(e_w2 + lane * 4);
    float4 w1 = *(const float4*)(e_w2 + 256 + lane * 4);
    float p0 = v.x * w0.x + v.y * w0.y + v.z * w0.z + v.w * w0.w;
    float p1 = v.x * w1.x + v.y * w1.y + v.z * w1.z + v.w * w1.w;
    #pragma unroll
    for (int off = 32; off > 0; off >>= 1) {
        p0 += __shfl_down(p0, off, 64);
        p1 += __shfl_down(p1, off, 64);
    }
    if (lane == 0) {
        int t = row & (T_ - 1);
        int be = row >> 6;
        int e = be % E_, b = be / E_;
        size_t o = (size_t)(B_ * T_ * E_ * K_) + (((size_t)b * T_ + t) * E_ + e) * K_;
        out[o] = p0 + e_b2[0];
        out[o + 1] = p1 + e_b2[1];
    }
}

// ---------------------------------------------------------------------------
extern "C" void kernel_launch(void* const* d_in, const int* in_sizes, int n_in,
                              void* d_out, int out_size, void* d_ws, size_t ws_size,
                              hipStream_t stream)
{
    const float* rel    = (const float*)d_in[0];
    const float* ear    = (const float*)d_in[1];
    const float* epos   = (const float*)d_in[2];
    const float* ef_w1  = (const float*)d_in[3];
    const float* ef_b1  = (const float*)d_in[4];
    const float* ef_w2  = (const float*)d_in[5];
    const float* ef_b2  = (const float*)d_in[6];
    const float* res_w  = (const float*)d_in[7];
    const float* res_b  = (const float*)d_in[8];
    const float* m3_w1  = (const float*)d_in[9];
    const float* m3_b1  = (const float*)d_in[10];
    const float* m3_w2  = (const float*)d_in[11];
    const float* m3_b2  = (const float*)d_in[12];
    const float* m4_w1  = (const float*)d_in[13];
    const float* m4_b1  = (const float*)d_in[14];
    const float* m4_w2  = (const float*)d_in[15];
    const float* m4_b2  = (const float*)d_in[16];
    const float* f_wih  = (const float*)d_in[17];
    const float* f_whh  = (const float*)d_in[18];
    const float* f_bih  = (const float*)d_in[19];
    const float* f_bhh  = (const float*)d_in[20];
    const float* r_wih  = (const float*)d_in[21];
    const float* r_whh  = (const float*)d_in[22];
    const float* r_bih  = (const float*)d_in[23];
    const float* r_bhh  = (const float*)d_in[24];
    const float* p_w    = (const float*)d_in[25];
    const float* p_b    = (const float*)d_in[26];
    const float* e_w1   = (const float*)d_in[27];
    const float* e_b1   = (const float*)d_in[28];
    const float* e_w2   = (const float*)d_in[29];
    const float* e_b2   = (const float*)d_in[30];
    float* out = (float*)d_out;

    // workspace layout (bytes): total 174,073,856 B ~= 174 MB
    char* ws = (char*)d_ws;
    const size_t BIGB = (size_t)BET_ * H_ * sizeof(ushort_t);   // 62,914,560
    const size_t NODB = (size_t)BVT_ * H_ * sizeof(float);      //  8,388,608
    const size_t HB   = (size_t)BET_ * RH_ * sizeof(ushort_t);  // 15,728,640
    ushort_t* R1 = (ushort_t*)(ws);
    ushort_t* R2 = (ushort_t*)(ws + BIGB);
    float*    X  = (float*)   (ws + 2 * BIGB);
    float*    XH = (float*)   (ws + 2 * BIGB + NODB);
    ushort_t* HF = (ushort_t*)(ws + 2 * BIGB + 2 * NODB);
    ushort_t* HR = (ushort_t*)(ws + 2 * BIGB + 2 * NODB + HB);

    dim3 blk(256);
    dim3 gE(BET_ / 64, 4);     // edge-row GEMMs, N=256
    dim3 gN(BVT_ / 64, 4);     // node-row GEMMs

    // 1. edge filter MLP (concat fused into loader)
    gemm_ein_k<<<gE, blk, 0, stream>>>(ear, epos, ef_w1, ef_b1, R1);
    gemm_t<ushort_t, ushort_t><<<gE, blk, 0, stream>>>(R1, ef_w2, ef_b2, nullptr, R2, BET_, H_, H_, 1);  // EA
    // 2. edge2node + residual
    e2n_k<<<BVT_, blk, 0, stream>>>(R2, rel, res_w, res_b, X);
    // 3. mlp3 (node rows, f32)
    gemm_t<float, float><<<gN, blk, 0, stream>>>(X, m3_w1, m3_b1, nullptr, XH, BVT_, H_, H_, 1);
    gemm_t<float, float><<<gN, blk, 0, stream>>>(XH, m3_w2, m3_b2, nullptr, X, BVT_, H_, H_, 1);  // X2 -> X
    // 4. node2edge gather + mlp4
    gemm_mlp4_k<<<dim3(BE_, 4), blk, 0, stream>>>(X, R2, m4_w1, m4_b1, R1);
    gemm_t<ushort_t, ushort_t><<<gE, blk, 0, stream>>>(R1, m4_w2, m4_b2, nullptr, R2, BET_, H_, H_, 1); // M2
    // 5. LSTM fwd: gates then scan; then rev reusing R1
    gemm_t<ushort_t, ushort_t><<<gE, blk, 0, stream>>>(R2, f_wih, f_bih, f_bhh, R1, BET_, H_, H_, 0);   // GF
    lstm_k<<<BE_ / 4, blk, 0, stream>>>(R1, f_whh, HF, 0);
    gemm_t<ushort_t, ushort_t><<<gE, blk, 0, stream>>>(R2, r_wih, r_bih, r_bhh, R1, BET_, H_, H_, 0);   // GR
    lstm_k<<<BE_ / 4, blk, 0, stream>>>(R1, r_whh, HR, 1);
    // 6. heads
    prior_k<<<BET_ / 4, blk, 0, stream>>>(HF, p_w, p_b, out);
    gemm_enc1_k<<<gE, blk, 0, stream>>>(HF, HR, e_w1, e_b1, R1);    // ENCH
    encout_k<<<BET_ / 4, blk, 0, stream>>>(R1, e_w2, e_b2, out);
}

// Round 3
// 1319.014 us; speedup vs baseline: 2.0073x; 2.0073x over previous
//
#include <hip/hip_runtime.h>
#include <cstdint>
#include <cstddef>
#include <type_traits>

// Problem constants
#define B_ 8
#define V_ 16
#define T_ 64
#define E_ 240          // V*(V-1)
#define H_ 256
#define RH_ 64
#define K_ 2
#define DIN_ 6
#define BET_ (B_*E_*T_)   // 122880
#define BVT_ (B_*V_*T_)   // 8192
#define BE_ (B_*E_)       // 1920

typedef unsigned short ushort_t;
typedef unsigned int u32;
typedef __attribute__((ext_vector_type(8))) short bf16x8;
typedef __attribute__((ext_vector_type(4))) float f32x4;

__device__ __forceinline__ float eluf(float x) { return x > 0.f ? x : __expf(x) - 1.f; }
__device__ __forceinline__ float fsig(float x) { return 1.f / (1.f + __expf(-x)); }
__device__ __forceinline__ float ftanh_(float x) {
    float y = fminf(fmaxf(x, -8.f), 8.f);
    float e = __expf(2.f * y);
    return (e - 1.f) / (e + 1.f);
}
__device__ __forceinline__ float b2f(ushort_t u) {
    union { float f; uint32_t i; } v; v.i = ((uint32_t)u) << 16; return v.f;
}
__device__ __forceinline__ ushort_t f2b(float f) {
    union { float f; uint32_t i; } v; v.f = f;
    uint32_t r = (v.i + 0x7FFFu + ((v.i >> 16) & 1u)) >> 16;
    return (ushort_t)r;
}

// async global->LDS, 16B per lane; LDS dest = wave-uniform base + lane*16
__device__ __forceinline__ void gll16(const void* g, void* l) {
    __builtin_amdgcn_global_load_lds(
        (const __attribute__((address_space(1))) u32*)g,
        (__attribute__((address_space(3))) u32*)l, 16, 0, 0);
}

// ===========================================================================
// MFMA bf16 GEMM: C[m,n] = act( sum_k A[m,k]*W[n,k] + b1[n] (+b2[n]) ), bf16 out
// A [M,KD] bf16 row-major, W [N,KD] bf16 row-major, N = 256.
// BM=128, BN=128, K-step 32, 4 waves (2x2), each wave 64x64 (4x4 frags 16x16).
// LDS in fragment order: [buf][A/B][frag 0..7][lane*8 bf16]  (zero-conflict b128)
// mfma(Wfrag, Afrag): lane holds C rows m=lane&15, cols n=(lane>>4)*4+r (r=0..3)
// ===========================================================================
template<int KD, int ACT>
__global__ __launch_bounds__(256) void mfma_gemm_k(
    const ushort_t* __restrict__ A, const ushort_t* __restrict__ Wt,
    const float* __restrict__ b1, const float* __restrict__ b2,
    ushort_t* __restrict__ C)
{
    __shared__ ushort_t lds[2][2][8][512];   // 32 KB
    const int tid = threadIdx.x;
    const int lane = tid & 63;
    const int w = tid >> 6;
    const int wr = w >> 1, wc = w & 1;
    const int m0 = blockIdx.x * 128;
    const int n0 = blockIdx.y * 128;
    const int r16 = lane & 15, kq = lane >> 4;
    constexpr int NKT = KD / 32;

    const ushort_t* Abase[2];
    const ushort_t* Wbase[2];
    #pragma unroll
    for (int ff = 0; ff < 2; ++ff) {
        int f = 2 * w + ff;
        Abase[ff] = A  + (size_t)(m0 + f * 16 + r16) * KD + kq * 8;
        Wbase[ff] = Wt + (size_t)(n0 + f * 16 + r16) * KD + kq * 8;
    }

    f32x4 acc[4][4];
    #pragma unroll
    for (int i = 0; i < 4; ++i)
        #pragma unroll
        for (int j = 0; j < 4; ++j)
            acc[i][j] = (f32x4){0.f, 0.f, 0.f, 0.f};

#define STAGE_G(bufi, kt) do {                                              \
    _Pragma("unroll")                                                       \
    for (int ff = 0; ff < 2; ++ff) {                                        \
        int f = 2 * w + ff;                                                 \
        gll16(Abase[ff] + (kt) * 32, &lds[bufi][0][f][0]);                  \
        gll16(Wbase[ff] + (kt) * 32, &lds[bufi][1][f][0]);                  \
    } } while (0)

#define COMPUTE_G(bufi) do {                                                \
    bf16x8 af[4], bfr[4];                                                   \
    _Pragma("unroll")                                                       \
    for (int mf = 0; mf < 4; ++mf) af[mf] = *(const bf16x8*)&lds[bufi][0][wr*4+mf][lane*8]; \
    _Pragma("unroll")                                                       \
    for (int nf = 0; nf < 4; ++nf) bfr[nf] = *(const bf16x8*)&lds[bufi][1][wc*4+nf][lane*8]; \
    _Pragma("unroll")                                                       \
    for (int mf = 0; mf < 4; ++mf)                                          \
        _Pragma("unroll")                                                   \
        for (int nf = 0; nf < 4; ++nf)                                      \
            acc[mf][nf] = __builtin_amdgcn_mfma_f32_16x16x32_bf16(bfr[nf], af[mf], acc[mf][nf], 0, 0, 0); \
    } while (0)

    STAGE_G(0, 0);
    __syncthreads();
    int buf = 0;
    for (int kt = 0; kt < NKT - 1; ++kt) {
        STAGE_G(buf ^ 1, kt + 1);
        COMPUTE_G(buf);
        __syncthreads();
        buf ^= 1;
    }
    COMPUTE_G(buf);

    #pragma unroll
    for (int mf = 0; mf < 4; ++mf) {
        int mrow = m0 + wr * 64 + mf * 16 + r16;
        #pragma unroll
        for (int nf = 0; nf < 4; ++nf) {
            int nb = n0 + wc * 64 + nf * 16 + kq * 4;
            float4 bb = *(const float4*)&b1[nb];
            if (b2) {
                float4 b2v = *(const float4*)&b2[nb];
                bb.x += b2v.x; bb.y += b2v.y; bb.z += b2v.z; bb.w += b2v.w;
            }
            float v0 = acc[mf][nf][0] + bb.x;
            float v1 = acc[mf][nf][1] + bb.y;
            float v2 = acc[mf][nf][2] + bb.z;
            float v3 = acc[mf][nf][3] + bb.w;
            if (ACT) { v0 = eluf(v0); v1 = eluf(v1); v2 = eluf(v2); v3 = eluf(v3); }
            ushort4 o; o.x = f2b(v0); o.y = f2b(v1); o.z = f2b(v2); o.w = f2b(v3);
            *(ushort4*)&C[(size_t)mrow * 256 + nb] = o;
        }
    }
#undef STAGE_G
#undef COMPUTE_G
}

// ===========================================================================
// mlp4 layer-1 MFMA GEMM with fused gather, KD=768:
// row m=(be*64+t); k<256 -> X2b[b,send,t,k]; k<512 -> X2b[b,recv,t,·]; else EA[be,t,·]
// ===========================================================================
__global__ __launch_bounds__(256) void mfma_mlp4_k(
    const ushort_t* __restrict__ X2b, const ushort_t* __restrict__ EA,
    const ushort_t* __restrict__ Wt, const float* __restrict__ b1,
    ushort_t* __restrict__ C)
{
    __shared__ ushort_t lds[2][2][8][512];
    const int tid = threadIdx.x;
    const int lane = tid & 63;
    const int w = tid >> 6;
    const int wr = w >> 1, wc = w & 1;
    const int m0 = blockIdx.x * 128;
    const int n0 = blockIdx.y * 128;
    const int r16 = lane & 15, kq = lane >> 4;
    constexpr int NKT = 24;

    const ushort_t* AS[2]; const ushort_t* AR[2]; const ushort_t* AE[2];
    const ushort_t* Wbase[2];
    #pragma unroll
    for (int ff = 0; ff < 2; ++ff) {
        int f = 2 * w + ff;
        int m = m0 + f * 16 + r16;
        int be = m >> 6, t = m & 63;
        int b = be / E_, e = be % E_;
        int s = e / (V_ - 1);
        int r0 = e % (V_ - 1);
        int rr = r0 + (r0 >= s ? 1 : 0);
        AS[ff] = X2b + ((size_t)((b * V_ + s) * T_ + t)) * H_ + kq * 8;
        AR[ff] = X2b + ((size_t)((b * V_ + rr) * T_ + t)) * H_ + kq * 8;
        AE[ff] = EA + (size_t)m * H_ + kq * 8;
        Wbase[ff] = Wt + (size_t)(n0 + f * 16 + r16) * 768 + kq * 8;
    }

    f32x4 acc[4][4];
    #pragma unroll
    for (int i = 0; i < 4; ++i)
        #pragma unroll
        for (int j = 0; j < 4; ++j)
            acc[i][j] = (f32x4){0.f, 0.f, 0.f, 0.f};

#define STAGE_M(bufi, kt) do {                                              \
    int kk = (kt) * 32;                                                     \
    _Pragma("unroll")                                                       \
    for (int ff = 0; ff < 2; ++ff) {                                        \
        int f = 2 * w + ff;                                                 \
        const ushort_t* ga = (kk < 256) ? AS[ff] + kk                       \
                           : (kk < 512) ? AR[ff] + (kk - 256)               \
                                        : AE[ff] + (kk - 512);              \
        gll16(ga, &lds[bufi][0][f][0]);                                     \
        gll16(Wbase[ff] + kk, &lds[bufi][1][f][0]);                         \
    } } while (0)

#define COMPUTE_M(bufi) do {                                                \
    bf16x8 af[4], bfr[4];                                                   \
    _Pragma("unroll")                                                       \
    for (int mf = 0; mf < 4; ++mf) af[mf] = *(const bf16x8*)&lds[bufi][0][wr*4+mf][lane*8]; \
    _Pragma("unroll")                                                       \
    for (int nf = 0; nf < 4; ++nf) bfr[nf] = *(const bf16x8*)&lds[bufi][1][wc*4+nf][lane*8]; \
    _Pragma("unroll")                                                       \
    for (int mf = 0; mf < 4; ++mf)                                          \
        _Pragma("unroll")                                                   \
        for (int nf = 0; nf < 4; ++nf)                                      \
            acc[mf][nf] = __builtin_amdgcn_mfma_f32_16x16x32_bf16(bfr[nf], af[mf], acc[mf][nf], 0, 0, 0); \
    } while (0)

    STAGE_M(0, 0);
    __syncthreads();
    int buf = 0;
    for (int kt = 0; kt < NKT - 1; ++kt) {
        STAGE_M(buf ^ 1, kt + 1);
        COMPUTE_M(buf);
        __syncthreads();
        buf ^= 1;
    }
    COMPUTE_M(buf);

    #pragma unroll
    for (int mf = 0; mf < 4; ++mf) {
        int mrow = m0 + wr * 64 + mf * 16 + r16;
        #pragma unroll
        for (int nf = 0; nf < 4; ++nf) {
            int nb = n0 + wc * 64 + nf * 16 + kq * 4;
            float4 bb = *(const float4*)&b1[nb];
            float v0 = eluf(acc[mf][nf][0] + bb.x);
            float v1 = eluf(acc[mf][nf][1] + bb.y);
            float v2 = eluf(acc[mf][nf][2] + bb.z);
            float v3 = eluf(acc[mf][nf][3] + bb.w);
            ushort4 o; o.x = f2b(v0); o.y = f2b(v1); o.z = f2b(v2); o.w = f2b(v3);
            *(ushort4*)&C[(size_t)mrow * 256 + nb] = o;
        }
    }
#undef STAGE_M
#undef COMPUTE_M
}

// ===========================================================================
// weights f32 -> bf16 (packed): ef_w2 | m4_w1 | m4_w2 | f_wih | r_wih | e_w1
// ===========================================================================
__global__ __launch_bounds__(256) void wconv_k(
    const float* __restrict__ ef_w2, const float* __restrict__ m4_w1,
    const float* __restrict__ m4_w2, const float* __restrict__ f_wih,
    const float* __restrict__ r_wih, const float* __restrict__ e_w1,
    ushort_t* __restrict__ Wb)
{
    int i = blockIdx.x * 256 + threadIdx.x;   // < 491520
    const float* src; int off;
    if (i < 65536)       { src = ef_w2; off = i; }
    else if (i < 262144) { src = m4_w1; off = i - 65536; }
    else if (i < 327680) { src = m4_w2; off = i - 262144; }
    else if (i < 393216) { src = f_wih; off = i - 327680; }
    else if (i < 458752) { src = r_wih; off = i - 393216; }
    else                 { src = e_w1;  off = i - 458752; }
    Wb[i] = f2b(src[off]);
}

// ---------------------------------------------------------------------------
// Generic VALU GEMM (kept for mlp3 node rows): C = act(A@W.T + b1)
// ---------------------------------------------------------------------------
template<typename TA, typename TO>
__global__ __launch_bounds__(256) void gemm_t(
    const TA* __restrict__ A, const float* __restrict__ W,
    const float* __restrict__ b1, const float* __restrict__ b2,
    TO* __restrict__ C, int M, int Kd, int N, int act)
{
    __shared__ float As[16][64];
    __shared__ float Ws[16][64];
    const int m0 = blockIdx.x * 64, n0 = blockIdx.y * 64;
    const int tid = threadIdx.x;
    const int tm = tid >> 4, tn = tid & 15;
    const int lm = tid >> 2, lq = tid & 3;
    float acc[4][4] = {};
    const TA* Arow = A + (size_t)(m0 + lm) * Kd + lq * 4;
    const float* Wrow = W + (size_t)(n0 + lm) * Kd + lq * 4;
    for (int k0 = 0; k0 < Kd; k0 += 16) {
        float4 av, wv;
        if constexpr (std::is_same<TA, ushort_t>::value) {
            ushort4 u = *(const ushort4*)(Arow + k0);
            av.x = b2f(u.x); av.y = b2f(u.y); av.z = b2f(u.z); av.w = b2f(u.w);
        } else {
            av = *(const float4*)(Arow + k0);
        }
        wv = *(const float4*)(Wrow + k0);
        __syncthreads();
        As[lq*4+0][lm] = av.x; As[lq*4+1][lm] = av.y; As[lq*4+2][lm] = av.z; As[lq*4+3][lm] = av.w;
        Ws[lq*4+0][lm] = wv.x; Ws[lq*4+1][lm] = wv.y; Ws[lq*4+2][lm] = wv.z; Ws[lq*4+3][lm] = wv.w;
        __syncthreads();
        #pragma unroll
        for (int k = 0; k < 16; ++k) {
            float4 a = *(const float4*)&As[k][tm * 4];
            float4 w = *(const float4*)&Ws[k][tn * 4];
            float a_[4] = {a.x, a.y, a.z, a.w};
            float w_[4] = {w.x, w.y, w.z, w.w};
            #pragma unroll
            for (int i = 0; i < 4; ++i)
                #pragma unroll
                for (int j = 0; j < 4; ++j)
                    acc[i][j] += a_[i] * w_[j];
        }
    }
    float bb[4];
    #pragma unroll
    for (int j = 0; j < 4; ++j) {
        int n = n0 + tn * 4 + j;
        bb[j] = b1[n] + (b2 ? b2[n] : 0.f);
    }
    #pragma unroll
    for (int i = 0; i < 4; ++i) {
        float v0 = acc[i][0] + bb[0], v1 = acc[i][1] + bb[1];
        float v2 = acc[i][2] + bb[2], v3 = acc[i][3] + bb[3];
        if (act) { v0 = eluf(v0); v1 = eluf(v1); v2 = eluf(v2); v3 = eluf(v3); }
        TO* dst = C + (size_t)(m0 + tm * 4 + i) * N + (n0 + tn * 4);
        if constexpr (std::is_same<TO, ushort_t>::value) {
            ushort4 o; o.x = f2b(v0); o.y = f2b(v1); o.z = f2b(v2); o.w = f2b(v3);
            *(ushort4*)dst = o;
        } else {
            float4 o; o.x = v0; o.y = v1; o.z = v2; o.w = v3;
            *(float4*)dst = o;
        }
    }
}

// ---------------------------------------------------------------------------
// First GEMM with fused concat: A[m,c] = c<13 ? ear[m,c] : epos[m,c-13], Kd=16.
// ---------------------------------------------------------------------------
__global__ __launch_bounds__(256) void gemm_ein_k(
    const float* __restrict__ ear, const float* __restrict__ epos,
    const float* __restrict__ W, const float* __restrict__ b1,
    ushort_t* __restrict__ C)
{
    __shared__ float As[16][64];
    __shared__ float Ws[16][64];
    const int m0 = blockIdx.x * 64, n0 = blockIdx.y * 64;
    const int tid = threadIdx.x;
    const int tm = tid >> 4, tn = tid & 15;
    const int lm = tid >> 2, lq = tid & 3;
    const int m = m0 + lm;
    float a_[4];
    #pragma unroll
    for (int q = 0; q < 4; ++q) {
        int c = lq * 4 + q;
        a_[q] = (c < 13) ? ear[(size_t)m * 13 + c] : epos[(size_t)m * 3 + (c - 13)];
    }
    float4 wv = *(const float4*)(W + (size_t)(n0 + lm) * 16 + lq * 4);
    As[lq*4+0][lm] = a_[0]; As[lq*4+1][lm] = a_[1]; As[lq*4+2][lm] = a_[2]; As[lq*4+3][lm] = a_[3];
    Ws[lq*4+0][lm] = wv.x; Ws[lq*4+1][lm] = wv.y; Ws[lq*4+2][lm] = wv.z; Ws[lq*4+3][lm] = wv.w;
    __syncthreads();
    float acc[4][4] = {};
    #pragma unroll
    for (int k = 0; k < 16; ++k) {
        float4 a = *(const float4*)&As[k][tm * 4];
        float4 w = *(const float4*)&Ws[k][tn * 4];
        float aa[4] = {a.x, a.y, a.z, a.w};
        float ww[4] = {w.x, w.y, w.z, w.w};
        #pragma unroll
        for (int i = 0; i < 4; ++i)
            #pragma unroll
            for (int j = 0; j < 4; ++j)
                acc[i][j] += aa[i] * ww[j];
    }
    #pragma unroll
    for (int i = 0; i < 4; ++i) {
        ushort4 o;
        o.x = f2b(eluf(acc[i][0] + b1[n0 + tn*4 + 0]));
        o.y = f2b(eluf(acc[i][1] + b1[n0 + tn*4 + 1]));
        o.z = f2b(eluf(acc[i][2] + b1[n0 + tn*4 + 2]));
        o.w = f2b(eluf(acc[i][3] + b1[n0 + tn*4 + 3]));
        *(ushort4*)(C + (size_t)(m0 + tm * 4 + i) * H_ + (n0 + tn * 4)) = o;
    }
}

// ---------------------------------------------------------------------------
// edge2node: X[b,v,t,h] = (1/15)*sum_{e:RECV==v} EA[b,e,t,h] + rel@res_w.T + res_b
// ---------------------------------------------------------------------------
__global__ __launch_bounds__(256) void e2n_k(
    const ushort_t* __restrict__ EA, const float* __restrict__ rel,
    const float* __restrict__ res_w, const float* __restrict__ res_b,
    float* __restrict__ X)
{
    const int idx = blockIdx.x;            // (b*V+v)*T + t
    const int t = idx & (T_ - 1);
    const int bv = idx >> 6;
    const int v = bv & (V_ - 1);
    const int b = bv >> 4;
    const int h = threadIdx.x;
    float sum = 0.f;
    #pragma unroll
    for (int i = 0; i < V_; ++i) {
        if (i == v) continue;
        int jj = (v < i) ? v : v - 1;
        int e = i * (V_ - 1) + jj;
        sum += b2f(EA[(((size_t)(b * E_ + e)) * T_ + t) * H_ + h]);
    }
    const float* rp = rel + ((size_t)bv * T_ + t) * DIN_;
    float res = res_b[h];
    #pragma unroll
    for (int d = 0; d < DIN_; ++d) res += rp[d] * res_w[h * DIN_ + d];
    X[((size_t)bv * T_ + t) * H_ + h] = sum * (1.f / 15.f) + res;
}

// ---------------------------------------------------------------------------
// LSTM scan, one direction per launch; writes into comb buffer (row stride 128).
// ---------------------------------------------------------------------------
__global__ __launch_bounds__(256) void lstm_k(
    const ushort_t* __restrict__ G, const float* __restrict__ whh,
    ushort_t* __restrict__ Hh, int dir)
{
    __shared__ float4 wt[64 * 64];
    const int tid = threadIdx.x;
    const int seq = tid >> 6, j = tid & 63;
    const int n = blockIdx.x * 4 + seq;
    #pragma unroll
    for (int ii = 0; ii < 16; ++ii) {
        int pos = tid + ii * 256;
        int k = pos >> 6, jj = pos & 63;
        float4 w;
        w.x = whh[(size_t)(jj) * 64 + k];
        w.y = whh[(size_t)(64 + jj) * 64 + k];
        w.z = whh[(size_t)(128 + jj) * 64 + k];
        w.w = whh[(size_t)(192 + jj) * 64 + k];
        wt[pos] = w;
    }
    __syncthreads();
    const ushort_t* gbase = G + (size_t)n * T_ * 256;
    ushort_t* hbase = Hh + (size_t)n * T_ * 128;
    float h = 0.f, c = 0.f;
    for (int s = 0; s < T_; ++s) {
        int t = dir ? (T_ - 1 - s) : s;
        const ushort_t* g = gbase + (size_t)t * 256;
        float zi = b2f(g[j]), zf = b2f(g[64 + j]), zg = b2f(g[128 + j]), zo = b2f(g[192 + j]);
        #pragma unroll
        for (int k = 0; k < 64; ++k) {
            float hk = __shfl(h, k, 64);
            float4 w = wt[k * 64 + j];
            zi += hk * w.x; zf += hk * w.y; zg += hk * w.z; zo += hk * w.w;
        }
        c = fsig(zf) * c + fsig(zi) * ftanh_(zg);
        h = fsig(zo) * ftanh_(c);
        hbase[(size_t)t * 128 + j] = f2b(h);
    }
}

// ---------------------------------------------------------------------------
// prior head: reads fwd hidden from comb[:, 0:64] (row stride 128)
// ---------------------------------------------------------------------------
__global__ __launch_bounds__(256) void prior_k(
    const ushort_t* __restrict__ COMB, const float* __restrict__ p_w,
    const float* __restrict__ p_b, float* __restrict__ out)
{
    const int row = blockIdx.x * 4 + (threadIdx.x >> 6);  // [0, BET)
    const int lane = threadIdx.x & 63;
    float hf = b2f(COMB[(size_t)row * 128 + lane]);
    float v0 = hf * p_w[lane];
    float v1 = hf * p_w[64 + lane];
    #pragma unroll
    for (int off = 32; off > 0; off >>= 1) {
        v0 += __shfl_down(v0, off, 64);
        v1 += __shfl_down(v1, off, 64);
    }
    if (lane == 0) {
        int t = row & (T_ - 1);
        int be = row >> 6;
        int e = be % E_, b = be / E_;
        size_t o = (((size_t)b * T_ + t) * E_ + e) * K_;
        out[o] = v0 + p_b[0];
        out[o + 1] = v1 + p_b[1];
    }
}

// ---------------------------------------------------------------------------
// enc head: out[b,t,e,k] = ENCH[row,:] . e_w2[k,:] + e_b2[k]; ENCH bf16 [BET,256]
// ---------------------------------------------------------------------------
__global__ __launch_bounds__(256) void encout_k(
    const ushort_t* __restrict__ ENCH, const float* __restrict__ e_w2,
    const float* __restrict__ e_b2, float* __restrict__ out)
{
    const int row = blockIdx.x * 4 + (threadIdx.x >> 6);
    const int lane = threadIdx.x & 63;
    ushort4 u = *(const ushort4*)(ENCH + (size_t)row * 256 + lane * 4);
    float4 v; v.x = b2f(u.x); v.y = b2f(u.y); v.z = b2f(u.z); v.w = b2f(u.w);
    float4 w0 = *(const float4*)(e_w2 + lane * 4);
    float4 w1 = *(const float4*)(e_w2 + 256 + lane * 4);
    float p0 = v.x * w0.x + v.y * w0.y + v.z * w0.z + v.w * w0.w;
    float p1 = v.x * w1.x + v.y * w1.y + v.z * w1.z + v.w * w1.w;
    #pragma unroll
    for (int off = 32; off > 0; off >>= 1) {
        p0 += __shfl_down(p0, off, 64);
        p1 += __shfl_down(p1, off, 64);
    }
    if (lane == 0) {
        int t = row & (T_ - 1);
        int be = row >> 6;
        int e = be % E_, b = be / E_;
        size_t o = (size_t)(B_ * T_ * E_ * K_) + (((size_t)b * T_ + t) * E_ + e) * K_;
        out[o] = p0 + e_b2[0];
        out[o + 1] = p1 + e_b2[1];
    }
}

// ---------------------------------------------------------------------------
extern "C" void kernel_launch(void* const* d_in, const int* in_sizes, int n_in,
                              void* d_out, int out_size, void* d_ws, size_t ws_size,
                              hipStream_t stream)
{
    const float* rel    = (const float*)d_in[0];
    const float* ear    = (const float*)d_in[1];
    const float* epos   = (const float*)d_in[2];
    const float* ef_w1  = (const float*)d_in[3];
    const float* ef_b1  = (const float*)d_in[4];
    const float* ef_w2  = (const float*)d_in[5];
    const float* ef_b2  = (const float*)d_in[6];
    const float* res_w  = (const float*)d_in[7];
    const float* res_b  = (const float*)d_in[8];
    const float* m3_w1  = (const float*)d_in[9];
    const float* m3_b1  = (const float*)d_in[10];
    const float* m3_w2  = (const float*)d_in[11];
    const float* m3_b2  = (const float*)d_in[12];
    const float* m4_w1  = (const float*)d_in[13];
    const float* m4_b1  = (const float*)d_in[14];
    const float* m4_w2  = (const float*)d_in[15];
    const float* m4_b2  = (const float*)d_in[16];
    const float* f_wih  = (const float*)d_in[17];
    const float* f_whh  = (const float*)d_in[18];
    const float* f_bih  = (const float*)d_in[19];
    const float* f_bhh  = (const float*)d_in[20];
    const float* r_wih  = (const float*)d_in[21];
    const float* r_whh  = (const float*)d_in[22];
    const float* r_bih  = (const float*)d_in[23];
    const float* r_bhh  = (const float*)d_in[24];
    const float* p_w    = (const float*)d_in[25];
    const float* p_b    = (const float*)d_in[26];
    const float* e_w1   = (const float*)d_in[27];
    const float* e_b1   = (const float*)d_in[28];
    const float* e_w2   = (const float*)d_in[29];
    const float* e_b2   = (const float*)d_in[30];
    float* out = (float*)d_out;

    // workspace layout (bytes), total ~162.5 MB
    char* ws = (char*)d_ws;
    const size_t BIGB  = (size_t)BET_ * H_ * sizeof(ushort_t);   // 62,914,560
    const size_t COMBB = (size_t)BET_ * 128 * sizeof(ushort_t);  // 31,457,280
    const size_t X2BB  = (size_t)BVT_ * H_ * sizeof(ushort_t);   //  4,194,304
    ushort_t* R1   = (ushort_t*)(ws);
    ushort_t* R2   = (ushort_t*)(ws + BIGB);
    ushort_t* COMB = (ushort_t*)(ws + 2 * BIGB);
    ushort_t* X2b  = (ushort_t*)(ws + 2 * BIGB + COMBB);
    ushort_t* Wb   = (ushort_t*)(ws + 2 * BIGB + COMBB + X2BB);
    // node-stage f32 scratch lives inside (dead) R1 region
    float* X  = (float*)(ws);
    float* XH = (float*)(ws + (size_t)BVT_ * H_ * sizeof(float));
    // packed bf16 weight offsets (elements)
    const ushort_t* wb_ef2  = Wb + 0;
    const ushort_t* wb_m41  = Wb + 65536;
    const ushort_t* wb_m42  = Wb + 262144;
    const ushort_t* wb_fwih = Wb + 327680;
    const ushort_t* wb_rwih = Wb + 393216;
    const ushort_t* wb_ew1  = Wb + 458752;

    dim3 blk(256);
    dim3 gM(BET_ / 128, 2);    // MFMA edge GEMMs: 960 x 2
    dim3 gE64(BET_ / 64, 4);   // VALU edge GEMM (ein)
    dim3 gN(BVT_ / 64, 4);     // VALU node GEMMs

    // 0. weights -> bf16
    wconv_k<<<1920, blk, 0, stream>>>(ef_w2, m4_w1, m4_w2, f_wih, r_wih, e_w1, Wb);
    // 1. edge filter MLP
    gemm_ein_k<<<gE64, blk, 0, stream>>>(ear, epos, ef_w1, ef_b1, R1);
    mfma_gemm_k<256, 1><<<gM, blk, 0, stream>>>(R1, wb_ef2, ef_b2, nullptr, R2);     // EA
    // 2. edge2node + residual
    e2n_k<<<BVT_, blk, 0, stream>>>(R2, rel, res_w, res_b, X);
    // 3. mlp3 (node rows, f32 VALU)
    gemm_t<float, float><<<gN, blk, 0, stream>>>(X, m3_w1, m3_b1, nullptr, XH, BVT_, H_, H_, 1);
    gemm_t<float, ushort_t><<<gN, blk, 0, stream>>>(XH, m3_w2, m3_b2, nullptr, X2b, BVT_, H_, H_, 1);
    // 4. node2edge gather + mlp4
    mfma_mlp4_k<<<gM, blk, 0, stream>>>(X2b, R2, wb_m41, m4_b1, R1);
    mfma_gemm_k<256, 1><<<gM, blk, 0, stream>>>(R1, wb_m42, m4_b2, nullptr, R2);     // M2
    // 5. LSTM: gates then scan (fwd into COMB[:,0:64], rev into COMB[:,64:128])
    mfma_gemm_k<256, 0><<<gM, blk, 0, stream>>>(R2, wb_fwih, f_bih, f_bhh, R1);      // GF
    lstm_k<<<BE_ / 4, blk, 0, stream>>>(R1, f_whh, COMB, 0);
    mfma_gemm_k<256, 0><<<gM, blk, 0, stream>>>(R2, wb_rwih, r_bih, r_bhh, R1);      // GR
    lstm_k<<<BE_ / 4, blk, 0, stream>>>(R1, r_whh, COMB + 64, 1);
    // 6. heads
    prior_k<<<BET_ / 4, blk, 0, stream>>>(COMB, p_w, p_b, out);
    mfma_gemm_k<128, 1><<<gM, blk, 0, stream>>>(COMB, wb_ew1, e_b1, nullptr, R2);    // ENCH
    encout_k<<<BET_ / 4, blk, 0, stream>>>(R2, e_w2, e_b2, out);
}

// Round 4
// 910.218 us; speedup vs baseline: 2.9088x; 1.4491x over previous
//
#include <hip/hip_runtime.h>
#include <cstdint>
#include <cstddef>
#include <type_traits>

// Problem constants
#define B_ 8
#define V_ 16
#define T_ 64
#define E_ 240          // V*(V-1)
#define H_ 256
#define RH_ 64
#define K_ 2
#define DIN_ 6
#define BET_ (B_*E_*T_)   // 122880
#define BVT_ (B_*V_*T_)   // 8192
#define BE_ (B_*E_)       // 1920

typedef unsigned short ushort_t;
typedef unsigned int u32;
typedef __attribute__((ext_vector_type(8))) short bf16x8;
typedef __attribute__((ext_vector_type(4))) float f32x4;

__device__ __forceinline__ float eluf(float x) { return x > 0.f ? x : __expf(x) - 1.f; }
__device__ __forceinline__ float fsig(float x) { return 1.f / (1.f + __expf(-x)); }
__device__ __forceinline__ float ftanh_(float x) {
    float y = fminf(fmaxf(x, -8.f), 8.f);
    float e = __expf(2.f * y);
    return (e - 1.f) / (e + 1.f);
}
__device__ __forceinline__ float b2f(ushort_t u) {
    union { float f; uint32_t i; } v; v.i = ((uint32_t)u) << 16; return v.f;
}
__device__ __forceinline__ ushort_t f2b(float f) {
    union { float f; uint32_t i; } v; v.f = f;
    uint32_t r = (v.i + 0x7FFFu + ((v.i >> 16) & 1u)) >> 16;
    return (ushort_t)r;
}

// async global->LDS, 16B per lane; LDS dest = wave-uniform base + lane*16
__device__ __forceinline__ void gll16(const void* g, void* l) {
    __builtin_amdgcn_global_load_lds(
        (const __attribute__((address_space(1))) u32*)g,
        (__attribute__((address_space(3))) u32*)l, 16, 0, 0);
}

// ===========================================================================
// MFMA bf16 GEMM: C[m,n] = act( sum_k A[m,k]*W[n,k] + b1[n] (+b2[n]) ), bf16 out
// A [M,KD] bf16 row-major, W [N,KD] bf16 row-major, N = 256.
// BM=128, BN=128, K-step 32, 4 waves (2x2), each wave 64x64 (4x4 frags 16x16).
// LDS in fragment order: [buf][A/B][frag 0..7][lane*8 bf16]  (zero-conflict b128)
// mfma(Wfrag, Afrag): lane holds C rows m=lane&15, cols n=(lane>>4)*4+r (r=0..3)
// ===========================================================================
template<int KD, int ACT>
__global__ __launch_bounds__(256) void mfma_gemm_k(
    const ushort_t* __restrict__ A, const ushort_t* __restrict__ Wt,
    const float* __restrict__ b1, const float* __restrict__ b2,
    ushort_t* __restrict__ C)
{
    __shared__ ushort_t lds[2][2][8][512];   // 32 KB
    const int tid = threadIdx.x;
    const int lane = tid & 63;
    const int w = tid >> 6;
    const int wr = w >> 1, wc = w & 1;
    const int m0 = blockIdx.x * 128;
    const int n0 = blockIdx.y * 128;
    const int r16 = lane & 15, kq = lane >> 4;
    constexpr int NKT = KD / 32;

    const ushort_t* Abase[2];
    const ushort_t* Wbase[2];
    #pragma unroll
    for (int ff = 0; ff < 2; ++ff) {
        int f = 2 * w + ff;
        Abase[ff] = A  + (size_t)(m0 + f * 16 + r16) * KD + kq * 8;
        Wbase[ff] = Wt + (size_t)(n0 + f * 16 + r16) * KD + kq * 8;
    }

    f32x4 acc[4][4];
    #pragma unroll
    for (int i = 0; i < 4; ++i)
        #pragma unroll
        for (int j = 0; j < 4; ++j)
            acc[i][j] = (f32x4){0.f, 0.f, 0.f, 0.f};

#define STAGE_G(bufi, kt) do {                                              \
    _Pragma("unroll")                                                       \
    for (int ff = 0; ff < 2; ++ff) {                                        \
        int f = 2 * w + ff;                                                 \
        gll16(Abase[ff] + (kt) * 32, &lds[bufi][0][f][0]);                  \
        gll16(Wbase[ff] + (kt) * 32, &lds[bufi][1][f][0]);                  \
    } } while (0)

#define COMPUTE_G(bufi) do {                                                \
    bf16x8 af[4], bfr[4];                                                   \
    _Pragma("unroll")                                                       \
    for (int mf = 0; mf < 4; ++mf) af[mf] = *(const bf16x8*)&lds[bufi][0][wr*4+mf][lane*8]; \
    _Pragma("unroll")                                                       \
    for (int nf = 0; nf < 4; ++nf) bfr[nf] = *(const bf16x8*)&lds[bufi][1][wc*4+nf][lane*8]; \
    _Pragma("unroll")                                                       \
    for (int mf = 0; mf < 4; ++mf)                                          \
        _Pragma("unroll")                                                   \
        for (int nf = 0; nf < 4; ++nf)                                      \
            acc[mf][nf] = __builtin_amdgcn_mfma_f32_16x16x32_bf16(bfr[nf], af[mf], acc[mf][nf], 0, 0, 0); \
    } while (0)

    STAGE_G(0, 0);
    __syncthreads();
    int buf = 0;
    for (int kt = 0; kt < NKT - 1; ++kt) {
        STAGE_G(buf ^ 1, kt + 1);
        COMPUTE_G(buf);
        __syncthreads();
        buf ^= 1;
    }
    COMPUTE_G(buf);

    #pragma unroll
    for (int mf = 0; mf < 4; ++mf) {
        int mrow = m0 + wr * 64 + mf * 16 + r16;
        #pragma unroll
        for (int nf = 0; nf < 4; ++nf) {
            int nb = n0 + wc * 64 + nf * 16 + kq * 4;
            float4 bb = *(const float4*)&b1[nb];
            if (b2) {
                float4 b2v = *(const float4*)&b2[nb];
                bb.x += b2v.x; bb.y += b2v.y; bb.z += b2v.z; bb.w += b2v.w;
            }
            float v0 = acc[mf][nf][0] + bb.x;
            float v1 = acc[mf][nf][1] + bb.y;
            float v2 = acc[mf][nf][2] + bb.z;
            float v3 = acc[mf][nf][3] + bb.w;
            if (ACT) { v0 = eluf(v0); v1 = eluf(v1); v2 = eluf(v2); v3 = eluf(v3); }
            ushort4 o; o.x = f2b(v0); o.y = f2b(v1); o.z = f2b(v2); o.w = f2b(v3);
            *(ushort4*)&C[(size_t)mrow * 256 + nb] = o;
        }
    }
#undef STAGE_G
#undef COMPUTE_G
}

// ===========================================================================
// mlp4 layer-1 MFMA GEMM with fused gather, KD=768:
// row m=(be*64+t); k<256 -> X2b[b,send,t,k]; k<512 -> X2b[b,recv,t,·]; else EA[be,t,·]
// ===========================================================================
__global__ __launch_bounds__(256) void mfma_mlp4_k(
    const ushort_t* __restrict__ X2b, const ushort_t* __restrict__ EA,
    const ushort_t* __restrict__ Wt, const float* __restrict__ b1,
    ushort_t* __restrict__ C)
{
    __shared__ ushort_t lds[2][2][8][512];
    const int tid = threadIdx.x;
    const int lane = tid & 63;
    const int w = tid >> 6;
    const int wr = w >> 1, wc = w & 1;
    const int m0 = blockIdx.x * 128;
    const int n0 = blockIdx.y * 128;
    const int r16 = lane & 15, kq = lane >> 4;
    constexpr int NKT = 24;

    const ushort_t* AS[2]; const ushort_t* AR[2]; const ushort_t* AE[2];
    const ushort_t* Wbase[2];
    #pragma unroll
    for (int ff = 0; ff < 2; ++ff) {
        int f = 2 * w + ff;
        int m = m0 + f * 16 + r16;
        int be = m >> 6, t = m & 63;
        int b = be / E_, e = be % E_;
        int s = e / (V_ - 1);
        int r0 = e % (V_ - 1);
        int rr = r0 + (r0 >= s ? 1 : 0);
        AS[ff] = X2b + ((size_t)((b * V_ + s) * T_ + t)) * H_ + kq * 8;
        AR[ff] = X2b + ((size_t)((b * V_ + rr) * T_ + t)) * H_ + kq * 8;
        AE[ff] = EA + (size_t)m * H_ + kq * 8;
        Wbase[ff] = Wt + (size_t)(n0 + f * 16 + r16) * 768 + kq * 8;
    }

    f32x4 acc[4][4];
    #pragma unroll
    for (int i = 0; i < 4; ++i)
        #pragma unroll
        for (int j = 0; j < 4; ++j)
            acc[i][j] = (f32x4){0.f, 0.f, 0.f, 0.f};

#define STAGE_M(bufi, kt) do {                                              \
    int kk = (kt) * 32;                                                     \
    _Pragma("unroll")                                                       \
    for (int ff = 0; ff < 2; ++ff) {                                        \
        int f = 2 * w + ff;                                                 \
        const ushort_t* ga = (kk < 256) ? AS[ff] + kk                       \
                           : (kk < 512) ? AR[ff] + (kk - 256)               \
                                        : AE[ff] + (kk - 512);              \
        gll16(ga, &lds[bufi][0][f][0]);                                     \
        gll16(Wbase[ff] + kk, &lds[bufi][1][f][0]);                         \
    } } while (0)

#define COMPUTE_M(bufi) do {                                                \
    bf16x8 af[4], bfr[4];                                                   \
    _Pragma("unroll")                                                       \
    for (int mf = 0; mf < 4; ++mf) af[mf] = *(const bf16x8*)&lds[bufi][0][wr*4+mf][lane*8]; \
    _Pragma("unroll")                                                       \
    for (int nf = 0; nf < 4; ++nf) bfr[nf] = *(const bf16x8*)&lds[bufi][1][wc*4+nf][lane*8]; \
    _Pragma("unroll")                                                       \
    for (int mf = 0; mf < 4; ++mf)                                          \
        _Pragma("unroll")                                                   \
        for (int nf = 0; nf < 4; ++nf)                                      \
            acc[mf][nf] = __builtin_amdgcn_mfma_f32_16x16x32_bf16(bfr[nf], af[mf], acc[mf][nf], 0, 0, 0); \
    } while (0)

    STAGE_M(0, 0);
    __syncthreads();
    int buf = 0;
    for (int kt = 0; kt < NKT - 1; ++kt) {
        STAGE_M(buf ^ 1, kt + 1);
        COMPUTE_M(buf);
        __syncthreads();
        buf ^= 1;
    }
    COMPUTE_M(buf);

    #pragma unroll
    for (int mf = 0; mf < 4; ++mf) {
        int mrow = m0 + wr * 64 + mf * 16 + r16;
        #pragma unroll
        for (int nf = 0; nf < 4; ++nf) {
            int nb = n0 + wc * 64 + nf * 16 + kq * 4;
            float4 bb = *(const float4*)&b1[nb];
            float v0 = eluf(acc[mf][nf][0] + bb.x);
            float v1 = eluf(acc[mf][nf][1] + bb.y);
            float v2 = eluf(acc[mf][nf][2] + bb.z);
            float v3 = eluf(acc[mf][nf][3] + bb.w);
            ushort4 o; o.x = f2b(v0); o.y = f2b(v1); o.z = f2b(v2); o.w = f2b(v3);
            *(ushort4*)&C[(size_t)mrow * 256 + nb] = o;
        }
    }
#undef STAGE_M
#undef COMPUTE_M
}

// ===========================================================================
// weights f32 -> bf16 (packed): ef_w2 | m4_w1 | m4_w2 | f_wih | r_wih | e_w1
// ===========================================================================
__global__ __launch_bounds__(256) void wconv_k(
    const float* __restrict__ ef_w2, const float* __restrict__ m4_w1,
    const float* __restrict__ m4_w2, const float* __restrict__ f_wih,
    const float* __restrict__ r_wih, const float* __restrict__ e_w1,
    ushort_t* __restrict__ Wb)
{
    int i = blockIdx.x * 256 + threadIdx.x;   // < 491520
    const float* src; int off;
    if (i < 65536)       { src = ef_w2; off = i; }
    else if (i < 262144) { src = m4_w1; off = i - 65536; }
    else if (i < 327680) { src = m4_w2; off = i - 262144; }
    else if (i < 393216) { src = f_wih; off = i - 327680; }
    else if (i < 458752) { src = r_wih; off = i - 393216; }
    else                 { src = e_w1;  off = i - 458752; }
    Wb[i] = f2b(src[off]);
}

// ---------------------------------------------------------------------------
// Generic VALU GEMM (kept for mlp3 node rows): C = act(A@W.T + b1)
// ---------------------------------------------------------------------------
template<typename TA, typename TO>
__global__ __launch_bounds__(256) void gemm_t(
    const TA* __restrict__ A, const float* __restrict__ W,
    const float* __restrict__ b1, const float* __restrict__ b2,
    TO* __restrict__ C, int M, int Kd, int N, int act)
{
    __shared__ float As[16][64];
    __shared__ float Ws[16][64];
    const int m0 = blockIdx.x * 64, n0 = blockIdx.y * 64;
    const int tid = threadIdx.x;
    const int tm = tid >> 4, tn = tid & 15;
    const int lm = tid >> 2, lq = tid & 3;
    float acc[4][4] = {};
    const TA* Arow = A + (size_t)(m0 + lm) * Kd + lq * 4;
    const float* Wrow = W + (size_t)(n0 + lm) * Kd + lq * 4;
    for (int k0 = 0; k0 < Kd; k0 += 16) {
        float4 av, wv;
        if constexpr (std::is_same<TA, ushort_t>::value) {
            ushort4 u = *(const ushort4*)(Arow + k0);
            av.x = b2f(u.x); av.y = b2f(u.y); av.z = b2f(u.z); av.w = b2f(u.w);
        } else {
            av = *(const float4*)(Arow + k0);
        }
        wv = *(const float4*)(Wrow + k0);
        __syncthreads();
        As[lq*4+0][lm] = av.x; As[lq*4+1][lm] = av.y; As[lq*4+2][lm] = av.z; As[lq*4+3][lm] = av.w;
        Ws[lq*4+0][lm] = wv.x; Ws[lq*4+1][lm] = wv.y; Ws[lq*4+2][lm] = wv.z; Ws[lq*4+3][lm] = wv.w;
        __syncthreads();
        #pragma unroll
        for (int k = 0; k < 16; ++k) {
            float4 a = *(const float4*)&As[k][tm * 4];
            float4 w = *(const float4*)&Ws[k][tn * 4];
            float a_[4] = {a.x, a.y, a.z, a.w};
            float w_[4] = {w.x, w.y, w.z, w.w};
            #pragma unroll
            for (int i = 0; i < 4; ++i)
                #pragma unroll
                for (int j = 0; j < 4; ++j)
                    acc[i][j] += a_[i] * w_[j];
        }
    }
    float bb[4];
    #pragma unroll
    for (int j = 0; j < 4; ++j) {
        int n = n0 + tn * 4 + j;
        bb[j] = b1[n] + (b2 ? b2[n] : 0.f);
    }
    #pragma unroll
    for (int i = 0; i < 4; ++i) {
        float v0 = acc[i][0] + bb[0], v1 = acc[i][1] + bb[1];
        float v2 = acc[i][2] + bb[2], v3 = acc[i][3] + bb[3];
        if (act) { v0 = eluf(v0); v1 = eluf(v1); v2 = eluf(v2); v3 = eluf(v3); }
        TO* dst = C + (size_t)(m0 + tm * 4 + i) * N + (n0 + tn * 4);
        if constexpr (std::is_same<TO, ushort_t>::value) {
            ushort4 o; o.x = f2b(v0); o.y = f2b(v1); o.z = f2b(v2); o.w = f2b(v3);
            *(ushort4*)dst = o;
        } else {
            float4 o; o.x = v0; o.y = v1; o.z = v2; o.w = v3;
            *(float4*)dst = o;
        }
    }
}

// ---------------------------------------------------------------------------
// First GEMM with fused concat: A[m,c] = c<13 ? ear[m,c] : epos[m,c-13], Kd=16.
// ---------------------------------------------------------------------------
__global__ __launch_bounds__(256) void gemm_ein_k(
    const float* __restrict__ ear, const float* __restrict__ epos,
    const float* __restrict__ W, const float* __restrict__ b1,
    ushort_t* __restrict__ C)
{
    __shared__ float As[16][64];
    __shared__ float Ws[16][64];
    const int m0 = blockIdx.x * 64, n0 = blockIdx.y * 64;
    const int tid = threadIdx.x;
    const int tm = tid >> 4, tn = tid & 15;
    const int lm = tid >> 2, lq = tid & 3;
    const int m = m0 + lm;
    float a_[4];
    #pragma unroll
    for (int q = 0; q < 4; ++q) {
        int c = lq * 4 + q;
        a_[q] = (c < 13) ? ear[(size_t)m * 13 + c] : epos[(size_t)m * 3 + (c - 13)];
    }
    float4 wv = *(const float4*)(W + (size_t)(n0 + lm) * 16 + lq * 4);
    As[lq*4+0][lm] = a_[0]; As[lq*4+1][lm] = a_[1]; As[lq*4+2][lm] = a_[2]; As[lq*4+3][lm] = a_[3];
    Ws[lq*4+0][lm] = wv.x; Ws[lq*4+1][lm] = wv.y; Ws[lq*4+2][lm] = wv.z; Ws[lq*4+3][lm] = wv.w;
    __syncthreads();
    float acc[4][4] = {};
    #pragma unroll
    for (int k = 0; k < 16; ++k) {
        float4 a = *(const float4*)&As[k][tm * 4];
        float4 w = *(const float4*)&Ws[k][tn * 4];
        float aa[4] = {a.x, a.y, a.z, a.w};
        float ww[4] = {w.x, w.y, w.z, w.w};
        #pragma unroll
        for (int i = 0; i < 4; ++i)
            #pragma unroll
            for (int j = 0; j < 4; ++j)
                acc[i][j] += aa[i] * ww[j];
    }
    #pragma unroll
    for (int i = 0; i < 4; ++i) {
        ushort4 o;
        o.x = f2b(eluf(acc[i][0] + b1[n0 + tn*4 + 0]));
        o.y = f2b(eluf(acc[i][1] + b1[n0 + tn*4 + 1]));
        o.z = f2b(eluf(acc[i][2] + b1[n0 + tn*4 + 2]));
        o.w = f2b(eluf(acc[i][3] + b1[n0 + tn*4 + 3]));
        *(ushort4*)(C + (size_t)(m0 + tm * 4 + i) * H_ + (n0 + tn * 4)) = o;
    }
}

// ---------------------------------------------------------------------------
// edge2node: X[b,v,t,h] = (1/15)*sum_{e:RECV==v} EA[b,e,t,h] + rel@res_w.T + res_b
// ---------------------------------------------------------------------------
__global__ __launch_bounds__(256) void e2n_k(
    const ushort_t* __restrict__ EA, const float* __restrict__ rel,
    const float* __restrict__ res_w, const float* __restrict__ res_b,
    float* __restrict__ X)
{
    const int idx = blockIdx.x;            // (b*V+v)*T + t
    const int t = idx & (T_ - 1);
    const int bv = idx >> 6;
    const int v = bv & (V_ - 1);
    const int b = bv >> 4;
    const int h = threadIdx.x;
    float sum = 0.f;
    #pragma unroll
    for (int i = 0; i < V_; ++i) {
        if (i == v) continue;
        int jj = (v < i) ? v : v - 1;
        int e = i * (V_ - 1) + jj;
        sum += b2f(EA[(((size_t)(b * E_ + e)) * T_ + t) * H_ + h]);
    }
    const float* rp = rel + ((size_t)bv * T_ + t) * DIN_;
    float res = res_b[h];
    #pragma unroll
    for (int d = 0; d < DIN_; ++d) res += rp[d] * res_w[h * DIN_ + d];
    X[((size_t)bv * T_ + t) * H_ + h] = sum * (1.f / 15.f) + res;
}

// ===========================================================================
// MFMA LSTM scan: 1 wave per block, 16 sequences per wave.
// whh held in registers as 32 B-fragments (16 n-tiles x 2 k-steps).
// Per step: z(16x256) = gates(prefetched) + h(16x64)@whh^T via 32 MFMA.
// Lane l owns C cells (seq=l&15, n=16*nt + 4*(l>>4) + r) -> all 4 gates of
// j = 16*(nt&3)+4*(l>>4)+r. c kept f32 in regs; h -> 2KB swizzled LDS ->
// A-fragments (lane reads j = ks*32+(l>>4)*8+e for its seq).
// Writes h to COMB[row][dir*64 + j] (row stride 128).
// ===========================================================================
__global__ __launch_bounds__(64) void lstm_mfma_k(
    const ushort_t* __restrict__ G, const float* __restrict__ whh,
    ushort_t* __restrict__ COMB, int dir)
{
    __shared__ ushort_t hlds[1024];   // 2 KB: h[seq][j] bf16, XOR-swizzled
    const int lane = threadIdx.x & 63;
    const int seq = lane & 15, kq = lane >> 4;
    const int be0 = blockIdx.x * 16;
    const int swz = (seq & 7) << 4;

    // whh -> B-fragments in registers: wf[nt][ks], lane holds n=nt*16+seq, k=ks*32+kq*8+e
    bf16x8 wf[16][2];
    #pragma unroll
    for (int nt = 0; nt < 16; ++nt) {
        #pragma unroll
        for (int ks = 0; ks < 2; ++ks) {
            const float* p = whh + (size_t)(nt * 16 + seq) * 64 + ks * 32 + kq * 8;
            float4 x0 = *(const float4*)p;
            float4 x1 = *(const float4*)(p + 4);
            bf16x8 v;
            v[0] = (short)f2b(x0.x); v[1] = (short)f2b(x0.y);
            v[2] = (short)f2b(x0.z); v[3] = (short)f2b(x0.w);
            v[4] = (short)f2b(x1.x); v[5] = (short)f2b(x1.y);
            v[6] = (short)f2b(x1.z); v[7] = (short)f2b(x1.w);
            wf[nt][ks] = v;
        }
    }

    const ushort_t* grow = G + ((size_t)(be0 + seq) * T_) * 256 + kq * 4;
    ushort_t* crow = COMB + ((size_t)(be0 + seq) * T_) * 128 + (dir ? 64 : 0) + kq * 4;

    float c[4][4] = {};
    ushort4 gx[16];
    const int t0 = dir ? (T_ - 1) : 0;
    #pragma unroll
    for (int nt = 0; nt < 16; ++nt)
        gx[nt] = *(const ushort4*)(grow + (size_t)t0 * 256 + nt * 16);

    for (int s = 0; s < T_; ++s) {
        const int t = dir ? (T_ - 1 - s) : s;
        f32x4 acc[16];
        #pragma unroll
        for (int nt = 0; nt < 16; ++nt) {
            ushort4 g = gx[nt];
            acc[nt] = (f32x4){b2f(g.x), b2f(g.y), b2f(g.z), b2f(g.w)};
        }
        if (s < T_ - 1) {      // prefetch next step's gates (hidden under MFMA+act)
            const int tn = dir ? (T_ - 2 - s) : (s + 1);
            #pragma unroll
            for (int nt = 0; nt < 16; ++nt)
                gx[nt] = *(const ushort4*)(grow + (size_t)tn * 256 + nt * 16);
        }
        if (s) {
            bf16x8 af[2];
            #pragma unroll
            for (int ks = 0; ks < 2; ++ks) {
                int boff = (seq * 128 + ks * 64 + kq * 16) ^ swz;
                af[ks] = *(const bf16x8*)((const char*)hlds + boff);
            }
            #pragma unroll
            for (int nt = 0; nt < 16; ++nt) {
                acc[nt] = __builtin_amdgcn_mfma_f32_16x16x32_bf16(wf[nt][0], af[0], acc[nt], 0, 0, 0);
                acc[nt] = __builtin_amdgcn_mfma_f32_16x16x32_bf16(wf[nt][1], af[1], acc[nt], 0, 0, 0);
            }
        }
        #pragma unroll
        for (int a = 0; a < 4; ++a) {
            float hh[4];
            #pragma unroll
            for (int r = 0; r < 4; ++r) {
                float zi = acc[a][r], zf = acc[4 + a][r], zg = acc[8 + a][r], zo = acc[12 + a][r];
                float cc = fsig(zf) * c[a][r] + fsig(zi) * ftanh_(zg);
                c[a][r] = cc;
                hh[r] = fsig(zo) * ftanh_(cc);
            }
            ushort4 hv;
            hv.x = f2b(hh[0]); hv.y = f2b(hh[1]); hv.z = f2b(hh[2]); hv.w = f2b(hh[3]);
            int wb = (seq * 128 + a * 32 + kq * 8) ^ swz;
            *(ushort4*)((char*)hlds + wb) = hv;
            *(ushort4*)(crow + (size_t)t * 128 + a * 16) = hv;
        }
    }
}

// ---------------------------------------------------------------------------
// prior head: reads fwd hidden from comb[:, 0:64] (row stride 128)
// ---------------------------------------------------------------------------
__global__ __launch_bounds__(256) void prior_k(
    const ushort_t* __restrict__ COMB, const float* __restrict__ p_w,
    const float* __restrict__ p_b, float* __restrict__ out)
{
    const int row = blockIdx.x * 4 + (threadIdx.x >> 6);  // [0, BET)
    const int lane = threadIdx.x & 63;
    float hf = b2f(COMB[(size_t)row * 128 + lane]);
    float v0 = hf * p_w[lane];
    float v1 = hf * p_w[64 + lane];
    #pragma unroll
    for (int off = 32; off > 0; off >>= 1) {
        v0 += __shfl_down(v0, off, 64);
        v1 += __shfl_down(v1, off, 64);
    }
    if (lane == 0) {
        int t = row & (T_ - 1);
        int be = row >> 6;
        int e = be % E_, b = be / E_;
        size_t o = (((size_t)b * T_ + t) * E_ + e) * K_;
        out[o] = v0 + p_b[0];
        out[o + 1] = v1 + p_b[1];
    }
}

// ---------------------------------------------------------------------------
// enc head: out[b,t,e,k] = ENCH[row,:] . e_w2[k,:] + e_b2[k]; ENCH bf16 [BET,256]
// ---------------------------------------------------------------------------
__global__ __launch_bounds__(256) void encout_k(
    const ushort_t* __restrict__ ENCH, const float* __restrict__ e_w2,
    const float* __restrict__ e_b2, float* __restrict__ out)
{
    const int row = blockIdx.x * 4 + (threadIdx.x >> 6);
    const int lane = threadIdx.x & 63;
    ushort4 u = *(const ushort4*)(ENCH + (size_t)row * 256 + lane * 4);
    float4 v; v.x = b2f(u.x); v.y = b2f(u.y); v.z = b2f(u.z); v.w = b2f(u.w);
    float4 w0 = *(const float4*)(e_w2 + lane * 4);
    float4 w1 = *(const float4*)(e_w2 + 256 + lane * 4);
    float p0 = v.x * w0.x + v.y * w0.y + v.z * w0.z + v.w * w0.w;
    float p1 = v.x * w1.x + v.y * w1.y + v.z * w1.z + v.w * w1.w;
    #pragma unroll
    for (int off = 32; off > 0; off >>= 1) {
        p0 += __shfl_down(p0, off, 64);
        p1 += __shfl_down(p1, off, 64);
    }
    if (lane == 0) {
        int t = row & (T_ - 1);
        int be = row >> 6;
        int e = be % E_, b = be / E_;
        size_t o = (size_t)(B_ * T_ * E_ * K_) + (((size_t)b * T_ + t) * E_ + e) * K_;
        out[o] = p0 + e_b2[0];
        out[o + 1] = p1 + e_b2[1];
    }
}

// ---------------------------------------------------------------------------
extern "C" void kernel_launch(void* const* d_in, const int* in_sizes, int n_in,
                              void* d_out, int out_size, void* d_ws, size_t ws_size,
                              hipStream_t stream)
{
    const float* rel    = (const float*)d_in[0];
    const float* ear    = (const float*)d_in[1];
    const float* epos   = (const float*)d_in[2];
    const float* ef_w1  = (const float*)d_in[3];
    const float* ef_b1  = (const float*)d_in[4];
    const float* ef_w2  = (const float*)d_in[5];
    const float* ef_b2  = (const float*)d_in[6];
    const float* res_w  = (const float*)d_in[7];
    const float* res_b  = (const float*)d_in[8];
    const float* m3_w1  = (const float*)d_in[9];
    const float* m3_b1  = (const float*)d_in[10];
    const float* m3_w2  = (const float*)d_in[11];
    const float* m3_b2  = (const float*)d_in[12];
    const float* m4_w1  = (const float*)d_in[13];
    const float* m4_b1  = (const float*)d_in[14];
    const float* m4_w2  = (const float*)d_in[15];
    const float* m4_b2  = (const float*)d_in[16];
    const float* f_wih  = (const float*)d_in[17];
    const float* f_whh  = (const float*)d_in[18];
    const float* f_bih  = (const float*)d_in[19];
    const float* f_bhh  = (const float*)d_in[20];
    const float* r_wih  = (const float*)d_in[21];
    const float* r_whh  = (const float*)d_in[22];
    const float* r_bih  = (const float*)d_in[23];
    const float* r_bhh  = (const float*)d_in[24];
    const float* p_w    = (const float*)d_in[25];
    const float* p_b    = (const float*)d_in[26];
    const float* e_w1   = (const float*)d_in[27];
    const float* e_b1   = (const float*)d_in[28];
    const float* e_w2   = (const float*)d_in[29];
    const float* e_b2   = (const float*)d_in[30];
    float* out = (float*)d_out;

    // workspace layout (bytes), total ~162.5 MB
    char* ws = (char*)d_ws;
    const size_t BIGB  = (size_t)BET_ * H_ * sizeof(ushort_t);   // 62,914,560
    const size_t COMBB = (size_t)BET_ * 128 * sizeof(ushort_t);  // 31,457,280
    const size_t X2BB  = (size_t)BVT_ * H_ * sizeof(ushort_t);   //  4,194,304
    ushort_t* R1   = (ushort_t*)(ws);
    ushort_t* R2   = (ushort_t*)(ws + BIGB);
    ushort_t* COMB = (ushort_t*)(ws + 2 * BIGB);
    ushort_t* X2b  = (ushort_t*)(ws + 2 * BIGB + COMBB);
    ushort_t* Wb   = (ushort_t*)(ws + 2 * BIGB + COMBB + X2BB);
    // node-stage f32 scratch lives inside (dead) R1 region
    float* X  = (float*)(ws);
    float* XH = (float*)(ws + (size_t)BVT_ * H_ * sizeof(float));
    // packed bf16 weight offsets (elements)
    const ushort_t* wb_ef2  = Wb + 0;
    const ushort_t* wb_m41  = Wb + 65536;
    const ushort_t* wb_m42  = Wb + 262144;
    const ushort_t* wb_fwih = Wb + 327680;
    const ushort_t* wb_rwih = Wb + 393216;
    const ushort_t* wb_ew1  = Wb + 458752;

    dim3 blk(256);
    dim3 gM(BET_ / 128, 2);    // MFMA edge GEMMs: 960 x 2
    dim3 gE64(BET_ / 64, 4);   // VALU edge GEMM (ein)
    dim3 gN(BVT_ / 64, 4);     // VALU node GEMMs

    // 0. weights -> bf16
    wconv_k<<<1920, blk, 0, stream>>>(ef_w2, m4_w1, m4_w2, f_wih, r_wih, e_w1, Wb);
    // 1. edge filter MLP
    gemm_ein_k<<<gE64, blk, 0, stream>>>(ear, epos, ef_w1, ef_b1, R1);
    mfma_gemm_k<256, 1><<<gM, blk, 0, stream>>>(R1, wb_ef2, ef_b2, nullptr, R2);     // EA
    // 2. edge2node + residual
    e2n_k<<<BVT_, blk, 0, stream>>>(R2, rel, res_w, res_b, X);
    // 3. mlp3 (node rows, f32 VALU)
    gemm_t<float, float><<<gN, blk, 0, stream>>>(X, m3_w1, m3_b1, nullptr, XH, BVT_, H_, H_, 1);
    gemm_t<float, ushort_t><<<gN, blk, 0, stream>>>(XH, m3_w2, m3_b2, nullptr, X2b, BVT_, H_, H_, 1);
    // 4. node2edge gather + mlp4
    mfma_mlp4_k<<<gM, blk, 0, stream>>>(X2b, R2, wb_m41, m4_b1, R1);
    mfma_gemm_k<256, 1><<<gM, blk, 0, stream>>>(R1, wb_m42, m4_b2, nullptr, R2);     // M2
    // 5. LSTM: gate GEMM then register-resident MFMA scan, per direction
    mfma_gemm_k<256, 0><<<gM, blk, 0, stream>>>(R2, wb_fwih, f_bih, f_bhh, R1);      // GF
    lstm_mfma_k<<<BE_ / 16, dim3(64), 0, stream>>>(R1, f_whh, COMB, 0);
    mfma_gemm_k<256, 0><<<gM, blk, 0, stream>>>(R2, wb_rwih, r_bih, r_bhh, R1);      // GR
    lstm_mfma_k<<<BE_ / 16, dim3(64), 0, stream>>>(R1, r_whh, COMB, 1);
    // 6. heads
    prior_k<<<BET_ / 4, blk, 0, stream>>>(COMB, p_w, p_b, out);
    mfma_gemm_k<128, 1><<<gM, blk, 0, stream>>>(COMB, wb_ew1, e_b1, nullptr, R2);    // ENCH
    encout_k<<<BET_ / 4, blk, 0, stream>>>(R2, e_w2, e_b2, out);
}

// Round 5
// 584.651 us; speedup vs baseline: 4.5286x; 1.5569x over previous
//
#include <hip/hip_runtime.h>
#include <cstdint>
#include <cstddef>
#include <type_traits>

// Problem constants
#define B_ 8
#define V_ 16
#define T_ 64
#define E_ 240          // V*(V-1)
#define H_ 256
#define RH_ 64
#define K_ 2
#define DIN_ 6
#define BET_ (B_*E_*T_)   // 122880
#define BVT_ (B_*V_*T_)   // 8192
#define BE_ (B_*E_)       // 1920

typedef unsigned short ushort_t;
typedef unsigned int u32;
typedef __attribute__((ext_vector_type(8))) short bf16x8;
typedef __attribute__((ext_vector_type(4))) float f32x4;

__device__ __forceinline__ float eluf(float x) { return x > 0.f ? x : __expf(x) - 1.f; }
__device__ __forceinline__ float fsig(float x) { return 1.f / (1.f + __expf(-x)); }
__device__ __forceinline__ float ftanh_(float x) {
    float y = fminf(fmaxf(x, -8.f), 8.f);
    float e = __expf(2.f * y);
    return (e - 1.f) / (e + 1.f);
}
__device__ __forceinline__ float b2f(ushort_t u) {
    union { float f; uint32_t i; } v; v.i = ((uint32_t)u) << 16; return v.f;
}
__device__ __forceinline__ ushort_t f2b(float f) {
    union { float f; uint32_t i; } v; v.f = f;
    uint32_t r = (v.i + 0x7FFFu + ((v.i >> 16) & 1u)) >> 16;
    return (ushort_t)r;
}

// async global->LDS, 16B per lane; LDS dest = wave-uniform base + lane*16
__device__ __forceinline__ void gll16(const void* g, void* l) {
    __builtin_amdgcn_global_load_lds(
        (const __attribute__((address_space(1))) u32*)g,
        (__attribute__((address_space(3))) u32*)l, 16, 0, 0);
}

// ===========================================================================
// MFMA bf16 GEMM: C[m,n] = act( sum_k A[m,k]*W[n,k] + b1[n] (+b2[n]) ), bf16 out
// A [M,KD] bf16 row-major, W [N,KD] bf16 row-major, N = 256.
// BM=128, BN=128, K-step 32, 4 waves (2x2), each wave 64x64 (4x4 frags 16x16).
// LDS in fragment order: [buf][A/B][frag 0..7][lane*8 bf16]  (zero-conflict b128)
// mfma(Wfrag, Afrag): lane holds C rows m=lane&15, cols n=(lane>>4)*4+r (r=0..3)
// ===========================================================================
template<int KD, int ACT>
__global__ __launch_bounds__(256) void mfma_gemm_k(
    const ushort_t* __restrict__ A, const ushort_t* __restrict__ Wt,
    const float* __restrict__ b1, const float* __restrict__ b2,
    ushort_t* __restrict__ C)
{
    __shared__ ushort_t lds[2][2][8][512];   // 32 KB
    const int tid = threadIdx.x;
    const int lane = tid & 63;
    const int w = tid >> 6;
    const int wr = w >> 1, wc = w & 1;
    const int m0 = blockIdx.x * 128;
    const int n0 = blockIdx.y * 128;
    const int r16 = lane & 15, kq = lane >> 4;
    constexpr int NKT = KD / 32;

    const ushort_t* Abase[2];
    const ushort_t* Wbase[2];
    #pragma unroll
    for (int ff = 0; ff < 2; ++ff) {
        int f = 2 * w + ff;
        Abase[ff] = A  + (size_t)(m0 + f * 16 + r16) * KD + kq * 8;
        Wbase[ff] = Wt + (size_t)(n0 + f * 16 + r16) * KD + kq * 8;
    }

    f32x4 acc[4][4];
    #pragma unroll
    for (int i = 0; i < 4; ++i)
        #pragma unroll
        for (int j = 0; j < 4; ++j)
            acc[i][j] = (f32x4){0.f, 0.f, 0.f, 0.f};

#define STAGE_G(bufi, kt) do {                                              \
    _Pragma("unroll")                                                       \
    for (int ff = 0; ff < 2; ++ff) {                                        \
        int f = 2 * w + ff;                                                 \
        gll16(Abase[ff] + (kt) * 32, &lds[bufi][0][f][0]);                  \
        gll16(Wbase[ff] + (kt) * 32, &lds[bufi][1][f][0]);                  \
    } } while (0)

#define COMPUTE_G(bufi) do {                                                \
    bf16x8 af[4], bfr[4];                                                   \
    _Pragma("unroll")                                                       \
    for (int mf = 0; mf < 4; ++mf) af[mf] = *(const bf16x8*)&lds[bufi][0][wr*4+mf][lane*8]; \
    _Pragma("unroll")                                                       \
    for (int nf = 0; nf < 4; ++nf) bfr[nf] = *(const bf16x8*)&lds[bufi][1][wc*4+nf][lane*8]; \
    _Pragma("unroll")                                                       \
    for (int mf = 0; mf < 4; ++mf)                                          \
        _Pragma("unroll")                                                   \
        for (int nf = 0; nf < 4; ++nf)                                      \
            acc[mf][nf] = __builtin_amdgcn_mfma_f32_16x16x32_bf16(bfr[nf], af[mf], acc[mf][nf], 0, 0, 0); \
    } while (0)

    STAGE_G(0, 0);
    __syncthreads();
    int buf = 0;
    for (int kt = 0; kt < NKT - 1; ++kt) {
        STAGE_G(buf ^ 1, kt + 1);
        COMPUTE_G(buf);
        __syncthreads();
        buf ^= 1;
    }
    COMPUTE_G(buf);

    #pragma unroll
    for (int mf = 0; mf < 4; ++mf) {
        int mrow = m0 + wr * 64 + mf * 16 + r16;
        #pragma unroll
        for (int nf = 0; nf < 4; ++nf) {
            int nb = n0 + wc * 64 + nf * 16 + kq * 4;
            float4 bb = *(const float4*)&b1[nb];
            if (b2) {
                float4 b2v = *(const float4*)&b2[nb];
                bb.x += b2v.x; bb.y += b2v.y; bb.z += b2v.z; bb.w += b2v.w;
            }
            float v0 = acc[mf][nf][0] + bb.x;
            float v1 = acc[mf][nf][1] + bb.y;
            float v2 = acc[mf][nf][2] + bb.z;
            float v3 = acc[mf][nf][3] + bb.w;
            if (ACT) { v0 = eluf(v0); v1 = eluf(v1); v2 = eluf(v2); v3 = eluf(v3); }
            ushort4 o; o.x = f2b(v0); o.y = f2b(v1); o.z = f2b(v2); o.w = f2b(v3);
            *(ushort4*)&C[(size_t)mrow * 256 + nb] = o;
        }
    }
#undef STAGE_G
#undef COMPUTE_G
}

// ===========================================================================
// mlp4 layer-1 MFMA GEMM with fused gather, KD=768:
// row m=(be*64+t); k<256 -> X2b[b,send,t,k]; k<512 -> X2b[b,recv,t,·]; else EA[be,t,·]
// ===========================================================================
__global__ __launch_bounds__(256) void mfma_mlp4_k(
    const ushort_t* __restrict__ X2b, const ushort_t* __restrict__ EA,
    const ushort_t* __restrict__ Wt, const float* __restrict__ b1,
    ushort_t* __restrict__ C)
{
    __shared__ ushort_t lds[2][2][8][512];
    const int tid = threadIdx.x;
    const int lane = tid & 63;
    const int w = tid >> 6;
    const int wr = w >> 1, wc = w & 1;
    const int m0 = blockIdx.x * 128;
    const int n0 = blockIdx.y * 128;
    const int r16 = lane & 15, kq = lane >> 4;
    constexpr int NKT = 24;

    const ushort_t* AS[2]; const ushort_t* AR[2]; const ushort_t* AE[2];
    const ushort_t* Wbase[2];
    #pragma unroll
    for (int ff = 0; ff < 2; ++ff) {
        int f = 2 * w + ff;
        int m = m0 + f * 16 + r16;
        int be = m >> 6, t = m & 63;
        int b = be / E_, e = be % E_;
        int s = e / (V_ - 1);
        int r0 = e % (V_ - 1);
        int rr = r0 + (r0 >= s ? 1 : 0);
        AS[ff] = X2b + ((size_t)((b * V_ + s) * T_ + t)) * H_ + kq * 8;
        AR[ff] = X2b + ((size_t)((b * V_ + rr) * T_ + t)) * H_ + kq * 8;
        AE[ff] = EA + (size_t)m * H_ + kq * 8;
        Wbase[ff] = Wt + (size_t)(n0 + f * 16 + r16) * 768 + kq * 8;
    }

    f32x4 acc[4][4];
    #pragma unroll
    for (int i = 0; i < 4; ++i)
        #pragma unroll
        for (int j = 0; j < 4; ++j)
            acc[i][j] = (f32x4){0.f, 0.f, 0.f, 0.f};

#define STAGE_M(bufi, kt) do {                                              \
    int kk = (kt) * 32;                                                     \
    _Pragma("unroll")                                                       \
    for (int ff = 0; ff < 2; ++ff) {                                        \
        int f = 2 * w + ff;                                                 \
        const ushort_t* ga = (kk < 256) ? AS[ff] + kk                       \
                           : (kk < 512) ? AR[ff] + (kk - 256)               \
                                        : AE[ff] + (kk - 512);              \
        gll16(ga, &lds[bufi][0][f][0]);                                     \
        gll16(Wbase[ff] + kk, &lds[bufi][1][f][0]);                         \
    } } while (0)

#define COMPUTE_M(bufi) do {                                                \
    bf16x8 af[4], bfr[4];                                                   \
    _Pragma("unroll")                                                       \
    for (int mf = 0; mf < 4; ++mf) af[mf] = *(const bf16x8*)&lds[bufi][0][wr*4+mf][lane*8]; \
    _Pragma("unroll")                                                       \
    for (int nf = 0; nf < 4; ++nf) bfr[nf] = *(const bf16x8*)&lds[bufi][1][wc*4+nf][lane*8]; \
    _Pragma("unroll")                                                       \
    for (int mf = 0; mf < 4; ++mf)                                          \
        _Pragma("unroll")                                                   \
        for (int nf = 0; nf < 4; ++nf)                                      \
            acc[mf][nf] = __builtin_amdgcn_mfma_f32_16x16x32_bf16(bfr[nf], af[mf], acc[mf][nf], 0, 0, 0); \
    } while (0)

    STAGE_M(0, 0);
    __syncthreads();
    int buf = 0;
    for (int kt = 0; kt < NKT - 1; ++kt) {
        STAGE_M(buf ^ 1, kt + 1);
        COMPUTE_M(buf);
        __syncthreads();
        buf ^= 1;
    }
    COMPUTE_M(buf);

    #pragma unroll
    for (int mf = 0; mf < 4; ++mf) {
        int mrow = m0 + wr * 64 + mf * 16 + r16;
        #pragma unroll
        for (int nf = 0; nf < 4; ++nf) {
            int nb = n0 + wc * 64 + nf * 16 + kq * 4;
            float4 bb = *(const float4*)&b1[nb];
            float v0 = eluf(acc[mf][nf][0] + bb.x);
            float v1 = eluf(acc[mf][nf][1] + bb.y);
            float v2 = eluf(acc[mf][nf][2] + bb.z);
            float v3 = eluf(acc[mf][nf][3] + bb.w);
            ushort4 o; o.x = f2b(v0); o.y = f2b(v1); o.z = f2b(v2); o.w = f2b(v3);
            *(ushort4*)&C[(size_t)mrow * 256 + nb] = o;
        }
    }
#undef STAGE_M
#undef COMPUTE_M
}

// ===========================================================================
// weights f32 -> bf16 (packed): ef_w2 | m4_w1 | m4_w2 | f_wih | r_wih | e_w1
// ===========================================================================
__global__ __launch_bounds__(256) void wconv_k(
    const float* __restrict__ ef_w2, const float* __restrict__ m4_w1,
    const float* __restrict__ m4_w2, const float* __restrict__ f_wih,
    const float* __restrict__ r_wih, const float* __restrict__ e_w1,
    ushort_t* __restrict__ Wb)
{
    int i = blockIdx.x * 256 + threadIdx.x;   // < 491520
    const float* src; int off;
    if (i < 65536)       { src = ef_w2; off = i; }
    else if (i < 262144) { src = m4_w1; off = i - 65536; }
    else if (i < 327680) { src = m4_w2; off = i - 262144; }
    else if (i < 393216) { src = f_wih; off = i - 327680; }
    else if (i < 458752) { src = r_wih; off = i - 393216; }
    else                 { src = e_w1;  off = i - 458752; }
    Wb[i] = f2b(src[off]);
}

// ---------------------------------------------------------------------------
// Generic VALU GEMM (kept for mlp3 node rows): C = act(A@W.T + b1)
// ---------------------------------------------------------------------------
template<typename TA, typename TO>
__global__ __launch_bounds__(256) void gemm_t(
    const TA* __restrict__ A, const float* __restrict__ W,
    const float* __restrict__ b1, const float* __restrict__ b2,
    TO* __restrict__ C, int M, int Kd, int N, int act)
{
    __shared__ float As[16][64];
    __shared__ float Ws[16][64];
    const int m0 = blockIdx.x * 64, n0 = blockIdx.y * 64;
    const int tid = threadIdx.x;
    const int tm = tid >> 4, tn = tid & 15;
    const int lm = tid >> 2, lq = tid & 3;
    float acc[4][4] = {};
    const TA* Arow = A + (size_t)(m0 + lm) * Kd + lq * 4;
    const float* Wrow = W + (size_t)(n0 + lm) * Kd + lq * 4;
    for (int k0 = 0; k0 < Kd; k0 += 16) {
        float4 av, wv;
        if constexpr (std::is_same<TA, ushort_t>::value) {
            ushort4 u = *(const ushort4*)(Arow + k0);
            av.x = b2f(u.x); av.y = b2f(u.y); av.z = b2f(u.z); av.w = b2f(u.w);
        } else {
            av = *(const float4*)(Arow + k0);
        }
        wv = *(const float4*)(Wrow + k0);
        __syncthreads();
        As[lq*4+0][lm] = av.x; As[lq*4+1][lm] = av.y; As[lq*4+2][lm] = av.z; As[lq*4+3][lm] = av.w;
        Ws[lq*4+0][lm] = wv.x; Ws[lq*4+1][lm] = wv.y; Ws[lq*4+2][lm] = wv.z; Ws[lq*4+3][lm] = wv.w;
        __syncthreads();
        #pragma unroll
        for (int k = 0; k < 16; ++k) {
            float4 a = *(const float4*)&As[k][tm * 4];
            float4 w = *(const float4*)&Ws[k][tn * 4];
            float a_[4] = {a.x, a.y, a.z, a.w};
            float w_[4] = {w.x, w.y, w.z, w.w};
            #pragma unroll
            for (int i = 0; i < 4; ++i)
                #pragma unroll
                for (int j = 0; j < 4; ++j)
                    acc[i][j] += a_[i] * w_[j];
        }
    }
    float bb[4];
    #pragma unroll
    for (int j = 0; j < 4; ++j) {
        int n = n0 + tn * 4 + j;
        bb[j] = b1[n] + (b2 ? b2[n] : 0.f);
    }
    #pragma unroll
    for (int i = 0; i < 4; ++i) {
        float v0 = acc[i][0] + bb[0], v1 = acc[i][1] + bb[1];
        float v2 = acc[i][2] + bb[2], v3 = acc[i][3] + bb[3];
        if (act) { v0 = eluf(v0); v1 = eluf(v1); v2 = eluf(v2); v3 = eluf(v3); }
        TO* dst = C + (size_t)(m0 + tm * 4 + i) * N + (n0 + tn * 4);
        if constexpr (std::is_same<TO, ushort_t>::value) {
            ushort4 o; o.x = f2b(v0); o.y = f2b(v1); o.z = f2b(v2); o.w = f2b(v3);
            *(ushort4*)dst = o;
        } else {
            float4 o; o.x = v0; o.y = v1; o.z = v2; o.w = v3;
            *(float4*)dst = o;
        }
    }
}

// ---------------------------------------------------------------------------
// First GEMM with fused concat: A[m,c] = c<13 ? ear[m,c] : epos[m,c-13], Kd=16.
// ---------------------------------------------------------------------------
__global__ __launch_bounds__(256) void gemm_ein_k(
    const float* __restrict__ ear, const float* __restrict__ epos,
    const float* __restrict__ W, const float* __restrict__ b1,
    ushort_t* __restrict__ C)
{
    __shared__ float As[16][64];
    __shared__ float Ws[16][64];
    const int m0 = blockIdx.x * 64, n0 = blockIdx.y * 64;
    const int tid = threadIdx.x;
    const int tm = tid >> 4, tn = tid & 15;
    const int lm = tid >> 2, lq = tid & 3;
    const int m = m0 + lm;
    float a_[4];
    #pragma unroll
    for (int q = 0; q < 4; ++q) {
        int c = lq * 4 + q;
        a_[q] = (c < 13) ? ear[(size_t)m * 13 + c] : epos[(size_t)m * 3 + (c - 13)];
    }
    float4 wv = *(const float4*)(W + (size_t)(n0 + lm) * 16 + lq * 4);
    As[lq*4+0][lm] = a_[0]; As[lq*4+1][lm] = a_[1]; As[lq*4+2][lm] = a_[2]; As[lq*4+3][lm] = a_[3];
    Ws[lq*4+0][lm] = wv.x; Ws[lq*4+1][lm] = wv.y; Ws[lq*4+2][lm] = wv.z; Ws[lq*4+3][lm] = wv.w;
    __syncthreads();
    float acc[4][4] = {};
    #pragma unroll
    for (int k = 0; k < 16; ++k) {
        float4 a = *(const float4*)&As[k][tm * 4];
        float4 w = *(const float4*)&Ws[k][tn * 4];
        float aa[4] = {a.x, a.y, a.z, a.w};
        float ww[4] = {w.x, w.y, w.z, w.w};
        #pragma unroll
        for (int i = 0; i < 4; ++i)
            #pragma unroll
            for (int j = 0; j < 4; ++j)
                acc[i][j] += aa[i] * ww[j];
    }
    #pragma unroll
    for (int i = 0; i < 4; ++i) {
        ushort4 o;
        o.x = f2b(eluf(acc[i][0] + b1[n0 + tn*4 + 0]));
        o.y = f2b(eluf(acc[i][1] + b1[n0 + tn*4 + 1]));
        o.z = f2b(eluf(acc[i][2] + b1[n0 + tn*4 + 2]));
        o.w = f2b(eluf(acc[i][3] + b1[n0 + tn*4 + 3]));
        *(ushort4*)(C + (size_t)(m0 + tm * 4 + i) * H_ + (n0 + tn * 4)) = o;
    }
}

// ---------------------------------------------------------------------------
// edge2node: X[b,v,t,h] = (1/15)*sum_{e:RECV==v} EA[b,e,t,h] + rel@res_w.T + res_b
// ---------------------------------------------------------------------------
__global__ __launch_bounds__(256) void e2n_k(
    const ushort_t* __restrict__ EA, const float* __restrict__ rel,
    const float* __restrict__ res_w, const float* __restrict__ res_b,
    float* __restrict__ X)
{
    const int idx = blockIdx.x;            // (b*V+v)*T + t
    const int t = idx & (T_ - 1);
    const int bv = idx >> 6;
    const int v = bv & (V_ - 1);
    const int b = bv >> 4;
    const int h = threadIdx.x;
    float sum = 0.f;
    #pragma unroll
    for (int i = 0; i < V_; ++i) {
        if (i == v) continue;
        int jj = (v < i) ? v : v - 1;
        int e = i * (V_ - 1) + jj;
        sum += b2f(EA[(((size_t)(b * E_ + e)) * T_ + t) * H_ + h]);
    }
    const float* rp = rel + ((size_t)bv * T_ + t) * DIN_;
    float res = res_b[h];
    #pragma unroll
    for (int d = 0; d < DIN_; ++d) res += rp[d] * res_w[h * DIN_ + d];
    X[((size_t)bv * T_ + t) * H_ + h] = sum * (1.f / 15.f) + res;
}

// ===========================================================================
// MFMA LSTM scan, 4 cooperative waves per block, 16 sequences per block.
// Wave w owns n-tiles nt = {w, 4+w, 8+w, 12+w} = gates {i,f,g,o} for
// j-block [16w,16w+16). Per step/wave: 8 MFMAs + 4 cells of activation.
// whh B-fragments in registers (8 bf16x8 per lane). h round-trips through a
// double-buffered XOR-swizzled 2x2KB LDS buffer; ONE barrier per step.
// Lane l: seq=l&15, kq=l>>4; cell j = 16w + 4kq + r (r=0..3).
// Writes h to COMB[row][dir*64 + j] (row stride 128).
// ===========================================================================
__global__ __launch_bounds__(256) void lstm_mfma4_k(
    const ushort_t* __restrict__ G, const float* __restrict__ whh,
    ushort_t* __restrict__ COMB, int dir)
{
    __shared__ ushort_t hlds[2][1024];   // 2 x 2KB: h[seq][j] bf16, XOR-swizzled
    const int tid = threadIdx.x;
    const int lane = tid & 63;
    const int w = tid >> 6;              // wave id = j-block
    const int seq = lane & 15, kq = lane >> 4;
    const int be0 = blockIdx.x * 16;
    const int swz = (seq & 7) << 4;

    // whh -> B-fragments: wf[a][ks] holds whh row n = (a*4+w)*16 + seq,
    // k-cols ks*32 + kq*8 .. +8  (gate a: 0=i,1=f,2=g,3=o at j-block w)
    bf16x8 wf[4][2];
    #pragma unroll
    for (int a = 0; a < 4; ++a) {
        #pragma unroll
        for (int ks = 0; ks < 2; ++ks) {
            const float* p = whh + (size_t)((a * 4 + w) * 16 + seq) * 64 + ks * 32 + kq * 8;
            float4 x0 = *(const float4*)p;
            float4 x1 = *(const float4*)(p + 4);
            bf16x8 v;
            v[0] = (short)f2b(x0.x); v[1] = (short)f2b(x0.y);
            v[2] = (short)f2b(x0.z); v[3] = (short)f2b(x0.w);
            v[4] = (short)f2b(x1.x); v[5] = (short)f2b(x1.y);
            v[6] = (short)f2b(x1.z); v[7] = (short)f2b(x1.w);
            wf[a][ks] = v;
        }
    }

    const ushort_t* grow = G + ((size_t)(be0 + seq) * T_) * 256 + kq * 4;
    ushort_t* crow = COMB + ((size_t)(be0 + seq) * T_) * 128 + (dir ? 64 : 0) + 16 * w + 4 * kq;

    float c[4] = {};
    ushort4 gx[4];
    const int t0 = dir ? (T_ - 1) : 0;
    #pragma unroll
    for (int a = 0; a < 4; ++a)
        gx[a] = *(const ushort4*)(grow + (size_t)t0 * 256 + (a * 4 + w) * 16);

    for (int s = 0; s < T_; ++s) {
        const int t = dir ? (T_ - 1 - s) : s;
        f32x4 acc[4];
        #pragma unroll
        for (int a = 0; a < 4; ++a) {
            ushort4 g = gx[a];
            acc[a] = (f32x4){b2f(g.x), b2f(g.y), b2f(g.z), b2f(g.w)};
        }
        if (s < T_ - 1) {      // prefetch next step's gates (hidden under MFMA+act)
            const int tn = dir ? (T_ - 2 - s) : (s + 1);
            #pragma unroll
            for (int a = 0; a < 4; ++a)
                gx[a] = *(const ushort4*)(grow + (size_t)tn * 256 + (a * 4 + w) * 16);
        }
        if (s) {
            bf16x8 af[2];
            #pragma unroll
            for (int ks = 0; ks < 2; ++ks) {
                int boff = (seq * 128 + ks * 64 + kq * 16) ^ swz;
                af[ks] = *(const bf16x8*)((const char*)hlds[(s - 1) & 1] + boff);
            }
            #pragma unroll
            for (int a = 0; a < 4; ++a) {
                acc[a] = __builtin_amdgcn_mfma_f32_16x16x32_bf16(wf[a][0], af[0], acc[a], 0, 0, 0);
                acc[a] = __builtin_amdgcn_mfma_f32_16x16x32_bf16(wf[a][1], af[1], acc[a], 0, 0, 0);
            }
        }
        float hh[4];
        #pragma unroll
        for (int r = 0; r < 4; ++r) {
            float zi = acc[0][r], zf = acc[1][r], zg = acc[2][r], zo = acc[3][r];
            float cc = fsig(zf) * c[r] + fsig(zi) * ftanh_(zg);
            c[r] = cc;
            hh[r] = fsig(zo) * ftanh_(cc);
        }
        ushort4 hv;
        hv.x = f2b(hh[0]); hv.y = f2b(hh[1]); hv.z = f2b(hh[2]); hv.w = f2b(hh[3]);
        int wb = (seq * 128 + 32 * w + 8 * kq) ^ swz;
        *(ushort4*)((char*)hlds[s & 1] + wb) = hv;
        *(ushort4*)(crow + (size_t)t * 128) = hv;
        __syncthreads();
    }
}

// ---------------------------------------------------------------------------
// prior head: reads fwd hidden from comb[:, 0:64] (row stride 128)
// ---------------------------------------------------------------------------
__global__ __launch_bounds__(256) void prior_k(
    const ushort_t* __restrict__ COMB, const float* __restrict__ p_w,
    const float* __restrict__ p_b, float* __restrict__ out)
{
    const int row = blockIdx.x * 4 + (threadIdx.x >> 6);  // [0, BET)
    const int lane = threadIdx.x & 63;
    float hf = b2f(COMB[(size_t)row * 128 + lane]);
    float v0 = hf * p_w[lane];
    float v1 = hf * p_w[64 + lane];
    #pragma unroll
    for (int off = 32; off > 0; off >>= 1) {
        v0 += __shfl_down(v0, off, 64);
        v1 += __shfl_down(v1, off, 64);
    }
    if (lane == 0) {
        int t = row & (T_ - 1);
        int be = row >> 6;
        int e = be % E_, b = be / E_;
        size_t o = (((size_t)b * T_ + t) * E_ + e) * K_;
        out[o] = v0 + p_b[0];
        out[o + 1] = v1 + p_b[1];
    }
}

// ---------------------------------------------------------------------------
// enc head: out[b,t,e,k] = ENCH[row,:] . e_w2[k,:] + e_b2[k]; ENCH bf16 [BET,256]
// ---------------------------------------------------------------------------
__global__ __launch_bounds__(256) void encout_k(
    const ushort_t* __restrict__ ENCH, const float* __restrict__ e_w2,
    const float* __restrict__ e_b2, float* __restrict__ out)
{
    const int row = blockIdx.x * 4 + (threadIdx.x >> 6);
    const int lane = threadIdx.x & 63;
    ushort4 u = *(const ushort4*)(ENCH + (size_t)row * 256 + lane * 4);
    float4 v; v.x = b2f(u.x); v.y = b2f(u.y); v.z = b2f(u.z); v.w = b2f(u.w);
    float4 w0 = *(const float4*)(e_w2 + lane * 4);
    float4 w1 = *(const float4*)(e_w2 + 256 + lane * 4);
    float p0 = v.x * w0.x + v.y * w0.y + v.z * w0.z + v.w * w0.w;
    float p1 = v.x * w1.x + v.y * w1.y + v.z * w1.z + v.w * w1.w;
    #pragma unroll
    for (int off = 32; off > 0; off >>= 1) {
        p0 += __shfl_down(p0, off, 64);
        p1 += __shfl_down(p1, off, 64);
    }
    if (lane == 0) {
        int t = row & (T_ - 1);
        int be = row >> 6;
        int e = be % E_, b = be / E_;
        size_t o = (size_t)(B_ * T_ * E_ * K_) + (((size_t)b * T_ + t) * E_ + e) * K_;
        out[o] = p0 + e_b2[0];
        out[o + 1] = p1 + e_b2[1];
    }
}

// ---------------------------------------------------------------------------
extern "C" void kernel_launch(void* const* d_in, const int* in_sizes, int n_in,
                              void* d_out, int out_size, void* d_ws, size_t ws_size,
                              hipStream_t stream)
{
    const float* rel    = (const float*)d_in[0];
    const float* ear    = (const float*)d_in[1];
    const float* epos   = (const float*)d_in[2];
    const float* ef_w1  = (const float*)d_in[3];
    const float* ef_b1  = (const float*)d_in[4];
    const float* ef_w2  = (const float*)d_in[5];
    const float* ef_b2  = (const float*)d_in[6];
    const float* res_w  = (const float*)d_in[7];
    const float* res_b  = (const float*)d_in[8];
    const float* m3_w1  = (const float*)d_in[9];
    const float* m3_b1  = (const float*)d_in[10];
    const float* m3_w2  = (const float*)d_in[11];
    const float* m3_b2  = (const float*)d_in[12];
    const float* m4_w1  = (const float*)d_in[13];
    const float* m4_b1  = (const float*)d_in[14];
    const float* m4_w2  = (const float*)d_in[15];
    const float* m4_b2  = (const float*)d_in[16];
    const float* f_wih  = (const float*)d_in[17];
    const float* f_whh  = (const float*)d_in[18];
    const float* f_bih  = (const float*)d_in[19];
    const float* f_bhh  = (const float*)d_in[20];
    const float* r_wih  = (const float*)d_in[21];
    const float* r_whh  = (const float*)d_in[22];
    const float* r_bih  = (const float*)d_in[23];
    const float* r_bhh  = (const float*)d_in[24];
    const float* p_w    = (const float*)d_in[25];
    const float* p_b    = (const float*)d_in[26];
    const float* e_w1   = (const float*)d_in[27];
    const float* e_b1   = (const float*)d_in[28];
    const float* e_w2   = (const float*)d_in[29];
    const float* e_b2   = (const float*)d_in[30];
    float* out = (float*)d_out;

    // workspace layout (bytes), total ~162.5 MB
    char* ws = (char*)d_ws;
    const size_t BIGB  = (size_t)BET_ * H_ * sizeof(ushort_t);   // 62,914,560
    const size_t COMBB = (size_t)BET_ * 128 * sizeof(ushort_t);  // 31,457,280
    const size_t X2BB  = (size_t)BVT_ * H_ * sizeof(ushort_t);   //  4,194,304
    ushort_t* R1   = (ushort_t*)(ws);
    ushort_t* R2   = (ushort_t*)(ws + BIGB);
    ushort_t* COMB = (ushort_t*)(ws + 2 * BIGB);
    ushort_t* X2b  = (ushort_t*)(ws + 2 * BIGB + COMBB);
    ushort_t* Wb   = (ushort_t*)(ws + 2 * BIGB + COMBB + X2BB);
    // node-stage f32 scratch lives inside (dead) R1 region
    float* X  = (float*)(ws);
    float* XH = (float*)(ws + (size_t)BVT_ * H_ * sizeof(float));
    // packed bf16 weight offsets (elements)
    const ushort_t* wb_ef2  = Wb + 0;
    const ushort_t* wb_m41  = Wb + 65536;
    const ushort_t* wb_m42  = Wb + 262144;
    const ushort_t* wb_fwih = Wb + 327680;
    const ushort_t* wb_rwih = Wb + 393216;
    const ushort_t* wb_ew1  = Wb + 458752;

    dim3 blk(256);
    dim3 gM(BET_ / 128, 2);    // MFMA edge GEMMs: 960 x 2
    dim3 gE64(BET_ / 64, 4);   // VALU edge GEMM (ein)
    dim3 gN(BVT_ / 64, 4);     // VALU node GEMMs

    // 0. weights -> bf16
    wconv_k<<<1920, blk, 0, stream>>>(ef_w2, m4_w1, m4_w2, f_wih, r_wih, e_w1, Wb);
    // 1. edge filter MLP
    gemm_ein_k<<<gE64, blk, 0, stream>>>(ear, epos, ef_w1, ef_b1, R1);
    mfma_gemm_k<256, 1><<<gM, blk, 0, stream>>>(R1, wb_ef2, ef_b2, nullptr, R2);     // EA
    // 2. edge2node + residual
    e2n_k<<<BVT_, blk, 0, stream>>>(R2, rel, res_w, res_b, X);
    // 3. mlp3 (node rows, f32 VALU)
    gemm_t<float, float><<<gN, blk, 0, stream>>>(X, m3_w1, m3_b1, nullptr, XH, BVT_, H_, H_, 1);
    gemm_t<float, ushort_t><<<gN, blk, 0, stream>>>(XH, m3_w2, m3_b2, nullptr, X2b, BVT_, H_, H_, 1);
    // 4. node2edge gather + mlp4
    mfma_mlp4_k<<<gM, blk, 0, stream>>>(X2b, R2, wb_m41, m4_b1, R1);
    mfma_gemm_k<256, 1><<<gM, blk, 0, stream>>>(R1, wb_m42, m4_b2, nullptr, R2);     // M2
    // 5. LSTM: gate GEMM then 4-wave cooperative MFMA scan, per direction
    mfma_gemm_k<256, 0><<<gM, blk, 0, stream>>>(R2, wb_fwih, f_bih, f_bhh, R1);      // GF
    lstm_mfma4_k<<<BE_ / 16, blk, 0, stream>>>(R1, f_whh, COMB, 0);
    mfma_gemm_k<256, 0><<<gM, blk, 0, stream>>>(R2, wb_rwih, r_bih, r_bhh, R1);      // GR
    lstm_mfma4_k<<<BE_ / 16, blk, 0, stream>>>(R1, r_whh, COMB, 1);
    // 6. heads
    prior_k<<<BET_ / 4, blk, 0, stream>>>(COMB, p_w, p_b, out);
    mfma_gemm_k<128, 1><<<gM, blk, 0, stream>>>(COMB, wb_ew1, e_b1, nullptr, R2);    // ENCH
    encout_k<<<BET_ / 4, blk, 0, stream>>>(R2, e_w2, e_b2, out);
}

// Round 6
// 575.913 us; speedup vs baseline: 4.5973x; 1.0152x over previous
//
#include <hip/hip_runtime.h>
#include <cstdint>
#include <cstddef>
#include <type_traits>

// Problem constants
#define B_ 8
#define V_ 16
#define T_ 64
#define E_ 240          // V*(V-1)
#define H_ 256
#define RH_ 64
#define K_ 2
#define DIN_ 6
#define BET_ (B_*E_*T_)   // 122880
#define BVT_ (B_*V_*T_)   // 8192
#define BE_ (B_*E_)       // 1920

typedef unsigned short ushort_t;
typedef unsigned int u32;
typedef __attribute__((ext_vector_type(8))) short bf16x8;
typedef __attribute__((ext_vector_type(4))) float f32x4;

__device__ __forceinline__ float eluf(float x) { return x > 0.f ? x : __expf(x) - 1.f; }
__device__ __forceinline__ float fsig(float x) { return 1.f / (1.f + __expf(-x)); }
__device__ __forceinline__ float ftanh_(float x) {
    float y = fminf(fmaxf(x, -8.f), 8.f);
    float e = __expf(2.f * y);
    return (e - 1.f) / (e + 1.f);
}
__device__ __forceinline__ float b2f(ushort_t u) {
    union { float f; uint32_t i; } v; v.i = ((uint32_t)u) << 16; return v.f;
}
__device__ __forceinline__ ushort_t f2b(float f) {
    union { float f; uint32_t i; } v; v.f = f;
    uint32_t r = (v.i + 0x7FFFu + ((v.i >> 16) & 1u)) >> 16;
    return (ushort_t)r;
}

// async global->LDS, 16B per lane; LDS dest = wave-uniform base + lane*16
__device__ __forceinline__ void gll16(const void* g, void* l) {
    __builtin_amdgcn_global_load_lds(
        (const __attribute__((address_space(1))) u32*)g,
        (__attribute__((address_space(3))) u32*)l, 16, 0, 0);
}

// ===========================================================================
// MFMA bf16 GEMM: C[m,n] = act( sum_k A[m,k]*W[n,k] + b1[n] (+b2[n]) ), bf16 out
// A [M,KD] bf16 row-major, W [N,KD] bf16 row-major, N = 256.
// BM=128, BN=128, K-step 32, 4 waves (2x2), each wave 64x64 (4x4 frags 16x16).
// LDS in fragment order: [buf][A/B][frag 0..7][lane*8 bf16]  (zero-conflict b128)
// 3-buffer pipeline, counted vmcnt(4) + raw s_barrier (T3+T4): each STAGE
// issues exactly 4 global_load_lds per wave; vmcnt(4) with 8 outstanding
// waits the oldest 4 (= current buffer). Barrier covers buffer-reuse WAR.
// mfma(Wfrag, Afrag): lane holds C rows m=lane&15, cols n=(lane>>4)*4+r (r=0..3)
// ===========================================================================
template<int KD, int ACT>
__global__ __launch_bounds__(256) void mfma_gemm_k(
    const ushort_t* __restrict__ A, const ushort_t* __restrict__ Wt,
    const float* __restrict__ b1, const float* __restrict__ b2,
    ushort_t* __restrict__ C)
{
    __shared__ ushort_t lds[3][2][8][512];   // 48 KB
    const int tid = threadIdx.x;
    const int lane = tid & 63;
    const int w = tid >> 6;
    const int wr = w >> 1, wc = w & 1;
    const int m0 = blockIdx.x * 128;
    const int n0 = blockIdx.y * 128;
    const int r16 = lane & 15, kq = lane >> 4;
    constexpr int NKT = KD / 32;

    const ushort_t* Abase[2];
    const ushort_t* Wbase[2];
    #pragma unroll
    for (int ff = 0; ff < 2; ++ff) {
        int f = 2 * w + ff;
        Abase[ff] = A  + (size_t)(m0 + f * 16 + r16) * KD + kq * 8;
        Wbase[ff] = Wt + (size_t)(n0 + f * 16 + r16) * KD + kq * 8;
    }

    f32x4 acc[4][4];
    #pragma unroll
    for (int i = 0; i < 4; ++i)
        #pragma unroll
        for (int j = 0; j < 4; ++j)
            acc[i][j] = (f32x4){0.f, 0.f, 0.f, 0.f};

#define STAGE_G(bufi, kt) do {                                              \
    _Pragma("unroll")                                                       \
    for (int ff = 0; ff < 2; ++ff) {                                        \
        int f = 2 * w + ff;                                                 \
        gll16(Abase[ff] + (kt) * 32, &lds[bufi][0][f][0]);                  \
        gll16(Wbase[ff] + (kt) * 32, &lds[bufi][1][f][0]);                  \
    } } while (0)

#define COMPUTE_G(bufi) do {                                                \
    bf16x8 af[4], bfr[4];                                                   \
    _Pragma("unroll")                                                       \
    for (int mf = 0; mf < 4; ++mf) af[mf] = *(const bf16x8*)&lds[bufi][0][wr*4+mf][lane*8]; \
    _Pragma("unroll")                                                       \
    for (int nf = 0; nf < 4; ++nf) bfr[nf] = *(const bf16x8*)&lds[bufi][1][wc*4+nf][lane*8]; \
    _Pragma("unroll")                                                       \
    for (int mf = 0; mf < 4; ++mf)                                          \
        _Pragma("unroll")                                                   \
        for (int nf = 0; nf < 4; ++nf)                                      \
            acc[mf][nf] = __builtin_amdgcn_mfma_f32_16x16x32_bf16(bfr[nf], af[mf], acc[mf][nf], 0, 0, 0); \
    } while (0)

    STAGE_G(0, 0);
    STAGE_G(1, 1);
    for (int kt = 0; kt < NKT; ++kt) {
        const int cur = kt % 3;
        if (kt < NKT - 1) { asm volatile("s_waitcnt vmcnt(4)" ::: "memory"); }
        else              { asm volatile("s_waitcnt vmcnt(0)" ::: "memory"); }
        __builtin_amdgcn_s_barrier();
        if (kt + 2 < NKT) {
            const int nxt = (kt + 2) % 3;
            STAGE_G(nxt, kt + 2);
        }
        COMPUTE_G(cur);
    }

    #pragma unroll
    for (int mf = 0; mf < 4; ++mf) {
        int mrow = m0 + wr * 64 + mf * 16 + r16;
        #pragma unroll
        for (int nf = 0; nf < 4; ++nf) {
            int nb = n0 + wc * 64 + nf * 16 + kq * 4;
            float4 bb = *(const float4*)&b1[nb];
            if (b2) {
                float4 b2v = *(const float4*)&b2[nb];
                bb.x += b2v.x; bb.y += b2v.y; bb.z += b2v.z; bb.w += b2v.w;
            }
            float v0 = acc[mf][nf][0] + bb.x;
            float v1 = acc[mf][nf][1] + bb.y;
            float v2 = acc[mf][nf][2] + bb.z;
            float v3 = acc[mf][nf][3] + bb.w;
            if (ACT) { v0 = eluf(v0); v1 = eluf(v1); v2 = eluf(v2); v3 = eluf(v3); }
            ushort4 o; o.x = f2b(v0); o.y = f2b(v1); o.z = f2b(v2); o.w = f2b(v3);
            *(ushort4*)&C[(size_t)mrow * 256 + nb] = o;
        }
    }
#undef STAGE_G
#undef COMPUTE_G
}

// ===========================================================================
// mlp4 layer-1 MFMA GEMM with fused gather, KD=768, same 3-buffer pipeline:
// row m=(be*64+t); k<256 -> X2b[b,send,t,k]; k<512 -> X2b[b,recv,t,·]; else EA[be,t,·]
// ===========================================================================
__global__ __launch_bounds__(256) void mfma_mlp4_k(
    const ushort_t* __restrict__ X2b, const ushort_t* __restrict__ EA,
    const ushort_t* __restrict__ Wt, const float* __restrict__ b1,
    ushort_t* __restrict__ C)
{
    __shared__ ushort_t lds[3][2][8][512];   // 48 KB
    const int tid = threadIdx.x;
    const int lane = tid & 63;
    const int w = tid >> 6;
    const int wr = w >> 1, wc = w & 1;
    const int m0 = blockIdx.x * 128;
    const int n0 = blockIdx.y * 128;
    const int r16 = lane & 15, kq = lane >> 4;
    constexpr int NKT = 24;

    const ushort_t* AS[2]; const ushort_t* AR[2]; const ushort_t* AE[2];
    const ushort_t* Wbase[2];
    #pragma unroll
    for (int ff = 0; ff < 2; ++ff) {
        int f = 2 * w + ff;
        int m = m0 + f * 16 + r16;
        int be = m >> 6, t = m & 63;
        int b = be / E_, e = be % E_;
        int s = e / (V_ - 1);
        int r0 = e % (V_ - 1);
        int rr = r0 + (r0 >= s ? 1 : 0);
        AS[ff] = X2b + ((size_t)((b * V_ + s) * T_ + t)) * H_ + kq * 8;
        AR[ff] = X2b + ((size_t)((b * V_ + rr) * T_ + t)) * H_ + kq * 8;
        AE[ff] = EA + (size_t)m * H_ + kq * 8;
        Wbase[ff] = Wt + (size_t)(n0 + f * 16 + r16) * 768 + kq * 8;
    }

    f32x4 acc[4][4];
    #pragma unroll
    for (int i = 0; i < 4; ++i)
        #pragma unroll
        for (int j = 0; j < 4; ++j)
            acc[i][j] = (f32x4){0.f, 0.f, 0.f, 0.f};

#define STAGE_M(bufi, kt) do {                                              \
    int kk = (kt) * 32;                                                     \
    _Pragma("unroll")                                                       \
    for (int ff = 0; ff < 2; ++ff) {                                        \
        int f = 2 * w + ff;                                                 \
        const ushort_t* ga = (kk < 256) ? AS[ff] + kk                       \
                           : (kk < 512) ? AR[ff] + (kk - 256)               \
                                        : AE[ff] + (kk - 512);              \
        gll16(ga, &lds[bufi][0][f][0]);                                     \
        gll16(Wbase[ff] + kk, &lds[bufi][1][f][0]);                         \
    } } while (0)

#define COMPUTE_M(bufi) do {                                                \
    bf16x8 af[4], bfr[4];                                                   \
    _Pragma("unroll")                                                       \
    for (int mf = 0; mf < 4; ++mf) af[mf] = *(const bf16x8*)&lds[bufi][0][wr*4+mf][lane*8]; \
    _Pragma("unroll")                                                       \
    for (int nf = 0; nf < 4; ++nf) bfr[nf] = *(const bf16x8*)&lds[bufi][1][wc*4+nf][lane*8]; \
    _Pragma("unroll")                                                       \
    for (int mf = 0; mf < 4; ++mf)                                          \
        _Pragma("unroll")                                                   \
        for (int nf = 0; nf < 4; ++nf)                                      \
            acc[mf][nf] = __builtin_amdgcn_mfma_f32_16x16x32_bf16(bfr[nf], af[mf], acc[mf][nf], 0, 0, 0); \
    } while (0)

    STAGE_M(0, 0);
    STAGE_M(1, 1);
    for (int kt = 0; kt < NKT; ++kt) {
        const int cur = kt % 3;
        if (kt < NKT - 1) { asm volatile("s_waitcnt vmcnt(4)" ::: "memory"); }
        else              { asm volatile("s_waitcnt vmcnt(0)" ::: "memory"); }
        __builtin_amdgcn_s_barrier();
        if (kt + 2 < NKT) {
            const int nxt = (kt + 2) % 3;
            STAGE_M(nxt, kt + 2);
        }
        COMPUTE_M(cur);
    }

    #pragma unroll
    for (int mf = 0; mf < 4; ++mf) {
        int mrow = m0 + wr * 64 + mf * 16 + r16;
        #pragma unroll
        for (int nf = 0; nf < 4; ++nf) {
            int nb = n0 + wc * 64 + nf * 16 + kq * 4;
            float4 bb = *(const float4*)&b1[nb];
            float v0 = eluf(acc[mf][nf][0] + bb.x);
            float v1 = eluf(acc[mf][nf][1] + bb.y);
            float v2 = eluf(acc[mf][nf][2] + bb.z);
            float v3 = eluf(acc[mf][nf][3] + bb.w);
            ushort4 o; o.x = f2b(v0); o.y = f2b(v1); o.z = f2b(v2); o.w = f2b(v3);
            *(ushort4*)&C[(size_t)mrow * 256 + nb] = o;
        }
    }
#undef STAGE_M
#undef COMPUTE_M
}

// ===========================================================================
// weights f32 -> bf16 (packed): ef_w2 | m4_w1 | m4_w2 | f_wih | r_wih | e_w1
// ===========================================================================
__global__ __launch_bounds__(256) void wconv_k(
    const float* __restrict__ ef_w2, const float* __restrict__ m4_w1,
    const float* __restrict__ m4_w2, const float* __restrict__ f_wih,
    const float* __restrict__ r_wih, const float* __restrict__ e_w1,
    ushort_t* __restrict__ Wb)
{
    int i = blockIdx.x * 256 + threadIdx.x;   // < 491520
    const float* src; int off;
    if (i < 65536)       { src = ef_w2; off = i; }
    else if (i < 262144) { src = m4_w1; off = i - 65536; }
    else if (i < 327680) { src = m4_w2; off = i - 262144; }
    else if (i < 393216) { src = f_wih; off = i - 327680; }
    else if (i < 458752) { src = r_wih; off = i - 393216; }
    else                 { src = e_w1;  off = i - 458752; }
    Wb[i] = f2b(src[off]);
}

// ---------------------------------------------------------------------------
// Generic VALU GEMM (kept for mlp3 node rows): C = act(A@W.T + b1)
// ---------------------------------------------------------------------------
template<typename TA, typename TO>
__global__ __launch_bounds__(256) void gemm_t(
    const TA* __restrict__ A, const float* __restrict__ W,
    const float* __restrict__ b1, const float* __restrict__ b2,
    TO* __restrict__ C, int M, int Kd, int N, int act)
{
    __shared__ float As[16][64];
    __shared__ float Ws[16][64];
    const int m0 = blockIdx.x * 64, n0 = blockIdx.y * 64;
    const int tid = threadIdx.x;
    const int tm = tid >> 4, tn = tid & 15;
    const int lm = tid >> 2, lq = tid & 3;
    float acc[4][4] = {};
    const TA* Arow = A + (size_t)(m0 + lm) * Kd + lq * 4;
    const float* Wrow = W + (size_t)(n0 + lm) * Kd + lq * 4;
    for (int k0 = 0; k0 < Kd; k0 += 16) {
        float4 av, wv;
        if constexpr (std::is_same<TA, ushort_t>::value) {
            ushort4 u = *(const ushort4*)(Arow + k0);
            av.x = b2f(u.x); av.y = b2f(u.y); av.z = b2f(u.z); av.w = b2f(u.w);
        } else {
            av = *(const float4*)(Arow + k0);
        }
        wv = *(const float4*)(Wrow + k0);
        __syncthreads();
        As[lq*4+0][lm] = av.x; As[lq*4+1][lm] = av.y; As[lq*4+2][lm] = av.z; As[lq*4+3][lm] = av.w;
        Ws[lq*4+0][lm] = wv.x; Ws[lq*4+1][lm] = wv.y; Ws[lq*4+2][lm] = wv.z; Ws[lq*4+3][lm] = wv.w;
        __syncthreads();
        #pragma unroll
        for (int k = 0; k < 16; ++k) {
            float4 a = *(const float4*)&As[k][tm * 4];
            float4 w = *(const float4*)&Ws[k][tn * 4];
            float a_[4] = {a.x, a.y, a.z, a.w};
            float w_[4] = {w.x, w.y, w.z, w.w};
            #pragma unroll
            for (int i = 0; i < 4; ++i)
                #pragma unroll
                for (int j = 0; j < 4; ++j)
                    acc[i][j] += a_[i] * w_[j];
        }
    }
    float bb[4];
    #pragma unroll
    for (int j = 0; j < 4; ++j) {
        int n = n0 + tn * 4 + j;
        bb[j] = b1[n] + (b2 ? b2[n] : 0.f);
    }
    #pragma unroll
    for (int i = 0; i < 4; ++i) {
        float v0 = acc[i][0] + bb[0], v1 = acc[i][1] + bb[1];
        float v2 = acc[i][2] + bb[2], v3 = acc[i][3] + bb[3];
        if (act) { v0 = eluf(v0); v1 = eluf(v1); v2 = eluf(v2); v3 = eluf(v3); }
        TO* dst = C + (size_t)(m0 + tm * 4 + i) * N + (n0 + tn * 4);
        if constexpr (std::is_same<TO, ushort_t>::value) {
            ushort4 o; o.x = f2b(v0); o.y = f2b(v1); o.z = f2b(v2); o.w = f2b(v3);
            *(ushort4*)dst = o;
        } else {
            float4 o; o.x = v0; o.y = v1; o.z = v2; o.w = v3;
            *(float4*)dst = o;
        }
    }
}

// ---------------------------------------------------------------------------
// First GEMM with fused concat: A[m,c] = c<13 ? ear[m,c] : epos[m,c-13], Kd=16.
// ---------------------------------------------------------------------------
__global__ __launch_bounds__(256) void gemm_ein_k(
    const float* __restrict__ ear, const float* __restrict__ epos,
    const float* __restrict__ W, const float* __restrict__ b1,
    ushort_t* __restrict__ C)
{
    __shared__ float As[16][64];
    __shared__ float Ws[16][64];
    const int m0 = blockIdx.x * 64, n0 = blockIdx.y * 64;
    const int tid = threadIdx.x;
    const int tm = tid >> 4, tn = tid & 15;
    const int lm = tid >> 2, lq = tid & 3;
    const int m = m0 + lm;
    float a_[4];
    #pragma unroll
    for (int q = 0; q < 4; ++q) {
        int c = lq * 4 + q;
        a_[q] = (c < 13) ? ear[(size_t)m * 13 + c] : epos[(size_t)m * 3 + (c - 13)];
    }
    float4 wv = *(const float4*)(W + (size_t)(n0 + lm) * 16 + lq * 4);
    As[lq*4+0][lm] = a_[0]; As[lq*4+1][lm] = a_[1]; As[lq*4+2][lm] = a_[2]; As[lq*4+3][lm] = a_[3];
    Ws[lq*4+0][lm] = wv.x; Ws[lq*4+1][lm] = wv.y; Ws[lq*4+2][lm] = wv.z; Ws[lq*4+3][lm] = wv.w;
    __syncthreads();
    float acc[4][4] = {};
    #pragma unroll
    for (int k = 0; k < 16; ++k) {
        float4 a = *(const float4*)&As[k][tm * 4];
        float4 w = *(const float4*)&Ws[k][tn * 4];
        float aa[4] = {a.x, a.y, a.z, a.w};
        float ww[4] = {w.x, w.y, w.z, w.w};
        #pragma unroll
        for (int i = 0; i < 4; ++i)
            #pragma unroll
            for (int j = 0; j < 4; ++j)
                acc[i][j] += aa[i] * ww[j];
    }
    #pragma unroll
    for (int i = 0; i < 4; ++i) {
        ushort4 o;
        o.x = f2b(eluf(acc[i][0] + b1[n0 + tn*4 + 0]));
        o.y = f2b(eluf(acc[i][1] + b1[n0 + tn*4 + 1]));
        o.z = f2b(eluf(acc[i][2] + b1[n0 + tn*4 + 2]));
        o.w = f2b(eluf(acc[i][3] + b1[n0 + tn*4 + 3]));
        *(ushort4*)(C + (size_t)(m0 + tm * 4 + i) * H_ + (n0 + tn * 4)) = o;
    }
}

// ---------------------------------------------------------------------------
// edge2node: X[b,v,t,h] = (1/15)*sum_{e:RECV==v} EA[b,e,t,h] + rel@res_w.T + res_b
// ---------------------------------------------------------------------------
__global__ __launch_bounds__(256) void e2n_k(
    const ushort_t* __restrict__ EA, const float* __restrict__ rel,
    const float* __restrict__ res_w, const float* __restrict__ res_b,
    float* __restrict__ X)
{
    const int idx = blockIdx.x;            // (b*V+v)*T + t
    const int t = idx & (T_ - 1);
    const int bv = idx >> 6;
    const int v = bv & (V_ - 1);
    const int b = bv >> 4;
    const int h = threadIdx.x;
    float sum = 0.f;
    #pragma unroll
    for (int i = 0; i < V_; ++i) {
        if (i == v) continue;
        int jj = (v < i) ? v : v - 1;
        int e = i * (V_ - 1) + jj;
        sum += b2f(EA[(((size_t)(b * E_ + e)) * T_ + t) * H_ + h]);
    }
    const float* rp = rel + ((size_t)bv * T_ + t) * DIN_;
    float res = res_b[h];
    #pragma unroll
    for (int d = 0; d < DIN_; ++d) res += rp[d] * res_w[h * DIN_ + d];
    X[((size_t)bv * T_ + t) * H_ + h] = sum * (1.f / 15.f) + res;
}

// ===========================================================================
// MFMA LSTM scan, 4 cooperative waves per block, 16 sequences per block.
// Wave w owns n-tiles nt = {w, 4+w, 8+w, 12+w} = gates {i,f,g,o} for
// j-block [16w,16w+16). Per step/wave: 8 MFMAs + 4 cells of activation.
// whh B-fragments in registers. h double-buffered in XOR-swizzled LDS;
// per-step sync = lgkmcnt(0) + raw s_barrier (no vmcnt drain, so the gate
// prefetch loads stay in flight across the barrier).
// ===========================================================================
__global__ __launch_bounds__(256) void lstm_mfma4_k(
    const ushort_t* __restrict__ G, const float* __restrict__ whh,
    ushort_t* __restrict__ COMB, int dir)
{
    __shared__ ushort_t hlds[2][1024];   // 2 x 2KB: h[seq][j] bf16, XOR-swizzled
    const int tid = threadIdx.x;
    const int lane = tid & 63;
    const int w = tid >> 6;              // wave id = j-block
    const int seq = lane & 15, kq = lane >> 4;
    const int be0 = blockIdx.x * 16;
    const int swz = (seq & 7) << 4;

    // whh -> B-fragments: wf[a][ks] holds whh row n = (a*4+w)*16 + seq,
    // k-cols ks*32 + kq*8 .. +8  (gate a: 0=i,1=f,2=g,3=o at j-block w)
    bf16x8 wf[4][2];
    #pragma unroll
    for (int a = 0; a < 4; ++a) {
        #pragma unroll
        for (int ks = 0; ks < 2; ++ks) {
            const float* p = whh + (size_t)((a * 4 + w) * 16 + seq) * 64 + ks * 32 + kq * 8;
            float4 x0 = *(const float4*)p;
            float4 x1 = *(const float4*)(p + 4);
            bf16x8 v;
            v[0] = (short)f2b(x0.x); v[1] = (short)f2b(x0.y);
            v[2] = (short)f2b(x0.z); v[3] = (short)f2b(x0.w);
            v[4] = (short)f2b(x1.x); v[5] = (short)f2b(x1.y);
            v[6] = (short)f2b(x1.z); v[7] = (short)f2b(x1.w);
            wf[a][ks] = v;
        }
    }

    const ushort_t* grow = G + ((size_t)(be0 + seq) * T_) * 256 + kq * 4;
    ushort_t* crow = COMB + ((size_t)(be0 + seq) * T_) * 128 + (dir ? 64 : 0) + 16 * w + 4 * kq;

    float c[4] = {};
    ushort4 gx[4];
    const int t0 = dir ? (T_ - 1) : 0;
    #pragma unroll
    for (int a = 0; a < 4; ++a)
        gx[a] = *(const ushort4*)(grow + (size_t)t0 * 256 + (a * 4 + w) * 16);

    for (int s = 0; s < T_; ++s) {
        const int t = dir ? (T_ - 1 - s) : s;
        f32x4 acc[4];
        #pragma unroll
        for (int a = 0; a < 4; ++a) {
            ushort4 g = gx[a];
            acc[a] = (f32x4){b2f(g.x), b2f(g.y), b2f(g.z), b2f(g.w)};
        }
        if (s < T_ - 1) {      // prefetch next step's gates (crosses the barrier)
            const int tn = dir ? (T_ - 2 - s) : (s + 1);
            #pragma unroll
            for (int a = 0; a < 4; ++a)
                gx[a] = *(const ushort4*)(grow + (size_t)tn * 256 + (a * 4 + w) * 16);
        }
        if (s) {
            bf16x8 af[2];
            #pragma unroll
            for (int ks = 0; ks < 2; ++ks) {
                int boff = (seq * 128 + ks * 64 + kq * 16) ^ swz;
                af[ks] = *(const bf16x8*)((const char*)hlds[(s - 1) & 1] + boff);
            }
            #pragma unroll
            for (int a = 0; a < 4; ++a) {
                acc[a] = __builtin_amdgcn_mfma_f32_16x16x32_bf16(wf[a][0], af[0], acc[a], 0, 0, 0);
                acc[a] = __builtin_amdgcn_mfma_f32_16x16x32_bf16(wf[a][1], af[1], acc[a], 0, 0, 0);
            }
        }
        float hh[4];
        #pragma unroll
        for (int r = 0; r < 4; ++r) {
            float zi = acc[0][r], zf = acc[1][r], zg = acc[2][r], zo = acc[3][r];
            float cc = fsig(zf) * c[r] + fsig(zi) * ftanh_(zg);
            c[r] = cc;
            hh[r] = fsig(zo) * ftanh_(cc);
        }
        ushort4 hv;
        hv.x = f2b(hh[0]); hv.y = f2b(hh[1]); hv.z = f2b(hh[2]); hv.w = f2b(hh[3]);
        int wb = (seq * 128 + 32 * w + 8 * kq) ^ swz;
        *(ushort4*)((char*)hlds[s & 1] + wb) = hv;
        *(ushort4*)(crow + (size_t)t * 128) = hv;
        // barrier without vmcnt drain: LDS writes must be visible (lgkmcnt),
        // but gate-prefetch global loads stay outstanding.
        asm volatile("s_waitcnt lgkmcnt(0)" ::: "memory");
        __builtin_amdgcn_sched_barrier(0);
        __builtin_amdgcn_s_barrier();
    }
}

// ---------------------------------------------------------------------------
// prior head: reads fwd hidden from comb[:, 0:64] (row stride 128)
// ---------------------------------------------------------------------------
__global__ __launch_bounds__(256) void prior_k(
    const ushort_t* __restrict__ COMB, const float* __restrict__ p_w,
    const float* __restrict__ p_b, float* __restrict__ out)
{
    const int row = blockIdx.x * 4 + (threadIdx.x >> 6);  // [0, BET)
    const int lane = threadIdx.x & 63;
    float hf = b2f(COMB[(size_t)row * 128 + lane]);
    float v0 = hf * p_w[lane];
    float v1 = hf * p_w[64 + lane];
    #pragma unroll
    for (int off = 32; off > 0; off >>= 1) {
        v0 += __shfl_down(v0, off, 64);
        v1 += __shfl_down(v1, off, 64);
    }
    if (lane == 0) {
        int t = row & (T_ - 1);
        int be = row >> 6;
        int e = be % E_, b = be / E_;
        size_t o = (((size_t)b * T_ + t) * E_ + e) * K_;
        out[o] = v0 + p_b[0];
        out[o + 1] = v1 + p_b[1];
    }
}

// ---------------------------------------------------------------------------
// enc head: out[b,t,e,k] = ENCH[row,:] . e_w2[k,:] + e_b2[k]; ENCH bf16 [BET,256]
// ---------------------------------------------------------------------------
__global__ __launch_bounds__(256) void encout_k(
    const ushort_t* __restrict__ ENCH, const float* __restrict__ e_w2,
    const float* __restrict__ e_b2, float* __restrict__ out)
{
    const int row = blockIdx.x * 4 + (threadIdx.x >> 6);
    const int lane = threadIdx.x & 63;
    ushort4 u = *(const ushort4*)(ENCH + (size_t)row * 256 + lane * 4);
    float4 v; v.x = b2f(u.x); v.y = b2f(u.y); v.z = b2f(u.z); v.w = b2f(u.w);
    float4 w0 = *(const float4*)(e_w2 + lane * 4);
    float4 w1 = *(const float4*)(e_w2 + 256 + lane * 4);
    float p0 = v.x * w0.x + v.y * w0.y + v.z * w0.z + v.w * w0.w;
    float p1 = v.x * w1.x + v.y * w1.y + v.z * w1.z + v.w * w1.w;
    #pragma unroll
    for (int off = 32; off > 0; off >>= 1) {
        p0 += __shfl_down(p0, off, 64);
        p1 += __shfl_down(p1, off, 64);
    }
    if (lane == 0) {
        int t = row & (T_ - 1);
        int be = row >> 6;
        int e = be % E_, b = be / E_;
        size_t o = (size_t)(B_ * T_ * E_ * K_) + (((size_t)b * T_ + t) * E_ + e) * K_;
        out[o] = p0 + e_b2[0];
        out[o + 1] = p1 + e_b2[1];
    }
}

// ---------------------------------------------------------------------------
extern "C" void kernel_launch(void* const* d_in, const int* in_sizes, int n_in,
                              void* d_out, int out_size, void* d_ws, size_t ws_size,
                              hipStream_t stream)
{
    const float* rel    = (const float*)d_in[0];
    const float* ear    = (const float*)d_in[1];
    const float* epos   = (const float*)d_in[2];
    const float* ef_w1  = (const float*)d_in[3];
    const float* ef_b1  = (const float*)d_in[4];
    const float* ef_w2  = (const float*)d_in[5];
    const float* ef_b2  = (const float*)d_in[6];
    const float* res_w  = (const float*)d_in[7];
    const float* res_b  = (const float*)d_in[8];
    const float* m3_w1  = (const float*)d_in[9];
    const float* m3_b1  = (const float*)d_in[10];
    const float* m3_w2  = (const float*)d_in[11];
    const float* m3_b2  = (const float*)d_in[12];
    const float* m4_w1  = (const float*)d_in[13];
    const float* m4_b1  = (const float*)d_in[14];
    const float* m4_w2  = (const float*)d_in[15];
    const float* m4_b2  = (const float*)d_in[16];
    const float* f_wih  = (const float*)d_in[17];
    const float* f_whh  = (const float*)d_in[18];
    const float* f_bih  = (const float*)d_in[19];
    const float* f_bhh  = (const float*)d_in[20];
    const float* r_wih  = (const float*)d_in[21];
    const float* r_whh  = (const float*)d_in[22];
    const float* r_bih  = (const float*)d_in[23];
    const float* r_bhh  = (const float*)d_in[24];
    const float* p_w    = (const float*)d_in[25];
    const float* p_b    = (const float*)d_in[26];
    const float* e_w1   = (const float*)d_in[27];
    const float* e_b1   = (const float*)d_in[28];
    const float* e_w2   = (const float*)d_in[29];
    const float* e_b2   = (const float*)d_in[30];
    float* out = (float*)d_out;

    // workspace layout (bytes), total ~162.5 MB
    char* ws = (char*)d_ws;
    const size_t BIGB  = (size_t)BET_ * H_ * sizeof(ushort_t);   // 62,914,560
    const size_t COMBB = (size_t)BET_ * 128 * sizeof(ushort_t);  // 31,457,280
    const size_t X2BB  = (size_t)BVT_ * H_ * sizeof(ushort_t);   //  4,194,304
    ushort_t* R1   = (ushort_t*)(ws);
    ushort_t* R2   = (ushort_t*)(ws + BIGB);
    ushort_t* COMB = (ushort_t*)(ws + 2 * BIGB);
    ushort_t* X2b  = (ushort_t*)(ws + 2 * BIGB + COMBB);
    ushort_t* Wb   = (ushort_t*)(ws + 2 * BIGB + COMBB + X2BB);
    // node-stage f32 scratch lives inside (dead) R1 region
    float* X  = (float*)(ws);
    float* XH = (float*)(ws + (size_t)BVT_ * H_ * sizeof(float));
    // packed bf16 weight offsets (elements)
    const ushort_t* wb_ef2  = Wb + 0;
    const ushort_t* wb_m41  = Wb + 65536;
    const ushort_t* wb_m42  = Wb + 262144;
    const ushort_t* wb_fwih = Wb + 327680;
    const ushort_t* wb_rwih = Wb + 393216;
    const ushort_t* wb_ew1  = Wb + 458752;

    dim3 blk(256);
    dim3 gM(BET_ / 128, 2);    // MFMA edge GEMMs: 960 x 2
    dim3 gE64(BET_ / 64, 4);   // VALU edge GEMM (ein)
    dim3 gN(BVT_ / 64, 4);     // VALU node GEMMs

    // 0. weights -> bf16
    wconv_k<<<1920, blk, 0, stream>>>(ef_w2, m4_w1, m4_w2, f_wih, r_wih, e_w1, Wb);
    // 1. edge filter MLP
    gemm_ein_k<<<gE64, blk, 0, stream>>>(ear, epos, ef_w1, ef_b1, R1);
    mfma_gemm_k<256, 1><<<gM, blk, 0, stream>>>(R1, wb_ef2, ef_b2, nullptr, R2);     // EA
    // 2. edge2node + residual
    e2n_k<<<BVT_, blk, 0, stream>>>(R2, rel, res_w, res_b, X);
    // 3. mlp3 (node rows, f32 VALU)
    gemm_t<float, float><<<gN, blk, 0, stream>>>(X, m3_w1, m3_b1, nullptr, XH, BVT_, H_, H_, 1);
    gemm_t<float, ushort_t><<<gN, blk, 0, stream>>>(XH, m3_w2, m3_b2, nullptr, X2b, BVT_, H_, H_, 1);
    // 4. node2edge gather + mlp4
    mfma_mlp4_k<<<gM, blk, 0, stream>>>(X2b, R2, wb_m41, m4_b1, R1);
    mfma_gemm_k<256, 1><<<gM, blk, 0, stream>>>(R1, wb_m42, m4_b2, nullptr, R2);     // M2
    // 5. LSTM: gate GEMM then 4-wave cooperative MFMA scan, per direction
    mfma_gemm_k<256, 0><<<gM, blk, 0, stream>>>(R2, wb_fwih, f_bih, f_bhh, R1);      // GF
    lstm_mfma4_k<<<BE_ / 16, blk, 0, stream>>>(R1, f_whh, COMB, 0);
    mfma_gemm_k<256, 0><<<gM, blk, 0, stream>>>(R2, wb_rwih, r_bih, r_bhh, R1);      // GR
    lstm_mfma4_k<<<BE_ / 16, blk, 0, stream>>>(R1, r_whh, COMB, 1);
    // 6. heads
    prior_k<<<BET_ / 4, blk, 0, stream>>>(COMB, p_w, p_b, out);
    mfma_gemm_k<128, 1><<<gM, blk, 0, stream>>>(COMB, wb_ew1, e_b1, nullptr, R2);    // ENCH
    encout_k<<<BET_ / 4, blk, 0, stream>>>(R2, e_w2, e_b2, out);
}

// Round 7
// 562.669 us; speedup vs baseline: 4.7055x; 1.0235x over previous
//
#include <hip/hip_runtime.h>
#include <cstdint>
#include <cstddef>
#include <type_traits>

// Problem constants
#define B_ 8
#define V_ 16
#define T_ 64
#define E_ 240          // V*(V-1)
#define H_ 256
#define RH_ 64
#define K_ 2
#define DIN_ 6
#define BET_ (B_*E_*T_)   // 122880
#define BVT_ (B_*V_*T_)   // 8192
#define BE_ (B_*E_)       // 1920

typedef unsigned short ushort_t;
typedef unsigned int u32;
typedef __attribute__((ext_vector_type(8))) short bf16x8;
typedef __attribute__((ext_vector_type(4))) float f32x4;

__device__ __forceinline__ float eluf(float x) { return x > 0.f ? x : __expf(x) - 1.f; }
__device__ __forceinline__ float fsig(float x) { return 1.f / (1.f + __expf(-x)); }
__device__ __forceinline__ float ftanh_(float x) {
    float y = fminf(fmaxf(x, -8.f), 8.f);
    float e = __expf(2.f * y);
    return (e - 1.f) / (e + 1.f);
}
__device__ __forceinline__ float b2f(ushort_t u) {
    union { float f; uint32_t i; } v; v.i = ((uint32_t)u) << 16; return v.f;
}
__device__ __forceinline__ ushort_t f2b(float f) {
    union { float f; uint32_t i; } v; v.f = f;
    uint32_t r = (v.i + 0x7FFFu + ((v.i >> 16) & 1u)) >> 16;
    return (ushort_t)r;
}

// async global->LDS, 16B per lane; LDS dest = wave-uniform base + lane*16
__device__ __forceinline__ void gll16(const void* g, void* l) {
    __builtin_amdgcn_global_load_lds(
        (const __attribute__((address_space(1))) u32*)g,
        (__attribute__((address_space(3))) u32*)l, 16, 0, 0);
}

// ===========================================================================
// MFMA bf16 GEMM (kept for ef2): C = act(A@W.T + b1 (+b2)), bf16 out. N=256.
// BM=128, BN=128, K-step 32, 4 waves, 3-buffer pipeline.
// ===========================================================================
template<int KD, int ACT>
__global__ __launch_bounds__(256) void mfma_gemm_k(
    const ushort_t* __restrict__ A, const ushort_t* __restrict__ Wt,
    const float* __restrict__ b1, const float* __restrict__ b2,
    ushort_t* __restrict__ C)
{
    __shared__ ushort_t lds[3][2][8][512];   // 48 KB
    const int tid = threadIdx.x;
    const int lane = tid & 63;
    const int w = tid >> 6;
    const int wr = w >> 1, wc = w & 1;
    const int m0 = blockIdx.x * 128;
    const int n0 = blockIdx.y * 128;
    const int r16 = lane & 15, kq = lane >> 4;
    constexpr int NKT = KD / 32;

    const ushort_t* Abase[2];
    const ushort_t* Wbase[2];
    #pragma unroll
    for (int ff = 0; ff < 2; ++ff) {
        int f = 2 * w + ff;
        Abase[ff] = A  + (size_t)(m0 + f * 16 + r16) * KD + kq * 8;
        Wbase[ff] = Wt + (size_t)(n0 + f * 16 + r16) * KD + kq * 8;
    }

    f32x4 acc[4][4];
    #pragma unroll
    for (int i = 0; i < 4; ++i)
        #pragma unroll
        for (int j = 0; j < 4; ++j)
            acc[i][j] = (f32x4){0.f, 0.f, 0.f, 0.f};

#define STAGE_G(bufi, kt) do {                                              \
    _Pragma("unroll")                                                       \
    for (int ff = 0; ff < 2; ++ff) {                                        \
        int f = 2 * w + ff;                                                 \
        gll16(Abase[ff] + (kt) * 32, &lds[bufi][0][f][0]);                  \
        gll16(Wbase[ff] + (kt) * 32, &lds[bufi][1][f][0]);                  \
    } } while (0)

#define COMPUTE_G(bufi) do {                                                \
    bf16x8 af[4], bfr[4];                                                   \
    _Pragma("unroll")                                                       \
    for (int mf = 0; mf < 4; ++mf) af[mf] = *(const bf16x8*)&lds[bufi][0][wr*4+mf][lane*8]; \
    _Pragma("unroll")                                                       \
    for (int nf = 0; nf < 4; ++nf) bfr[nf] = *(const bf16x8*)&lds[bufi][1][wc*4+nf][lane*8]; \
    _Pragma("unroll")                                                       \
    for (int mf = 0; mf < 4; ++mf)                                          \
        _Pragma("unroll")                                                   \
        for (int nf = 0; nf < 4; ++nf)                                      \
            acc[mf][nf] = __builtin_amdgcn_mfma_f32_16x16x32_bf16(bfr[nf], af[mf], acc[mf][nf], 0, 0, 0); \
    } while (0)

    STAGE_G(0, 0);
    STAGE_G(1, 1);
    for (int kt = 0; kt < NKT; ++kt) {
        const int cur = kt % 3;
        if (kt < NKT - 1) { asm volatile("s_waitcnt vmcnt(4)" ::: "memory"); }
        else              { asm volatile("s_waitcnt vmcnt(0)" ::: "memory"); }
        __builtin_amdgcn_s_barrier();
        if (kt + 2 < NKT) {
            const int nxt = (kt + 2) % 3;
            STAGE_G(nxt, kt + 2);
        }
        COMPUTE_G(cur);
    }

    #pragma unroll
    for (int mf = 0; mf < 4; ++mf) {
        int mrow = m0 + wr * 64 + mf * 16 + r16;
        #pragma unroll
        for (int nf = 0; nf < 4; ++nf) {
            int nb = n0 + wc * 64 + nf * 16 + kq * 4;
            float4 bb = *(const float4*)&b1[nb];
            if (b2) {
                float4 b2v = *(const float4*)&b2[nb];
                bb.x += b2v.x; bb.y += b2v.y; bb.z += b2v.z; bb.w += b2v.w;
            }
            float v0 = acc[mf][nf][0] + bb.x;
            float v1 = acc[mf][nf][1] + bb.y;
            float v2 = acc[mf][nf][2] + bb.z;
            float v3 = acc[mf][nf][3] + bb.w;
            if (ACT) { v0 = eluf(v0); v1 = eluf(v1); v2 = eluf(v2); v3 = eluf(v3); }
            ushort4 o; o.x = f2b(v0); o.y = f2b(v1); o.z = f2b(v2); o.w = f2b(v3);
            *(ushort4*)&C[(size_t)mrow * 256 + nb] = o;
        }
    }
#undef STAGE_G
#undef COMPUTE_G
}

// ===========================================================================
// mlp4 layer-1 MFMA GEMM with fused gather, KD=768, 3-buffer pipeline.
// ===========================================================================
__global__ __launch_bounds__(256) void mfma_mlp4_k(
    const ushort_t* __restrict__ X2b, const ushort_t* __restrict__ EA,
    const ushort_t* __restrict__ Wt, const float* __restrict__ b1,
    ushort_t* __restrict__ C)
{
    __shared__ ushort_t lds[3][2][8][512];   // 48 KB
    const int tid = threadIdx.x;
    const int lane = tid & 63;
    const int w = tid >> 6;
    const int wr = w >> 1, wc = w & 1;
    const int m0 = blockIdx.x * 128;
    const int n0 = blockIdx.y * 128;
    const int r16 = lane & 15, kq = lane >> 4;
    constexpr int NKT = 24;

    const ushort_t* AS[2]; const ushort_t* AR[2]; const ushort_t* AE[2];
    const ushort_t* Wbase[2];
    #pragma unroll
    for (int ff = 0; ff < 2; ++ff) {
        int f = 2 * w + ff;
        int m = m0 + f * 16 + r16;
        int be = m >> 6, t = m & 63;
        int b = be / E_, e = be % E_;
        int s = e / (V_ - 1);
        int r0 = e % (V_ - 1);
        int rr = r0 + (r0 >= s ? 1 : 0);
        AS[ff] = X2b + ((size_t)((b * V_ + s) * T_ + t)) * H_ + kq * 8;
        AR[ff] = X2b + ((size_t)((b * V_ + rr) * T_ + t)) * H_ + kq * 8;
        AE[ff] = EA + (size_t)m * H_ + kq * 8;
        Wbase[ff] = Wt + (size_t)(n0 + f * 16 + r16) * 768 + kq * 8;
    }

    f32x4 acc[4][4];
    #pragma unroll
    for (int i = 0; i < 4; ++i)
        #pragma unroll
        for (int j = 0; j < 4; ++j)
            acc[i][j] = (f32x4){0.f, 0.f, 0.f, 0.f};

#define STAGE_M(bufi, kt) do {                                              \
    int kk = (kt) * 32;                                                     \
    _Pragma("unroll")                                                       \
    for (int ff = 0; ff < 2; ++ff) {                                        \
        int f = 2 * w + ff;                                                 \
        const ushort_t* ga = (kk < 256) ? AS[ff] + kk                       \
                           : (kk < 512) ? AR[ff] + (kk - 256)               \
                                        : AE[ff] + (kk - 512);              \
        gll16(ga, &lds[bufi][0][f][0]);                                     \
        gll16(Wbase[ff] + kk, &lds[bufi][1][f][0]);                         \
    } } while (0)

#define COMPUTE_M(bufi) do {                                                \
    bf16x8 af[4], bfr[4];                                                   \
    _Pragma("unroll")                                                       \
    for (int mf = 0; mf < 4; ++mf) af[mf] = *(const bf16x8*)&lds[bufi][0][wr*4+mf][lane*8]; \
    _Pragma("unroll")                                                       \
    for (int nf = 0; nf < 4; ++nf) bfr[nf] = *(const bf16x8*)&lds[bufi][1][wc*4+nf][lane*8]; \
    _Pragma("unroll")                                                       \
    for (int mf = 0; mf < 4; ++mf)                                          \
        _Pragma("unroll")                                                   \
        for (int nf = 0; nf < 4; ++nf)                                      \
            acc[mf][nf] = __builtin_amdgcn_mfma_f32_16x16x32_bf16(bfr[nf], af[mf], acc[mf][nf], 0, 0, 0); \
    } while (0)

    STAGE_M(0, 0);
    STAGE_M(1, 1);
    for (int kt = 0; kt < NKT; ++kt) {
        const int cur = kt % 3;
        if (kt < NKT - 1) { asm volatile("s_waitcnt vmcnt(4)" ::: "memory"); }
        else              { asm volatile("s_waitcnt vmcnt(0)" ::: "memory"); }
        __builtin_amdgcn_s_barrier();
        if (kt + 2 < NKT) {
            const int nxt = (kt + 2) % 3;
            STAGE_M(nxt, kt + 2);
        }
        COMPUTE_M(cur);
    }

    #pragma unroll
    for (int mf = 0; mf < 4; ++mf) {
        int mrow = m0 + wr * 64 + mf * 16 + r16;
        #pragma unroll
        for (int nf = 0; nf < 4; ++nf) {
            int nb = n0 + wc * 64 + nf * 16 + kq * 4;
            float4 bb = *(const float4*)&b1[nb];
            float v0 = eluf(acc[mf][nf][0] + bb.x);
            float v1 = eluf(acc[mf][nf][1] + bb.y);
            float v2 = eluf(acc[mf][nf][2] + bb.z);
            float v3 = eluf(acc[mf][nf][3] + bb.w);
            ushort4 o; o.x = f2b(v0); o.y = f2b(v1); o.z = f2b(v2); o.w = f2b(v3);
            *(ushort4*)&C[(size_t)mrow * 256 + nb] = o;
        }
    }
#undef STAGE_M
#undef COMPUTE_M
}

// ===========================================================================
// FUSED: M2 = elu(T1@m4w2+b) kept in LDS (fragment order), then
// GF = M2@fwih + (f_bih+f_bhh) -> T1 (in-place), GR = M2@rwih + (r_bih+r_bhh).
// 8 waves (512 thr), 128 rows/block, N=256. 24 unified K-steps.
// M2 LDS write mapping: value (row,col) -> frag=row>>4, kt=col>>5,
// lane' = (row&15)+16*((col&31)>>3), elem = col&7  (exact A-frag layout).
// ===========================================================================
__global__ __launch_bounds__(512) void fused_gates_k(
    ushort_t* __restrict__ T1, ushort_t* __restrict__ GR,
    const ushort_t* __restrict__ w_m42, const ushort_t* __restrict__ w_fih,
    const ushort_t* __restrict__ w_rih, const float* __restrict__ m4_b2,
    const float* __restrict__ f_bih, const float* __restrict__ f_bhh,
    const float* __restrict__ r_bih, const float* __restrict__ r_bhh)
{
    __shared__ ushort_t sA[2][8][512];    // 16 KB
    __shared__ ushort_t sW[2][16][512];   // 32 KB
    __shared__ ushort_t M2[8][8][512];    // 64 KB  (112 KB total)
    const int tid = threadIdx.x;
    const int lane = tid & 63;
    const int w = tid >> 6;            // 0..7
    const int wr = w >> 2, wc = w & 3;
    const int m0 = blockIdx.x * 128;
    const int r16 = lane & 15, kq = lane >> 4;

    const ushort_t* Asrc = T1 + (size_t)(m0 + w * 16 + r16) * 256 + kq * 8;
    const size_t woffA = (size_t)((2 * w) * 16 + r16) * 256 + kq * 8;
    const size_t woffB = (size_t)((2 * w + 1) * 16 + r16) * 256 + kq * 8;

    f32x4 acc[4][4];
    #pragma unroll
    for (int i = 0; i < 4; ++i)
        #pragma unroll
        for (int j = 0; j < 4; ++j)
            acc[i][j] = (f32x4){0.f, 0.f, 0.f, 0.f};

#define FG_STAGE(bufi, s) do {                                               \
    int kt_ = (s) & 7;                                                       \
    if ((s) < 8) gll16(Asrc + kt_ * 32, &sA[bufi][w][lane * 8]);             \
    const ushort_t* Wp_ = ((s) < 8) ? w_m42 : ((s) < 16) ? w_fih : w_rih;    \
    gll16(Wp_ + woffA + kt_ * 32, &sW[bufi][2 * w][lane * 8]);               \
    gll16(Wp_ + woffB + kt_ * 32, &sW[bufi][2 * w + 1][lane * 8]);           \
} while (0)

    FG_STAGE(0, 0);
    asm volatile("s_waitcnt vmcnt(0)" ::: "memory");
    __builtin_amdgcn_s_barrier();

    for (int s = 0; s < 24; ++s) {
        const int buf = s & 1;
        if (s < 23) FG_STAGE(buf ^ 1, s + 1);
        const int kt = s & 7;
        bf16x8 af[4], bfr[4];
        if (s < 8) {
            #pragma unroll
            for (int mf = 0; mf < 4; ++mf)
                af[mf] = *(const bf16x8*)&sA[buf][wr * 4 + mf][lane * 8];
        } else {
            #pragma unroll
            for (int mf = 0; mf < 4; ++mf)
                af[mf] = *(const bf16x8*)&M2[wr * 4 + mf][kt][lane * 8];
        }
        #pragma unroll
        for (int nf = 0; nf < 4; ++nf)
            bfr[nf] = *(const bf16x8*)&sW[buf][wc * 4 + nf][lane * 8];
        #pragma unroll
        for (int mf = 0; mf < 4; ++mf)
            #pragma unroll
            for (int nf = 0; nf < 4; ++nf)
                acc[mf][nf] = __builtin_amdgcn_mfma_f32_16x16x32_bf16(bfr[nf], af[mf], acc[mf][nf], 0, 0, 0);

        if (s == 7) {           // M2 epilogue -> LDS (fragment order), reset acc
            #pragma unroll
            for (int mf = 0; mf < 4; ++mf) {
                #pragma unroll
                for (int nf = 0; nf < 4; ++nf) {
                    int col = wc * 64 + nf * 16 + kq * 4;
                    float4 bb = *(const float4*)&m4_b2[col];
                    ushort4 o;
                    o.x = f2b(eluf(acc[mf][nf][0] + bb.x));
                    o.y = f2b(eluf(acc[mf][nf][1] + bb.y));
                    o.z = f2b(eluf(acc[mf][nf][2] + bb.z));
                    o.w = f2b(eluf(acc[mf][nf][3] + bb.w));
                    int ktw = wc * 2 + (nf >> 1);
                    int lanew = r16 + 16 * (((nf & 1) << 1) | (kq >> 1));
                    *(ushort4*)&M2[wr * 4 + mf][ktw][lanew * 8 + (kq & 1) * 4] = o;
                    acc[mf][nf] = (f32x4){0.f, 0.f, 0.f, 0.f};
                }
            }
            asm volatile("s_waitcnt lgkmcnt(0)" ::: "memory");
        }
        if (s == 15) {          // GF epilogue -> T1 (in-place), reset acc
            #pragma unroll
            for (int mf = 0; mf < 4; ++mf) {
                int row = m0 + wr * 64 + mf * 16 + r16;
                #pragma unroll
                for (int nf = 0; nf < 4; ++nf) {
                    int col = wc * 64 + nf * 16 + kq * 4;
                    float4 b1v = *(const float4*)&f_bih[col];
                    float4 b2v = *(const float4*)&f_bhh[col];
                    ushort4 o;
                    o.x = f2b(acc[mf][nf][0] + b1v.x + b2v.x);
                    o.y = f2b(acc[mf][nf][1] + b1v.y + b2v.y);
                    o.z = f2b(acc[mf][nf][2] + b1v.z + b2v.z);
                    o.w = f2b(acc[mf][nf][3] + b1v.w + b2v.w);
                    *(ushort4*)&T1[(size_t)row * 256 + col] = o;
                    acc[mf][nf] = (f32x4){0.f, 0.f, 0.f, 0.f};
                }
            }
        }
        if (s == 23) {          // GR epilogue
            #pragma unroll
            for (int mf = 0; mf < 4; ++mf) {
                int row = m0 + wr * 64 + mf * 16 + r16;
                #pragma unroll
                for (int nf = 0; nf < 4; ++nf) {
                    int col = wc * 64 + nf * 16 + kq * 4;
                    float4 b1v = *(const float4*)&r_bih[col];
                    float4 b2v = *(const float4*)&r_bhh[col];
                    ushort4 o;
                    o.x = f2b(acc[mf][nf][0] + b1v.x + b2v.x);
                    o.y = f2b(acc[mf][nf][1] + b1v.y + b2v.y);
                    o.z = f2b(acc[mf][nf][2] + b1v.z + b2v.z);
                    o.w = f2b(acc[mf][nf][3] + b1v.w + b2v.w);
                    *(ushort4*)&GR[(size_t)row * 256 + col] = o;
                }
            }
        }
        asm volatile("s_waitcnt vmcnt(0)" ::: "memory");
        __builtin_amdgcn_s_barrier();
    }
#undef FG_STAGE
}

// ===========================================================================
// FUSED: ENCH = elu(COMB@e_w1.T + e_b1) in regs, then out = ENCH@e_w2.T + e_b2
// with transpose-scatter. 8 waves, 128 rows/block, K=128 (4 steps).
// ===========================================================================
__global__ __launch_bounds__(512) void fused_enc_k(
    const ushort_t* __restrict__ COMB, const ushort_t* __restrict__ w_e1,
    const float* __restrict__ e_b1, const float* __restrict__ e_w2,
    const float* __restrict__ e_b2, float* __restrict__ out)
{
    __shared__ ushort_t sA[2][8][512];    // 16 KB
    __shared__ ushort_t sW[2][16][512];   // 32 KB
    __shared__ float part[128][4][2];     // 4 KB
    const int tid = threadIdx.x;
    const int lane = tid & 63;
    const int w = tid >> 6;
    const int wr = w >> 2, wc = w & 3;
    const int m0 = blockIdx.x * 128;
    const int r16 = lane & 15, kq = lane >> 4;

    const ushort_t* Asrc = COMB + (size_t)(m0 + w * 16 + r16) * 128 + kq * 8;
    const size_t woffA = (size_t)((2 * w) * 16 + r16) * 128 + kq * 8;
    const size_t woffB = (size_t)((2 * w + 1) * 16 + r16) * 128 + kq * 8;

    float4 w2v[2][4];
    #pragma unroll
    for (int j = 0; j < 2; ++j)
        #pragma unroll
        for (int nf = 0; nf < 4; ++nf)
            w2v[j][nf] = *(const float4*)&e_w2[j * 256 + wc * 64 + nf * 16 + kq * 4];

    f32x4 acc[4][4];
    #pragma unroll
    for (int i = 0; i < 4; ++i)
        #pragma unroll
        for (int j = 0; j < 4; ++j)
            acc[i][j] = (f32x4){0.f, 0.f, 0.f, 0.f};

#define FE_STAGE(bufi, kt_) do {                                             \
    gll16(Asrc + (kt_) * 32, &sA[bufi][w][lane * 8]);                        \
    gll16(w_e1 + woffA + (kt_) * 32, &sW[bufi][2 * w][lane * 8]);            \
    gll16(w_e1 + woffB + (kt_) * 32, &sW[bufi][2 * w + 1][lane * 8]);        \
} while (0)

    FE_STAGE(0, 0);
    asm volatile("s_waitcnt vmcnt(0)" ::: "memory");
    __builtin_amdgcn_s_barrier();

    for (int s = 0; s < 4; ++s) {
        const int buf = s & 1;
        if (s < 3) FE_STAGE(buf ^ 1, s + 1);
        bf16x8 af[4], bfr[4];
        #pragma unroll
        for (int mf = 0; mf < 4; ++mf)
            af[mf] = *(const bf16x8*)&sA[buf][wr * 4 + mf][lane * 8];
        #pragma unroll
        for (int nf = 0; nf < 4; ++nf)
            bfr[nf] = *(const bf16x8*)&sW[buf][wc * 4 + nf][lane * 8];
        #pragma unroll
        for (int mf = 0; mf < 4; ++mf)
            #pragma unroll
            for (int nf = 0; nf < 4; ++nf)
                acc[mf][nf] = __builtin_amdgcn_mfma_f32_16x16x32_bf16(bfr[nf], af[mf], acc[mf][nf], 0, 0, 0);
        asm volatile("s_waitcnt vmcnt(0)" ::: "memory");
        __builtin_amdgcn_s_barrier();
    }

    // epilogue: elu + dot with e_w2, reduce across kq groups, then across waves
    #pragma unroll
    for (int mf = 0; mf < 4; ++mf) {
        float s0 = 0.f, s1 = 0.f;
        #pragma unroll
        for (int nf = 0; nf < 4; ++nf) {
            int col = wc * 64 + nf * 16 + kq * 4;
            float4 bb = *(const float4*)&e_b1[col];
            float v0 = eluf(acc[mf][nf][0] + bb.x);
            float v1 = eluf(acc[mf][nf][1] + bb.y);
            float v2 = eluf(acc[mf][nf][2] + bb.z);
            float v3 = eluf(acc[mf][nf][3] + bb.w);
            s0 += v0 * w2v[0][nf].x + v1 * w2v[0][nf].y + v2 * w2v[0][nf].z + v3 * w2v[0][nf].w;
            s1 += v0 * w2v[1][nf].x + v1 * w2v[1][nf].y + v2 * w2v[1][nf].z + v3 * w2v[1][nf].w;
        }
        s0 += __shfl_xor(s0, 16, 64); s0 += __shfl_xor(s0, 32, 64);
        s1 += __shfl_xor(s1, 16, 64); s1 += __shfl_xor(s1, 32, 64);
        if (kq == 0) {
            part[wr * 64 + mf * 16 + r16][wc][0] = s0;
            part[wr * 64 + mf * 16 + r16][wc][1] = s1;
        }
    }
    __syncthreads();
    if (tid < 256) {
        int row = tid >> 1, k = tid & 1;
        float v = part[row][0][k] + part[row][1][k] + part[row][2][k] + part[row][3][k] + e_b2[k];
        int gr = m0 + row;
        int be = gr >> 6, t = gr & 63;
        int e = be % E_, b = be / E_;
        out[(size_t)(B_ * T_ * E_ * K_) + (((size_t)b * T_ + t) * E_ + e) * K_ + k] = v;
    }
#undef FE_STAGE
}

// ===========================================================================
// weights f32 -> bf16 (packed): ef_w2 | m4_w1 | m4_w2 | f_wih | r_wih | e_w1
// ===========================================================================
__global__ __launch_bounds__(256) void wconv_k(
    const float* __restrict__ ef_w2, const float* __restrict__ m4_w1,
    const float* __restrict__ m4_w2, const float* __restrict__ f_wih,
    const float* __restrict__ r_wih, const float* __restrict__ e_w1,
    ushort_t* __restrict__ Wb)
{
    int i = blockIdx.x * 256 + threadIdx.x;   // < 491520
    const float* src; int off;
    if (i < 65536)       { src = ef_w2; off = i; }
    else if (i < 262144) { src = m4_w1; off = i - 65536; }
    else if (i < 327680) { src = m4_w2; off = i - 262144; }
    else if (i < 393216) { src = f_wih; off = i - 327680; }
    else if (i < 458752) { src = r_wih; off = i - 393216; }
    else                 { src = e_w1;  off = i - 458752; }
    Wb[i] = f2b(src[off]);
}

// ---------------------------------------------------------------------------
// Generic VALU GEMM (kept for mlp3 node rows): C = act(A@W.T + b1)
// ---------------------------------------------------------------------------
template<typename TA, typename TO>
__global__ __launch_bounds__(256) void gemm_t(
    const TA* __restrict__ A, const float* __restrict__ W,
    const float* __restrict__ b1, const float* __restrict__ b2,
    TO* __restrict__ C, int M, int Kd, int N, int act)
{
    __shared__ float As[16][64];
    __shared__ float Ws[16][64];
    const int m0 = blockIdx.x * 64, n0 = blockIdx.y * 64;
    const int tid = threadIdx.x;
    const int tm = tid >> 4, tn = tid & 15;
    const int lm = tid >> 2, lq = tid & 3;
    float acc[4][4] = {};
    const TA* Arow = A + (size_t)(m0 + lm) * Kd + lq * 4;
    const float* Wrow = W + (size_t)(n0 + lm) * Kd + lq * 4;
    for (int k0 = 0; k0 < Kd; k0 += 16) {
        float4 av, wv;
        if constexpr (std::is_same<TA, ushort_t>::value) {
            ushort4 u = *(const ushort4*)(Arow + k0);
            av.x = b2f(u.x); av.y = b2f(u.y); av.z = b2f(u.z); av.w = b2f(u.w);
        } else {
            av = *(const float4*)(Arow + k0);
        }
        wv = *(const float4*)(Wrow + k0);
        __syncthreads();
        As[lq*4+0][lm] = av.x; As[lq*4+1][lm] = av.y; As[lq*4+2][lm] = av.z; As[lq*4+3][lm] = av.w;
        Ws[lq*4+0][lm] = wv.x; Ws[lq*4+1][lm] = wv.y; Ws[lq*4+2][lm] = wv.z; Ws[lq*4+3][lm] = wv.w;
        __syncthreads();
        #pragma unroll
        for (int k = 0; k < 16; ++k) {
            float4 a = *(const float4*)&As[k][tm * 4];
            float4 w = *(const float4*)&Ws[k][tn * 4];
            float a_[4] = {a.x, a.y, a.z, a.w};
            float w_[4] = {w.x, w.y, w.z, w.w};
            #pragma unroll
            for (int i = 0; i < 4; ++i)
                #pragma unroll
                for (int j = 0; j < 4; ++j)
                    acc[i][j] += a_[i] * w_[j];
        }
    }
    float bb[4];
    #pragma unroll
    for (int j = 0; j < 4; ++j) {
        int n = n0 + tn * 4 + j;
        bb[j] = b1[n] + (b2 ? b2[n] : 0.f);
    }
    #pragma unroll
    for (int i = 0; i < 4; ++i) {
        float v0 = acc[i][0] + bb[0], v1 = acc[i][1] + bb[1];
        float v2 = acc[i][2] + bb[2], v3 = acc[i][3] + bb[3];
        if (act) { v0 = eluf(v0); v1 = eluf(v1); v2 = eluf(v2); v3 = eluf(v3); }
        TO* dst = C + (size_t)(m0 + tm * 4 + i) * N + (n0 + tn * 4);
        if constexpr (std::is_same<TO, ushort_t>::value) {
            ushort4 o; o.x = f2b(v0); o.y = f2b(v1); o.z = f2b(v2); o.w = f2b(v3);
            *(ushort4*)dst = o;
        } else {
            float4 o; o.x = v0; o.y = v1; o.z = v2; o.w = v3;
            *(float4*)dst = o;
        }
    }
}

// ---------------------------------------------------------------------------
// First GEMM with fused concat: A[m,c] = c<13 ? ear[m,c] : epos[m,c-13], Kd=16.
// ---------------------------------------------------------------------------
__global__ __launch_bounds__(256) void gemm_ein_k(
    const float* __restrict__ ear, const float* __restrict__ epos,
    const float* __restrict__ W, const float* __restrict__ b1,
    ushort_t* __restrict__ C)
{
    __shared__ float As[16][64];
    __shared__ float Ws[16][64];
    const int m0 = blockIdx.x * 64, n0 = blockIdx.y * 64;
    const int tid = threadIdx.x;
    const int tm = tid >> 4, tn = tid & 15;
    const int lm = tid >> 2, lq = tid & 3;
    const int m = m0 + lm;
    float a_[4];
    #pragma unroll
    for (int q = 0; q < 4; ++q) {
        int c = lq * 4 + q;
        a_[q] = (c < 13) ? ear[(size_t)m * 13 + c] : epos[(size_t)m * 3 + (c - 13)];
    }
    float4 wv = *(const float4*)(W + (size_t)(n0 + lm) * 16 + lq * 4);
    As[lq*4+0][lm] = a_[0]; As[lq*4+1][lm] = a_[1]; As[lq*4+2][lm] = a_[2]; As[lq*4+3][lm] = a_[3];
    Ws[lq*4+0][lm] = wv.x; Ws[lq*4+1][lm] = wv.y; Ws[lq*4+2][lm] = wv.z; Ws[lq*4+3][lm] = wv.w;
    __syncthreads();
    float acc[4][4] = {};
    #pragma unroll
    for (int k = 0; k < 16; ++k) {
        float4 a = *(const float4*)&As[k][tm * 4];
        float4 w = *(const float4*)&Ws[k][tn * 4];
        float aa[4] = {a.x, a.y, a.z, a.w};
        float ww[4] = {w.x, w.y, w.z, w.w};
        #pragma unroll
        for (int i = 0; i < 4; ++i)
            #pragma unroll
            for (int j = 0; j < 4; ++j)
                acc[i][j] += aa[i] * ww[j];
    }
    #pragma unroll
    for (int i = 0; i < 4; ++i) {
        ushort4 o;
        o.x = f2b(eluf(acc[i][0] + b1[n0 + tn*4 + 0]));
        o.y = f2b(eluf(acc[i][1] + b1[n0 + tn*4 + 1]));
        o.z = f2b(eluf(acc[i][2] + b1[n0 + tn*4 + 2]));
        o.w = f2b(eluf(acc[i][3] + b1[n0 + tn*4 + 3]));
        *(ushort4*)(C + (size_t)(m0 + tm * 4 + i) * H_ + (n0 + tn * 4)) = o;
    }
}

// ---------------------------------------------------------------------------
// edge2node: X[b,v,t,h] = (1/15)*sum_{e:RECV==v} EA[b,e,t,h] + rel@res_w.T + res_b
// ---------------------------------------------------------------------------
__global__ __launch_bounds__(256) void e2n_k(
    const ushort_t* __restrict__ EA, const float* __restrict__ rel,
    const float* __restrict__ res_w, const float* __restrict__ res_b,
    float* __restrict__ X)
{
    const int idx = blockIdx.x;            // (b*V+v)*T + t
    const int t = idx & (T_ - 1);
    const int bv = idx >> 6;
    const int v = bv & (V_ - 1);
    const int b = bv >> 4;
    const int h = threadIdx.x;
    float sum = 0.f;
    #pragma unroll
    for (int i = 0; i < V_; ++i) {
        if (i == v) continue;
        int jj = (v < i) ? v : v - 1;
        int e = i * (V_ - 1) + jj;
        sum += b2f(EA[(((size_t)(b * E_ + e)) * T_ + t) * H_ + h]);
    }
    const float* rp = rel + ((size_t)bv * T_ + t) * DIN_;
    float res = res_b[h];
    #pragma unroll
    for (int d = 0; d < DIN_; ++d) res += rp[d] * res_w[h * DIN_ + d];
    X[((size_t)bv * T_ + t) * H_ + h] = sum * (1.f / 15.f) + res;
}

// ===========================================================================
// MFMA LSTM scan, 4 cooperative waves per block, 16 sequences per block.
// ===========================================================================
__global__ __launch_bounds__(256) void lstm_mfma4_k(
    const ushort_t* __restrict__ G, const float* __restrict__ whh,
    ushort_t* __restrict__ COMB, int dir)
{
    __shared__ ushort_t hlds[2][1024];   // 2 x 2KB: h[seq][j] bf16, XOR-swizzled
    const int tid = threadIdx.x;
    const int lane = tid & 63;
    const int w = tid >> 6;              // wave id = j-block
    const int seq = lane & 15, kq = lane >> 4;
    const int be0 = blockIdx.x * 16;
    const int swz = (seq & 7) << 4;

    bf16x8 wf[4][2];
    #pragma unroll
    for (int a = 0; a < 4; ++a) {
        #pragma unroll
        for (int ks = 0; ks < 2; ++ks) {
            const float* p = whh + (size_t)((a * 4 + w) * 16 + seq) * 64 + ks * 32 + kq * 8;
            float4 x0 = *(const float4*)p;
            float4 x1 = *(const float4*)(p + 4);
            bf16x8 v;
            v[0] = (short)f2b(x0.x); v[1] = (short)f2b(x0.y);
            v[2] = (short)f2b(x0.z); v[3] = (short)f2b(x0.w);
            v[4] = (short)f2b(x1.x); v[5] = (short)f2b(x1.y);
            v[6] = (short)f2b(x1.z); v[7] = (short)f2b(x1.w);
            wf[a][ks] = v;
        }
    }

    const ushort_t* grow = G + ((size_t)(be0 + seq) * T_) * 256 + kq * 4;
    ushort_t* crow = COMB + ((size_t)(be0 + seq) * T_) * 128 + (dir ? 64 : 0) + 16 * w + 4 * kq;

    float c[4] = {};
    ushort4 gx[4];
    const int t0 = dir ? (T_ - 1) : 0;
    #pragma unroll
    for (int a = 0; a < 4; ++a)
        gx[a] = *(const ushort4*)(grow + (size_t)t0 * 256 + (a * 4 + w) * 16);

    for (int s = 0; s < T_; ++s) {
        const int t = dir ? (T_ - 1 - s) : s;
        f32x4 acc[4];
        #pragma unroll
        for (int a = 0; a < 4; ++a) {
            ushort4 g = gx[a];
            acc[a] = (f32x4){b2f(g.x), b2f(g.y), b2f(g.z), b2f(g.w)};
        }
        if (s < T_ - 1) {
            const int tn = dir ? (T_ - 2 - s) : (s + 1);
            #pragma unroll
            for (int a = 0; a < 4; ++a)
                gx[a] = *(const ushort4*)(grow + (size_t)tn * 256 + (a * 4 + w) * 16);
        }
        if (s) {
            bf16x8 af[2];
            #pragma unroll
            for (int ks = 0; ks < 2; ++ks) {
                int boff = (seq * 128 + ks * 64 + kq * 16) ^ swz;
                af[ks] = *(const bf16x8*)((const char*)hlds[(s - 1) & 1] + boff);
            }
            #pragma unroll
            for (int a = 0; a < 4; ++a) {
                acc[a] = __builtin_amdgcn_mfma_f32_16x16x32_bf16(wf[a][0], af[0], acc[a], 0, 0, 0);
                acc[a] = __builtin_amdgcn_mfma_f32_16x16x32_bf16(wf[a][1], af[1], acc[a], 0, 0, 0);
            }
        }
        float hh[4];
        #pragma unroll
        for (int r = 0; r < 4; ++r) {
            float zi = acc[0][r], zf = acc[1][r], zg = acc[2][r], zo = acc[3][r];
            float cc = fsig(zf) * c[r] + fsig(zi) * ftanh_(zg);
            c[r] = cc;
            hh[r] = fsig(zo) * ftanh_(cc);
        }
        ushort4 hv;
        hv.x = f2b(hh[0]); hv.y = f2b(hh[1]); hv.z = f2b(hh[2]); hv.w = f2b(hh[3]);
        int wb = (seq * 128 + 32 * w + 8 * kq) ^ swz;
        *(ushort4*)((char*)hlds[s & 1] + wb) = hv;
        *(ushort4*)(crow + (size_t)t * 128) = hv;
        asm volatile("s_waitcnt lgkmcnt(0)" ::: "memory");
        __builtin_amdgcn_sched_barrier(0);
        __builtin_amdgcn_s_barrier();
    }
}

// ---------------------------------------------------------------------------
// prior head: reads fwd hidden from comb[:, 0:64] (row stride 128)
// ---------------------------------------------------------------------------
__global__ __launch_bounds__(256) void prior_k(
    const ushort_t* __restrict__ COMB, const float* __restrict__ p_w,
    const float* __restrict__ p_b, float* __restrict__ out)
{
    const int row = blockIdx.x * 4 + (threadIdx.x >> 6);  // [0, BET)
    const int lane = threadIdx.x & 63;
    float hf = b2f(COMB[(size_t)row * 128 + lane]);
    float v0 = hf * p_w[lane];
    float v1 = hf * p_w[64 + lane];
    #pragma unroll
    for (int off = 32; off > 0; off >>= 1) {
        v0 += __shfl_down(v0, off, 64);
        v1 += __shfl_down(v1, off, 64);
    }
    if (lane == 0) {
        int t = row & (T_ - 1);
        int be = row >> 6;
        int e = be % E_, b = be / E_;
        size_t o = (((size_t)b * T_ + t) * E_ + e) * K_;
        out[o] = v0 + p_b[0];
        out[o + 1] = v1 + p_b[1];
    }
}

// ---------------------------------------------------------------------------
extern "C" void kernel_launch(void* const* d_in, const int* in_sizes, int n_in,
                              void* d_out, int out_size, void* d_ws, size_t ws_size,
                              hipStream_t stream)
{
    const float* rel    = (const float*)d_in[0];
    const float* ear    = (const float*)d_in[1];
    const float* epos   = (const float*)d_in[2];
    const float* ef_w1  = (const float*)d_in[3];
    const float* ef_b1  = (const float*)d_in[4];
    const float* ef_w2  = (const float*)d_in[5];
    const float* ef_b2  = (const float*)d_in[6];
    const float* res_w  = (const float*)d_in[7];
    const float* res_b  = (const float*)d_in[8];
    const float* m3_w1  = (const float*)d_in[9];
    const float* m3_b1  = (const float*)d_in[10];
    const float* m3_w2  = (const float*)d_in[11];
    const float* m3_b2  = (const float*)d_in[12];
    const float* m4_w1  = (const float*)d_in[13];
    const float* m4_b1  = (const float*)d_in[14];
    const float* m4_w2  = (const float*)d_in[15];
    const float* m4_b2  = (const float*)d_in[16];
    const float* f_wih  = (const float*)d_in[17];
    const float* f_whh  = (const float*)d_in[18];
    const float* f_bih  = (const float*)d_in[19];
    const float* f_bhh  = (const float*)d_in[20];
    const float* r_wih  = (const float*)d_in[21];
    const float* r_whh  = (const float*)d_in[22];
    const float* r_bih  = (const float*)d_in[23];
    const float* r_bhh  = (const float*)d_in[24];
    const float* p_w    = (const float*)d_in[25];
    const float* p_b    = (const float*)d_in[26];
    const float* e_w1   = (const float*)d_in[27];
    const float* e_b1   = (const float*)d_in[28];
    const float* e_w2   = (const float*)d_in[29];
    const float* e_b2   = (const float*)d_in[30];
    float* out = (float*)d_out;

    // workspace layout (bytes), total ~162.5 MB
    char* ws = (char*)d_ws;
    const size_t BIGB  = (size_t)BET_ * H_ * sizeof(ushort_t);   // 62,914,560
    const size_t COMBB = (size_t)BET_ * 128 * sizeof(ushort_t);  // 31,457,280
    const size_t X2BB  = (size_t)BVT_ * H_ * sizeof(ushort_t);   //  4,194,304
    ushort_t* R1   = (ushort_t*)(ws);
    ushort_t* R2   = (ushort_t*)(ws + BIGB);
    ushort_t* COMB = (ushort_t*)(ws + 2 * BIGB);
    ushort_t* X2b  = (ushort_t*)(ws + 2 * BIGB + COMBB);
    ushort_t* Wb   = (ushort_t*)(ws + 2 * BIGB + COMBB + X2BB);
    // node-stage f32 scratch lives inside (dead) R1 region
    float* X  = (float*)(ws);
    float* XH = (float*)(ws + (size_t)BVT_ * H_ * sizeof(float));
    // packed bf16 weight offsets (elements)
    const ushort_t* wb_ef2  = Wb + 0;
    const ushort_t* wb_m41  = Wb + 65536;
    const ushort_t* wb_m42  = Wb + 262144;
    const ushort_t* wb_fwih = Wb + 327680;
    const ushort_t* wb_rwih = Wb + 393216;
    const ushort_t* wb_ew1  = Wb + 458752;

    dim3 blk(256);
    dim3 gM(BET_ / 128, 2);    // MFMA edge GEMMs: 960 x 2
    dim3 gE64(BET_ / 64, 4);   // VALU edge GEMM (ein)
    dim3 gN(BVT_ / 64, 4);     // VALU node GEMMs

    // 0. weights -> bf16
    wconv_k<<<1920, blk, 0, stream>>>(ef_w2, m4_w1, m4_w2, f_wih, r_wih, e_w1, Wb);
    // 1. edge filter MLP
    gemm_ein_k<<<gE64, blk, 0, stream>>>(ear, epos, ef_w1, ef_b1, R1);
    mfma_gemm_k<256, 1><<<gM, blk, 0, stream>>>(R1, wb_ef2, ef_b2, nullptr, R2);     // EA
    // 2. edge2node + residual
    e2n_k<<<BVT_, blk, 0, stream>>>(R2, rel, res_w, res_b, X);
    // 3. mlp3 (node rows, f32 VALU)
    gemm_t<float, float><<<gN, blk, 0, stream>>>(X, m3_w1, m3_b1, nullptr, XH, BVT_, H_, H_, 1);
    gemm_t<float, ushort_t><<<gN, blk, 0, stream>>>(XH, m3_w2, m3_b2, nullptr, X2b, BVT_, H_, H_, 1);
    // 4. node2edge gather + mlp4 layer 1
    mfma_mlp4_k<<<gM, blk, 0, stream>>>(X2b, R2, wb_m41, m4_b1, R1);                 // T1
    // 5. FUSED: mlp4-l2 + both gate GEMMs (M2 stays in LDS)
    fused_gates_k<<<BET_ / 128, dim3(512), 0, stream>>>(
        R1, R2, wb_m42, wb_fwih, wb_rwih, m4_b2, f_bih, f_bhh, r_bih, r_bhh);
    // 6. LSTM scans (GF in R1, GR in R2)
    lstm_mfma4_k<<<BE_ / 16, blk, 0, stream>>>(R1, f_whh, COMB, 0);
    lstm_mfma4_k<<<BE_ / 16, blk, 0, stream>>>(R2, r_whh, COMB, 1);
    // 7. heads
    prior_k<<<BET_ / 4, blk, 0, stream>>>(COMB, p_w, p_b, out);
    fused_enc_k<<<BET_ / 128, dim3(512), 0, stream>>>(COMB, wb_ew1, e_b1, e_w2, e_b2, out);
}

// Round 8
// 493.892 us; speedup vs baseline: 5.3608x; 1.1393x over previous
//
#include <hip/hip_runtime.h>
#include <cstdint>
#include <cstddef>
#include <type_traits>

// Problem constants
#define B_ 8
#define V_ 16
#define T_ 64
#define E_ 240          // V*(V-1)
#define H_ 256
#define RH_ 64
#define K_ 2
#define DIN_ 6
#define BET_ (B_*E_*T_)   // 122880
#define BVT_ (B_*V_*T_)   // 8192
#define BE_ (B_*E_)       // 1920

typedef unsigned short ushort_t;
typedef unsigned int u32;
typedef __attribute__((ext_vector_type(8))) short bf16x8;
typedef __attribute__((ext_vector_type(4))) float f32x4;

__device__ __forceinline__ float eluf(float x) { return x > 0.f ? x : __expf(x) - 1.f; }
__device__ __forceinline__ float fsig(float x) { return 1.f / (1.f + __expf(-x)); }
__device__ __forceinline__ float ftanh_(float x) {
    float y = fminf(fmaxf(x, -8.f), 8.f);
    float e = __expf(2.f * y);
    return (e - 1.f) / (e + 1.f);
}
__device__ __forceinline__ float b2f(ushort_t u) {
    union { float f; uint32_t i; } v; v.i = ((uint32_t)u) << 16; return v.f;
}
__device__ __forceinline__ ushort_t f2b(float f) {
    union { float f; uint32_t i; } v; v.f = f;
    uint32_t r = (v.i + 0x7FFFu + ((v.i >> 16) & 1u)) >> 16;
    return (ushort_t)r;
}

// async global->LDS, 16B per lane; LDS dest = wave-uniform base + lane*16
__device__ __forceinline__ void gll16(const void* g, void* l) {
    __builtin_amdgcn_global_load_lds(
        (const __attribute__((address_space(1))) u32*)g,
        (__attribute__((address_space(3))) u32*)l, 16, 0, 0);
}

// ===========================================================================
// 8-wave half-tile-pipelined MFMA GEMM (m201-style schedule, plain HIP):
// C[m,n] = act( sum_k A[m,k]*W[n,k] + b1[n] (+b2[n]) ), bf16 out.
// BM=256, BN=256 (=N), wave-tile 128x64 (2m x 4n waves), K-half = 32.
// LDS: 4 half-slots x 32 entries x 1KB = 128 KB.
//   entry f (0..15)  = A frag rows f*16..f*16+15, k-cols kk..kk+31
//   entry 16+g       = W frag rows g*16..,        k-cols kk..kk+31
// Per half per wave: stage 4 gll16 (slot h+3), 12 ds_read_b128, 2x16 MFMA
// wrapped in setprio. Boundary: lgkmcnt(0) + counted vmcnt(8/4/0) + s_barrier.
// Loads stay 2 halves in flight (counted vmcnt, never drained mid-loop).
// ===========================================================================
template<int KD, int ACT>
__global__ __launch_bounds__(512, 2) void gemm8_k(
    const ushort_t* __restrict__ A, const ushort_t* __restrict__ Wt,
    const float* __restrict__ b1, const float* __restrict__ b2,
    ushort_t* __restrict__ C)
{
    __shared__ ushort_t lds[4][32][512];   // 128 KB
    const int tid = threadIdx.x;
    const int lane = tid & 63;
    const int w = tid >> 6;                // 0..7
    const int wm = w >> 2, wn = w & 3;     // 2m x 4n
    const int m0 = blockIdx.x * 256;
    const int r16 = lane & 15, kq = lane >> 4;
    constexpr int NH = KD / 32;

    const ushort_t* Ag0 = A + (size_t)(m0 + w * 16 + r16) * KD + kq * 8;
    const ushort_t* Ag1 = A + (size_t)(m0 + (w + 8) * 16 + r16) * KD + kq * 8;
    const ushort_t* Bg0 = Wt + (size_t)(w * 16 + r16) * KD + kq * 8;
    const ushort_t* Bg1 = Wt + (size_t)((w + 8) * 16 + r16) * KD + kq * 8;

    f32x4 acc[8][4];
    #pragma unroll
    for (int i = 0; i < 8; ++i)
        #pragma unroll
        for (int j = 0; j < 4; ++j)
            acc[i][j] = (f32x4){0.f, 0.f, 0.f, 0.f};

#define ST8(h) do { int sl_ = (h) & 3; int kk_ = (h) * 32;                  \
    gll16(Ag0 + kk_, &lds[sl_][w][0]);                                      \
    gll16(Ag1 + kk_, &lds[sl_][w + 8][0]);                                  \
    gll16(Bg0 + kk_, &lds[sl_][16 + w][0]);                                 \
    gll16(Bg1 + kk_, &lds[sl_][16 + w + 8][0]);                             \
} while (0)

    ST8(0); ST8(1); ST8(2);
    asm volatile("s_waitcnt vmcnt(8)" ::: "memory");   // half 0 landed
    __builtin_amdgcn_s_barrier();

    for (int h = 0; h < NH; ++h) {
        if (h + 3 < NH) ST8(h + 3);
        const int sl = h & 3;
        bf16x8 bfr[4];
        #pragma unroll
        for (int nf = 0; nf < 4; ++nf)
            bfr[nf] = *(const bf16x8*)&lds[sl][16 + wn * 4 + nf][lane * 8];
        #pragma unroll
        for (int mh = 0; mh < 2; ++mh) {
            bf16x8 af[4];
            #pragma unroll
            for (int mf = 0; mf < 4; ++mf)
                af[mf] = *(const bf16x8*)&lds[sl][wm * 8 + mh * 4 + mf][lane * 8];
            __builtin_amdgcn_s_setprio(1);
            #pragma unroll
            for (int mf = 0; mf < 4; ++mf)
                #pragma unroll
                for (int nf = 0; nf < 4; ++nf)
                    acc[mh * 4 + mf][nf] = __builtin_amdgcn_mfma_f32_16x16x32_bf16(
                        bfr[nf], af[mf], acc[mh * 4 + mf][nf], 0, 0, 0);
            __builtin_amdgcn_s_setprio(0);
        }
        asm volatile("s_waitcnt lgkmcnt(0)" ::: "memory");  // my reads of slot done
        if (h < NH - 3)       { asm volatile("s_waitcnt vmcnt(8)" ::: "memory"); }
        else if (h == NH - 3) { asm volatile("s_waitcnt vmcnt(4)" ::: "memory"); }
        else if (h == NH - 2) { asm volatile("s_waitcnt vmcnt(0)" ::: "memory"); }
        if (h < NH - 1) __builtin_amdgcn_s_barrier();
    }
#undef ST8

    #pragma unroll
    for (int mi = 0; mi < 8; ++mi) {
        int mrow = m0 + wm * 128 + mi * 16 + r16;
        #pragma unroll
        for (int nf = 0; nf < 4; ++nf) {
            int nb = wn * 64 + nf * 16 + kq * 4;
            float4 bb = *(const float4*)&b1[nb];
            if (b2) {
                float4 b2v = *(const float4*)&b2[nb];
                bb.x += b2v.x; bb.y += b2v.y; bb.z += b2v.z; bb.w += b2v.w;
            }
            float v0 = acc[mi][nf][0] + bb.x;
            float v1 = acc[mi][nf][1] + bb.y;
            float v2 = acc[mi][nf][2] + bb.z;
            float v3 = acc[mi][nf][3] + bb.w;
            if (ACT) { v0 = eluf(v0); v1 = eluf(v1); v2 = eluf(v2); v3 = eluf(v3); }
            ushort4 o; o.x = f2b(v0); o.y = f2b(v1); o.z = f2b(v2); o.w = f2b(v3);
            *(ushort4*)&C[(size_t)mrow * 256 + nb] = o;
        }
    }
}

// ===========================================================================
// mlp4 layer-1 variant: KD=768, A gathered on the fly.
// row m=(be*64+t); k<256 -> X2b[b,send,t,k]; k<512 -> X2b[b,recv,t,.]; else EA.
// Half h: kk=h*32, seg=h>>3 (whole 32-col halves lie in one segment).
// ===========================================================================
__global__ __launch_bounds__(512, 2) void gemm8_mlp4_k(
    const ushort_t* __restrict__ X2b, const ushort_t* __restrict__ EA,
    const ushort_t* __restrict__ Wt, const float* __restrict__ b1,
    ushort_t* __restrict__ C)
{
    __shared__ ushort_t lds[4][32][512];   // 128 KB
    const int tid = threadIdx.x;
    const int lane = tid & 63;
    const int w = tid >> 6;
    const int wm = w >> 2, wn = w & 3;
    const int m0 = blockIdx.x * 256;
    const int r16 = lane & 15, kq = lane >> 4;
    constexpr int NH = 24;

    // gather bases for staged A-frags f = w and w+8
    const ushort_t* AS[2]; const ushort_t* AR[2]; const ushort_t* AE[2];
    #pragma unroll
    for (int ff = 0; ff < 2; ++ff) {
        int f = w + ff * 8;
        int m = m0 + f * 16 + r16;
        int be = m >> 6, t = m & 63;
        int b = be / E_, e = be % E_;
        int s = e / (V_ - 1);
        int r0 = e % (V_ - 1);
        int rr = r0 + (r0 >= s ? 1 : 0);
        AS[ff] = X2b + ((size_t)((b * V_ + s) * T_ + t)) * H_ + kq * 8;
        AR[ff] = X2b + ((size_t)((b * V_ + rr) * T_ + t)) * H_ + kq * 8;
        AE[ff] = EA + (size_t)m * H_ + kq * 8;
    }
    const ushort_t* Bg0 = Wt + (size_t)(w * 16 + r16) * 768 + kq * 8;
    const ushort_t* Bg1 = Wt + (size_t)((w + 8) * 16 + r16) * 768 + kq * 8;

    f32x4 acc[8][4];
    #pragma unroll
    for (int i = 0; i < 8; ++i)
        #pragma unroll
        for (int j = 0; j < 4; ++j)
            acc[i][j] = (f32x4){0.f, 0.f, 0.f, 0.f};

#define STM(h) do { int sl_ = (h) & 3; int kk_ = (h) * 32;                  \
    int seg_ = kk_ >> 8, off_ = kk_ & 255;                                  \
    const ushort_t* a0_ = (seg_ == 0 ? AS[0] : seg_ == 1 ? AR[0] : AE[0]) + off_; \
    const ushort_t* a1_ = (seg_ == 0 ? AS[1] : seg_ == 1 ? AR[1] : AE[1]) + off_; \
    gll16(a0_, &lds[sl_][w][0]);                                            \
    gll16(a1_, &lds[sl_][w + 8][0]);                                        \
    gll16(Bg0 + kk_, &lds[sl_][16 + w][0]);                                 \
    gll16(Bg1 + kk_, &lds[sl_][16 + w + 8][0]);                             \
} while (0)

    STM(0); STM(1); STM(2);
    asm volatile("s_waitcnt vmcnt(8)" ::: "memory");
    __builtin_amdgcn_s_barrier();

    for (int h = 0; h < NH; ++h) {
        if (h + 3 < NH) STM(h + 3);
        const int sl = h & 3;
        bf16x8 bfr[4];
        #pragma unroll
        for (int nf = 0; nf < 4; ++nf)
            bfr[nf] = *(const bf16x8*)&lds[sl][16 + wn * 4 + nf][lane * 8];
        #pragma unroll
        for (int mh = 0; mh < 2; ++mh) {
            bf16x8 af[4];
            #pragma unroll
            for (int mf = 0; mf < 4; ++mf)
                af[mf] = *(const bf16x8*)&lds[sl][wm * 8 + mh * 4 + mf][lane * 8];
            __builtin_amdgcn_s_setprio(1);
            #pragma unroll
            for (int mf = 0; mf < 4; ++mf)
                #pragma unroll
                for (int nf = 0; nf < 4; ++nf)
                    acc[mh * 4 + mf][nf] = __builtin_amdgcn_mfma_f32_16x16x32_bf16(
                        bfr[nf], af[mf], acc[mh * 4 + mf][nf], 0, 0, 0);
            __builtin_amdgcn_s_setprio(0);
        }
        asm volatile("s_waitcnt lgkmcnt(0)" ::: "memory");
        if (h < NH - 3)       { asm volatile("s_waitcnt vmcnt(8)" ::: "memory"); }
        else if (h == NH - 3) { asm volatile("s_waitcnt vmcnt(4)" ::: "memory"); }
        else if (h == NH - 2) { asm volatile("s_waitcnt vmcnt(0)" ::: "memory"); }
        if (h < NH - 1) __builtin_amdgcn_s_barrier();
    }
#undef STM

    #pragma unroll
    for (int mi = 0; mi < 8; ++mi) {
        int mrow = m0 + wm * 128 + mi * 16 + r16;
        #pragma unroll
        for (int nf = 0; nf < 4; ++nf) {
            int nb = wn * 64 + nf * 16 + kq * 4;
            float4 bb = *(const float4*)&b1[nb];
            float v0 = eluf(acc[mi][nf][0] + bb.x);
            float v1 = eluf(acc[mi][nf][1] + bb.y);
            float v2 = eluf(acc[mi][nf][2] + bb.z);
            float v3 = eluf(acc[mi][nf][3] + bb.w);
            ushort4 o; o.x = f2b(v0); o.y = f2b(v1); o.z = f2b(v2); o.w = f2b(v3);
            *(ushort4*)&C[(size_t)mrow * 256 + nb] = o;
        }
    }
}

// ===========================================================================
// weights f32 -> bf16 (packed): ef_w2 | m4_w1 | m4_w2 | f_wih | r_wih | e_w1
// ===========================================================================
__global__ __launch_bounds__(256) void wconv_k(
    const float* __restrict__ ef_w2, const float* __restrict__ m4_w1,
    const float* __restrict__ m4_w2, const float* __restrict__ f_wih,
    const float* __restrict__ r_wih, const float* __restrict__ e_w1,
    ushort_t* __restrict__ Wb)
{
    int i = blockIdx.x * 256 + threadIdx.x;   // < 491520
    const float* src; int off;
    if (i < 65536)       { src = ef_w2; off = i; }
    else if (i < 262144) { src = m4_w1; off = i - 65536; }
    else if (i < 327680) { src = m4_w2; off = i - 262144; }
    else if (i < 393216) { src = f_wih; off = i - 327680; }
    else if (i < 458752) { src = r_wih; off = i - 393216; }
    else                 { src = e_w1;  off = i - 458752; }
    Wb[i] = f2b(src[off]);
}

// ---------------------------------------------------------------------------
// Generic VALU GEMM (kept for mlp3 node rows): C = act(A@W.T + b1)
// ---------------------------------------------------------------------------
template<typename TA, typename TO>
__global__ __launch_bounds__(256) void gemm_t(
    const TA* __restrict__ A, const float* __restrict__ W,
    const float* __restrict__ b1, const float* __restrict__ b2,
    TO* __restrict__ C, int M, int Kd, int N, int act)
{
    __shared__ float As[16][64];
    __shared__ float Ws[16][64];
    const int m0 = blockIdx.x * 64, n0 = blockIdx.y * 64;
    const int tid = threadIdx.x;
    const int tm = tid >> 4, tn = tid & 15;
    const int lm = tid >> 2, lq = tid & 3;
    float acc[4][4] = {};
    const TA* Arow = A + (size_t)(m0 + lm) * Kd + lq * 4;
    const float* Wrow = W + (size_t)(n0 + lm) * Kd + lq * 4;
    for (int k0 = 0; k0 < Kd; k0 += 16) {
        float4 av, wv;
        if constexpr (std::is_same<TA, ushort_t>::value) {
            ushort4 u = *(const ushort4*)(Arow + k0);
            av.x = b2f(u.x); av.y = b2f(u.y); av.z = b2f(u.z); av.w = b2f(u.w);
        } else {
            av = *(const float4*)(Arow + k0);
        }
        wv = *(const float4*)(Wrow + k0);
        __syncthreads();
        As[lq*4+0][lm] = av.x; As[lq*4+1][lm] = av.y; As[lq*4+2][lm] = av.z; As[lq*4+3][lm] = av.w;
        Ws[lq*4+0][lm] = wv.x; Ws[lq*4+1][lm] = wv.y; Ws[lq*4+2][lm] = wv.z; Ws[lq*4+3][lm] = wv.w;
        __syncthreads();
        #pragma unroll
        for (int k = 0; k < 16; ++k) {
            float4 a = *(const float4*)&As[k][tm * 4];
            float4 w = *(const float4*)&Ws[k][tn * 4];
            float a_[4] = {a.x, a.y, a.z, a.w};
            float w_[4] = {w.x, w.y, w.z, w.w};
            #pragma unroll
            for (int i = 0; i < 4; ++i)
                #pragma unroll
                for (int j = 0; j < 4; ++j)
                    acc[i][j] += a_[i] * w_[j];
        }
    }
    float bb[4];
    #pragma unroll
    for (int j = 0; j < 4; ++j) {
        int n = n0 + tn * 4 + j;
        bb[j] = b1[n] + (b2 ? b2[n] : 0.f);
    }
    #pragma unroll
    for (int i = 0; i < 4; ++i) {
        float v0 = acc[i][0] + bb[0], v1 = acc[i][1] + bb[1];
        float v2 = acc[i][2] + bb[2], v3 = acc[i][3] + bb[3];
        if (act) { v0 = eluf(v0); v1 = eluf(v1); v2 = eluf(v2); v3 = eluf(v3); }
        TO* dst = C + (size_t)(m0 + tm * 4 + i) * N + (n0 + tn * 4);
        if constexpr (std::is_same<TO, ushort_t>::value) {
            ushort4 o; o.x = f2b(v0); o.y = f2b(v1); o.z = f2b(v2); o.w = f2b(v3);
            *(ushort4*)dst = o;
        } else {
            float4 o; o.x = v0; o.y = v1; o.z = v2; o.w = v3;
            *(float4*)dst = o;
        }
    }
}

// ---------------------------------------------------------------------------
// First GEMM with fused concat: A[m,c] = c<13 ? ear[m,c] : epos[m,c-13], Kd=16.
// ---------------------------------------------------------------------------
__global__ __launch_bounds__(256) void gemm_ein_k(
    const float* __restrict__ ear, const float* __restrict__ epos,
    const float* __restrict__ W, const float* __restrict__ b1,
    ushort_t* __restrict__ C)
{
    __shared__ float As[16][64];
    __shared__ float Ws[16][64];
    const int m0 = blockIdx.x * 64, n0 = blockIdx.y * 64;
    const int tid = threadIdx.x;
    const int tm = tid >> 4, tn = tid & 15;
    const int lm = tid >> 2, lq = tid & 3;
    const int m = m0 + lm;
    float a_[4];
    #pragma unroll
    for (int q = 0; q < 4; ++q) {
        int c = lq * 4 + q;
        a_[q] = (c < 13) ? ear[(size_t)m * 13 + c] : epos[(size_t)m * 3 + (c - 13)];
    }
    float4 wv = *(const float4*)(W + (size_t)(n0 + lm) * 16 + lq * 4);
    As[lq*4+0][lm] = a_[0]; As[lq*4+1][lm] = a_[1]; As[lq*4+2][lm] = a_[2]; As[lq*4+3][lm] = a_[3];
    Ws[lq*4+0][lm] = wv.x; Ws[lq*4+1][lm] = wv.y; Ws[lq*4+2][lm] = wv.z; Ws[lq*4+3][lm] = wv.w;
    __syncthreads();
    float acc[4][4] = {};
    #pragma unroll
    for (int k = 0; k < 16; ++k) {
        float4 a = *(const float4*)&As[k][tm * 4];
        float4 w = *(const float4*)&Ws[k][tn * 4];
        float aa[4] = {a.x, a.y, a.z, a.w};
        float ww[4] = {w.x, w.y, w.z, w.w};
        #pragma unroll
        for (int i = 0; i < 4; ++i)
            #pragma unroll
            for (int j = 0; j < 4; ++j)
                acc[i][j] += aa[i] * ww[j];
    }
    #pragma unroll
    for (int i = 0; i < 4; ++i) {
        ushort4 o;
        o.x = f2b(eluf(acc[i][0] + b1[n0 + tn*4 + 0]));
        o.y = f2b(eluf(acc[i][1] + b1[n0 + tn*4 + 1]));
        o.z = f2b(eluf(acc[i][2] + b1[n0 + tn*4 + 2]));
        o.w = f2b(eluf(acc[i][3] + b1[n0 + tn*4 + 3]));
        *(ushort4*)(C + (size_t)(m0 + tm * 4 + i) * H_ + (n0 + tn * 4)) = o;
    }
}

// ---------------------------------------------------------------------------
// edge2node: X[b,v,t,h] = (1/15)*sum_{e:RECV==v} EA[b,e,t,h] + rel@res_w.T + res_b
// ---------------------------------------------------------------------------
__global__ __launch_bounds__(256) void e2n_k(
    const ushort_t* __restrict__ EA, const float* __restrict__ rel,
    const float* __restrict__ res_w, const float* __restrict__ res_b,
    float* __restrict__ X)
{
    const int idx = blockIdx.x;            // (b*V+v)*T + t
    const int t = idx & (T_ - 1);
    const int bv = idx >> 6;
    const int v = bv & (V_ - 1);
    const int b = bv >> 4;
    const int h = threadIdx.x;
    float sum = 0.f;
    #pragma unroll
    for (int i = 0; i < V_; ++i) {
        if (i == v) continue;
        int jj = (v < i) ? v : v - 1;
        int e = i * (V_ - 1) + jj;
        sum += b2f(EA[(((size_t)(b * E_ + e)) * T_ + t) * H_ + h]);
    }
    const float* rp = rel + ((size_t)bv * T_ + t) * DIN_;
    float res = res_b[h];
    #pragma unroll
    for (int d = 0; d < DIN_; ++d) res += rp[d] * res_w[h * DIN_ + d];
    X[((size_t)bv * T_ + t) * H_ + h] = sum * (1.f / 15.f) + res;
}

// ===========================================================================
// MFMA LSTM scan, 4 cooperative waves per block, 16 sequences per block.
// ===========================================================================
__global__ __launch_bounds__(256) void lstm_mfma4_k(
    const ushort_t* __restrict__ G, const float* __restrict__ whh,
    ushort_t* __restrict__ COMB, int dir)
{
    __shared__ ushort_t hlds[2][1024];   // 2 x 2KB: h[seq][j] bf16, XOR-swizzled
    const int tid = threadIdx.x;
    const int lane = tid & 63;
    const int w = tid >> 6;              // wave id = j-block
    const int seq = lane & 15, kq = lane >> 4;
    const int be0 = blockIdx.x * 16;
    const int swz = (seq & 7) << 4;

    bf16x8 wf[4][2];
    #pragma unroll
    for (int a = 0; a < 4; ++a) {
        #pragma unroll
        for (int ks = 0; ks < 2; ++ks) {
            const float* p = whh + (size_t)((a * 4 + w) * 16 + seq) * 64 + ks * 32 + kq * 8;
            float4 x0 = *(const float4*)p;
            float4 x1 = *(const float4*)(p + 4);
            bf16x8 v;
            v[0] = (short)f2b(x0.x); v[1] = (short)f2b(x0.y);
            v[2] = (short)f2b(x0.z); v[3] = (short)f2b(x0.w);
            v[4] = (short)f2b(x1.x); v[5] = (short)f2b(x1.y);
            v[6] = (short)f2b(x1.z); v[7] = (short)f2b(x1.w);
            wf[a][ks] = v;
        }
    }

    const ushort_t* grow = G + ((size_t)(be0 + seq) * T_) * 256 + kq * 4;
    ushort_t* crow = COMB + ((size_t)(be0 + seq) * T_) * 128 + (dir ? 64 : 0) + 16 * w + 4 * kq;

    float c[4] = {};
    ushort4 gx[4];
    const int t0 = dir ? (T_ - 1) : 0;
    #pragma unroll
    for (int a = 0; a < 4; ++a)
        gx[a] = *(const ushort4*)(grow + (size_t)t0 * 256 + (a * 4 + w) * 16);

    for (int s = 0; s < T_; ++s) {
        const int t = dir ? (T_ - 1 - s) : s;
        f32x4 acc[4];
        #pragma unroll
        for (int a = 0; a < 4; ++a) {
            ushort4 g = gx[a];
            acc[a] = (f32x4){b2f(g.x), b2f(g.y), b2f(g.z), b2f(g.w)};
        }
        if (s < T_ - 1) {
            const int tn = dir ? (T_ - 2 - s) : (s + 1);
            #pragma unroll
            for (int a = 0; a < 4; ++a)
                gx[a] = *(const ushort4*)(grow + (size_t)tn * 256 + (a * 4 + w) * 16);
        }
        if (s) {
            bf16x8 af[2];
            #pragma unroll
            for (int ks = 0; ks < 2; ++ks) {
                int boff = (seq * 128 + ks * 64 + kq * 16) ^ swz;
                af[ks] = *(const bf16x8*)((const char*)hlds[(s - 1) & 1] + boff);
            }
            #pragma unroll
            for (int a = 0; a < 4; ++a) {
                acc[a] = __builtin_amdgcn_mfma_f32_16x16x32_bf16(wf[a][0], af[0], acc[a], 0, 0, 0);
                acc[a] = __builtin_amdgcn_mfma_f32_16x16x32_bf16(wf[a][1], af[1], acc[a], 0, 0, 0);
            }
        }
        float hh[4];
        #pragma unroll
        for (int r = 0; r < 4; ++r) {
            float zi = acc[0][r], zf = acc[1][r], zg = acc[2][r], zo = acc[3][r];
            float cc = fsig(zf) * c[r] + fsig(zi) * ftanh_(zg);
            c[r] = cc;
            hh[r] = fsig(zo) * ftanh_(cc);
        }
        ushort4 hv;
        hv.x = f2b(hh[0]); hv.y = f2b(hh[1]); hv.z = f2b(hh[2]); hv.w = f2b(hh[3]);
        int wb = (seq * 128 + 32 * w + 8 * kq) ^ swz;
        *(ushort4*)((char*)hlds[s & 1] + wb) = hv;
        *(ushort4*)(crow + (size_t)t * 128) = hv;
        asm volatile("s_waitcnt lgkmcnt(0)" ::: "memory");
        __builtin_amdgcn_sched_barrier(0);
        __builtin_amdgcn_s_barrier();
    }
}

// ---------------------------------------------------------------------------
// prior head: reads fwd hidden from comb[:, 0:64] (row stride 128)
// ---------------------------------------------------------------------------
__global__ __launch_bounds__(256) void prior_k(
    const ushort_t* __restrict__ COMB, const float* __restrict__ p_w,
    const float* __restrict__ p_b, float* __restrict__ out)
{
    const int row = blockIdx.x * 4 + (threadIdx.x >> 6);  // [0, BET)
    const int lane = threadIdx.x & 63;
    float hf = b2f(COMB[(size_t)row * 128 + lane]);
    float v0 = hf * p_w[lane];
    float v1 = hf * p_w[64 + lane];
    #pragma unroll
    for (int off = 32; off > 0; off >>= 1) {
        v0 += __shfl_down(v0, off, 64);
        v1 += __shfl_down(v1, off, 64);
    }
    if (lane == 0) {
        int t = row & (T_ - 1);
        int be = row >> 6;
        int e = be % E_, b = be / E_;
        size_t o = (((size_t)b * T_ + t) * E_ + e) * K_;
        out[o] = v0 + p_b[0];
        out[o + 1] = v1 + p_b[1];
    }
}

// ===========================================================================
// FUSED: ENCH = elu(COMB@e_w1.T + e_b1) in regs, then out = ENCH@e_w2.T + e_b2
// with transpose-scatter. 8 waves, 128 rows/block, K=128 (4 steps).
// ===========================================================================
__global__ __launch_bounds__(512) void fused_enc_k(
    const ushort_t* __restrict__ COMB, const ushort_t* __restrict__ w_e1,
    const float* __restrict__ e_b1, const float* __restrict__ e_w2,
    const float* __restrict__ e_b2, float* __restrict__ out)
{
    __shared__ ushort_t sA[2][8][512];    // 16 KB
    __shared__ ushort_t sW[2][16][512];   // 32 KB
    __shared__ float part[128][4][2];     // 4 KB
    const int tid = threadIdx.x;
    const int lane = tid & 63;
    const int w = tid >> 6;
    const int wr = w >> 2, wc = w & 3;
    const int m0 = blockIdx.x * 128;
    const int r16 = lane & 15, kq = lane >> 4;

    const ushort_t* Asrc = COMB + (size_t)(m0 + w * 16 + r16) * 128 + kq * 8;
    const size_t woffA = (size_t)((2 * w) * 16 + r16) * 128 + kq * 8;
    const size_t woffB = (size_t)((2 * w + 1) * 16 + r16) * 128 + kq * 8;

    float4 w2v[2][4];
    #pragma unroll
    for (int j = 0; j < 2; ++j)
        #pragma unroll
        for (int nf = 0; nf < 4; ++nf)
            w2v[j][nf] = *(const float4*)&e_w2[j * 256 + wc * 64 + nf * 16 + kq * 4];

    f32x4 acc[4][4];
    #pragma unroll
    for (int i = 0; i < 4; ++i)
        #pragma unroll
        for (int j = 0; j < 4; ++j)
            acc[i][j] = (f32x4){0.f, 0.f, 0.f, 0.f};

#define FE_STAGE(bufi, kt_) do {                                             \
    gll16(Asrc + (kt_) * 32, &sA[bufi][w][0]);                               \
    gll16(w_e1 + woffA + (kt_) * 32, &sW[bufi][2 * w][0]);                   \
    gll16(w_e1 + woffB + (kt_) * 32, &sW[bufi][2 * w + 1][0]);               \
} while (0)

    FE_STAGE(0, 0);
    asm volatile("s_waitcnt vmcnt(0)" ::: "memory");
    __builtin_amdgcn_s_barrier();

    for (int s = 0; s < 4; ++s) {
        const int buf = s & 1;
        if (s < 3) FE_STAGE(buf ^ 1, s + 1);
        bf16x8 af[4], bfr[4];
        #pragma unroll
        for (int mf = 0; mf < 4; ++mf)
            af[mf] = *(const bf16x8*)&sA[buf][wr * 4 + mf][lane * 8];
        #pragma unroll
        for (int nf = 0; nf < 4; ++nf)
            bfr[nf] = *(const bf16x8*)&sW[buf][wc * 4 + nf][lane * 8];
        #pragma unroll
        for (int mf = 0; mf < 4; ++mf)
            #pragma unroll
            for (int nf = 0; nf < 4; ++nf)
                acc[mf][nf] = __builtin_amdgcn_mfma_f32_16x16x32_bf16(bfr[nf], af[mf], acc[mf][nf], 0, 0, 0);
        asm volatile("s_waitcnt vmcnt(0)" ::: "memory");
        __builtin_amdgcn_s_barrier();
    }

    #pragma unroll
    for (int mf = 0; mf < 4; ++mf) {
        float s0 = 0.f, s1 = 0.f;
        #pragma unroll
        for (int nf = 0; nf < 4; ++nf) {
            int col = wc * 64 + nf * 16 + kq * 4;
            float4 bb = *(const float4*)&e_b1[col];
            float v0 = eluf(acc[mf][nf][0] + bb.x);
            float v1 = eluf(acc[mf][nf][1] + bb.y);
            float v2 = eluf(acc[mf][nf][2] + bb.z);
            float v3 = eluf(acc[mf][nf][3] + bb.w);
            s0 += v0 * w2v[0][nf].x + v1 * w2v[0][nf].y + v2 * w2v[0][nf].z + v3 * w2v[0][nf].w;
            s1 += v0 * w2v[1][nf].x + v1 * w2v[1][nf].y + v2 * w2v[1][nf].z + v3 * w2v[1][nf].w;
        }
        s0 += __shfl_xor(s0, 16, 64); s0 += __shfl_xor(s0, 32, 64);
        s1 += __shfl_xor(s1, 16, 64); s1 += __shfl_xor(s1, 32, 64);
        if (kq == 0) {
            part[wr * 64 + mf * 16 + r16][wc][0] = s0;
            part[wr * 64 + mf * 16 + r16][wc][1] = s1;
        }
    }
    __syncthreads();
    if (tid < 256) {
        int row = tid >> 1, k = tid & 1;
        float v = part[row][0][k] + part[row][1][k] + part[row][2][k] + part[row][3][k] + e_b2[k];
        int gr = m0 + row;
        int be = gr >> 6, t = gr & 63;
        int e = be % E_, b = be / E_;
        out[(size_t)(B_ * T_ * E_ * K_) + (((size_t)b * T_ + t) * E_ + e) * K_ + k] = v;
    }
#undef FE_STAGE
}

// ---------------------------------------------------------------------------
extern "C" void kernel_launch(void* const* d_in, const int* in_sizes, int n_in,
                              void* d_out, int out_size, void* d_ws, size_t ws_size,
                              hipStream_t stream)
{
    const float* rel    = (const float*)d_in[0];
    const float* ear    = (const float*)d_in[1];
    const float* epos   = (const float*)d_in[2];
    const float* ef_w1  = (const float*)d_in[3];
    const float* ef_b1  = (const float*)d_in[4];
    const float* ef_w2  = (const float*)d_in[5];
    const float* ef_b2  = (const float*)d_in[6];
    const float* res_w  = (const float*)d_in[7];
    const float* res_b  = (const float*)d_in[8];
    const float* m3_w1  = (const float*)d_in[9];
    const float* m3_b1  = (const float*)d_in[10];
    const float* m3_w2  = (const float*)d_in[11];
    const float* m3_b2  = (const float*)d_in[12];
    const float* m4_w1  = (const float*)d_in[13];
    const float* m4_b1  = (const float*)d_in[14];
    const float* m4_w2  = (const float*)d_in[15];
    const float* m4_b2  = (const float*)d_in[16];
    const float* f_wih  = (const float*)d_in[17];
    const float* f_whh  = (const float*)d_in[18];
    const float* f_bih  = (const float*)d_in[19];
    const float* f_bhh  = (const float*)d_in[20];
    const float* r_wih  = (const float*)d_in[21];
    const float* r_whh  = (const float*)d_in[22];
    const float* r_bih  = (const float*)d_in[23];
    const float* r_bhh  = (const float*)d_in[24];
    const float* p_w    = (const float*)d_in[25];
    const float* p_b    = (const float*)d_in[26];
    const float* e_w1   = (const float*)d_in[27];
    const float* e_b1   = (const float*)d_in[28];
    const float* e_w2   = (const float*)d_in[29];
    const float* e_b2   = (const float*)d_in[30];
    float* out = (float*)d_out;

    // workspace layout (bytes), total ~162.5 MB
    char* ws = (char*)d_ws;
    const size_t BIGB  = (size_t)BET_ * H_ * sizeof(ushort_t);   // 62,914,560
    const size_t COMBB = (size_t)BET_ * 128 * sizeof(ushort_t);  // 31,457,280
    const size_t X2BB  = (size_t)BVT_ * H_ * sizeof(ushort_t);   //  4,194,304
    ushort_t* R1   = (ushort_t*)(ws);
    ushort_t* R2   = (ushort_t*)(ws + BIGB);
    ushort_t* COMB = (ushort_t*)(ws + 2 * BIGB);
    ushort_t* X2b  = (ushort_t*)(ws + 2 * BIGB + COMBB);
    ushort_t* Wb   = (ushort_t*)(ws + 2 * BIGB + COMBB + X2BB);
    // node-stage f32 scratch lives inside (dead) R1 region
    float* X  = (float*)(ws);
    float* XH = (float*)(ws + (size_t)BVT_ * H_ * sizeof(float));
    // packed bf16 weight offsets (elements)
    const ushort_t* wb_ef2  = Wb + 0;
    const ushort_t* wb_m41  = Wb + 65536;
    const ushort_t* wb_m42  = Wb + 262144;
    const ushort_t* wb_fwih = Wb + 327680;
    const ushort_t* wb_rwih = Wb + 393216;
    const ushort_t* wb_ew1  = Wb + 458752;

    dim3 blk(256);
    dim3 blk8(512);
    dim3 g8(BET_ / 256);       // 480 blocks for the 8-wave GEMMs
    dim3 gE64(BET_ / 64, 4);   // VALU edge GEMM (ein)
    dim3 gN(BVT_ / 64, 4);     // VALU node GEMMs

    // 0. weights -> bf16
    wconv_k<<<1920, blk, 0, stream>>>(ef_w2, m4_w1, m4_w2, f_wih, r_wih, e_w1, Wb);
    // 1. edge filter MLP
    gemm_ein_k<<<gE64, blk, 0, stream>>>(ear, epos, ef_w1, ef_b1, R1);
    gemm8_k<256, 1><<<g8, blk8, 0, stream>>>(R1, wb_ef2, ef_b2, nullptr, R2);        // EA
    // 2. edge2node + residual
    e2n_k<<<BVT_, blk, 0, stream>>>(R2, rel, res_w, res_b, X);
    // 3. mlp3 (node rows, f32 VALU)
    gemm_t<float, float><<<gN, blk, 0, stream>>>(X, m3_w1, m3_b1, nullptr, XH, BVT_, H_, H_, 1);
    gemm_t<float, ushort_t><<<gN, blk, 0, stream>>>(XH, m3_w2, m3_b2, nullptr, X2b, BVT_, H_, H_, 1);
    // 4. node2edge gather + mlp4
    gemm8_mlp4_k<<<g8, blk8, 0, stream>>>(X2b, R2, wb_m41, m4_b1, R1);               // T1
    gemm8_k<256, 1><<<g8, blk8, 0, stream>>>(R1, wb_m42, m4_b2, nullptr, R2);        // M2 (EA dead)
    // 5. gates + LSTM scans
    gemm8_k<256, 0><<<g8, blk8, 0, stream>>>(R2, wb_fwih, f_bih, f_bhh, R1);         // GF
    lstm_mfma4_k<<<BE_ / 16, blk, 0, stream>>>(R1, f_whh, COMB, 0);
    gemm8_k<256, 0><<<g8, blk8, 0, stream>>>(R2, wb_rwih, r_bih, r_bhh, R1);         // GR
    lstm_mfma4_k<<<BE_ / 16, blk, 0, stream>>>(R1, r_whh, COMB, 1);
    // 6. heads
    prior_k<<<BET_ / 4, blk, 0, stream>>>(COMB, p_w, p_b, out);
    fused_enc_k<<<BET_ / 128, blk8, 0, stream>>>(COMB, wb_ew1, e_b1, e_w2, e_b2, out);
}

// Round 9
// 452.960 us; speedup vs baseline: 5.8452x; 1.0904x over previous
//
#include <hip/hip_runtime.h>
#include <cstdint>
#include <cstddef>
#include <type_traits>

// Problem constants
#define B_ 8
#define V_ 16
#define T_ 64
#define E_ 240          // V*(V-1)
#define H_ 256
#define RH_ 64
#define K_ 2
#define DIN_ 6
#define BET_ (B_*E_*T_)   // 122880
#define BVT_ (B_*V_*T_)   // 8192
#define BE_ (B_*E_)       // 1920

typedef unsigned short ushort_t;
typedef unsigned int u32;
typedef __attribute__((ext_vector_type(8))) short bf16x8;
typedef __attribute__((ext_vector_type(4))) float f32x4;

__device__ __forceinline__ float eluf(float x) { return x > 0.f ? x : __expf(x) - 1.f; }
__device__ __forceinline__ float fsig(float x) { return 1.f / (1.f + __expf(-x)); }
__device__ __forceinline__ float ftanh_(float x) {
    float y = fminf(fmaxf(x, -8.f), 8.f);
    float e = __expf(2.f * y);
    return (e - 1.f) / (e + 1.f);
}
__device__ __forceinline__ float b2f(ushort_t u) {
    union { float f; uint32_t i; } v; v.i = ((uint32_t)u) << 16; return v.f;
}
__device__ __forceinline__ ushort_t f2b(float f) {
    union { float f; uint32_t i; } v; v.f = f;
    uint32_t r = (v.i + 0x7FFFu + ((v.i >> 16) & 1u)) >> 16;
    return (ushort_t)r;
}

// async global->LDS, 16B per lane; LDS dest = wave-uniform base + lane*16
__device__ __forceinline__ void gll16(const void* g, void* l) {
    __builtin_amdgcn_global_load_lds(
        (const __attribute__((address_space(1))) u32*)g,
        (__attribute__((address_space(3))) u32*)l, 16, 0, 0);
}

// ===========================================================================
// FUSED ein(K=16 f32) + ef2(K=256) : EA = elu(elu(ein@efw1+b1)@efw2+b2)
// BM=128, 8 waves, wave-tile 64x64. Layer-1 via zero-padded K=32 MFMA from
// per-lane f32 loads; H1 kept in LDS fragment order (round-7-verified map);
// layer-2 B staged with counted vmcnt (4 slots, depth 3, 2 loads/half).
// ===========================================================================
__global__ __launch_bounds__(512, 1) void gemm8_ef_k(
    const float* __restrict__ ear, const float* __restrict__ epos,
    const float* __restrict__ ef_w1, const float* __restrict__ ef_b1,
    const ushort_t* __restrict__ w_ef2, const float* __restrict__ ef_b2,
    ushort_t* __restrict__ EA)
{
    __shared__ ushort_t H1[8][8][512];      // 64 KB
    __shared__ ushort_t slotB[4][16][512];  // 64 KB  (total 128 KB)
    const int tid = threadIdx.x;
    const int lane = tid & 63;
    const int w = tid >> 6;
    const int wm = w >> 2, wn = w & 3;
    const int m0 = blockIdx.x * 128;
    const int r16 = lane & 15, kq = lane >> 4;

    // ---- layer 1: K=16 (zero-padded to 32) ----
    f32x4 acc[4][4];
    #pragma unroll
    for (int i = 0; i < 4; ++i)
        #pragma unroll
        for (int j = 0; j < 4; ++j)
            acc[i][j] = (f32x4){0.f, 0.f, 0.f, 0.f};
    {
        bf16x8 af[4], bfr[4];
        #pragma unroll
        for (int mf = 0; mf < 4; ++mf) {
            int m = m0 + wm * 64 + mf * 16 + r16;
            #pragma unroll
            for (int e = 0; e < 8; ++e) {
                float v = 0.f;
                if (kq < 2) {
                    int c = kq * 8 + e;
                    v = (c < 13) ? ear[(size_t)m * 13 + c] : epos[(size_t)m * 3 + (c - 13)];
                }
                af[mf][e] = (short)f2b(v);
            }
        }
        #pragma unroll
        for (int nf = 0; nf < 4; ++nf) {
            int n = wn * 64 + nf * 16 + r16;
            #pragma unroll
            for (int e = 0; e < 8; ++e) {
                float v = 0.f;
                if (kq < 2) v = ef_w1[(size_t)n * 16 + kq * 8 + e];
                bfr[nf][e] = (short)f2b(v);
            }
        }
        #pragma unroll
        for (int mf = 0; mf < 4; ++mf)
            #pragma unroll
            for (int nf = 0; nf < 4; ++nf)
                acc[mf][nf] = __builtin_amdgcn_mfma_f32_16x16x32_bf16(bfr[nf], af[mf], acc[mf][nf], 0, 0, 0);
    }

    const size_t bo0 = (size_t)(2 * w * 16 + r16) * 256 + kq * 8;
    const size_t bo1 = (size_t)((2 * w + 1) * 16 + r16) * 256 + kq * 8;
#define EF_ST(h) do { int sl_ = (h) & 3;                                    \
    gll16(w_ef2 + bo0 + (h) * 32, &slotB[sl_][2 * w][0]);                   \
    gll16(w_ef2 + bo1 + (h) * 32, &slotB[sl_][2 * w + 1][0]);               \
} while (0)

    EF_ST(0); EF_ST(1); EF_ST(2);

    // H1 epilogue -> LDS fragment order (round-7-verified mapping)
    #pragma unroll
    for (int mf = 0; mf < 4; ++mf) {
        #pragma unroll
        for (int nf = 0; nf < 4; ++nf) {
            int col = wn * 64 + nf * 16 + kq * 4;
            float4 bb = *(const float4*)&ef_b1[col];
            ushort4 o;
            o.x = f2b(eluf(acc[mf][nf][0] + bb.x));
            o.y = f2b(eluf(acc[mf][nf][1] + bb.y));
            o.z = f2b(eluf(acc[mf][nf][2] + bb.z));
            o.w = f2b(eluf(acc[mf][nf][3] + bb.w));
            int ktw = wn * 2 + (nf >> 1);
            int lanew = r16 + 16 * (((nf & 1) << 1) | (kq >> 1));
            *(ushort4*)&H1[wm * 4 + mf][ktw][lanew * 8 + (kq & 1) * 4] = o;
            acc[mf][nf] = (f32x4){0.f, 0.f, 0.f, 0.f};
        }
    }
    asm volatile("s_waitcnt lgkmcnt(0)" ::: "memory");
    asm volatile("s_waitcnt vmcnt(4)" ::: "memory");
    __builtin_amdgcn_s_barrier();

    // ---- layer 2: K=256, A from H1-LDS, B staged ----
    #pragma unroll
    for (int h = 0; h < 8; ++h) {
        if (h + 3 < 8) EF_ST(h + 3);
        const int sl = h & 3;
        bf16x8 af[4], bfr[4];
        #pragma unroll
        for (int nf = 0; nf < 4; ++nf)
            bfr[nf] = *(const bf16x8*)&slotB[sl][wn * 4 + nf][lane * 8];
        #pragma unroll
        for (int mf = 0; mf < 4; ++mf)
            af[mf] = *(const bf16x8*)&H1[wm * 4 + mf][h][lane * 8];
        __builtin_amdgcn_s_setprio(1);
        #pragma unroll
        for (int mf = 0; mf < 4; ++mf)
            #pragma unroll
            for (int nf = 0; nf < 4; ++nf)
                acc[mf][nf] = __builtin_amdgcn_mfma_f32_16x16x32_bf16(bfr[nf], af[mf], acc[mf][nf], 0, 0, 0);
        __builtin_amdgcn_s_setprio(0);
        asm volatile("s_waitcnt lgkmcnt(0)" ::: "memory");
        if (h <= 4)      { asm volatile("s_waitcnt vmcnt(4)" ::: "memory"); }
        else if (h == 5) { asm volatile("s_waitcnt vmcnt(2)" ::: "memory"); }
        else if (h == 6) { asm volatile("s_waitcnt vmcnt(0)" ::: "memory"); }
        if (h < 7) __builtin_amdgcn_s_barrier();
    }
#undef EF_ST

    #pragma unroll
    for (int mf = 0; mf < 4; ++mf) {
        int row = m0 + wm * 64 + mf * 16 + r16;
        #pragma unroll
        for (int nf = 0; nf < 4; ++nf) {
            int col = wn * 64 + nf * 16 + kq * 4;
            float4 bb = *(const float4*)&ef_b2[col];
            ushort4 o;
            o.x = f2b(eluf(acc[mf][nf][0] + bb.x));
            o.y = f2b(eluf(acc[mf][nf][1] + bb.y));
            o.z = f2b(eluf(acc[mf][nf][2] + bb.z));
            o.w = f2b(eluf(acc[mf][nf][3] + bb.w));
            *(ushort4*)&EA[(size_t)row * 256 + col] = o;
        }
    }
}

// ===========================================================================
// FUSED m4l2 -> M2(LDS) -> GF,GR on the counted-vmcnt half-tile schedule.
// BM=128, 8 waves, wave-tile 64x64, 24 halves (3 phases x 8).
// Phase 0: A=T1 staged (3-slot A+B, 3 loads/half), B=m4w2.
// Phases 1,2: A=M2 from LDS, stage only B (2 loads/half).
// Counted vmcnt: h<=5 -> 3, 6<=h<=21 -> 2 (h=15 -> 0: store drain), h=22 -> 0.
// Biases hoisted to registers (no mid-loop VMEM).
// ===========================================================================
__global__ __launch_bounds__(512, 1) void fused_gates8_k(
    ushort_t* __restrict__ T1, ushort_t* __restrict__ GR,
    const ushort_t* __restrict__ w_m42, const ushort_t* __restrict__ w_fih,
    const ushort_t* __restrict__ w_rih, const float* __restrict__ m4_b2,
    const float* __restrict__ f_bih, const float* __restrict__ f_bhh,
    const float* __restrict__ r_bih, const float* __restrict__ r_bhh)
{
    __shared__ ushort_t M2[8][8][512];      // 64 KB
    __shared__ ushort_t slotA[3][8][512];   // 24 KB
    __shared__ ushort_t slotB[3][16][512];  // 48 KB  (total 136 KB)
    const int tid = threadIdx.x;
    const int lane = tid & 63;
    const int w = tid >> 6;
    const int wm = w >> 2, wn = w & 3;
    const int m0 = blockIdx.x * 128;
    const int r16 = lane & 15, kq = lane >> 4;

    const ushort_t* Ag = T1 + (size_t)(m0 + w * 16 + r16) * 256 + kq * 8;
    const size_t bo0 = (size_t)(2 * w * 16 + r16) * 256 + kq * 8;
    const size_t bo1 = (size_t)((2 * w + 1) * 16 + r16) * 256 + kq * 8;

    // hoisted biases
    float4 bm4[4], bfv[4], brv[4];
    #pragma unroll
    for (int nf = 0; nf < 4; ++nf) {
        int col = wn * 64 + nf * 16 + kq * 4;
        bm4[nf] = *(const float4*)&m4_b2[col];
        float4 a = *(const float4*)&f_bih[col];
        float4 b = *(const float4*)&f_bhh[col];
        bfv[nf] = (float4){a.x + b.x, a.y + b.y, a.z + b.z, a.w + b.w};
        a = *(const float4*)&r_bih[col];
        b = *(const float4*)&r_bhh[col];
        brv[nf] = (float4){a.x + b.x, a.y + b.y, a.z + b.z, a.w + b.w};
    }

    f32x4 acc[4][4];
    #pragma unroll
    for (int i = 0; i < 4; ++i)
        #pragma unroll
        for (int j = 0; j < 4; ++j)
            acc[i][j] = (f32x4){0.f, 0.f, 0.f, 0.f};

#define FG_ST(h) do { int sl_ = (h) % 3;                                    \
    if ((h) < 8) {                                                          \
        gll16(Ag + (h) * 32, &slotA[sl_][w][0]);                            \
        gll16(w_m42 + bo0 + (h) * 32, &slotB[sl_][2 * w][0]);               \
        gll16(w_m42 + bo1 + (h) * 32, &slotB[sl_][2 * w + 1][0]);           \
    } else {                                                                \
        const ushort_t* Wp_ = ((h) < 16) ? w_fih : w_rih;                   \
        int kk_ = ((h) & 7) * 32;                                           \
        gll16(Wp_ + bo0 + kk_, &slotB[sl_][2 * w][0]);                      \
        gll16(Wp_ + bo1 + kk_, &slotB[sl_][2 * w + 1][0]);                  \
    } } while (0)

    FG_ST(0); FG_ST(1);
    asm volatile("s_waitcnt vmcnt(3)" ::: "memory");
    __builtin_amdgcn_s_barrier();

    #pragma unroll
    for (int h = 0; h < 24; ++h) {
        if (h + 2 < 24) FG_ST(h + 2);
        const int sl = h % 3, kt = h & 7;
        bf16x8 af[4], bfr[4];
        #pragma unroll
        for (int nf = 0; nf < 4; ++nf)
            bfr[nf] = *(const bf16x8*)&slotB[sl][wn * 4 + nf][lane * 8];
        if (h < 8) {
            #pragma unroll
            for (int mf = 0; mf < 4; ++mf)
                af[mf] = *(const bf16x8*)&slotA[sl][wm * 4 + mf][lane * 8];
        } else {
            #pragma unroll
            for (int mf = 0; mf < 4; ++mf)
                af[mf] = *(const bf16x8*)&M2[wm * 4 + mf][kt][lane * 8];
        }
        __builtin_amdgcn_s_setprio(1);
        #pragma unroll
        for (int mf = 0; mf < 4; ++mf)
            #pragma unroll
            for (int nf = 0; nf < 4; ++nf)
                acc[mf][nf] = __builtin_amdgcn_mfma_f32_16x16x32_bf16(bfr[nf], af[mf], acc[mf][nf], 0, 0, 0);
        __builtin_amdgcn_s_setprio(0);

        if (h == 7) {     // M2 -> LDS (fragment order), reset acc
            #pragma unroll
            for (int mf = 0; mf < 4; ++mf) {
                #pragma unroll
                for (int nf = 0; nf < 4; ++nf) {
                    ushort4 o;
                    o.x = f2b(eluf(acc[mf][nf][0] + bm4[nf].x));
                    o.y = f2b(eluf(acc[mf][nf][1] + bm4[nf].y));
                    o.z = f2b(eluf(acc[mf][nf][2] + bm4[nf].z));
                    o.w = f2b(eluf(acc[mf][nf][3] + bm4[nf].w));
                    int ktw = wn * 2 + (nf >> 1);
                    int lanew = r16 + 16 * (((nf & 1) << 1) | (kq >> 1));
                    *(ushort4*)&M2[wm * 4 + mf][ktw][lanew * 8 + (kq & 1) * 4] = o;
                    acc[mf][nf] = (f32x4){0.f, 0.f, 0.f, 0.f};
                }
            }
        }
        if (h == 15) {    // GF -> T1 (in-place, block-private rows), reset acc
            #pragma unroll
            for (int mf = 0; mf < 4; ++mf) {
                int row = m0 + wm * 64 + mf * 16 + r16;
                #pragma unroll
                for (int nf = 0; nf < 4; ++nf) {
                    int col = wn * 64 + nf * 16 + kq * 4;
                    ushort4 o;
                    o.x = f2b(acc[mf][nf][0] + bfv[nf].x);
                    o.y = f2b(acc[mf][nf][1] + bfv[nf].y);
                    o.z = f2b(acc[mf][nf][2] + bfv[nf].z);
                    o.w = f2b(acc[mf][nf][3] + bfv[nf].w);
                    *(ushort4*)&T1[(size_t)row * 256 + col] = o;
                    acc[mf][nf] = (f32x4){0.f, 0.f, 0.f, 0.f};
                }
            }
        }
        if (h == 23) {    // GR
            #pragma unroll
            for (int mf = 0; mf < 4; ++mf) {
                int row = m0 + wm * 64 + mf * 16 + r16;
                #pragma unroll
                for (int nf = 0; nf < 4; ++nf) {
                    int col = wn * 64 + nf * 16 + kq * 4;
                    ushort4 o;
                    o.x = f2b(acc[mf][nf][0] + brv[nf].x);
                    o.y = f2b(acc[mf][nf][1] + brv[nf].y);
                    o.z = f2b(acc[mf][nf][2] + brv[nf].z);
                    o.w = f2b(acc[mf][nf][3] + brv[nf].w);
                    *(ushort4*)&GR[(size_t)row * 256 + col] = o;
                }
            }
        }

        asm volatile("s_waitcnt lgkmcnt(0)" ::: "memory");
        if (h == 15)      { asm volatile("s_waitcnt vmcnt(0)" ::: "memory"); }
        else if (h <= 5)  { asm volatile("s_waitcnt vmcnt(3)" ::: "memory"); }
        else if (h <= 21) { asm volatile("s_waitcnt vmcnt(2)" ::: "memory"); }
        else if (h == 22) { asm volatile("s_waitcnt vmcnt(0)" ::: "memory"); }
        if (h < 23) __builtin_amdgcn_s_barrier();
    }
#undef FG_ST
}

// ===========================================================================
// mlp4 layer-1 variant: KD=768, A gathered on the fly (unchanged from r8).
// ===========================================================================
__global__ __launch_bounds__(512, 2) void gemm8_mlp4_k(
    const ushort_t* __restrict__ X2b, const ushort_t* __restrict__ EA,
    const ushort_t* __restrict__ Wt, const float* __restrict__ b1,
    ushort_t* __restrict__ C)
{
    __shared__ ushort_t lds[4][32][512];   // 128 KB
    const int tid = threadIdx.x;
    const int lane = tid & 63;
    const int w = tid >> 6;
    const int wm = w >> 2, wn = w & 3;
    const int m0 = blockIdx.x * 256;
    const int r16 = lane & 15, kq = lane >> 4;
    constexpr int NH = 24;

    const ushort_t* AS[2]; const ushort_t* AR[2]; const ushort_t* AE[2];
    #pragma unroll
    for (int ff = 0; ff < 2; ++ff) {
        int f = w + ff * 8;
        int m = m0 + f * 16 + r16;
        int be = m >> 6, t = m & 63;
        int b = be / E_, e = be % E_;
        int s = e / (V_ - 1);
        int r0 = e % (V_ - 1);
        int rr = r0 + (r0 >= s ? 1 : 0);
        AS[ff] = X2b + ((size_t)((b * V_ + s) * T_ + t)) * H_ + kq * 8;
        AR[ff] = X2b + ((size_t)((b * V_ + rr) * T_ + t)) * H_ + kq * 8;
        AE[ff] = EA + (size_t)m * H_ + kq * 8;
    }
    const ushort_t* Bg0 = Wt + (size_t)(w * 16 + r16) * 768 + kq * 8;
    const ushort_t* Bg1 = Wt + (size_t)((w + 8) * 16 + r16) * 768 + kq * 8;

    f32x4 acc[8][4];
    #pragma unroll
    for (int i = 0; i < 8; ++i)
        #pragma unroll
        for (int j = 0; j < 4; ++j)
            acc[i][j] = (f32x4){0.f, 0.f, 0.f, 0.f};

#define STM(h) do { int sl_ = (h) & 3; int kk_ = (h) * 32;                  \
    int seg_ = kk_ >> 8, off_ = kk_ & 255;                                  \
    const ushort_t* a0_ = (seg_ == 0 ? AS[0] : seg_ == 1 ? AR[0] : AE[0]) + off_; \
    const ushort_t* a1_ = (seg_ == 0 ? AS[1] : seg_ == 1 ? AR[1] : AE[1]) + off_; \
    gll16(a0_, &lds[sl_][w][0]);                                            \
    gll16(a1_, &lds[sl_][w + 8][0]);                                        \
    gll16(Bg0 + kk_, &lds[sl_][16 + w][0]);                                 \
    gll16(Bg1 + kk_, &lds[sl_][16 + w + 8][0]);                             \
} while (0)

    STM(0); STM(1); STM(2);
    asm volatile("s_waitcnt vmcnt(8)" ::: "memory");
    __builtin_amdgcn_s_barrier();

    for (int h = 0; h < NH; ++h) {
        if (h + 3 < NH) STM(h + 3);
        const int sl = h & 3;
        bf16x8 bfr[4];
        #pragma unroll
        for (int nf = 0; nf < 4; ++nf)
            bfr[nf] = *(const bf16x8*)&lds[sl][16 + wn * 4 + nf][lane * 8];
        #pragma unroll
        for (int mh = 0; mh < 2; ++mh) {
            bf16x8 af[4];
            #pragma unroll
            for (int mf = 0; mf < 4; ++mf)
                af[mf] = *(const bf16x8*)&lds[sl][wm * 8 + mh * 4 + mf][lane * 8];
            __builtin_amdgcn_s_setprio(1);
            #pragma unroll
            for (int mf = 0; mf < 4; ++mf)
                #pragma unroll
                for (int nf = 0; nf < 4; ++nf)
                    acc[mh * 4 + mf][nf] = __builtin_amdgcn_mfma_f32_16x16x32_bf16(
                        bfr[nf], af[mf], acc[mh * 4 + mf][nf], 0, 0, 0);
            __builtin_amdgcn_s_setprio(0);
        }
        asm volatile("s_waitcnt lgkmcnt(0)" ::: "memory");
        if (h < NH - 3)       { asm volatile("s_waitcnt vmcnt(8)" ::: "memory"); }
        else if (h == NH - 3) { asm volatile("s_waitcnt vmcnt(4)" ::: "memory"); }
        else if (h == NH - 2) { asm volatile("s_waitcnt vmcnt(0)" ::: "memory"); }
        if (h < NH - 1) __builtin_amdgcn_s_barrier();
    }
#undef STM

    #pragma unroll
    for (int mi = 0; mi < 8; ++mi) {
        int mrow = m0 + wm * 128 + mi * 16 + r16;
        #pragma unroll
        for (int nf = 0; nf < 4; ++nf) {
            int nb = wn * 64 + nf * 16 + kq * 4;
            float4 bb = *(const float4*)&b1[nb];
            float v0 = eluf(acc[mi][nf][0] + bb.x);
            float v1 = eluf(acc[mi][nf][1] + bb.y);
            float v2 = eluf(acc[mi][nf][2] + bb.z);
            float v3 = eluf(acc[mi][nf][3] + bb.w);
            ushort4 o; o.x = f2b(v0); o.y = f2b(v1); o.z = f2b(v2); o.w = f2b(v3);
            *(ushort4*)&C[(size_t)mrow * 256 + nb] = o;
        }
    }
}

// ===========================================================================
// weights f32 -> bf16 (packed): ef_w2 | m4_w1 | m4_w2 | f_wih | r_wih | e_w1
// ===========================================================================
__global__ __launch_bounds__(256) void wconv_k(
    const float* __restrict__ ef_w2, const float* __restrict__ m4_w1,
    const float* __restrict__ m4_w2, const float* __restrict__ f_wih,
    const float* __restrict__ r_wih, const float* __restrict__ e_w1,
    ushort_t* __restrict__ Wb)
{
    int i = blockIdx.x * 256 + threadIdx.x;   // < 491520
    const float* src; int off;
    if (i < 65536)       { src = ef_w2; off = i; }
    else if (i < 262144) { src = m4_w1; off = i - 65536; }
    else if (i < 327680) { src = m4_w2; off = i - 262144; }
    else if (i < 393216) { src = f_wih; off = i - 327680; }
    else if (i < 458752) { src = r_wih; off = i - 393216; }
    else                 { src = e_w1;  off = i - 458752; }
    Wb[i] = f2b(src[off]);
}

// ---------------------------------------------------------------------------
// Generic VALU GEMM (kept for mlp3 node rows): C = act(A@W.T + b1)
// ---------------------------------------------------------------------------
template<typename TA, typename TO>
__global__ __launch_bounds__(256) void gemm_t(
    const TA* __restrict__ A, const float* __restrict__ W,
    const float* __restrict__ b1, const float* __restrict__ b2,
    TO* __restrict__ C, int M, int Kd, int N, int act)
{
    __shared__ float As[16][64];
    __shared__ float Ws[16][64];
    const int m0 = blockIdx.x * 64, n0 = blockIdx.y * 64;
    const int tid = threadIdx.x;
    const int tm = tid >> 4, tn = tid & 15;
    const int lm = tid >> 2, lq = tid & 3;
    float acc[4][4] = {};
    const TA* Arow = A + (size_t)(m0 + lm) * Kd + lq * 4;
    const float* Wrow = W + (size_t)(n0 + lm) * Kd + lq * 4;
    for (int k0 = 0; k0 < Kd; k0 += 16) {
        float4 av, wv;
        if constexpr (std::is_same<TA, ushort_t>::value) {
            ushort4 u = *(const ushort4*)(Arow + k0);
            av.x = b2f(u.x); av.y = b2f(u.y); av.z = b2f(u.z); av.w = b2f(u.w);
        } else {
            av = *(const float4*)(Arow + k0);
        }
        wv = *(const float4*)(Wrow + k0);
        __syncthreads();
        As[lq*4+0][lm] = av.x; As[lq*4+1][lm] = av.y; As[lq*4+2][lm] = av.z; As[lq*4+3][lm] = av.w;
        Ws[lq*4+0][lm] = wv.x; Ws[lq*4+1][lm] = wv.y; Ws[lq*4+2][lm] = wv.z; Ws[lq*4+3][lm] = wv.w;
        __syncthreads();
        #pragma unroll
        for (int k = 0; k < 16; ++k) {
            float4 a = *(const float4*)&As[k][tm * 4];
            float4 w = *(const float4*)&Ws[k][tn * 4];
            float a_[4] = {a.x, a.y, a.z, a.w};
            float w_[4] = {w.x, w.y, w.z, w.w};
            #pragma unroll
            for (int i = 0; i < 4; ++i)
                #pragma unroll
                for (int j = 0; j < 4; ++j)
                    acc[i][j] += a_[i] * w_[j];
        }
    }
    float bb[4];
    #pragma unroll
    for (int j = 0; j < 4; ++j) {
        int n = n0 + tn * 4 + j;
        bb[j] = b1[n] + (b2 ? b2[n] : 0.f);
    }
    #pragma unroll
    for (int i = 0; i < 4; ++i) {
        float v0 = acc[i][0] + bb[0], v1 = acc[i][1] + bb[1];
        float v2 = acc[i][2] + bb[2], v3 = acc[i][3] + bb[3];
        if (act) { v0 = eluf(v0); v1 = eluf(v1); v2 = eluf(v2); v3 = eluf(v3); }
        TO* dst = C + (size_t)(m0 + tm * 4 + i) * N + (n0 + tn * 4);
        if constexpr (std::is_same<TO, ushort_t>::value) {
            ushort4 o; o.x = f2b(v0); o.y = f2b(v1); o.z = f2b(v2); o.w = f2b(v3);
            *(ushort4*)dst = o;
        } else {
            float4 o; o.x = v0; o.y = v1; o.z = v2; o.w = v3;
            *(float4*)dst = o;
        }
    }
}

// ---------------------------------------------------------------------------
// edge2node: X[b,v,t,h] = (1/15)*sum_{e:RECV==v} EA[b,e,t,h] + rel@res_w.T + res_b
// ---------------------------------------------------------------------------
__global__ __launch_bounds__(256) void e2n_k(
    const ushort_t* __restrict__ EA, const float* __restrict__ rel,
    const float* __restrict__ res_w, const float* __restrict__ res_b,
    float* __restrict__ X)
{
    const int idx = blockIdx.x;            // (b*V+v)*T + t
    const int t = idx & (T_ - 1);
    const int bv = idx >> 6;
    const int v = bv & (V_ - 1);
    const int b = bv >> 4;
    const int h = threadIdx.x;
    float sum = 0.f;
    #pragma unroll
    for (int i = 0; i < V_; ++i) {
        if (i == v) continue;
        int jj = (v < i) ? v : v - 1;
        int e = i * (V_ - 1) + jj;
        sum += b2f(EA[(((size_t)(b * E_ + e)) * T_ + t) * H_ + h]);
    }
    const float* rp = rel + ((size_t)bv * T_ + t) * DIN_;
    float res = res_b[h];
    #pragma unroll
    for (int d = 0; d < DIN_; ++d) res += rp[d] * res_w[h * DIN_ + d];
    X[((size_t)bv * T_ + t) * H_ + h] = sum * (1.f / 15.f) + res;
}

// ===========================================================================
// MFMA LSTM scan, both directions in one dispatch (blockIdx.y = dir).
// 4 cooperative waves per block, 16 sequences per block.
// ===========================================================================
__global__ __launch_bounds__(256) void lstm_mfma4_k(
    const ushort_t* __restrict__ Gf, const ushort_t* __restrict__ Gr,
    const float* __restrict__ whh_f, const float* __restrict__ whh_r,
    ushort_t* __restrict__ COMB)
{
    __shared__ ushort_t hlds[2][1024];   // 2 x 2KB: h[seq][j] bf16, XOR-swizzled
    const int dir = blockIdx.y;
    const ushort_t* G = dir ? Gr : Gf;
    const float* whh = dir ? whh_r : whh_f;
    const int tid = threadIdx.x;
    const int lane = tid & 63;
    const int w = tid >> 6;              // wave id = j-block
    const int seq = lane & 15, kq = lane >> 4;
    const int be0 = blockIdx.x * 16;
    const int swz = (seq & 7) << 4;

    bf16x8 wf[4][2];
    #pragma unroll
    for (int a = 0; a < 4; ++a) {
        #pragma unroll
        for (int ks = 0; ks < 2; ++ks) {
            const float* p = whh + (size_t)((a * 4 + w) * 16 + seq) * 64 + ks * 32 + kq * 8;
            float4 x0 = *(const float4*)p;
            float4 x1 = *(const float4*)(p + 4);
            bf16x8 v;
            v[0] = (short)f2b(x0.x); v[1] = (short)f2b(x0.y);
            v[2] = (short)f2b(x0.z); v[3] = (short)f2b(x0.w);
            v[4] = (short)f2b(x1.x); v[5] = (short)f2b(x1.y);
            v[6] = (short)f2b(x1.z); v[7] = (short)f2b(x1.w);
            wf[a][ks] = v;
        }
    }

    const ushort_t* grow = G + ((size_t)(be0 + seq) * T_) * 256 + kq * 4;
    ushort_t* crow = COMB + ((size_t)(be0 + seq) * T_) * 128 + (dir ? 64 : 0) + 16 * w + 4 * kq;

    float c[4] = {};
    ushort4 gx[4];
    const int t0 = dir ? (T_ - 1) : 0;
    #pragma unroll
    for (int a = 0; a < 4; ++a)
        gx[a] = *(const ushort4*)(grow + (size_t)t0 * 256 + (a * 4 + w) * 16);

    for (int s = 0; s < T_; ++s) {
        const int t = dir ? (T_ - 1 - s) : s;
        f32x4 acc[4];
        #pragma unroll
        for (int a = 0; a < 4; ++a) {
            ushort4 g = gx[a];
            acc[a] = (f32x4){b2f(g.x), b2f(g.y), b2f(g.z), b2f(g.w)};
        }
        if (s < T_ - 1) {
            const int tn = dir ? (T_ - 2 - s) : (s + 1);
            #pragma unroll
            for (int a = 0; a < 4; ++a)
                gx[a] = *(const ushort4*)(grow + (size_t)tn * 256 + (a * 4 + w) * 16);
        }
        if (s) {
            bf16x8 af[2];
            #pragma unroll
            for (int ks = 0; ks < 2; ++ks) {
                int boff = (seq * 128 + ks * 64 + kq * 16) ^ swz;
                af[ks] = *(const bf16x8*)((const char*)hlds[(s - 1) & 1] + boff);
            }
            #pragma unroll
            for (int a = 0; a < 4; ++a) {
                acc[a] = __builtin_amdgcn_mfma_f32_16x16x32_bf16(wf[a][0], af[0], acc[a], 0, 0, 0);
                acc[a] = __builtin_amdgcn_mfma_f32_16x16x32_bf16(wf[a][1], af[1], acc[a], 0, 0, 0);
            }
        }
        float hh[4];
        #pragma unroll
        for (int r = 0; r < 4; ++r) {
            float zi = acc[0][r], zf = acc[1][r], zg = acc[2][r], zo = acc[3][r];
            float cc = fsig(zf) * c[r] + fsig(zi) * ftanh_(zg);
            c[r] = cc;
            hh[r] = fsig(zo) * ftanh_(cc);
        }
        ushort4 hv;
        hv.x = f2b(hh[0]); hv.y = f2b(hh[1]); hv.z = f2b(hh[2]); hv.w = f2b(hh[3]);
        int wb = (seq * 128 + 32 * w + 8 * kq) ^ swz;
        *(ushort4*)((char*)hlds[s & 1] + wb) = hv;
        *(ushort4*)(crow + (size_t)t * 128) = hv;
        asm volatile("s_waitcnt lgkmcnt(0)" ::: "memory");
        __builtin_amdgcn_sched_barrier(0);
        __builtin_amdgcn_s_barrier();
    }
}

// ---------------------------------------------------------------------------
// prior head: reads fwd hidden from comb[:, 0:64] (row stride 128)
// ---------------------------------------------------------------------------
__global__ __launch_bounds__(256) void prior_k(
    const ushort_t* __restrict__ COMB, const float* __restrict__ p_w,
    const float* __restrict__ p_b, float* __restrict__ out)
{
    const int row = blockIdx.x * 4 + (threadIdx.x >> 6);  // [0, BET)
    const int lane = threadIdx.x & 63;
    float hf = b2f(COMB[(size_t)row * 128 + lane]);
    float v0 = hf * p_w[lane];
    float v1 = hf * p_w[64 + lane];
    #pragma unroll
    for (int off = 32; off > 0; off >>= 1) {
        v0 += __shfl_down(v0, off, 64);
        v1 += __shfl_down(v1, off, 64);
    }
    if (lane == 0) {
        int t = row & (T_ - 1);
        int be = row >> 6;
        int e = be % E_, b = be / E_;
        size_t o = (((size_t)b * T_ + t) * E_ + e) * K_;
        out[o] = v0 + p_b[0];
        out[o + 1] = v1 + p_b[1];
    }
}

// ===========================================================================
// FUSED: ENCH = elu(COMB@e_w1.T + e_b1) in regs, then out = ENCH@e_w2.T + e_b2
// with transpose-scatter. 8 waves, 128 rows/block, K=128 (4 steps).
// ===========================================================================
__global__ __launch_bounds__(512) void fused_enc_k(
    const ushort_t* __restrict__ COMB, const ushort_t* __restrict__ w_e1,
    const float* __restrict__ e_b1, const float* __restrict__ e_w2,
    const float* __restrict__ e_b2, float* __restrict__ out)
{
    __shared__ ushort_t sA[2][8][512];    // 16 KB
    __shared__ ushort_t sW[2][16][512];   // 32 KB
    __shared__ float part[128][4][2];     // 4 KB
    const int tid = threadIdx.x;
    const int lane = tid & 63;
    const int w = tid >> 6;
    const int wr = w >> 2, wc = w & 3;
    const int m0 = blockIdx.x * 128;
    const int r16 = lane & 15, kq = lane >> 4;

    const ushort_t* Asrc = COMB + (size_t)(m0 + w * 16 + r16) * 128 + kq * 8;
    const size_t woffA = (size_t)((2 * w) * 16 + r16) * 128 + kq * 8;
    const size_t woffB = (size_t)((2 * w + 1) * 16 + r16) * 128 + kq * 8;

    float4 w2v[2][4];
    #pragma unroll
    for (int j = 0; j < 2; ++j)
        #pragma unroll
        for (int nf = 0; nf < 4; ++nf)
            w2v[j][nf] = *(const float4*)&e_w2[j * 256 + wc * 64 + nf * 16 + kq * 4];

    f32x4 acc[4][4];
    #pragma unroll
    for (int i = 0; i < 4; ++i)
        #pragma unroll
        for (int j = 0; j < 4; ++j)
            acc[i][j] = (f32x4){0.f, 0.f, 0.f, 0.f};

#define FE_STAGE(bufi, kt_) do {                                             \
    gll16(Asrc + (kt_) * 32, &sA[bufi][w][0]);                               \
    gll16(w_e1 + woffA + (kt_) * 32, &sW[bufi][2 * w][0]);                   \
    gll16(w_e1 + woffB + (kt_) * 32, &sW[bufi][2 * w + 1][0]);               \
} while (0)

    FE_STAGE(0, 0);
    asm volatile("s_waitcnt vmcnt(0)" ::: "memory");
    __builtin_amdgcn_s_barrier();

    for (int s = 0; s < 4; ++s) {
        const int buf = s & 1;
        if (s < 3) FE_STAGE(buf ^ 1, s + 1);
        bf16x8 af[4], bfr[4];
        #pragma unroll
        for (int mf = 0; mf < 4; ++mf)
            af[mf] = *(const bf16x8*)&sA[buf][wr * 4 + mf][lane * 8];
        #pragma unroll
        for (int nf = 0; nf < 4; ++nf)
            bfr[nf] = *(const bf16x8*)&sW[buf][wc * 4 + nf][lane * 8];
        #pragma unroll
        for (int mf = 0; mf < 4; ++mf)
            #pragma unroll
            for (int nf = 0; nf < 4; ++nf)
                acc[mf][nf] = __builtin_amdgcn_mfma_f32_16x16x32_bf16(bfr[nf], af[mf], acc[mf][nf], 0, 0, 0);
        asm volatile("s_waitcnt vmcnt(0)" ::: "memory");
        __builtin_amdgcn_s_barrier();
    }

    #pragma unroll
    for (int mf = 0; mf < 4; ++mf) {
        float s0 = 0.f, s1 = 0.f;
        #pragma unroll
        for (int nf = 0; nf < 4; ++nf) {
            int col = wc * 64 + nf * 16 + kq * 4;
            float4 bb = *(const float4*)&e_b1[col];
            float v0 = eluf(acc[mf][nf][0] + bb.x);
            float v1 = eluf(acc[mf][nf][1] + bb.y);
            float v2 = eluf(acc[mf][nf][2] + bb.z);
            float v3 = eluf(acc[mf][nf][3] + bb.w);
            s0 += v0 * w2v[0][nf].x + v1 * w2v[0][nf].y + v2 * w2v[0][nf].z + v3 * w2v[0][nf].w;
            s1 += v0 * w2v[1][nf].x + v1 * w2v[1][nf].y + v2 * w2v[1][nf].z + v3 * w2v[1][nf].w;
        }
        s0 += __shfl_xor(s0, 16, 64); s0 += __shfl_xor(s0, 32, 64);
        s1 += __shfl_xor(s1, 16, 64); s1 += __shfl_xor(s1, 32, 64);
        if (kq == 0) {
            part[wr * 64 + mf * 16 + r16][wc][0] = s0;
            part[wr * 64 + mf * 16 + r16][wc][1] = s1;
        }
    }
    __syncthreads();
    if (tid < 256) {
        int row = tid >> 1, k = tid & 1;
        float v = part[row][0][k] + part[row][1][k] + part[row][2][k] + part[row][3][k] + e_b2[k];
        int gr = m0 + row;
        int be = gr >> 6, t = gr & 63;
        int e = be % E_, b = be / E_;
        out[(size_t)(B_ * T_ * E_ * K_) + (((size_t)b * T_ + t) * E_ + e) * K_ + k] = v;
    }
#undef FE_STAGE
}

// ---------------------------------------------------------------------------
extern "C" void kernel_launch(void* const* d_in, const int* in_sizes, int n_in,
                              void* d_out, int out_size, void* d_ws, size_t ws_size,
                              hipStream_t stream)
{
    const float* rel    = (const float*)d_in[0];
    const float* ear    = (const float*)d_in[1];
    const float* epos   = (const float*)d_in[2];
    const float* ef_w1  = (const float*)d_in[3];
    const float* ef_b1  = (const float*)d_in[4];
    const float* ef_w2  = (const float*)d_in[5];
    const float* ef_b2  = (const float*)d_in[6];
    const float* res_w  = (const float*)d_in[7];
    const float* res_b  = (const float*)d_in[8];
    const float* m3_w1  = (const float*)d_in[9];
    const float* m3_b1  = (const float*)d_in[10];
    const float* m3_w2  = (const float*)d_in[11];
    const float* m3_b2  = (const float*)d_in[12];
    const float* m4_w1  = (const float*)d_in[13];
    const float* m4_b1  = (const float*)d_in[14];
    const float* m4_w2  = (const float*)d_in[15];
    const float* m4_b2  = (const float*)d_in[16];
    const float* f_wih  = (const float*)d_in[17];
    const float* f_whh  = (const float*)d_in[18];
    const float* f_bih  = (const float*)d_in[19];
    const float* f_bhh  = (const float*)d_in[20];
    const float* r_wih  = (const float*)d_in[21];
    const float* r_whh  = (const float*)d_in[22];
    const float* r_bih  = (const float*)d_in[23];
    const float* r_bhh  = (const float*)d_in[24];
    const float* p_w    = (const float*)d_in[25];
    const float* p_b    = (const float*)d_in[26];
    const float* e_w1   = (const float*)d_in[27];
    const float* e_b1   = (const float*)d_in[28];
    const float* e_w2   = (const float*)d_in[29];
    const float* e_b2   = (const float*)d_in[30];
    float* out = (float*)d_out;

    // workspace layout (bytes), total ~162.5 MB
    char* ws = (char*)d_ws;
    const size_t BIGB  = (size_t)BET_ * H_ * sizeof(ushort_t);   // 62,914,560
    const size_t COMBB = (size_t)BET_ * 128 * sizeof(ushort_t);  // 31,457,280
    const size_t X2BB  = (size_t)BVT_ * H_ * sizeof(ushort_t);   //  4,194,304
    ushort_t* R1   = (ushort_t*)(ws);
    ushort_t* R2   = (ushort_t*)(ws + BIGB);
    ushort_t* COMB = (ushort_t*)(ws + 2 * BIGB);
    ushort_t* X2b  = (ushort_t*)(ws + 2 * BIGB + COMBB);
    ushort_t* Wb   = (ushort_t*)(ws + 2 * BIGB + COMBB + X2BB);
    // node-stage f32 scratch lives inside (dead) R1 region
    float* X  = (float*)(ws);
    float* XH = (float*)(ws + (size_t)BVT_ * H_ * sizeof(float));
    // packed bf16 weight offsets (elements)
    const ushort_t* wb_ef2  = Wb + 0;
    const ushort_t* wb_m41  = Wb + 65536;
    const ushort_t* wb_m42  = Wb + 262144;
    const ushort_t* wb_fwih = Wb + 327680;
    const ushort_t* wb_rwih = Wb + 393216;
    const ushort_t* wb_ew1  = Wb + 458752;

    dim3 blk(256);
    dim3 blk8(512);
    dim3 g128(BET_ / 128);     // 960 blocks (BM=128 kernels)
    dim3 g256(BET_ / 256);     // 480 blocks (BM=256 mlp4)
    dim3 gN(BVT_ / 64, 4);     // VALU node GEMMs

    // 0. weights -> bf16
    wconv_k<<<1920, blk, 0, stream>>>(ef_w2, m4_w1, m4_w2, f_wih, r_wih, e_w1, Wb);
    // 1. fused edge-filter MLP (ein K=16 + ef2 K=256) -> EA in R2
    gemm8_ef_k<<<g128, blk8, 0, stream>>>(ear, epos, ef_w1, ef_b1, wb_ef2, ef_b2, R2);
    // 2. edge2node + residual
    e2n_k<<<BVT_, blk, 0, stream>>>(R2, rel, res_w, res_b, X);
    // 3. mlp3 (node rows, f32 VALU)
    gemm_t<float, float><<<gN, blk, 0, stream>>>(X, m3_w1, m3_b1, nullptr, XH, BVT_, H_, H_, 1);
    gemm_t<float, ushort_t><<<gN, blk, 0, stream>>>(XH, m3_w2, m3_b2, nullptr, X2b, BVT_, H_, H_, 1);
    // 4. node2edge gather + mlp4 layer 1 -> T1 (R1)
    gemm8_mlp4_k<<<g256, blk8, 0, stream>>>(X2b, R2, wb_m41, m4_b1, R1);
    // 5. FUSED m4l2 + GF + GR (M2 in LDS): GF -> R1 (in-place), GR -> R2
    fused_gates8_k<<<g128, blk8, 0, stream>>>(
        R1, R2, wb_m42, wb_fwih, wb_rwih, m4_b2, f_bih, f_bhh, r_bih, r_bhh);
    // 6. LSTM scans, both directions in one dispatch
    lstm_mfma4_k<<<dim3(BE_ / 16, 2), blk, 0, stream>>>(R1, R2, f_whh, r_whh, COMB);
    // 7. heads
    prior_k<<<BET_ / 4, blk, 0, stream>>>(COMB, p_w, p_b, out);
    fused_enc_k<<<g128, blk8, 0, stream>>>(COMB, wb_ew1, e_b1, e_w2, e_b2, out);
}

// Round 10
// 448.597 us; speedup vs baseline: 5.9021x; 1.0097x over previous
//
#include <hip/hip_runtime.h>
#include <cstdint>
#include <cstddef>
#include <type_traits>

// Problem constants
#define B_ 8
#define V_ 16
#define T_ 64
#define E_ 240          // V*(V-1)
#define H_ 256
#define RH_ 64
#define K_ 2
#define DIN_ 6
#define BET_ (B_*E_*T_)   // 122880
#define BVT_ (B_*V_*T_)   // 8192
#define BE_ (B_*E_)       // 1920

typedef unsigned short ushort_t;
typedef unsigned int u32;
typedef __attribute__((ext_vector_type(8))) short bf16x8;
typedef __attribute__((ext_vector_type(4))) float f32x4;

__device__ __forceinline__ float eluf(float x) { return x > 0.f ? x : __expf(x) - 1.f; }
__device__ __forceinline__ float fsig(float x) { return 1.f / (1.f + __expf(-x)); }
__device__ __forceinline__ float ftanh_(float x) {
    float y = fminf(fmaxf(x, -8.f), 8.f);
    float e = __expf(2.f * y);
    return (e - 1.f) / (e + 1.f);
}
__device__ __forceinline__ float b2f(ushort_t u) {
    union { float f; uint32_t i; } v; v.i = ((uint32_t)u) << 16; return v.f;
}
__device__ __forceinline__ ushort_t f2b(float f) {
    union { float f; uint32_t i; } v; v.f = f;
    uint32_t r = (v.i + 0x7FFFu + ((v.i >> 16) & 1u)) >> 16;
    return (ushort_t)r;
}

// async global->LDS, 16B per lane; LDS dest = wave-uniform base + lane*16
__device__ __forceinline__ void gll16(const void* g, void* l) {
    __builtin_amdgcn_global_load_lds(
        (const __attribute__((address_space(1))) u32*)g,
        (__attribute__((address_space(3))) u32*)l, 16, 0, 0);
}

// ===========================================================================
// FUSED ein(K=16 f32) + ef2(K=256) : EA = elu(elu(ein@efw1+b1)@efw2+b2)
// (unchanged from round 9 — works)
// ===========================================================================
__global__ __launch_bounds__(512, 1) void gemm8_ef_k(
    const float* __restrict__ ear, const float* __restrict__ epos,
    const float* __restrict__ ef_w1, const float* __restrict__ ef_b1,
    const ushort_t* __restrict__ w_ef2, const float* __restrict__ ef_b2,
    ushort_t* __restrict__ EA)
{
    __shared__ ushort_t H1[8][8][512];      // 64 KB
    __shared__ ushort_t slotB[4][16][512];  // 64 KB  (total 128 KB)
    const int tid = threadIdx.x;
    const int lane = tid & 63;
    const int w = tid >> 6;
    const int wm = w >> 2, wn = w & 3;
    const int m0 = blockIdx.x * 128;
    const int r16 = lane & 15, kq = lane >> 4;

    f32x4 acc[4][4];
    #pragma unroll
    for (int i = 0; i < 4; ++i)
        #pragma unroll
        for (int j = 0; j < 4; ++j)
            acc[i][j] = (f32x4){0.f, 0.f, 0.f, 0.f};
    {
        bf16x8 af[4], bfr[4];
        #pragma unroll
        for (int mf = 0; mf < 4; ++mf) {
            int m = m0 + wm * 64 + mf * 16 + r16;
            #pragma unroll
            for (int e = 0; e < 8; ++e) {
                float v = 0.f;
                if (kq < 2) {
                    int c = kq * 8 + e;
                    v = (c < 13) ? ear[(size_t)m * 13 + c] : epos[(size_t)m * 3 + (c - 13)];
                }
                af[mf][e] = (short)f2b(v);
            }
        }
        #pragma unroll
        for (int nf = 0; nf < 4; ++nf) {
            int n = wn * 64 + nf * 16 + r16;
            #pragma unroll
            for (int e = 0; e < 8; ++e) {
                float v = 0.f;
                if (kq < 2) v = ef_w1[(size_t)n * 16 + kq * 8 + e];
                bfr[nf][e] = (short)f2b(v);
            }
        }
        #pragma unroll
        for (int mf = 0; mf < 4; ++mf)
            #pragma unroll
            for (int nf = 0; nf < 4; ++nf)
                acc[mf][nf] = __builtin_amdgcn_mfma_f32_16x16x32_bf16(bfr[nf], af[mf], acc[mf][nf], 0, 0, 0);
    }

    const size_t bo0 = (size_t)(2 * w * 16 + r16) * 256 + kq * 8;
    const size_t bo1 = (size_t)((2 * w + 1) * 16 + r16) * 256 + kq * 8;
#define EF_ST(h) do { int sl_ = (h) & 3;                                    \
    gll16(w_ef2 + bo0 + (h) * 32, &slotB[sl_][2 * w][0]);                   \
    gll16(w_ef2 + bo1 + (h) * 32, &slotB[sl_][2 * w + 1][0]);               \
} while (0)

    EF_ST(0); EF_ST(1); EF_ST(2);

    #pragma unroll
    for (int mf = 0; mf < 4; ++mf) {
        #pragma unroll
        for (int nf = 0; nf < 4; ++nf) {
            int col = wn * 64 + nf * 16 + kq * 4;
            float4 bb = *(const float4*)&ef_b1[col];
            ushort4 o;
            o.x = f2b(eluf(acc[mf][nf][0] + bb.x));
            o.y = f2b(eluf(acc[mf][nf][1] + bb.y));
            o.z = f2b(eluf(acc[mf][nf][2] + bb.z));
            o.w = f2b(eluf(acc[mf][nf][3] + bb.w));
            int ktw = wn * 2 + (nf >> 1);
            int lanew = r16 + 16 * (((nf & 1) << 1) | (kq >> 1));
            *(ushort4*)&H1[wm * 4 + mf][ktw][lanew * 8 + (kq & 1) * 4] = o;
            acc[mf][nf] = (f32x4){0.f, 0.f, 0.f, 0.f};
        }
    }
    asm volatile("s_waitcnt lgkmcnt(0)" ::: "memory");
    asm volatile("s_waitcnt vmcnt(4)" ::: "memory");
    __builtin_amdgcn_s_barrier();

    #pragma unroll
    for (int h = 0; h < 8; ++h) {
        if (h + 3 < 8) EF_ST(h + 3);
        const int sl = h & 3;
        bf16x8 af[4], bfr[4];
        #pragma unroll
        for (int nf = 0; nf < 4; ++nf)
            bfr[nf] = *(const bf16x8*)&slotB[sl][wn * 4 + nf][lane * 8];
        #pragma unroll
        for (int mf = 0; mf < 4; ++mf)
            af[mf] = *(const bf16x8*)&H1[wm * 4 + mf][h][lane * 8];
        __builtin_amdgcn_s_setprio(1);
        #pragma unroll
        for (int mf = 0; mf < 4; ++mf)
            #pragma unroll
            for (int nf = 0; nf < 4; ++nf)
                acc[mf][nf] = __builtin_amdgcn_mfma_f32_16x16x32_bf16(bfr[nf], af[mf], acc[mf][nf], 0, 0, 0);
        __builtin_amdgcn_s_setprio(0);
        asm volatile("s_waitcnt lgkmcnt(0)" ::: "memory");
        if (h <= 4)      { asm volatile("s_waitcnt vmcnt(4)" ::: "memory"); }
        else if (h == 5) { asm volatile("s_waitcnt vmcnt(2)" ::: "memory"); }
        else if (h == 6) { asm volatile("s_waitcnt vmcnt(0)" ::: "memory"); }
        if (h < 7) __builtin_amdgcn_s_barrier();
    }
#undef EF_ST

    #pragma unroll
    for (int mf = 0; mf < 4; ++mf) {
        int row = m0 + wm * 64 + mf * 16 + r16;
        #pragma unroll
        for (int nf = 0; nf < 4; ++nf) {
            int col = wn * 64 + nf * 16 + kq * 4;
            float4 bb = *(const float4*)&ef_b2[col];
            ushort4 o;
            o.x = f2b(eluf(acc[mf][nf][0] + bb.x));
            o.y = f2b(eluf(acc[mf][nf][1] + bb.y));
            o.z = f2b(eluf(acc[mf][nf][2] + bb.z));
            o.w = f2b(eluf(acc[mf][nf][3] + bb.w));
            *(ushort4*)&EA[(size_t)row * 256 + col] = o;
        }
    }
}

// ===========================================================================
// FUSED m4l2 -> M2(LDS) -> [GF | GR] (v2): BM=128, 8 waves.
// Phase 0 (8 halves): wave-tile 128x32 (acc[8][2]) computing M2 cols 32w..;
//   stage A(T1) 1 load/wave + B(m42) 2 loads/wave, 3 slots, depth stage h+2.
// Phase 1 (8 halves): N=512 = [GF|GR]; wave w -> cols 64*(w&3) of (w<4?GF:GR),
//   wave-tile 128x64 (acc[8][4]); A = M2 from LDS; B staged 4 loads/wave,
//   2 slots depth-1. ALL stores at the end (no mid-loop vmcnt(0) drain).
// LDS: M2 64 KB + slots union 72 KB = 136 KB.
// ===========================================================================
__global__ __launch_bounds__(512, 1) void fused_gates9_k(
    ushort_t* __restrict__ T1, ushort_t* __restrict__ GR,
    const ushort_t* __restrict__ w_m42, const ushort_t* __restrict__ w_fih,
    const ushort_t* __restrict__ w_rih, const float* __restrict__ m4_b2,
    const float* __restrict__ f_bih, const float* __restrict__ f_bhh,
    const float* __restrict__ r_bih, const float* __restrict__ r_bhh)
{
    __shared__ ushort_t M2[8][8][512];   // 64 KB
    __shared__ ushort_t slots[36864];    // 72 KB union
    const int tid = threadIdx.x;
    const int lane = tid & 63;
    const int w = tid >> 6;
    const int m0 = blockIdx.x * 128;
    const int r16 = lane & 15, kq = lane >> 4;

    const ushort_t* Ag = T1 + (size_t)(m0 + w * 16 + r16) * 256 + kq * 8;
    const size_t bo0 = (size_t)(2 * w * 16 + r16) * 256 + kq * 8;
    const size_t bo1 = (size_t)((2 * w + 1) * 16 + r16) * 256 + kq * 8;

    // hoisted biases
    float4 bm4[2];
    #pragma unroll
    for (int nf = 0; nf < 2; ++nf)
        bm4[nf] = *(const float4*)&m4_b2[w * 32 + nf * 16 + kq * 4];
    const float* bi = (w < 4) ? f_bih : r_bih;
    const float* bh = (w < 4) ? f_bhh : r_bhh;
    float4 bg[4];
    #pragma unroll
    for (int nf = 0; nf < 4; ++nf) {
        int col = (w & 3) * 64 + nf * 16 + kq * 4;
        float4 a = *(const float4*)&bi[col];
        float4 b = *(const float4*)&bh[col];
        bg[nf] = (float4){a.x + b.x, a.y + b.y, a.z + b.z, a.w + b.w};
    }

    // phase-1 B source: wave w stages frags 4w..4w+3 of [fih|rih]
    const ushort_t* WB = (w < 4) ? w_fih : w_rih;
    const int glb = (4 * w) & 15;   // local frag base within its matrix

#define P0_ST(h) do { int sl_ = (h) % 3;                                    \
    gll16(Ag + (h) * 32, &slots[sl_ * 12288 + w * 512]);                    \
    gll16(w_m42 + bo0 + (h) * 32, &slots[sl_ * 12288 + 4096 + 2 * w * 512]);\
    gll16(w_m42 + bo1 + (h) * 32, &slots[sl_ * 12288 + 4096 + (2 * w + 1) * 512]); \
} while (0)
#define P1_ST(h) do { int sl_ = (h) & 1; int kk_ = (h) * 32;                \
    _Pragma("unroll")                                                       \
    for (int j = 0; j < 4; ++j)                                             \
        gll16(WB + (size_t)((glb + j) * 16 + r16) * 256 + kq * 8 + kk_,     \
              &slots[sl_ * 16384 + (4 * w + j) * 512]);                     \
} while (0)

    // ---- phase 0 ----
    f32x4 acc0[8][2];
    #pragma unroll
    for (int i = 0; i < 8; ++i) { acc0[i][0] = (f32x4){0,0,0,0}; acc0[i][1] = (f32x4){0,0,0,0}; }

    P0_ST(0); P0_ST(1);
    asm volatile("s_waitcnt vmcnt(3)" ::: "memory");
    __builtin_amdgcn_s_barrier();

    for (int h = 0; h < 8; ++h) {
        if (h + 2 < 8) P0_ST(h + 2);
        const int sl = h % 3;
        bf16x8 af[8], bfr[2];
        #pragma unroll
        for (int mf = 0; mf < 8; ++mf)
            af[mf] = *(const bf16x8*)&slots[sl * 12288 + mf * 512 + lane * 8];
        #pragma unroll
        for (int nf = 0; nf < 2; ++nf)
            bfr[nf] = *(const bf16x8*)&slots[sl * 12288 + 4096 + (2 * w + nf) * 512 + lane * 8];
        __builtin_amdgcn_s_setprio(1);
        #pragma unroll
        for (int mf = 0; mf < 8; ++mf)
            #pragma unroll
            for (int nf = 0; nf < 2; ++nf)
                acc0[mf][nf] = __builtin_amdgcn_mfma_f32_16x16x32_bf16(bfr[nf], af[mf], acc0[mf][nf], 0, 0, 0);
        __builtin_amdgcn_s_setprio(0);
        asm volatile("s_waitcnt lgkmcnt(0)" ::: "memory");
        if (h <= 5)      { asm volatile("s_waitcnt vmcnt(3)" ::: "memory"); }
        else if (h == 6) { asm volatile("s_waitcnt vmcnt(0)" ::: "memory"); }
        if (h < 7) __builtin_amdgcn_s_barrier();
    }

    // issue first phase-1 B stage early, then write M2 (fragment order)
    P1_ST(0);
    #pragma unroll
    for (int mf = 0; mf < 8; ++mf) {
        #pragma unroll
        for (int nf = 0; nf < 2; ++nf) {
            ushort4 o;
            o.x = f2b(eluf(acc0[mf][nf][0] + bm4[nf].x));
            o.y = f2b(eluf(acc0[mf][nf][1] + bm4[nf].y));
            o.z = f2b(eluf(acc0[mf][nf][2] + bm4[nf].z));
            o.w = f2b(eluf(acc0[mf][nf][3] + bm4[nf].w));
            int lanew = r16 + 16 * ((nf << 1) | (kq >> 1));
            *(ushort4*)&M2[mf][w][lanew * 8 + (kq & 1) * 4] = o;
        }
    }
    asm volatile("s_waitcnt lgkmcnt(0)" ::: "memory");
    asm volatile("s_waitcnt vmcnt(0)" ::: "memory");
    __builtin_amdgcn_s_barrier();

    // ---- phase 1 ----
    f32x4 acc1[8][4];
    #pragma unroll
    for (int i = 0; i < 8; ++i)
        #pragma unroll
        for (int j = 0; j < 4; ++j)
            acc1[i][j] = (f32x4){0.f, 0.f, 0.f, 0.f};

    for (int h = 0; h < 8; ++h) {
        if (h + 1 < 8) P1_ST(h + 1);
        const int sl = h & 1;
        bf16x8 af[8], bfr[4];
        #pragma unroll
        for (int mf = 0; mf < 8; ++mf)
            af[mf] = *(const bf16x8*)&M2[mf][h][lane * 8];
        #pragma unroll
        for (int nf = 0; nf < 4; ++nf)
            bfr[nf] = *(const bf16x8*)&slots[sl * 16384 + (4 * w + nf) * 512 + lane * 8];
        __builtin_amdgcn_s_setprio(1);
        #pragma unroll
        for (int mf = 0; mf < 8; ++mf)
            #pragma unroll
            for (int nf = 0; nf < 4; ++nf)
                acc1[mf][nf] = __builtin_amdgcn_mfma_f32_16x16x32_bf16(bfr[nf], af[mf], acc1[mf][nf], 0, 0, 0);
        __builtin_amdgcn_s_setprio(0);
        asm volatile("s_waitcnt lgkmcnt(0)" ::: "memory");
        if (h + 1 < 8) { asm volatile("s_waitcnt vmcnt(0)" ::: "memory"); }
        if (h < 7) __builtin_amdgcn_s_barrier();
    }

    ushort_t* Wout = (w < 4) ? T1 : GR;
    #pragma unroll
    for (int mf = 0; mf < 8; ++mf) {
        int row = m0 + mf * 16 + r16;
        #pragma unroll
        for (int nf = 0; nf < 4; ++nf) {
            int col = (w & 3) * 64 + nf * 16 + kq * 4;
            ushort4 o;
            o.x = f2b(acc1[mf][nf][0] + bg[nf].x);
            o.y = f2b(acc1[mf][nf][1] + bg[nf].y);
            o.z = f2b(acc1[mf][nf][2] + bg[nf].z);
            o.w = f2b(acc1[mf][nf][3] + bg[nf].w);
            *(ushort4*)&Wout[(size_t)row * 256 + col] = o;
        }
    }
#undef P0_ST
#undef P1_ST
}

// ===========================================================================
// FUSED mlp3 (both layers, node rows): Out = elu(elu(Xb@w1+b1)@w2+b2)
// BM=128 (64 blocks), 8 waves, wave-tile 128x32 both phases, H1 in LDS.
// ===========================================================================
__global__ __launch_bounds__(512, 1) void gemm8_mlp3_k(
    const ushort_t* __restrict__ Xb, const ushort_t* __restrict__ w1,
    const float* __restrict__ b1, const ushort_t* __restrict__ w2,
    const float* __restrict__ b2, ushort_t* __restrict__ Out)
{
    __shared__ ushort_t H1[8][8][512];   // 64 KB
    __shared__ ushort_t slots[36864];    // 72 KB
    const int tid = threadIdx.x;
    const int lane = tid & 63;
    const int w = tid >> 6;
    const int m0 = blockIdx.x * 128;
    const int r16 = lane & 15, kq = lane >> 4;

    const ushort_t* Ag = Xb + (size_t)(m0 + w * 16 + r16) * 256 + kq * 8;
    const size_t bo0 = (size_t)(2 * w * 16 + r16) * 256 + kq * 8;
    const size_t bo1 = (size_t)((2 * w + 1) * 16 + r16) * 256 + kq * 8;

    float4 bb1[2], bb2[2];
    #pragma unroll
    for (int nf = 0; nf < 2; ++nf) {
        bb1[nf] = *(const float4*)&b1[w * 32 + nf * 16 + kq * 4];
        bb2[nf] = *(const float4*)&b2[w * 32 + nf * 16 + kq * 4];
    }

#define M3_ST0(h) do { int sl_ = (h) % 3;                                   \
    gll16(Ag + (h) * 32, &slots[sl_ * 12288 + w * 512]);                    \
    gll16(w1 + bo0 + (h) * 32, &slots[sl_ * 12288 + 4096 + 2 * w * 512]);   \
    gll16(w1 + bo1 + (h) * 32, &slots[sl_ * 12288 + 4096 + (2 * w + 1) * 512]); \
} while (0)
#define M3_ST1(h) do { int sl_ = (h) & 1; int kk_ = (h) * 32;               \
    gll16(w2 + bo0 + kk_, &slots[sl_ * 8192 + 2 * w * 512]);                \
    gll16(w2 + bo1 + kk_, &slots[sl_ * 8192 + (2 * w + 1) * 512]);          \
} while (0)

    f32x4 acc0[8][2];
    #pragma unroll
    for (int i = 0; i < 8; ++i) { acc0[i][0] = (f32x4){0,0,0,0}; acc0[i][1] = (f32x4){0,0,0,0}; }

    M3_ST0(0); M3_ST0(1);
    asm volatile("s_waitcnt vmcnt(3)" ::: "memory");
    __builtin_amdgcn_s_barrier();

    for (int h = 0; h < 8; ++h) {
        if (h + 2 < 8) M3_ST0(h + 2);
        const int sl = h % 3;
        bf16x8 af[8], bfr[2];
        #pragma unroll
        for (int mf = 0; mf < 8; ++mf)
            af[mf] = *(const bf16x8*)&slots[sl * 12288 + mf * 512 + lane * 8];
        #pragma unroll
        for (int nf = 0; nf < 2; ++nf)
            bfr[nf] = *(const bf16x8*)&slots[sl * 12288 + 4096 + (2 * w + nf) * 512 + lane * 8];
        #pragma unroll
        for (int mf = 0; mf < 8; ++mf)
            #pragma unroll
            for (int nf = 0; nf < 2; ++nf)
                acc0[mf][nf] = __builtin_amdgcn_mfma_f32_16x16x32_bf16(bfr[nf], af[mf], acc0[mf][nf], 0, 0, 0);
        asm volatile("s_waitcnt lgkmcnt(0)" ::: "memory");
        if (h <= 5)      { asm volatile("s_waitcnt vmcnt(3)" ::: "memory"); }
        else if (h == 6) { asm volatile("s_waitcnt vmcnt(0)" ::: "memory"); }
        if (h < 7) __builtin_amdgcn_s_barrier();
    }

    M3_ST1(0);
    #pragma unroll
    for (int mf = 0; mf < 8; ++mf) {
        #pragma unroll
        for (int nf = 0; nf < 2; ++nf) {
            ushort4 o;
            o.x = f2b(eluf(acc0[mf][nf][0] + bb1[nf].x));
            o.y = f2b(eluf(acc0[mf][nf][1] + bb1[nf].y));
            o.z = f2b(eluf(acc0[mf][nf][2] + bb1[nf].z));
            o.w = f2b(eluf(acc0[mf][nf][3] + bb1[nf].w));
            int lanew = r16 + 16 * ((nf << 1) | (kq >> 1));
            *(ushort4*)&H1[mf][w][lanew * 8 + (kq & 1) * 4] = o;
            acc0[mf][nf] = (f32x4){0.f, 0.f, 0.f, 0.f};
        }
    }
    asm volatile("s_waitcnt lgkmcnt(0)" ::: "memory");
    asm volatile("s_waitcnt vmcnt(0)" ::: "memory");
    __builtin_amdgcn_s_barrier();

    for (int h = 0; h < 8; ++h) {
        if (h + 1 < 8) M3_ST1(h + 1);
        const int sl = h & 1;
        bf16x8 af[8], bfr[2];
        #pragma unroll
        for (int mf = 0; mf < 8; ++mf)
            af[mf] = *(const bf16x8*)&H1[mf][h][lane * 8];
        #pragma unroll
        for (int nf = 0; nf < 2; ++nf)
            bfr[nf] = *(const bf16x8*)&slots[sl * 8192 + (2 * w + nf) * 512 + lane * 8];
        #pragma unroll
        for (int mf = 0; mf < 8; ++mf)
            #pragma unroll
            for (int nf = 0; nf < 2; ++nf)
                acc0[mf][nf] = __builtin_amdgcn_mfma_f32_16x16x32_bf16(bfr[nf], af[mf], acc0[mf][nf], 0, 0, 0);
        asm volatile("s_waitcnt lgkmcnt(0)" ::: "memory");
        if (h + 1 < 8) { asm volatile("s_waitcnt vmcnt(0)" ::: "memory"); }
        if (h < 7) __builtin_amdgcn_s_barrier();
    }

    #pragma unroll
    for (int mf = 0; mf < 8; ++mf) {
        int row = m0 + mf * 16 + r16;
        #pragma unroll
        for (int nf = 0; nf < 2; ++nf) {
            int col = w * 32 + nf * 16 + kq * 4;
            ushort4 o;
            o.x = f2b(eluf(acc0[mf][nf][0] + bb2[nf].x));
            o.y = f2b(eluf(acc0[mf][nf][1] + bb2[nf].y));
            o.z = f2b(eluf(acc0[mf][nf][2] + bb2[nf].z));
            o.w = f2b(eluf(acc0[mf][nf][3] + bb2[nf].w));
            *(ushort4*)&Out[(size_t)row * 256 + col] = o;
        }
    }
#undef M3_ST0
#undef M3_ST1
}

// ===========================================================================
// mlp4 layer-1 variant: KD=768, A gathered on the fly (unchanged from r8).
// ===========================================================================
__global__ __launch_bounds__(512, 2) void gemm8_mlp4_k(
    const ushort_t* __restrict__ X2b, const ushort_t* __restrict__ EA,
    const ushort_t* __restrict__ Wt, const float* __restrict__ b1,
    ushort_t* __restrict__ C)
{
    __shared__ ushort_t lds[4][32][512];   // 128 KB
    const int tid = threadIdx.x;
    const int lane = tid & 63;
    const int w = tid >> 6;
    const int wm = w >> 2, wn = w & 3;
    const int m0 = blockIdx.x * 256;
    const int r16 = lane & 15, kq = lane >> 4;
    constexpr int NH = 24;

    const ushort_t* AS[2]; const ushort_t* AR[2]; const ushort_t* AE[2];
    #pragma unroll
    for (int ff = 0; ff < 2; ++ff) {
        int f = w + ff * 8;
        int m = m0 + f * 16 + r16;
        int be = m >> 6, t = m & 63;
        int b = be / E_, e = be % E_;
        int s = e / (V_ - 1);
        int r0 = e % (V_ - 1);
        int rr = r0 + (r0 >= s ? 1 : 0);
        AS[ff] = X2b + ((size_t)((b * V_ + s) * T_ + t)) * H_ + kq * 8;
        AR[ff] = X2b + ((size_t)((b * V_ + rr) * T_ + t)) * H_ + kq * 8;
        AE[ff] = EA + (size_t)m * H_ + kq * 8;
    }
    const ushort_t* Bg0 = Wt + (size_t)(w * 16 + r16) * 768 + kq * 8;
    const ushort_t* Bg1 = Wt + (size_t)((w + 8) * 16 + r16) * 768 + kq * 8;

    f32x4 acc[8][4];
    #pragma unroll
    for (int i = 0; i < 8; ++i)
        #pragma unroll
        for (int j = 0; j < 4; ++j)
            acc[i][j] = (f32x4){0.f, 0.f, 0.f, 0.f};

#define STM(h) do { int sl_ = (h) & 3; int kk_ = (h) * 32;                  \
    int seg_ = kk_ >> 8, off_ = kk_ & 255;                                  \
    const ushort_t* a0_ = (seg_ == 0 ? AS[0] : seg_ == 1 ? AR[0] : AE[0]) + off_; \
    const ushort_t* a1_ = (seg_ == 0 ? AS[1] : seg_ == 1 ? AR[1] : AE[1]) + off_; \
    gll16(a0_, &lds[sl_][w][0]);                                            \
    gll16(a1_, &lds[sl_][w + 8][0]);                                        \
    gll16(Bg0 + kk_, &lds[sl_][16 + w][0]);                                 \
    gll16(Bg1 + kk_, &lds[sl_][16 + w + 8][0]);                             \
} while (0)

    STM(0); STM(1); STM(2);
    asm volatile("s_waitcnt vmcnt(8)" ::: "memory");
    __builtin_amdgcn_s_barrier();

    for (int h = 0; h < NH; ++h) {
        if (h + 3 < NH) STM(h + 3);
        const int sl = h & 3;
        bf16x8 bfr[4];
        #pragma unroll
        for (int nf = 0; nf < 4; ++nf)
            bfr[nf] = *(const bf16x8*)&lds[sl][16 + wn * 4 + nf][lane * 8];
        #pragma unroll
        for (int mh = 0; mh < 2; ++mh) {
            bf16x8 af[4];
            #pragma unroll
            for (int mf = 0; mf < 4; ++mf)
                af[mf] = *(const bf16x8*)&lds[sl][wm * 8 + mh * 4 + mf][lane * 8];
            __builtin_amdgcn_s_setprio(1);
            #pragma unroll
            for (int mf = 0; mf < 4; ++mf)
                #pragma unroll
                for (int nf = 0; nf < 4; ++nf)
                    acc[mh * 4 + mf][nf] = __builtin_amdgcn_mfma_f32_16x16x32_bf16(
                        bfr[nf], af[mf], acc[mh * 4 + mf][nf], 0, 0, 0);
            __builtin_amdgcn_s_setprio(0);
        }
        asm volatile("s_waitcnt lgkmcnt(0)" ::: "memory");
        if (h < NH - 3)       { asm volatile("s_waitcnt vmcnt(8)" ::: "memory"); }
        else if (h == NH - 3) { asm volatile("s_waitcnt vmcnt(4)" ::: "memory"); }
        else if (h == NH - 2) { asm volatile("s_waitcnt vmcnt(0)" ::: "memory"); }
        if (h < NH - 1) __builtin_amdgcn_s_barrier();
    }
#undef STM

    #pragma unroll
    for (int mi = 0; mi < 8; ++mi) {
        int mrow = m0 + wm * 128 + mi * 16 + r16;
        #pragma unroll
        for (int nf = 0; nf < 4; ++nf) {
            int nb = wn * 64 + nf * 16 + kq * 4;
            float4 bb = *(const float4*)&b1[nb];
            float v0 = eluf(acc[mi][nf][0] + bb.x);
            float v1 = eluf(acc[mi][nf][1] + bb.y);
            float v2 = eluf(acc[mi][nf][2] + bb.z);
            float v3 = eluf(acc[mi][nf][3] + bb.w);
            ushort4 o; o.x = f2b(v0); o.y = f2b(v1); o.z = f2b(v2); o.w = f2b(v3);
            *(ushort4*)&C[(size_t)mrow * 256 + nb] = o;
        }
    }
}

// ===========================================================================
// weights f32 -> bf16 (packed):
// ef_w2 | m4_w1 | m4_w2 | f_wih | r_wih | e_w1 | m3_w1 | m3_w2
// ===========================================================================
__global__ __launch_bounds__(256) void wconv_k(
    const float* __restrict__ ef_w2, const float* __restrict__ m4_w1,
    const float* __restrict__ m4_w2, const float* __restrict__ f_wih,
    const float* __restrict__ r_wih, const float* __restrict__ e_w1,
    const float* __restrict__ m3_w1, const float* __restrict__ m3_w2,
    ushort_t* __restrict__ Wb)
{
    int i = blockIdx.x * 256 + threadIdx.x;   // < 622592
    const float* src; int off;
    if (i < 65536)       { src = ef_w2; off = i; }
    else if (i < 262144) { src = m4_w1; off = i - 65536; }
    else if (i < 327680) { src = m4_w2; off = i - 262144; }
    else if (i < 393216) { src = f_wih; off = i - 327680; }
    else if (i < 458752) { src = r_wih; off = i - 393216; }
    else if (i < 491520) { src = e_w1;  off = i - 458752; }
    else if (i < 557056) { src = m3_w1; off = i - 491520; }
    else                 { src = m3_w2; off = i - 557056; }
    Wb[i] = f2b(src[off]);
}

// ---------------------------------------------------------------------------
// edge2node: X[b,v,t,h] = (1/15)*sum_{e:RECV==v} EA[b,e,t,h] + rel@res_w.T + res_b
// Output bf16 now (feeds MFMA mlp3).
// ---------------------------------------------------------------------------
__global__ __launch_bounds__(256) void e2n_k(
    const ushort_t* __restrict__ EA, const float* __restrict__ rel,
    const float* __restrict__ res_w, const float* __restrict__ res_b,
    ushort_t* __restrict__ X)
{
    const int idx = blockIdx.x;            // (b*V+v)*T + t
    const int t = idx & (T_ - 1);
    const int bv = idx >> 6;
    const int v = bv & (V_ - 1);
    const int b = bv >> 4;
    const int h = threadIdx.x;
    float sum = 0.f;
    #pragma unroll
    for (int i = 0; i < V_; ++i) {
        if (i == v) continue;
        int jj = (v < i) ? v : v - 1;
        int e = i * (V_ - 1) + jj;
        sum += b2f(EA[(((size_t)(b * E_ + e)) * T_ + t) * H_ + h]);
    }
    const float* rp = rel + ((size_t)bv * T_ + t) * DIN_;
    float res = res_b[h];
    #pragma unroll
    for (int d = 0; d < DIN_; ++d) res += rp[d] * res_w[h * DIN_ + d];
    X[((size_t)bv * T_ + t) * H_ + h] = f2b(sum * (1.f / 15.f) + res);
}

// ===========================================================================
// MFMA LSTM scan, both directions in one dispatch (blockIdx.y = dir).
// ===========================================================================
__global__ __launch_bounds__(256) void lstm_mfma4_k(
    const ushort_t* __restrict__ Gf, const ushort_t* __restrict__ Gr,
    const float* __restrict__ whh_f, const float* __restrict__ whh_r,
    ushort_t* __restrict__ COMB)
{
    __shared__ ushort_t hlds[2][1024];   // 2 x 2KB: h[seq][j] bf16, XOR-swizzled
    const int dir = blockIdx.y;
    const ushort_t* G = dir ? Gr : Gf;
    const float* whh = dir ? whh_r : whh_f;
    const int tid = threadIdx.x;
    const int lane = tid & 63;
    const int w = tid >> 6;              // wave id = j-block
    const int seq = lane & 15, kq = lane >> 4;
    const int be0 = blockIdx.x * 16;
    const int swz = (seq & 7) << 4;

    bf16x8 wf[4][2];
    #pragma unroll
    for (int a = 0; a < 4; ++a) {
        #pragma unroll
        for (int ks = 0; ks < 2; ++ks) {
            const float* p = whh + (size_t)((a * 4 + w) * 16 + seq) * 64 + ks * 32 + kq * 8;
            float4 x0 = *(const float4*)p;
            float4 x1 = *(const float4*)(p + 4);
            bf16x8 v;
            v[0] = (short)f2b(x0.x); v[1] = (short)f2b(x0.y);
            v[2] = (short)f2b(x0.z); v[3] = (short)f2b(x0.w);
            v[4] = (short)f2b(x1.x); v[5] = (short)f2b(x1.y);
            v[6] = (short)f2b(x1.z); v[7] = (short)f2b(x1.w);
            wf[a][ks] = v;
        }
    }

    const ushort_t* grow = G + ((size_t)(be0 + seq) * T_) * 256 + kq * 4;
    ushort_t* crow = COMB + ((size_t)(be0 + seq) * T_) * 128 + (dir ? 64 : 0) + 16 * w + 4 * kq;

    float c[4] = {};
    ushort4 gx[4];
    const int t0 = dir ? (T_ - 1) : 0;
    #pragma unroll
    for (int a = 0; a < 4; ++a)
        gx[a] = *(const ushort4*)(grow + (size_t)t0 * 256 + (a * 4 + w) * 16);

    for (int s = 0; s < T_; ++s) {
        const int t = dir ? (T_ - 1 - s) : s;
        f32x4 acc[4];
        #pragma unroll
        for (int a = 0; a < 4; ++a) {
            ushort4 g = gx[a];
            acc[a] = (f32x4){b2f(g.x), b2f(g.y), b2f(g.z), b2f(g.w)};
        }
        if (s < T_ - 1) {
            const int tn = dir ? (T_ - 2 - s) : (s + 1);
            #pragma unroll
            for (int a = 0; a < 4; ++a)
                gx[a] = *(const ushort4*)(grow + (size_t)tn * 256 + (a * 4 + w) * 16);
        }
        if (s) {
            bf16x8 af[2];
            #pragma unroll
            for (int ks = 0; ks < 2; ++ks) {
                int boff = (seq * 128 + ks * 64 + kq * 16) ^ swz;
                af[ks] = *(const bf16x8*)((const char*)hlds[(s - 1) & 1] + boff);
            }
            #pragma unroll
            for (int a = 0; a < 4; ++a) {
                acc[a] = __builtin_amdgcn_mfma_f32_16x16x32_bf16(wf[a][0], af[0], acc[a], 0, 0, 0);
                acc[a] = __builtin_amdgcn_mfma_f32_16x16x32_bf16(wf[a][1], af[1], acc[a], 0, 0, 0);
            }
        }
        float hh[4];
        #pragma unroll
        for (int r = 0; r < 4; ++r) {
            float zi = acc[0][r], zf = acc[1][r], zg = acc[2][r], zo = acc[3][r];
            float cc = fsig(zf) * c[r] + fsig(zi) * ftanh_(zg);
            c[r] = cc;
            hh[r] = fsig(zo) * ftanh_(cc);
        }
        ushort4 hv;
        hv.x = f2b(hh[0]); hv.y = f2b(hh[1]); hv.z = f2b(hh[2]); hv.w = f2b(hh[3]);
        int wb = (seq * 128 + 32 * w + 8 * kq) ^ swz;
        *(ushort4*)((char*)hlds[s & 1] + wb) = hv;
        *(ushort4*)(crow + (size_t)t * 128) = hv;
        asm volatile("s_waitcnt lgkmcnt(0)" ::: "memory");
        __builtin_amdgcn_sched_barrier(0);
        __builtin_amdgcn_s_barrier();
    }
}

// ---------------------------------------------------------------------------
// prior head: reads fwd hidden from comb[:, 0:64] (row stride 128)
// ---------------------------------------------------------------------------
__global__ __launch_bounds__(256) void prior_k(
    const ushort_t* __restrict__ COMB, const float* __restrict__ p_w,
    const float* __restrict__ p_b, float* __restrict__ out)
{
    const int row = blockIdx.x * 4 + (threadIdx.x >> 6);  // [0, BET)
    const int lane = threadIdx.x & 63;
    float hf = b2f(COMB[(size_t)row * 128 + lane]);
    float v0 = hf * p_w[lane];
    float v1 = hf * p_w[64 + lane];
    #pragma unroll
    for (int off = 32; off > 0; off >>= 1) {
        v0 += __shfl_down(v0, off, 64);
        v1 += __shfl_down(v1, off, 64);
    }
    if (lane == 0) {
        int t = row & (T_ - 1);
        int be = row >> 6;
        int e = be % E_, b = be / E_;
        size_t o = (((size_t)b * T_ + t) * E_ + e) * K_;
        out[o] = v0 + p_b[0];
        out[o + 1] = v1 + p_b[1];
    }
}

// ===========================================================================
// FUSED: ENCH = elu(COMB@e_w1.T + e_b1) in regs, then out = ENCH@e_w2.T + e_b2
// (unchanged from round 9)
// ===========================================================================
__global__ __launch_bounds__(512) void fused_enc_k(
    const ushort_t* __restrict__ COMB, const ushort_t* __restrict__ w_e1,
    const float* __restrict__ e_b1, const float* __restrict__ e_w2,
    const float* __restrict__ e_b2, float* __restrict__ out)
{
    __shared__ ushort_t sA[2][8][512];    // 16 KB
    __shared__ ushort_t sW[2][16][512];   // 32 KB
    __shared__ float part[128][4][2];     // 4 KB
    const int tid = threadIdx.x;
    const int lane = tid & 63;
    const int w = tid >> 6;
    const int wr = w >> 2, wc = w & 3;
    const int m0 = blockIdx.x * 128;
    const int r16 = lane & 15, kq = lane >> 4;

    const ushort_t* Asrc = COMB + (size_t)(m0 + w * 16 + r16) * 128 + kq * 8;
    const size_t woffA = (size_t)((2 * w) * 16 + r16) * 128 + kq * 8;
    const size_t woffB = (size_t)((2 * w + 1) * 16 + r16) * 128 + kq * 8;

    float4 w2v[2][4];
    #pragma unroll
    for (int j = 0; j < 2; ++j)
        #pragma unroll
        for (int nf = 0; nf < 4; ++nf)
            w2v[j][nf] = *(const float4*)&e_w2[j * 256 + wc * 64 + nf * 16 + kq * 4];

    f32x4 acc[4][4];
    #pragma unroll
    for (int i = 0; i < 4; ++i)
        #pragma unroll
        for (int j = 0; j < 4; ++j)
            acc[i][j] = (f32x4){0.f, 0.f, 0.f, 0.f};

#define FE_STAGE(bufi, kt_) do {                                             \
    gll16(Asrc + (kt_) * 32, &sA[bufi][w][0]);                               \
    gll16(w_e1 + woffA + (kt_) * 32, &sW[bufi][2 * w][0]);                   \
    gll16(w_e1 + woffB + (kt_) * 32, &sW[bufi][2 * w + 1][0]);               \
} while (0)

    FE_STAGE(0, 0);
    asm volatile("s_waitcnt vmcnt(0)" ::: "memory");
    __builtin_amdgcn_s_barrier();

    for (int s = 0; s < 4; ++s) {
        const int buf = s & 1;
        if (s < 3) FE_STAGE(buf ^ 1, s + 1);
        bf16x8 af[4], bfr[4];
        #pragma unroll
        for (int mf = 0; mf < 4; ++mf)
            af[mf] = *(const bf16x8*)&sA[buf][wr * 4 + mf][lane * 8];
        #pragma unroll
        for (int nf = 0; nf < 4; ++nf)
            bfr[nf] = *(const bf16x8*)&sW[buf][wc * 4 + nf][lane * 8];
        #pragma unroll
        for (int mf = 0; mf < 4; ++mf)
            #pragma unroll
            for (int nf = 0; nf < 4; ++nf)
                acc[mf][nf] = __builtin_amdgcn_mfma_f32_16x16x32_bf16(bfr[nf], af[mf], acc[mf][nf], 0, 0, 0);
        asm volatile("s_waitcnt vmcnt(0)" ::: "memory");
        __builtin_amdgcn_s_barrier();
    }

    #pragma unroll
    for (int mf = 0; mf < 4; ++mf) {
        float s0 = 0.f, s1 = 0.f;
        #pragma unroll
        for (int nf = 0; nf < 4; ++nf) {
            int col = wc * 64 + nf * 16 + kq * 4;
            float4 bb = *(const float4*)&e_b1[col];
            float v0 = eluf(acc[mf][nf][0] + bb.x);
            float v1 = eluf(acc[mf][nf][1] + bb.y);
            float v2 = eluf(acc[mf][nf][2] + bb.z);
            float v3 = eluf(acc[mf][nf][3] + bb.w);
            s0 += v0 * w2v[0][nf].x + v1 * w2v[0][nf].y + v2 * w2v[0][nf].z + v3 * w2v[0][nf].w;
            s1 += v0 * w2v[1][nf].x + v1 * w2v[1][nf].y + v2 * w2v[1][nf].z + v3 * w2v[1][nf].w;
        }
        s0 += __shfl_xor(s0, 16, 64); s0 += __shfl_xor(s0, 32, 64);
        s1 += __shfl_xor(s1, 16, 64); s1 += __shfl_xor(s1, 32, 64);
        if (kq == 0) {
            part[wr * 64 + mf * 16 + r16][wc][0] = s0;
            part[wr * 64 + mf * 16 + r16][wc][1] = s1;
        }
    }
    __syncthreads();
    if (tid < 256) {
        int row = tid >> 1, k = tid & 1;
        float v = part[row][0][k] + part[row][1][k] + part[row][2][k] + part[row][3][k] + e_b2[k];
        int gr = m0 + row;
        int be = gr >> 6, t = gr & 63;
        int e = be % E_, b = be / E_;
        out[(size_t)(B_ * T_ * E_ * K_) + (((size_t)b * T_ + t) * E_ + e) * K_ + k] = v;
    }
#undef FE_STAGE
}

// ---------------------------------------------------------------------------
extern "C" void kernel_launch(void* const* d_in, const int* in_sizes, int n_in,
                              void* d_out, int out_size, void* d_ws, size_t ws_size,
                              hipStream_t stream)
{
    const float* rel    = (const float*)d_in[0];
    const float* ear    = (const float*)d_in[1];
    const float* epos   = (const float*)d_in[2];
    const float* ef_w1  = (const float*)d_in[3];
    const float* ef_b1  = (const float*)d_in[4];
    const float* ef_w2  = (const float*)d_in[5];
    const float* ef_b2  = (const float*)d_in[6];
    const float* res_w  = (const float*)d_in[7];
    const float* res_b  = (const float*)d_in[8];
    const float* m3_w1  = (const float*)d_in[9];
    const float* m3_b1  = (const float*)d_in[10];
    const float* m3_w2  = (const float*)d_in[11];
    const float* m3_b2  = (const float*)d_in[12];
    const float* m4_w1  = (const float*)d_in[13];
    const float* m4_b1  = (const float*)d_in[14];
    const float* m4_w2  = (const float*)d_in[15];
    const float* m4_b2  = (const float*)d_in[16];
    const float* f_wih  = (const float*)d_in[17];
    const float* f_whh  = (const float*)d_in[18];
    const float* f_bih  = (const float*)d_in[19];
    const float* f_bhh  = (const float*)d_in[20];
    const float* r_wih  = (const float*)d_in[21];
    const float* r_whh  = (const float*)d_in[22];
    const float* r_bih  = (const float*)d_in[23];
    const float* r_bhh  = (const float*)d_in[24];
    const float* p_w    = (const float*)d_in[25];
    const float* p_b    = (const float*)d_in[26];
    const float* e_w1   = (const float*)d_in[27];
    const float* e_b1   = (const float*)d_in[28];
    const float* e_w2   = (const float*)d_in[29];
    const float* e_b2   = (const float*)d_in[30];
    float* out = (float*)d_out;

    // workspace layout (bytes), total ~163 MB
    char* ws = (char*)d_ws;
    const size_t BIGB  = (size_t)BET_ * H_ * sizeof(ushort_t);   // 62,914,560
    const size_t COMBB = (size_t)BET_ * 128 * sizeof(ushort_t);  // 31,457,280
    const size_t X2BB  = (size_t)BVT_ * H_ * sizeof(ushort_t);   //  4,194,304
    ushort_t* R1   = (ushort_t*)(ws);
    ushort_t* R2   = (ushort_t*)(ws + BIGB);
    ushort_t* COMB = (ushort_t*)(ws + 2 * BIGB);
    ushort_t* X2b  = (ushort_t*)(ws + 2 * BIGB + COMBB);
    ushort_t* Wb   = (ushort_t*)(ws + 2 * BIGB + COMBB + X2BB);
    // node-stage bf16 X lives inside (dead) R1 region
    ushort_t* Xbf = (ushort_t*)(ws);
    // packed bf16 weight offsets (elements)
    const ushort_t* wb_ef2  = Wb + 0;
    const ushort_t* wb_m41  = Wb + 65536;
    const ushort_t* wb_m42  = Wb + 262144;
    const ushort_t* wb_fwih = Wb + 327680;
    const ushort_t* wb_rwih = Wb + 393216;
    const ushort_t* wb_ew1  = Wb + 458752;
    const ushort_t* wb_m31  = Wb + 491520;
    const ushort_t* wb_m32  = Wb + 557056;

    dim3 blk(256);
    dim3 blk8(512);
    dim3 g128(BET_ / 128);     // 960 blocks (BM=128 kernels)
    dim3 g256(BET_ / 256);     // 480 blocks (BM=256 mlp4)

    // 0. weights -> bf16 (incl. mlp3)
    wconv_k<<<2432, blk, 0, stream>>>(ef_w2, m4_w1, m4_w2, f_wih, r_wih, e_w1, m3_w1, m3_w2, Wb);
    // 1. fused edge-filter MLP (ein K=16 + ef2 K=256) -> EA in R2
    gemm8_ef_k<<<g128, blk8, 0, stream>>>(ear, epos, ef_w1, ef_b1, wb_ef2, ef_b2, R2);
    // 2. edge2node + residual -> bf16 X
    e2n_k<<<BVT_, blk, 0, stream>>>(R2, rel, res_w, res_b, Xbf);
    // 3. fused mlp3 (both layers, MFMA) -> X2b
    gemm8_mlp3_k<<<BVT_ / 128, blk8, 0, stream>>>(Xbf, wb_m31, m3_b1, wb_m32, m3_b2, X2b);
    // 4. node2edge gather + mlp4 layer 1 -> T1 (R1)
    gemm8_mlp4_k<<<g256, blk8, 0, stream>>>(X2b, R2, wb_m41, m4_b1, R1);
    // 5. FUSED m4l2 + [GF|GR] (M2 in LDS): GF -> R1 (in-place), GR -> R2
    fused_gates9_k<<<g128, blk8, 0, stream>>>(
        R1, R2, wb_m42, wb_fwih, wb_rwih, m4_b2, f_bih, f_bhh, r_bih, r_bhh);
    // 6. LSTM scans, both directions in one dispatch
    lstm_mfma4_k<<<dim3(BE_ / 16, 2), blk, 0, stream>>>(R1, R2, f_whh, r_whh, COMB);
    // 7. heads
    prior_k<<<BET_ / 4, blk, 0, stream>>>(COMB, p_w, p_b, out);
    fused_enc_k<<<g128, blk8, 0, stream>>>(COMB, wb_ew1, e_b1, e_w2, e_b2, out);
}

// Round 11
// 423.982 us; speedup vs baseline: 6.2447x; 1.0581x over previous
//
#include <hip/hip_runtime.h>
#include <cstdint>
#include <cstddef>
#include <type_traits>

// Problem constants
#define B_ 8
#define V_ 16
#define T_ 64
#define E_ 240          // V*(V-1)
#define H_ 256
#define RH_ 64
#define K_ 2
#define DIN_ 6
#define BET_ (B_*E_*T_)   // 122880
#define BVT_ (B_*V_*T_)   // 8192
#define BE_ (B_*E_)       // 1920

typedef unsigned short ushort_t;
typedef unsigned int u32;
typedef __attribute__((ext_vector_type(8))) short bf16x8;
typedef __attribute__((ext_vector_type(4))) float f32x4;

__device__ __forceinline__ float eluf(float x) { return x > 0.f ? x : __expf(x) - 1.f; }
__device__ __forceinline__ float fsig(float x) { return 1.f / (1.f + __expf(-x)); }
__device__ __forceinline__ float ftanh_(float x) {
    float y = fminf(fmaxf(x, -8.f), 8.f);
    float e = __expf(2.f * y);
    return (e - 1.f) / (e + 1.f);
}
__device__ __forceinline__ float b2f(ushort_t u) {
    union { float f; uint32_t i; } v; v.i = ((uint32_t)u) << 16; return v.f;
}
__device__ __forceinline__ ushort_t f2b(float f) {
    union { float f; uint32_t i; } v; v.f = f;
    uint32_t r = (v.i + 0x7FFFu + ((v.i >> 16) & 1u)) >> 16;
    return (ushort_t)r;
}

// async global->LDS, 16B per lane; LDS dest = wave-uniform base + lane*16
__device__ __forceinline__ void gll16(const void* g, void* l) {
    __builtin_amdgcn_global_load_lds(
        (const __attribute__((address_space(1))) u32*)g,
        (__attribute__((address_space(3))) u32*)l, 16, 0, 0);
}

// ===========================================================================
// 8-wave half-tile-pipelined MFMA GEMM (r8-proven): C = act(A@W.T + b1 (+b2))
// BM=256, BN=256(=N), wave-tile 128x64 via mh-split (af[4] live at a time),
// K-half=32, 4 LDS slots, counted vmcnt(8/4/0). VGPR-safe (measured 120).
// GR can run in-place (C==A): per-block rows only; all A reads precede stores.
// ===========================================================================
template<int KD, int ACT>
__global__ __launch_bounds__(512, 2) void gemm8_k(
    const ushort_t* __restrict__ A, const ushort_t* __restrict__ Wt,
    const float* __restrict__ b1, const float* __restrict__ b2,
    ushort_t* __restrict__ C)
{
    __shared__ ushort_t lds[4][32][512];   // 128 KB
    const int tid = threadIdx.x;
    const int lane = tid & 63;
    const int w = tid >> 6;                // 0..7
    const int wm = w >> 2, wn = w & 3;     // 2m x 4n
    const int m0 = blockIdx.x * 256;
    const int r16 = lane & 15, kq = lane >> 4;
    constexpr int NH = KD / 32;

    const ushort_t* Ag0 = A + (size_t)(m0 + w * 16 + r16) * KD + kq * 8;
    const ushort_t* Ag1 = A + (size_t)(m0 + (w + 8) * 16 + r16) * KD + kq * 8;
    const ushort_t* Bg0 = Wt + (size_t)(w * 16 + r16) * KD + kq * 8;
    const ushort_t* Bg1 = Wt + (size_t)((w + 8) * 16 + r16) * KD + kq * 8;

    f32x4 acc[8][4];
    #pragma unroll
    for (int i = 0; i < 8; ++i)
        #pragma unroll
        for (int j = 0; j < 4; ++j)
            acc[i][j] = (f32x4){0.f, 0.f, 0.f, 0.f};

#define ST8(h) do { int sl_ = (h) & 3; int kk_ = (h) * 32;                  \
    gll16(Ag0 + kk_, &lds[sl_][w][0]);                                      \
    gll16(Ag1 + kk_, &lds[sl_][w + 8][0]);                                  \
    gll16(Bg0 + kk_, &lds[sl_][16 + w][0]);                                 \
    gll16(Bg1 + kk_, &lds[sl_][16 + w + 8][0]);                             \
} while (0)

    ST8(0); ST8(1); ST8(2);
    asm volatile("s_waitcnt vmcnt(8)" ::: "memory");   // half 0 landed
    __builtin_amdgcn_s_barrier();

    for (int h = 0; h < NH; ++h) {
        if (h + 3 < NH) ST8(h + 3);
        const int sl = h & 3;
        bf16x8 bfr[4];
        #pragma unroll
        for (int nf = 0; nf < 4; ++nf)
            bfr[nf] = *(const bf16x8*)&lds[sl][16 + wn * 4 + nf][lane * 8];
        #pragma unroll
        for (int mh = 0; mh < 2; ++mh) {
            bf16x8 af[4];
            #pragma unroll
            for (int mf = 0; mf < 4; ++mf)
                af[mf] = *(const bf16x8*)&lds[sl][wm * 8 + mh * 4 + mf][lane * 8];
            __builtin_amdgcn_s_setprio(1);
            #pragma unroll
            for (int mf = 0; mf < 4; ++mf)
                #pragma unroll
                for (int nf = 0; nf < 4; ++nf)
                    acc[mh * 4 + mf][nf] = __builtin_amdgcn_mfma_f32_16x16x32_bf16(
                        bfr[nf], af[mf], acc[mh * 4 + mf][nf], 0, 0, 0);
            __builtin_amdgcn_s_setprio(0);
        }
        asm volatile("s_waitcnt lgkmcnt(0)" ::: "memory");  // my reads of slot done
        if (h < NH - 3)       { asm volatile("s_waitcnt vmcnt(8)" ::: "memory"); }
        else if (h == NH - 3) { asm volatile("s_waitcnt vmcnt(4)" ::: "memory"); }
        else if (h == NH - 2) { asm volatile("s_waitcnt vmcnt(0)" ::: "memory"); }
        if (h < NH - 1) __builtin_amdgcn_s_barrier();
    }
#undef ST8

    #pragma unroll
    for (int mi = 0; mi < 8; ++mi) {
        int mrow = m0 + wm * 128 + mi * 16 + r16;
        #pragma unroll
        for (int nf = 0; nf < 4; ++nf) {
            int nb = wn * 64 + nf * 16 + kq * 4;
            float4 bb = *(const float4*)&b1[nb];
            if (b2) {
                float4 b2v = *(const float4*)&b2[nb];
                bb.x += b2v.x; bb.y += b2v.y; bb.z += b2v.z; bb.w += b2v.w;
            }
            float v0 = acc[mi][nf][0] + bb.x;
            float v1 = acc[mi][nf][1] + bb.y;
            float v2 = acc[mi][nf][2] + bb.z;
            float v3 = acc[mi][nf][3] + bb.w;
            if (ACT) { v0 = eluf(v0); v1 = eluf(v1); v2 = eluf(v2); v3 = eluf(v3); }
            ushort4 o; o.x = f2b(v0); o.y = f2b(v1); o.z = f2b(v2); o.w = f2b(v3);
            *(ushort4*)&C[(size_t)mrow * 256 + nb] = o;
        }
    }
}

// ===========================================================================
// FUSED ein(K=16 f32) + ef2(K=256) : EA = elu(elu(ein@efw1+b1)@efw2+b2)
// (unchanged from round 9/10 — works)
// ===========================================================================
__global__ __launch_bounds__(512, 1) void gemm8_ef_k(
    const float* __restrict__ ear, const float* __restrict__ epos,
    const float* __restrict__ ef_w1, const float* __restrict__ ef_b1,
    const ushort_t* __restrict__ w_ef2, const float* __restrict__ ef_b2,
    ushort_t* __restrict__ EA)
{
    __shared__ ushort_t H1[8][8][512];      // 64 KB
    __shared__ ushort_t slotB[4][16][512];  // 64 KB  (total 128 KB)
    const int tid = threadIdx.x;
    const int lane = tid & 63;
    const int w = tid >> 6;
    const int wm = w >> 2, wn = w & 3;
    const int m0 = blockIdx.x * 128;
    const int r16 = lane & 15, kq = lane >> 4;

    f32x4 acc[4][4];
    #pragma unroll
    for (int i = 0; i < 4; ++i)
        #pragma unroll
        for (int j = 0; j < 4; ++j)
            acc[i][j] = (f32x4){0.f, 0.f, 0.f, 0.f};
    {
        bf16x8 af[4], bfr[4];
        #pragma unroll
        for (int mf = 0; mf < 4; ++mf) {
            int m = m0 + wm * 64 + mf * 16 + r16;
            #pragma unroll
            for (int e = 0; e < 8; ++e) {
                float v = 0.f;
                if (kq < 2) {
                    int c = kq * 8 + e;
                    v = (c < 13) ? ear[(size_t)m * 13 + c] : epos[(size_t)m * 3 + (c - 13)];
                }
                af[mf][e] = (short)f2b(v);
            }
        }
        #pragma unroll
        for (int nf = 0; nf < 4; ++nf) {
            int n = wn * 64 + nf * 16 + r16;
            #pragma unroll
            for (int e = 0; e < 8; ++e) {
                float v = 0.f;
                if (kq < 2) v = ef_w1[(size_t)n * 16 + kq * 8 + e];
                bfr[nf][e] = (short)f2b(v);
            }
        }
        #pragma unroll
        for (int mf = 0; mf < 4; ++mf)
            #pragma unroll
            for (int nf = 0; nf < 4; ++nf)
                acc[mf][nf] = __builtin_amdgcn_mfma_f32_16x16x32_bf16(bfr[nf], af[mf], acc[mf][nf], 0, 0, 0);
    }

    const size_t bo0 = (size_t)(2 * w * 16 + r16) * 256 + kq * 8;
    const size_t bo1 = (size_t)((2 * w + 1) * 16 + r16) * 256 + kq * 8;
#define EF_ST(h) do { int sl_ = (h) & 3;                                    \
    gll16(w_ef2 + bo0 + (h) * 32, &slotB[sl_][2 * w][0]);                   \
    gll16(w_ef2 + bo1 + (h) * 32, &slotB[sl_][2 * w + 1][0]);               \
} while (0)

    EF_ST(0); EF_ST(1); EF_ST(2);

    #pragma unroll
    for (int mf = 0; mf < 4; ++mf) {
        #pragma unroll
        for (int nf = 0; nf < 4; ++nf) {
            int col = wn * 64 + nf * 16 + kq * 4;
            float4 bb = *(const float4*)&ef_b1[col];
            ushort4 o;
            o.x = f2b(eluf(acc[mf][nf][0] + bb.x));
            o.y = f2b(eluf(acc[mf][nf][1] + bb.y));
            o.z = f2b(eluf(acc[mf][nf][2] + bb.z));
            o.w = f2b(eluf(acc[mf][nf][3] + bb.w));
            int ktw = wn * 2 + (nf >> 1);
            int lanew = r16 + 16 * (((nf & 1) << 1) | (kq >> 1));
            *(ushort4*)&H1[wm * 4 + mf][ktw][lanew * 8 + (kq & 1) * 4] = o;
            acc[mf][nf] = (f32x4){0.f, 0.f, 0.f, 0.f};
        }
    }
    asm volatile("s_waitcnt lgkmcnt(0)" ::: "memory");
    asm volatile("s_waitcnt vmcnt(4)" ::: "memory");
    __builtin_amdgcn_s_barrier();

    #pragma unroll
    for (int h = 0; h < 8; ++h) {
        if (h + 3 < 8) EF_ST(h + 3);
        const int sl = h & 3;
        bf16x8 af[4], bfr[4];
        #pragma unroll
        for (int nf = 0; nf < 4; ++nf)
            bfr[nf] = *(const bf16x8*)&slotB[sl][wn * 4 + nf][lane * 8];
        #pragma unroll
        for (int mf = 0; mf < 4; ++mf)
            af[mf] = *(const bf16x8*)&H1[wm * 4 + mf][h][lane * 8];
        __builtin_amdgcn_s_setprio(1);
        #pragma unroll
        for (int mf = 0; mf < 4; ++mf)
            #pragma unroll
            for (int nf = 0; nf < 4; ++nf)
                acc[mf][nf] = __builtin_amdgcn_mfma_f32_16x16x32_bf16(bfr[nf], af[mf], acc[mf][nf], 0, 0, 0);
        __builtin_amdgcn_s_setprio(0);
        asm volatile("s_waitcnt lgkmcnt(0)" ::: "memory");
        if (h <= 4)      { asm volatile("s_waitcnt vmcnt(4)" ::: "memory"); }
        else if (h == 5) { asm volatile("s_waitcnt vmcnt(2)" ::: "memory"); }
        else if (h == 6) { asm volatile("s_waitcnt vmcnt(0)" ::: "memory"); }
        if (h < 7) __builtin_amdgcn_s_barrier();
    }
#undef EF_ST

    #pragma unroll
    for (int mf = 0; mf < 4; ++mf) {
        int row = m0 + wm * 64 + mf * 16 + r16;
        #pragma unroll
        for (int nf = 0; nf < 4; ++nf) {
            int col = wn * 64 + nf * 16 + kq * 4;
            float4 bb = *(const float4*)&ef_b2[col];
            ushort4 o;
            o.x = f2b(eluf(acc[mf][nf][0] + bb.x));
            o.y = f2b(eluf(acc[mf][nf][1] + bb.y));
            o.z = f2b(eluf(acc[mf][nf][2] + bb.z));
            o.w = f2b(eluf(acc[mf][nf][3] + bb.w));
            *(ushort4*)&EA[(size_t)row * 256 + col] = o;
        }
    }
}

// ===========================================================================
// FUSED mlp3 (both layers, node rows): Out = elu(elu(Xb@w1+b1)@w2+b2)
// (unchanged from round 10 — works)
// ===========================================================================
__global__ __launch_bounds__(512, 1) void gemm8_mlp3_k(
    const ushort_t* __restrict__ Xb, const ushort_t* __restrict__ w1,
    const float* __restrict__ b1, const ushort_t* __restrict__ w2,
    const float* __restrict__ b2, ushort_t* __restrict__ Out)
{
    __shared__ ushort_t H1[8][8][512];   // 64 KB
    __shared__ ushort_t slots[36864];    // 72 KB
    const int tid = threadIdx.x;
    const int lane = tid & 63;
    const int w = tid >> 6;
    const int m0 = blockIdx.x * 128;
    const int r16 = lane & 15, kq = lane >> 4;

    const ushort_t* Ag = Xb + (size_t)(m0 + w * 16 + r16) * 256 + kq * 8;
    const size_t bo0 = (size_t)(2 * w * 16 + r16) * 256 + kq * 8;
    const size_t bo1 = (size_t)((2 * w + 1) * 16 + r16) * 256 + kq * 8;

    float4 bb1[2], bb2[2];
    #pragma unroll
    for (int nf = 0; nf < 2; ++nf) {
        bb1[nf] = *(const float4*)&b1[w * 32 + nf * 16 + kq * 4];
        bb2[nf] = *(const float4*)&b2[w * 32 + nf * 16 + kq * 4];
    }

#define M3_ST0(h) do { int sl_ = (h) % 3;                                   \
    gll16(Ag + (h) * 32, &slots[sl_ * 12288 + w * 512]);                    \
    gll16(w1 + bo0 + (h) * 32, &slots[sl_ * 12288 + 4096 + 2 * w * 512]);   \
    gll16(w1 + bo1 + (h) * 32, &slots[sl_ * 12288 + 4096 + (2 * w + 1) * 512]); \
} while (0)
#define M3_ST1(h) do { int sl_ = (h) & 1; int kk_ = (h) * 32;               \
    gll16(w2 + bo0 + kk_, &slots[sl_ * 8192 + 2 * w * 512]);                \
    gll16(w2 + bo1 + kk_, &slots[sl_ * 8192 + (2 * w + 1) * 512]);          \
} while (0)

    f32x4 acc0[8][2];
    #pragma unroll
    for (int i = 0; i < 8; ++i) { acc0[i][0] = (f32x4){0,0,0,0}; acc0[i][1] = (f32x4){0,0,0,0}; }

    M3_ST0(0); M3_ST0(1);
    asm volatile("s_waitcnt vmcnt(3)" ::: "memory");
    __builtin_amdgcn_s_barrier();

    for (int h = 0; h < 8; ++h) {
        if (h + 2 < 8) M3_ST0(h + 2);
        const int sl = h % 3;
        bf16x8 af[8], bfr[2];
        #pragma unroll
        for (int mf = 0; mf < 8; ++mf)
            af[mf] = *(const bf16x8*)&slots[sl * 12288 + mf * 512 + lane * 8];
        #pragma unroll
        for (int nf = 0; nf < 2; ++nf)
            bfr[nf] = *(const bf16x8*)&slots[sl * 12288 + 4096 + (2 * w + nf) * 512 + lane * 8];
        #pragma unroll
        for (int mf = 0; mf < 8; ++mf)
            #pragma unroll
            for (int nf = 0; nf < 2; ++nf)
                acc0[mf][nf] = __builtin_amdgcn_mfma_f32_16x16x32_bf16(bfr[nf], af[mf], acc0[mf][nf], 0, 0, 0);
        asm volatile("s_waitcnt lgkmcnt(0)" ::: "memory");
        if (h <= 5)      { asm volatile("s_waitcnt vmcnt(3)" ::: "memory"); }
        else if (h == 6) { asm volatile("s_waitcnt vmcnt(0)" ::: "memory"); }
        if (h < 7) __builtin_amdgcn_s_barrier();
    }

    M3_ST1(0);
    #pragma unroll
    for (int mf = 0; mf < 8; ++mf) {
        #pragma unroll
        for (int nf = 0; nf < 2; ++nf) {
            ushort4 o;
            o.x = f2b(eluf(acc0[mf][nf][0] + bb1[nf].x));
            o.y = f2b(eluf(acc0[mf][nf][1] + bb1[nf].y));
            o.z = f2b(eluf(acc0[mf][nf][2] + bb1[nf].z));
            o.w = f2b(eluf(acc0[mf][nf][3] + bb1[nf].w));
            int lanew = r16 + 16 * ((nf << 1) | (kq >> 1));
            *(ushort4*)&H1[mf][w][lanew * 8 + (kq & 1) * 4] = o;
            acc0[mf][nf] = (f32x4){0.f, 0.f, 0.f, 0.f};
        }
    }
    asm volatile("s_waitcnt lgkmcnt(0)" ::: "memory");
    asm volatile("s_waitcnt vmcnt(0)" ::: "memory");
    __builtin_amdgcn_s_barrier();

    for (int h = 0; h < 8; ++h) {
        if (h + 1 < 8) M3_ST1(h + 1);
        const int sl = h & 1;
        bf16x8 af[8], bfr[2];
        #pragma unroll
        for (int mf = 0; mf < 8; ++mf)
            af[mf] = *(const bf16x8*)&H1[mf][h][lane * 8];
        #pragma unroll
        for (int nf = 0; nf < 2; ++nf)
            bfr[nf] = *(const bf16x8*)&slots[sl * 8192 + (2 * w + nf) * 512 + lane * 8];
        #pragma unroll
        for (int mf = 0; mf < 8; ++mf)
            #pragma unroll
            for (int nf = 0; nf < 2; ++nf)
                acc0[mf][nf] = __builtin_amdgcn_mfma_f32_16x16x32_bf16(bfr[nf], af[mf], acc0[mf][nf], 0, 0, 0);
        asm volatile("s_waitcnt lgkmcnt(0)" ::: "memory");
        if (h + 1 < 8) { asm volatile("s_waitcnt vmcnt(0)" ::: "memory"); }
        if (h < 7) __builtin_amdgcn_s_barrier();
    }

    #pragma unroll
    for (int mf = 0; mf < 8; ++mf) {
        int row = m0 + mf * 16 + r16;
        #pragma unroll
        for (int nf = 0; nf < 2; ++nf) {
            int col = w * 32 + nf * 16 + kq * 4;
            ushort4 o;
            o.x = f2b(eluf(acc0[mf][nf][0] + bb2[nf].x));
            o.y = f2b(eluf(acc0[mf][nf][1] + bb2[nf].y));
            o.z = f2b(eluf(acc0[mf][nf][2] + bb2[nf].z));
            o.w = f2b(eluf(acc0[mf][nf][3] + bb2[nf].w));
            *(ushort4*)&Out[(size_t)row * 256 + col] = o;
        }
    }
#undef M3_ST0
#undef M3_ST1
}

// ===========================================================================
// mlp4 layer-1 variant: KD=768, A gathered on the fly (unchanged from r8).
// ===========================================================================
__global__ __launch_bounds__(512, 2) void gemm8_mlp4_k(
    const ushort_t* __restrict__ X2b, const ushort_t* __restrict__ EA,
    const ushort_t* __restrict__ Wt, const float* __restrict__ b1,
    ushort_t* __restrict__ C)
{
    __shared__ ushort_t lds[4][32][512];   // 128 KB
    const int tid = threadIdx.x;
    const int lane = tid & 63;
    const int w = tid >> 6;
    const int wm = w >> 2, wn = w & 3;
    const int m0 = blockIdx.x * 256;
    const int r16 = lane & 15, kq = lane >> 4;
    constexpr int NH = 24;

    const ushort_t* AS[2]; const ushort_t* AR[2]; const ushort_t* AE[2];
    #pragma unroll
    for (int ff = 0; ff < 2; ++ff) {
        int f = w + ff * 8;
        int m = m0 + f * 16 + r16;
        int be = m >> 6, t = m & 63;
        int b = be / E_, e = be % E_;
        int s = e / (V_ - 1);
        int r0 = e % (V_ - 1);
        int rr = r0 + (r0 >= s ? 1 : 0);
        AS[ff] = X2b + ((size_t)((b * V_ + s) * T_ + t)) * H_ + kq * 8;
        AR[ff] = X2b + ((size_t)((b * V_ + rr) * T_ + t)) * H_ + kq * 8;
        AE[ff] = EA + (size_t)m * H_ + kq * 8;
    }
    const ushort_t* Bg0 = Wt + (size_t)(w * 16 + r16) * 768 + kq * 8;
    const ushort_t* Bg1 = Wt + (size_t)((w + 8) * 16 + r16) * 768 + kq * 8;

    f32x4 acc[8][4];
    #pragma unroll
    for (int i = 0; i < 8; ++i)
        #pragma unroll
        for (int j = 0; j < 4; ++j)
            acc[i][j] = (f32x4){0.f, 0.f, 0.f, 0.f};

#define STM(h) do { int sl_ = (h) & 3; int kk_ = (h) * 32;                  \
    int seg_ = kk_ >> 8, off_ = kk_ & 255;                                  \
    const ushort_t* a0_ = (seg_ == 0 ? AS[0] : seg_ == 1 ? AR[0] : AE[0]) + off_; \
    const ushort_t* a1_ = (seg_ == 0 ? AS[1] : seg_ == 1 ? AR[1] : AE[1]) + off_; \
    gll16(a0_, &lds[sl_][w][0]);                                            \
    gll16(a1_, &lds[sl_][w + 8][0]);                                        \
    gll16(Bg0 + kk_, &lds[sl_][16 + w][0]);                                 \
    gll16(Bg1 + kk_, &lds[sl_][16 + w + 8][0]);                             \
} while (0)

    STM(0); STM(1); STM(2);
    asm volatile("s_waitcnt vmcnt(8)" ::: "memory");
    __builtin_amdgcn_s_barrier();

    for (int h = 0; h < NH; ++h) {
        if (h + 3 < NH) STM(h + 3);
        const int sl = h & 3;
        bf16x8 bfr[4];
        #pragma unroll
        for (int nf = 0; nf < 4; ++nf)
            bfr[nf] = *(const bf16x8*)&lds[sl][16 + wn * 4 + nf][lane * 8];
        #pragma unroll
        for (int mh = 0; mh < 2; ++mh) {
            bf16x8 af[4];
            #pragma unroll
            for (int mf = 0; mf < 4; ++mf)
                af[mf] = *(const bf16x8*)&lds[sl][wm * 8 + mh * 4 + mf][lane * 8];
            __builtin_amdgcn_s_setprio(1);
            #pragma unroll
            for (int mf = 0; mf < 4; ++mf)
                #pragma unroll
                for (int nf = 0; nf < 4; ++nf)
                    acc[mh * 4 + mf][nf] = __builtin_amdgcn_mfma_f32_16x16x32_bf16(
                        bfr[nf], af[mf], acc[mh * 4 + mf][nf], 0, 0, 0);
            __builtin_amdgcn_s_setprio(0);
        }
        asm volatile("s_waitcnt lgkmcnt(0)" ::: "memory");
        if (h < NH - 3)       { asm volatile("s_waitcnt vmcnt(8)" ::: "memory"); }
        else if (h == NH - 3) { asm volatile("s_waitcnt vmcnt(4)" ::: "memory"); }
        else if (h == NH - 2) { asm volatile("s_waitcnt vmcnt(0)" ::: "memory"); }
        if (h < NH - 1) __builtin_amdgcn_s_barrier();
    }
#undef STM

    #pragma unroll
    for (int mi = 0; mi < 8; ++mi) {
        int mrow = m0 + wm * 128 + mi * 16 + r16;
        #pragma unroll
        for (int nf = 0; nf < 4; ++nf) {
            int nb = wn * 64 + nf * 16 + kq * 4;
            float4 bb = *(const float4*)&b1[nb];
            float v0 = eluf(acc[mi][nf][0] + bb.x);
            float v1 = eluf(acc[mi][nf][1] + bb.y);
            float v2 = eluf(acc[mi][nf][2] + bb.z);
            float v3 = eluf(acc[mi][nf][3] + bb.w);
            ushort4 o; o.x = f2b(v0); o.y = f2b(v1); o.z = f2b(v2); o.w = f2b(v3);
            *(ushort4*)&C[(size_t)mrow * 256 + nb] = o;
        }
    }
}

// ===========================================================================
// weights f32 -> bf16 (packed):
// ef_w2 | m4_w1 | m4_w2 | f_wih | r_wih | e_w1 | m3_w1 | m3_w2
// ===========================================================================
__global__ __launch_bounds__(256) void wconv_k(
    const float* __restrict__ ef_w2, const float* __restrict__ m4_w1,
    const float* __restrict__ m4_w2, const float* __restrict__ f_wih,
    const float* __restrict__ r_wih, const float* __restrict__ e_w1,
    const float* __restrict__ m3_w1, const float* __restrict__ m3_w2,
    ushort_t* __restrict__ Wb)
{
    int i = blockIdx.x * 256 + threadIdx.x;   // < 622592
    const float* src; int off;
    if (i < 65536)       { src = ef_w2; off = i; }
    else if (i < 262144) { src = m4_w1; off = i - 65536; }
    else if (i < 327680) { src = m4_w2; off = i - 262144; }
    else if (i < 393216) { src = f_wih; off = i - 327680; }
    else if (i < 458752) { src = r_wih; off = i - 393216; }
    else if (i < 491520) { src = e_w1;  off = i - 458752; }
    else if (i < 557056) { src = m3_w1; off = i - 491520; }
    else                 { src = m3_w2; off = i - 557056; }
    Wb[i] = f2b(src[off]);
}

// ---------------------------------------------------------------------------
// edge2node: X[b,v,t,h] = (1/15)*sum_{e:RECV==v} EA[b,e,t,h] + rel@res_w.T + res_b
// Output bf16 (feeds MFMA mlp3).
// ---------------------------------------------------------------------------
__global__ __launch_bounds__(256) void e2n_k(
    const ushort_t* __restrict__ EA, const float* __restrict__ rel,
    const float* __restrict__ res_w, const float* __restrict__ res_b,
    ushort_t* __restrict__ X)
{
    const int idx = blockIdx.x;            // (b*V+v)*T + t
    const int t = idx & (T_ - 1);
    const int bv = idx >> 6;
    const int v = bv & (V_ - 1);
    const int b = bv >> 4;
    const int h = threadIdx.x;
    float sum = 0.f;
    #pragma unroll
    for (int i = 0; i < V_; ++i) {
        if (i == v) continue;
        int jj = (v < i) ? v : v - 1;
        int e = i * (V_ - 1) + jj;
        sum += b2f(EA[(((size_t)(b * E_ + e)) * T_ + t) * H_ + h]);
    }
    const float* rp = rel + ((size_t)bv * T_ + t) * DIN_;
    float res = res_b[h];
    #pragma unroll
    for (int d = 0; d < DIN_; ++d) res += rp[d] * res_w[h * DIN_ + d];
    X[((size_t)bv * T_ + t) * H_ + h] = f2b(sum * (1.f / 15.f) + res);
}

// ===========================================================================
// MFMA LSTM scan, both directions in one dispatch (blockIdx.y = dir).
// ===========================================================================
__global__ __launch_bounds__(256) void lstm_mfma4_k(
    const ushort_t* __restrict__ Gf, const ushort_t* __restrict__ Gr,
    const float* __restrict__ whh_f, const float* __restrict__ whh_r,
    ushort_t* __restrict__ COMB)
{
    __shared__ ushort_t hlds[2][1024];   // 2 x 2KB: h[seq][j] bf16, XOR-swizzled
    const int dir = blockIdx.y;
    const ushort_t* G = dir ? Gr : Gf;
    const float* whh = dir ? whh_r : whh_f;
    const int tid = threadIdx.x;
    const int lane = tid & 63;
    const int w = tid >> 6;              // wave id = j-block
    const int seq = lane & 15, kq = lane >> 4;
    const int be0 = blockIdx.x * 16;
    const int swz = (seq & 7) << 4;

    bf16x8 wf[4][2];
    #pragma unroll
    for (int a = 0; a < 4; ++a) {
        #pragma unroll
        for (int ks = 0; ks < 2; ++ks) {
            const float* p = whh + (size_t)((a * 4 + w) * 16 + seq) * 64 + ks * 32 + kq * 8;
            float4 x0 = *(const float4*)p;
            float4 x1 = *(const float4*)(p + 4);
            bf16x8 v;
            v[0] = (short)f2b(x0.x); v[1] = (short)f2b(x0.y);
            v[2] = (short)f2b(x0.z); v[3] = (short)f2b(x0.w);
            v[4] = (short)f2b(x1.x); v[5] = (short)f2b(x1.y);
            v[6] = (short)f2b(x1.z); v[7] = (short)f2b(x1.w);
            wf[a][ks] = v;
        }
    }

    const ushort_t* grow = G + ((size_t)(be0 + seq) * T_) * 256 + kq * 4;
    ushort_t* crow = COMB + ((size_t)(be0 + seq) * T_) * 128 + (dir ? 64 : 0) + 16 * w + 4 * kq;

    float c[4] = {};
    ushort4 gx[4];
    const int t0 = dir ? (T_ - 1) : 0;
    #pragma unroll
    for (int a = 0; a < 4; ++a)
        gx[a] = *(const ushort4*)(grow + (size_t)t0 * 256 + (a * 4 + w) * 16);

    for (int s = 0; s < T_; ++s) {
        const int t = dir ? (T_ - 1 - s) : s;
        f32x4 acc[4];
        #pragma unroll
        for (int a = 0; a < 4; ++a) {
            ushort4 g = gx[a];
            acc[a] = (f32x4){b2f(g.x), b2f(g.y), b2f(g.z), b2f(g.w)};
        }
        if (s < T_ - 1) {
            const int tn = dir ? (T_ - 2 - s) : (s + 1);
            #pragma unroll
            for (int a = 0; a < 4; ++a)
                gx[a] = *(const ushort4*)(grow + (size_t)tn * 256 + (a * 4 + w) * 16);
        }
        if (s) {
            bf16x8 af[2];
            #pragma unroll
            for (int ks = 0; ks < 2; ++ks) {
                int boff = (seq * 128 + ks * 64 + kq * 16) ^ swz;
                af[ks] = *(const bf16x8*)((const char*)hlds[(s - 1) & 1] + boff);
            }
            #pragma unroll
            for (int a = 0; a < 4; ++a) {
                acc[a] = __builtin_amdgcn_mfma_f32_16x16x32_bf16(wf[a][0], af[0], acc[a], 0, 0, 0);
                acc[a] = __builtin_amdgcn_mfma_f32_16x16x32_bf16(wf[a][1], af[1], acc[a], 0, 0, 0);
            }
        }
        float hh[4];
        #pragma unroll
        for (int r = 0; r < 4; ++r) {
            float zi = acc[0][r], zf = acc[1][r], zg = acc[2][r], zo = acc[3][r];
            float cc = fsig(zf) * c[r] + fsig(zi) * ftanh_(zg);
            c[r] = cc;
            hh[r] = fsig(zo) * ftanh_(cc);
        }
        ushort4 hv;
        hv.x = f2b(hh[0]); hv.y = f2b(hh[1]); hv.z = f2b(hh[2]); hv.w = f2b(hh[3]);
        int wb = (seq * 128 + 32 * w + 8 * kq) ^ swz;
        *(ushort4*)((char*)hlds[s & 1] + wb) = hv;
        *(ushort4*)(crow + (size_t)t * 128) = hv;
        asm volatile("s_waitcnt lgkmcnt(0)" ::: "memory");
        __builtin_amdgcn_sched_barrier(0);
        __builtin_amdgcn_s_barrier();
    }
}

// ---------------------------------------------------------------------------
// prior head: reads fwd hidden from comb[:, 0:64] (row stride 128)
// ---------------------------------------------------------------------------
__global__ __launch_bounds__(256) void prior_k(
    const ushort_t* __restrict__ COMB, const float* __restrict__ p_w,
    const float* __restrict__ p_b, float* __restrict__ out)
{
    const int row = blockIdx.x * 4 + (threadIdx.x >> 6);  // [0, BET)
    const int lane = threadIdx.x & 63;
    float hf = b2f(COMB[(size_t)row * 128 + lane]);
    float v0 = hf * p_w[lane];
    float v1 = hf * p_w[64 + lane];
    #pragma unroll
    for (int off = 32; off > 0; off >>= 1) {
        v0 += __shfl_down(v0, off, 64);
        v1 += __shfl_down(v1, off, 64);
    }
    if (lane == 0) {
        int t = row & (T_ - 1);
        int be = row >> 6;
        int e = be % E_, b = be / E_;
        size_t o = (((size_t)b * T_ + t) * E_ + e) * K_;
        out[o] = v0 + p_b[0];
        out[o + 1] = v1 + p_b[1];
    }
}

// ===========================================================================
// FUSED: ENCH = elu(COMB@e_w1.T + e_b1) in regs, then out = ENCH@e_w2.T + e_b2
// (unchanged from round 9/10)
// ===========================================================================
__global__ __launch_bounds__(512) void fused_enc_k(
    const ushort_t* __restrict__ COMB, const ushort_t* __restrict__ w_e1,
    const float* __restrict__ e_b1, const float* __restrict__ e_w2,
    const float* __restrict__ e_b2, float* __restrict__ out)
{
    __shared__ ushort_t sA[2][8][512];    // 16 KB
    __shared__ ushort_t sW[2][16][512];   // 32 KB
    __shared__ float part[128][4][2];     // 4 KB
    const int tid = threadIdx.x;
    const int lane = tid & 63;
    const int w = tid >> 6;
    const int wr = w >> 2, wc = w & 3;
    const int m0 = blockIdx.x * 128;
    const int r16 = lane & 15, kq = lane >> 4;

    const ushort_t* Asrc = COMB + (size_t)(m0 + w * 16 + r16) * 128 + kq * 8;
    const size_t woffA = (size_t)((2 * w) * 16 + r16) * 128 + kq * 8;
    const size_t woffB = (size_t)((2 * w + 1) * 16 + r16) * 128 + kq * 8;

    float4 w2v[2][4];
    #pragma unroll
    for (int j = 0; j < 2; ++j)
        #pragma unroll
        for (int nf = 0; nf < 4; ++nf)
            w2v[j][nf] = *(const float4*)&e_w2[j * 256 + wc * 64 + nf * 16 + kq * 4];

    f32x4 acc[4][4];
    #pragma unroll
    for (int i = 0; i < 4; ++i)
        #pragma unroll
        for (int j = 0; j < 4; ++j)
            acc[i][j] = (f32x4){0.f, 0.f, 0.f, 0.f};

#define FE_STAGE(bufi, kt_) do {                                             \
    gll16(Asrc + (kt_) * 32, &sA[bufi][w][0]);                               \
    gll16(w_e1 + woffA + (kt_) * 32, &sW[bufi][2 * w][0]);                   \
    gll16(w_e1 + woffB + (kt_) * 32, &sW[bufi][2 * w + 1][0]);               \
} while (0)

    FE_STAGE(0, 0);
    asm volatile("s_waitcnt vmcnt(0)" ::: "memory");
    __builtin_amdgcn_s_barrier();

    for (int s = 0; s < 4; ++s) {
        const int buf = s & 1;
        if (s < 3) FE_STAGE(buf ^ 1, s + 1);
        bf16x8 af[4], bfr[4];
        #pragma unroll
        for (int mf = 0; mf < 4; ++mf)
            af[mf] = *(const bf16x8*)&sA[buf][wr * 4 + mf][lane * 8];
        #pragma unroll
        for (int nf = 0; nf < 4; ++nf)
            bfr[nf] = *(const bf16x8*)&sW[buf][wc * 4 + nf][lane * 8];
        #pragma unroll
        for (int mf = 0; mf < 4; ++mf)
            #pragma unroll
            for (int nf = 0; nf < 4; ++nf)
                acc[mf][nf] = __builtin_amdgcn_mfma_f32_16x16x32_bf16(bfr[nf], af[mf], acc[mf][nf], 0, 0, 0);
        asm volatile("s_waitcnt vmcnt(0)" ::: "memory");
        __builtin_amdgcn_s_barrier();
    }

    #pragma unroll
    for (int mf = 0; mf < 4; ++mf) {
        float s0 = 0.f, s1 = 0.f;
        #pragma unroll
        for (int nf = 0; nf < 4; ++nf) {
            int col = wc * 64 + nf * 16 + kq * 4;
            float4 bb = *(const float4*)&e_b1[col];
            float v0 = eluf(acc[mf][nf][0] + bb.x);
            float v1 = eluf(acc[mf][nf][1] + bb.y);
            float v2 = eluf(acc[mf][nf][2] + bb.z);
            float v3 = eluf(acc[mf][nf][3] + bb.w);
            s0 += v0 * w2v[0][nf].x + v1 * w2v[0][nf].y + v2 * w2v[0][nf].z + v3 * w2v[0][nf].w;
            s1 += v0 * w2v[1][nf].x + v1 * w2v[1][nf].y + v2 * w2v[1][nf].z + v3 * w2v[1][nf].w;
        }
        s0 += __shfl_xor(s0, 16, 64); s0 += __shfl_xor(s0, 32, 64);
        s1 += __shfl_xor(s1, 16, 64); s1 += __shfl_xor(s1, 32, 64);
        if (kq == 0) {
            part[wr * 64 + mf * 16 + r16][wc][0] = s0;
            part[wr * 64 + mf * 16 + r16][wc][1] = s1;
        }
    }
    __syncthreads();
    if (tid < 256) {
        int row = tid >> 1, k = tid & 1;
        float v = part[row][0][k] + part[row][1][k] + part[row][2][k] + part[row][3][k] + e_b2[k];
        int gr = m0 + row;
        int be = gr >> 6, t = gr & 63;
        int e = be % E_, b = be / E_;
        out[(size_t)(B_ * T_ * E_ * K_) + (((size_t)b * T_ + t) * E_ + e) * K_ + k] = v;
    }
#undef FE_STAGE
}

// ---------------------------------------------------------------------------
extern "C" void kernel_launch(void* const* d_in, const int* in_sizes, int n_in,
                              void* d_out, int out_size, void* d_ws, size_t ws_size,
                              hipStream_t stream)
{
    const float* rel    = (const float*)d_in[0];
    const float* ear    = (const float*)d_in[1];
    const float* epos   = (const float*)d_in[2];
    const float* ef_w1  = (const float*)d_in[3];
    const float* ef_b1  = (const float*)d_in[4];
    const float* ef_w2  = (const float*)d_in[5];
    const float* ef_b2  = (const float*)d_in[6];
    const float* res_w  = (const float*)d_in[7];
    const float* res_b  = (const float*)d_in[8];
    const float* m3_w1  = (const float*)d_in[9];
    const float* m3_b1  = (const float*)d_in[10];
    const float* m3_w2  = (const float*)d_in[11];
    const float* m3_b2  = (const float*)d_in[12];
    const float* m4_w1  = (const float*)d_in[13];
    const float* m4_b1  = (const float*)d_in[14];
    const float* m4_w2  = (const float*)d_in[15];
    const float* m4_b2  = (const float*)d_in[16];
    const float* f_wih  = (const float*)d_in[17];
    const float* f_whh  = (const float*)d_in[18];
    const float* f_bih  = (const float*)d_in[19];
    const float* f_bhh  = (const float*)d_in[20];
    const float* r_wih  = (const float*)d_in[21];
    const float* r_whh  = (const float*)d_in[22];
    const float* r_bih  = (const float*)d_in[23];
    const float* r_bhh  = (const float*)d_in[24];
    const float* p_w    = (const float*)d_in[25];
    const float* p_b    = (const float*)d_in[26];
    const float* e_w1   = (const float*)d_in[27];
    const float* e_b1   = (const float*)d_in[28];
    const float* e_w2   = (const float*)d_in[29];
    const float* e_b2   = (const float*)d_in[30];
    float* out = (float*)d_out;

    // workspace layout (bytes), total ~163 MB
    char* ws = (char*)d_ws;
    const size_t BIGB  = (size_t)BET_ * H_ * sizeof(ushort_t);   // 62,914,560
    const size_t COMBB = (size_t)BET_ * 128 * sizeof(ushort_t);  // 31,457,280
    const size_t X2BB  = (size_t)BVT_ * H_ * sizeof(ushort_t);   //  4,194,304
    ushort_t* R1   = (ushort_t*)(ws);
    ushort_t* R2   = (ushort_t*)(ws + BIGB);
    ushort_t* COMB = (ushort_t*)(ws + 2 * BIGB);
    ushort_t* X2b  = (ushort_t*)(ws + 2 * BIGB + COMBB);
    ushort_t* Wb   = (ushort_t*)(ws + 2 * BIGB + COMBB + X2BB);
    // node-stage bf16 X lives inside (dead) R1 region
    ushort_t* Xbf = (ushort_t*)(ws);
    // packed bf16 weight offsets (elements)
    const ushort_t* wb_ef2  = Wb + 0;
    const ushort_t* wb_m41  = Wb + 65536;
    const ushort_t* wb_m42  = Wb + 262144;
    const ushort_t* wb_fwih = Wb + 327680;
    const ushort_t* wb_rwih = Wb + 393216;
    const ushort_t* wb_ew1  = Wb + 458752;
    const ushort_t* wb_m31  = Wb + 491520;
    const ushort_t* wb_m32  = Wb + 557056;

    dim3 blk(256);
    dim3 blk8(512);
    dim3 g128(BET_ / 128);     // 960 blocks (BM=128 kernels)
    dim3 g256(BET_ / 256);     // 480 blocks (BM=256 kernels)

    // 0. weights -> bf16 (incl. mlp3)
    wconv_k<<<2432, blk, 0, stream>>>(ef_w2, m4_w1, m4_w2, f_wih, r_wih, e_w1, m3_w1, m3_w2, Wb);
    // 1. fused edge-filter MLP (ein K=16 + ef2 K=256) -> EA in R2
    gemm8_ef_k<<<g128, blk8, 0, stream>>>(ear, epos, ef_w1, ef_b1, wb_ef2, ef_b2, R2);
    // 2. edge2node + residual -> bf16 X
    e2n_k<<<BVT_, blk, 0, stream>>>(R2, rel, res_w, res_b, Xbf);
    // 3. fused mlp3 (both layers, MFMA) -> X2b
    gemm8_mlp3_k<<<BVT_ / 128, blk8, 0, stream>>>(Xbf, wb_m31, m3_b1, wb_m32, m3_b2, X2b);
    // 4. node2edge gather + mlp4 layer 1 -> T1 (R1)
    gemm8_mlp4_k<<<g256, blk8, 0, stream>>>(X2b, R2, wb_m41, m4_b1, R1);
    // 5. m4l2 + gate GEMMs on the proven BM=256 schedule:
    //    M2: R1 -> R2; GF: R2 -> R1; GR: R2 -> R2 (in-place, per-block rows)
    gemm8_k<256, 1><<<g256, blk8, 0, stream>>>(R1, wb_m42, m4_b2, nullptr, R2);
    gemm8_k<256, 0><<<g256, blk8, 0, stream>>>(R2, wb_fwih, f_bih, f_bhh, R1);
    gemm8_k<256, 0><<<g256, blk8, 0, stream>>>(R2, wb_rwih, r_bih, r_bhh, R2);
    // 6. LSTM scans, both directions in one dispatch (Gf=R1, Gr=R2)
    lstm_mfma4_k<<<dim3(BE_ / 16, 2), blk, 0, stream>>>(R1, R2, f_whh, r_whh, COMB);
    // 7. heads
    prior_k<<<BET_ / 4, blk, 0, stream>>>(COMB, p_w, p_b, out);
    fused_enc_k<<<g128, blk8, 0, stream>>>(COMB, wb_ew1, e_b1, e_w2, e_b2, out);
}

// Round 12
// 404.876 us; speedup vs baseline: 6.5394x; 1.0472x over previous
//
#include <hip/hip_runtime.h>
#include <cstdint>
#include <cstddef>
#include <type_traits>

// Problem constants
#define B_ 8
#define V_ 16
#define T_ 64
#define E_ 240          // V*(V-1)
#define H_ 256
#define RH_ 64
#define K_ 2
#define DIN_ 6
#define BET_ (B_*E_*T_)   // 122880
#define BVT_ (B_*V_*T_)   // 8192
#define BE_ (B_*E_)       // 1920

typedef unsigned short ushort_t;
typedef unsigned int u32;
typedef __attribute__((ext_vector_type(8))) short bf16x8;
typedef __attribute__((ext_vector_type(4))) float f32x4;

__device__ __forceinline__ float eluf(float x) { return x > 0.f ? x : __expf(x) - 1.f; }
__device__ __forceinline__ float fsig(float x) { return 1.f / (1.f + __expf(-x)); }
__device__ __forceinline__ float ftanh_(float x) {
    float y = fminf(fmaxf(x, -8.f), 8.f);
    float e = __expf(2.f * y);
    return (e - 1.f) / (e + 1.f);
}
__device__ __forceinline__ float b2f(ushort_t u) {
    union { float f; uint32_t i; } v; v.i = ((uint32_t)u) << 16; return v.f;
}
__device__ __forceinline__ ushort_t f2b(float f) {
    union { float f; uint32_t i; } v; v.f = f;
    uint32_t r = (v.i + 0x7FFFu + ((v.i >> 16) & 1u)) >> 16;
    return (ushort_t)r;
}

// async global->LDS, 16B per lane; LDS dest = wave-uniform base + lane*16
__device__ __forceinline__ void gll16(const void* g, void* l) {
    __builtin_amdgcn_global_load_lds(
        (const __attribute__((address_space(1))) u32*)g,
        (__attribute__((address_space(3))) u32*)l, 16, 0, 0);
}

// ===========================================================================
// 8-wave half-tile-pipelined MFMA GEMM (r8-proven): C = act(A@W.T + b1 (+b2))
// BM=256, BN=256(=N), wave-tile 128x64 via mh-split, K-half=32, 4 LDS slots,
// counted vmcnt(8/4/0). In-place safe for per-block rows.
// ===========================================================================
template<int KD, int ACT>
__global__ __launch_bounds__(512, 2) void gemm8_k(
    const ushort_t* __restrict__ A, const ushort_t* __restrict__ Wt,
    const float* __restrict__ b1, const float* __restrict__ b2,
    ushort_t* __restrict__ C)
{
    __shared__ ushort_t lds[4][32][512];   // 128 KB
    const int tid = threadIdx.x;
    const int lane = tid & 63;
    const int w = tid >> 6;                // 0..7
    const int wm = w >> 2, wn = w & 3;     // 2m x 4n
    const int m0 = blockIdx.x * 256;
    const int r16 = lane & 15, kq = lane >> 4;
    constexpr int NH = KD / 32;

    const ushort_t* Ag0 = A + (size_t)(m0 + w * 16 + r16) * KD + kq * 8;
    const ushort_t* Ag1 = A + (size_t)(m0 + (w + 8) * 16 + r16) * KD + kq * 8;
    const ushort_t* Bg0 = Wt + (size_t)(w * 16 + r16) * KD + kq * 8;
    const ushort_t* Bg1 = Wt + (size_t)((w + 8) * 16 + r16) * KD + kq * 8;

    f32x4 acc[8][4];
    #pragma unroll
    for (int i = 0; i < 8; ++i)
        #pragma unroll
        for (int j = 0; j < 4; ++j)
            acc[i][j] = (f32x4){0.f, 0.f, 0.f, 0.f};

#define ST8(h) do { int sl_ = (h) & 3; int kk_ = (h) * 32;                  \
    gll16(Ag0 + kk_, &lds[sl_][w][0]);                                      \
    gll16(Ag1 + kk_, &lds[sl_][w + 8][0]);                                  \
    gll16(Bg0 + kk_, &lds[sl_][16 + w][0]);                                 \
    gll16(Bg1 + kk_, &lds[sl_][16 + w + 8][0]);                             \
} while (0)

    ST8(0); ST8(1); ST8(2);
    asm volatile("s_waitcnt vmcnt(8)" ::: "memory");   // half 0 landed
    __builtin_amdgcn_s_barrier();

    for (int h = 0; h < NH; ++h) {
        if (h + 3 < NH) ST8(h + 3);
        const int sl = h & 3;
        bf16x8 bfr[4];
        #pragma unroll
        for (int nf = 0; nf < 4; ++nf)
            bfr[nf] = *(const bf16x8*)&lds[sl][16 + wn * 4 + nf][lane * 8];
        #pragma unroll
        for (int mh = 0; mh < 2; ++mh) {
            bf16x8 af[4];
            #pragma unroll
            for (int mf = 0; mf < 4; ++mf)
                af[mf] = *(const bf16x8*)&lds[sl][wm * 8 + mh * 4 + mf][lane * 8];
            __builtin_amdgcn_s_setprio(1);
            #pragma unroll
            for (int mf = 0; mf < 4; ++mf)
                #pragma unroll
                for (int nf = 0; nf < 4; ++nf)
                    acc[mh * 4 + mf][nf] = __builtin_amdgcn_mfma_f32_16x16x32_bf16(
                        bfr[nf], af[mf], acc[mh * 4 + mf][nf], 0, 0, 0);
            __builtin_amdgcn_s_setprio(0);
        }
        asm volatile("s_waitcnt lgkmcnt(0)" ::: "memory");  // my reads of slot done
        if (h < NH - 3)       { asm volatile("s_waitcnt vmcnt(8)" ::: "memory"); }
        else if (h == NH - 3) { asm volatile("s_waitcnt vmcnt(4)" ::: "memory"); }
        else if (h == NH - 2) { asm volatile("s_waitcnt vmcnt(0)" ::: "memory"); }
        if (h < NH - 1) __builtin_amdgcn_s_barrier();
    }
#undef ST8

    #pragma unroll
    for (int mi = 0; mi < 8; ++mi) {
        int mrow = m0 + wm * 128 + mi * 16 + r16;
        #pragma unroll
        for (int nf = 0; nf < 4; ++nf) {
            int nb = wn * 64 + nf * 16 + kq * 4;
            float4 bb = *(const float4*)&b1[nb];
            if (b2) {
                float4 b2v = *(const float4*)&b2[nb];
                bb.x += b2v.x; bb.y += b2v.y; bb.z += b2v.z; bb.w += b2v.w;
            }
            float v0 = acc[mi][nf][0] + bb.x;
            float v1 = acc[mi][nf][1] + bb.y;
            float v2 = acc[mi][nf][2] + bb.z;
            float v3 = acc[mi][nf][3] + bb.w;
            if (ACT) { v0 = eluf(v0); v1 = eluf(v1); v2 = eluf(v2); v3 = eluf(v3); }
            ushort4 o; o.x = f2b(v0); o.y = f2b(v1); o.z = f2b(v2); o.w = f2b(v3);
            *(ushort4*)&C[(size_t)mrow * 256 + nb] = o;
        }
    }
}

// ===========================================================================
// GF+GR merged GEMM: BM=128, N=512 ([fih|rih]), KD=256 (8 halves).
// Wave w (0..7): cols 64*(w&3) of (w<4 ? GF : GR). acc[8][4] + mh-split
// (same VGPR budget as gemm8_k). 3 LDS slots x 40KB = 120 KB.
// 5 loads/wave/half (1 A + 4 B); counted vmcnt(5), 0 at tail.
// GR may be in-place over A (per-block rows; A loads all landed by h=NH-2).
// ===========================================================================
__global__ __launch_bounds__(512, 1) void gemm8_gates_k(
    const ushort_t* __restrict__ A, const ushort_t* __restrict__ w_fih,
    const ushort_t* __restrict__ w_rih,
    const float* __restrict__ f_bih, const float* __restrict__ f_bhh,
    const float* __restrict__ r_bih, const float* __restrict__ r_bhh,
    ushort_t* __restrict__ GF, ushort_t* __restrict__ GR)
{
    __shared__ ushort_t lds[3][40][512];   // 120 KB: entries 0-7 A, 8-39 B
    const int tid = threadIdx.x;
    const int lane = tid & 63;
    const int w = tid >> 6;
    const int m0 = blockIdx.x * 128;
    const int r16 = lane & 15, kq = lane >> 4;
    constexpr int NH = 8;

    const ushort_t* Ag = A + (size_t)(m0 + w * 16 + r16) * 256 + kq * 8;
    const ushort_t* WB = (w < 4) ? w_fih : w_rih;
    const int cb = (w & 3) * 64;           // col base within its gate matrix

    // hoisted biases (bih + bhh) for this wave's cols
    const float* bi = (w < 4) ? f_bih : r_bih;
    const float* bh = (w < 4) ? f_bhh : r_bhh;
    float4 bg[4];
    #pragma unroll
    for (int nf = 0; nf < 4; ++nf) {
        int col = cb + nf * 16 + kq * 4;
        float4 a = *(const float4*)&bi[col];
        float4 b = *(const float4*)&bh[col];
        bg[nf] = (float4){a.x + b.x, a.y + b.y, a.z + b.z, a.w + b.w};
    }

    f32x4 acc[8][4];
    #pragma unroll
    for (int i = 0; i < 8; ++i)
        #pragma unroll
        for (int j = 0; j < 4; ++j)
            acc[i][j] = (f32x4){0.f, 0.f, 0.f, 0.f};

#define GST(h) do { int sl_ = (h) % 3; int kk_ = (h) * 32;                  \
    gll16(Ag + kk_, &lds[sl_][w][0]);                                       \
    _Pragma("unroll")                                                       \
    for (int j = 0; j < 4; ++j)                                             \
        gll16(WB + (size_t)(cb + j * 16 + r16) * 256 + kq * 8 + kk_,        \
              &lds[sl_][8 + 4 * w + j][0]);                                 \
} while (0)

    GST(0); GST(1);
    asm volatile("s_waitcnt vmcnt(5)" ::: "memory");   // half 0 landed
    __builtin_amdgcn_s_barrier();

    for (int h = 0; h < NH; ++h) {
        if (h + 2 < NH) GST(h + 2);
        const int sl = h % 3;
        bf16x8 bfr[4];
        #pragma unroll
        for (int nf = 0; nf < 4; ++nf)
            bfr[nf] = *(const bf16x8*)&lds[sl][8 + 4 * w + nf][lane * 8];
        #pragma unroll
        for (int mh = 0; mh < 2; ++mh) {
            bf16x8 af[4];
            #pragma unroll
            for (int mf = 0; mf < 4; ++mf)
                af[mf] = *(const bf16x8*)&lds[sl][mh * 4 + mf][lane * 8];
            __builtin_amdgcn_s_setprio(1);
            #pragma unroll
            for (int mf = 0; mf < 4; ++mf)
                #pragma unroll
                for (int nf = 0; nf < 4; ++nf)
                    acc[mh * 4 + mf][nf] = __builtin_amdgcn_mfma_f32_16x16x32_bf16(
                        bfr[nf], af[mf], acc[mh * 4 + mf][nf], 0, 0, 0);
            __builtin_amdgcn_s_setprio(0);
        }
        asm volatile("s_waitcnt lgkmcnt(0)" ::: "memory");
        if (h <= NH - 3)      { asm volatile("s_waitcnt vmcnt(5)" ::: "memory"); }
        else if (h == NH - 2) { asm volatile("s_waitcnt vmcnt(0)" ::: "memory"); }
        if (h < NH - 1) __builtin_amdgcn_s_barrier();
    }
#undef GST

    ushort_t* Wout = (w < 4) ? GF : GR;
    #pragma unroll
    for (int mi = 0; mi < 8; ++mi) {
        int mrow = m0 + mi * 16 + r16;
        #pragma unroll
        for (int nf = 0; nf < 4; ++nf) {
            int col = cb + nf * 16 + kq * 4;
            ushort4 o;
            o.x = f2b(acc[mi][nf][0] + bg[nf].x);
            o.y = f2b(acc[mi][nf][1] + bg[nf].y);
            o.z = f2b(acc[mi][nf][2] + bg[nf].z);
            o.w = f2b(acc[mi][nf][3] + bg[nf].w);
            *(ushort4*)&Wout[(size_t)mrow * 256 + col] = o;
        }
    }
}

// ===========================================================================
// VALU ein GEMM (r2-proven): H1 = elu(concat(ear,epos)@ef_w1.T + b1), Kd=16.
// ===========================================================================
__global__ __launch_bounds__(256) void gemm_ein_k(
    const float* __restrict__ ear, const float* __restrict__ epos,
    const float* __restrict__ W, const float* __restrict__ b1,
    ushort_t* __restrict__ C)
{
    __shared__ float As[16][64];
    __shared__ float Ws[16][64];
    const int m0 = blockIdx.x * 64, n0 = blockIdx.y * 64;
    const int tid = threadIdx.x;
    const int tm = tid >> 4, tn = tid & 15;
    const int lm = tid >> 2, lq = tid & 3;
    const int m = m0 + lm;
    float a_[4];
    #pragma unroll
    for (int q = 0; q < 4; ++q) {
        int c = lq * 4 + q;
        a_[q] = (c < 13) ? ear[(size_t)m * 13 + c] : epos[(size_t)m * 3 + (c - 13)];
    }
    float4 wv = *(const float4*)(W + (size_t)(n0 + lm) * 16 + lq * 4);
    As[lq*4+0][lm] = a_[0]; As[lq*4+1][lm] = a_[1]; As[lq*4+2][lm] = a_[2]; As[lq*4+3][lm] = a_[3];
    Ws[lq*4+0][lm] = wv.x; Ws[lq*4+1][lm] = wv.y; Ws[lq*4+2][lm] = wv.z; Ws[lq*4+3][lm] = wv.w;
    __syncthreads();
    float acc[4][4] = {};
    #pragma unroll
    for (int k = 0; k < 16; ++k) {
        float4 a = *(const float4*)&As[k][tm * 4];
        float4 w = *(const float4*)&Ws[k][tn * 4];
        float aa[4] = {a.x, a.y, a.z, a.w};
        float ww[4] = {w.x, w.y, w.z, w.w};
        #pragma unroll
        for (int i = 0; i < 4; ++i)
            #pragma unroll
            for (int j = 0; j < 4; ++j)
                acc[i][j] += aa[i] * ww[j];
    }
    #pragma unroll
    for (int i = 0; i < 4; ++i) {
        ushort4 o;
        o.x = f2b(eluf(acc[i][0] + b1[n0 + tn*4 + 0]));
        o.y = f2b(eluf(acc[i][1] + b1[n0 + tn*4 + 1]));
        o.z = f2b(eluf(acc[i][2] + b1[n0 + tn*4 + 2]));
        o.w = f2b(eluf(acc[i][3] + b1[n0 + tn*4 + 3]));
        *(ushort4*)(C + (size_t)(m0 + tm * 4 + i) * H_ + (n0 + tn * 4)) = o;
    }
}

// ===========================================================================
// FUSED mlp3 (both layers, node rows) — unchanged from r10 (works)
// ===========================================================================
__global__ __launch_bounds__(512, 1) void gemm8_mlp3_k(
    const ushort_t* __restrict__ Xb, const ushort_t* __restrict__ w1,
    const float* __restrict__ b1, const ushort_t* __restrict__ w2,
    const float* __restrict__ b2, ushort_t* __restrict__ Out)
{
    __shared__ ushort_t H1[8][8][512];   // 64 KB
    __shared__ ushort_t slots[36864];    // 72 KB
    const int tid = threadIdx.x;
    const int lane = tid & 63;
    const int w = tid >> 6;
    const int m0 = blockIdx.x * 128;
    const int r16 = lane & 15, kq = lane >> 4;

    const ushort_t* Ag = Xb + (size_t)(m0 + w * 16 + r16) * 256 + kq * 8;
    const size_t bo0 = (size_t)(2 * w * 16 + r16) * 256 + kq * 8;
    const size_t bo1 = (size_t)((2 * w + 1) * 16 + r16) * 256 + kq * 8;

    float4 bb1[2], bb2[2];
    #pragma unroll
    for (int nf = 0; nf < 2; ++nf) {
        bb1[nf] = *(const float4*)&b1[w * 32 + nf * 16 + kq * 4];
        bb2[nf] = *(const float4*)&b2[w * 32 + nf * 16 + kq * 4];
    }

#define M3_ST0(h) do { int sl_ = (h) % 3;                                   \
    gll16(Ag + (h) * 32, &slots[sl_ * 12288 + w * 512]);                    \
    gll16(w1 + bo0 + (h) * 32, &slots[sl_ * 12288 + 4096 + 2 * w * 512]);   \
    gll16(w1 + bo1 + (h) * 32, &slots[sl_ * 12288 + 4096 + (2 * w + 1) * 512]); \
} while (0)
#define M3_ST1(h) do { int sl_ = (h) & 1; int kk_ = (h) * 32;               \
    gll16(w2 + bo0 + kk_, &slots[sl_ * 8192 + 2 * w * 512]);                \
    gll16(w2 + bo1 + kk_, &slots[sl_ * 8192 + (2 * w + 1) * 512]);          \
} while (0)

    f32x4 acc0[8][2];
    #pragma unroll
    for (int i = 0; i < 8; ++i) { acc0[i][0] = (f32x4){0,0,0,0}; acc0[i][1] = (f32x4){0,0,0,0}; }

    M3_ST0(0); M3_ST0(1);
    asm volatile("s_waitcnt vmcnt(3)" ::: "memory");
    __builtin_amdgcn_s_barrier();

    for (int h = 0; h < 8; ++h) {
        if (h + 2 < 8) M3_ST0(h + 2);
        const int sl = h % 3;
        bf16x8 af[8], bfr[2];
        #pragma unroll
        for (int mf = 0; mf < 8; ++mf)
            af[mf] = *(const bf16x8*)&slots[sl * 12288 + mf * 512 + lane * 8];
        #pragma unroll
        for (int nf = 0; nf < 2; ++nf)
            bfr[nf] = *(const bf16x8*)&slots[sl * 12288 + 4096 + (2 * w + nf) * 512 + lane * 8];
        #pragma unroll
        for (int mf = 0; mf < 8; ++mf)
            #pragma unroll
            for (int nf = 0; nf < 2; ++nf)
                acc0[mf][nf] = __builtin_amdgcn_mfma_f32_16x16x32_bf16(bfr[nf], af[mf], acc0[mf][nf], 0, 0, 0);
        asm volatile("s_waitcnt lgkmcnt(0)" ::: "memory");
        if (h <= 5)      { asm volatile("s_waitcnt vmcnt(3)" ::: "memory"); }
        else if (h == 6) { asm volatile("s_waitcnt vmcnt(0)" ::: "memory"); }
        if (h < 7) __builtin_amdgcn_s_barrier();
    }

    M3_ST1(0);
    #pragma unroll
    for (int mf = 0; mf < 8; ++mf) {
        #pragma unroll
        for (int nf = 0; nf < 2; ++nf) {
            ushort4 o;
            o.x = f2b(eluf(acc0[mf][nf][0] + bb1[nf].x));
            o.y = f2b(eluf(acc0[mf][nf][1] + bb1[nf].y));
            o.z = f2b(eluf(acc0[mf][nf][2] + bb1[nf].z));
            o.w = f2b(eluf(acc0[mf][nf][3] + bb1[nf].w));
            int lanew = r16 + 16 * ((nf << 1) | (kq >> 1));
            *(ushort4*)&H1[mf][w][lanew * 8 + (kq & 1) * 4] = o;
            acc0[mf][nf] = (f32x4){0.f, 0.f, 0.f, 0.f};
        }
    }
    asm volatile("s_waitcnt lgkmcnt(0)" ::: "memory");
    asm volatile("s_waitcnt vmcnt(0)" ::: "memory");
    __builtin_amdgcn_s_barrier();

    for (int h = 0; h < 8; ++h) {
        if (h + 1 < 8) M3_ST1(h + 1);
        const int sl = h & 1;
        bf16x8 af[8], bfr[2];
        #pragma unroll
        for (int mf = 0; mf < 8; ++mf)
            af[mf] = *(const bf16x8*)&H1[mf][h][lane * 8];
        #pragma unroll
        for (int nf = 0; nf < 2; ++nf)
            bfr[nf] = *(const bf16x8*)&slots[sl * 8192 + (2 * w + nf) * 512 + lane * 8];
        #pragma unroll
        for (int mf = 0; mf < 8; ++mf)
            #pragma unroll
            for (int nf = 0; nf < 2; ++nf)
                acc0[mf][nf] = __builtin_amdgcn_mfma_f32_16x16x32_bf16(bfr[nf], af[mf], acc0[mf][nf], 0, 0, 0);
        asm volatile("s_waitcnt lgkmcnt(0)" ::: "memory");
        if (h + 1 < 8) { asm volatile("s_waitcnt vmcnt(0)" ::: "memory"); }
        if (h < 7) __builtin_amdgcn_s_barrier();
    }

    #pragma unroll
    for (int mf = 0; mf < 8; ++mf) {
        int row = m0 + mf * 16 + r16;
        #pragma unroll
        for (int nf = 0; nf < 2; ++nf) {
            int col = w * 32 + nf * 16 + kq * 4;
            ushort4 o;
            o.x = f2b(eluf(acc0[mf][nf][0] + bb2[nf].x));
            o.y = f2b(eluf(acc0[mf][nf][1] + bb2[nf].y));
            o.z = f2b(eluf(acc0[mf][nf][2] + bb2[nf].z));
            o.w = f2b(eluf(acc0[mf][nf][3] + bb2[nf].w));
            *(ushort4*)&Out[(size_t)row * 256 + col] = o;
        }
    }
#undef M3_ST0
#undef M3_ST1
}

// ===========================================================================
// mlp4 layer-1 variant: KD=768, A gathered on the fly (unchanged from r8).
// ===========================================================================
__global__ __launch_bounds__(512, 2) void gemm8_mlp4_k(
    const ushort_t* __restrict__ X2b, const ushort_t* __restrict__ EA,
    const ushort_t* __restrict__ Wt, const float* __restrict__ b1,
    ushort_t* __restrict__ C)
{
    __shared__ ushort_t lds[4][32][512];   // 128 KB
    const int tid = threadIdx.x;
    const int lane = tid & 63;
    const int w = tid >> 6;
    const int wm = w >> 2, wn = w & 3;
    const int m0 = blockIdx.x * 256;
    const int r16 = lane & 15, kq = lane >> 4;
    constexpr int NH = 24;

    const ushort_t* AS[2]; const ushort_t* AR[2]; const ushort_t* AE[2];
    #pragma unroll
    for (int ff = 0; ff < 2; ++ff) {
        int f = w + ff * 8;
        int m = m0 + f * 16 + r16;
        int be = m >> 6, t = m & 63;
        int b = be / E_, e = be % E_;
        int s = e / (V_ - 1);
        int r0 = e % (V_ - 1);
        int rr = r0 + (r0 >= s ? 1 : 0);
        AS[ff] = X2b + ((size_t)((b * V_ + s) * T_ + t)) * H_ + kq * 8;
        AR[ff] = X2b + ((size_t)((b * V_ + rr) * T_ + t)) * H_ + kq * 8;
        AE[ff] = EA + (size_t)m * H_ + kq * 8;
    }
    const ushort_t* Bg0 = Wt + (size_t)(w * 16 + r16) * 768 + kq * 8;
    const ushort_t* Bg1 = Wt + (size_t)((w + 8) * 16 + r16) * 768 + kq * 8;

    f32x4 acc[8][4];
    #pragma unroll
    for (int i = 0; i < 8; ++i)
        #pragma unroll
        for (int j = 0; j < 4; ++j)
            acc[i][j] = (f32x4){0.f, 0.f, 0.f, 0.f};

#define STM(h) do { int sl_ = (h) & 3; int kk_ = (h) * 32;                  \
    int seg_ = kk_ >> 8, off_ = kk_ & 255;                                  \
    const ushort_t* a0_ = (seg_ == 0 ? AS[0] : seg_ == 1 ? AR[0] : AE[0]) + off_; \
    const ushort_t* a1_ = (seg_ == 0 ? AS[1] : seg_ == 1 ? AR[1] : AE[1]) + off_; \
    gll16(a0_, &lds[sl_][w][0]);                                            \
    gll16(a1_, &lds[sl_][w + 8][0]);                                        \
    gll16(Bg0 + kk_, &lds[sl_][16 + w][0]);                                 \
    gll16(Bg1 + kk_, &lds[sl_][16 + w + 8][0]);                             \
} while (0)

    STM(0); STM(1); STM(2);
    asm volatile("s_waitcnt vmcnt(8)" ::: "memory");
    __builtin_amdgcn_s_barrier();

    for (int h = 0; h < NH; ++h) {
        if (h + 3 < NH) STM(h + 3);
        const int sl = h & 3;
        bf16x8 bfr[4];
        #pragma unroll
        for (int nf = 0; nf < 4; ++nf)
            bfr[nf] = *(const bf16x8*)&lds[sl][16 + wn * 4 + nf][lane * 8];
        #pragma unroll
        for (int mh = 0; mh < 2; ++mh) {
            bf16x8 af[4];
            #pragma unroll
            for (int mf = 0; mf < 4; ++mf)
                af[mf] = *(const bf16x8*)&lds[sl][wm * 8 + mh * 4 + mf][lane * 8];
            __builtin_amdgcn_s_setprio(1);
            #pragma unroll
            for (int mf = 0; mf < 4; ++mf)
                #pragma unroll
                for (int nf = 0; nf < 4; ++nf)
                    acc[mh * 4 + mf][nf] = __builtin_amdgcn_mfma_f32_16x16x32_bf16(
                        bfr[nf], af[mf], acc[mh * 4 + mf][nf], 0, 0, 0);
            __builtin_amdgcn_s_setprio(0);
        }
        asm volatile("s_waitcnt lgkmcnt(0)" ::: "memory");
        if (h < NH - 3)       { asm volatile("s_waitcnt vmcnt(8)" ::: "memory"); }
        else if (h == NH - 3) { asm volatile("s_waitcnt vmcnt(4)" ::: "memory"); }
        else if (h == NH - 2) { asm volatile("s_waitcnt vmcnt(0)" ::: "memory"); }
        if (h < NH - 1) __builtin_amdgcn_s_barrier();
    }
#undef STM

    #pragma unroll
    for (int mi = 0; mi < 8; ++mi) {
        int mrow = m0 + wm * 128 + mi * 16 + r16;
        #pragma unroll
        for (int nf = 0; nf < 4; ++nf) {
            int nb = wn * 64 + nf * 16 + kq * 4;
            float4 bb = *(const float4*)&b1[nb];
            float v0 = eluf(acc[mi][nf][0] + bb.x);
            float v1 = eluf(acc[mi][nf][1] + bb.y);
            float v2 = eluf(acc[mi][nf][2] + bb.z);
            float v3 = eluf(acc[mi][nf][3] + bb.w);
            ushort4 o; o.x = f2b(v0); o.y = f2b(v1); o.z = f2b(v2); o.w = f2b(v3);
            *(ushort4*)&C[(size_t)mrow * 256 + nb] = o;
        }
    }
}

// ===========================================================================
// weights f32 -> bf16 (packed):
// ef_w2 | m4_w1 | m4_w2 | f_wih | r_wih | e_w1 | m3_w1 | m3_w2
// ===========================================================================
__global__ __launch_bounds__(256) void wconv_k(
    const float* __restrict__ ef_w2, const float* __restrict__ m4_w1,
    const float* __restrict__ m4_w2, const float* __restrict__ f_wih,
    const float* __restrict__ r_wih, const float* __restrict__ e_w1,
    const float* __restrict__ m3_w1, const float* __restrict__ m3_w2,
    ushort_t* __restrict__ Wb)
{
    int i = blockIdx.x * 256 + threadIdx.x;   // < 622592
    const float* src; int off;
    if (i < 65536)       { src = ef_w2; off = i; }
    else if (i < 262144) { src = m4_w1; off = i - 65536; }
    else if (i < 327680) { src = m4_w2; off = i - 262144; }
    else if (i < 393216) { src = f_wih; off = i - 327680; }
    else if (i < 458752) { src = r_wih; off = i - 393216; }
    else if (i < 491520) { src = e_w1;  off = i - 458752; }
    else if (i < 557056) { src = m3_w1; off = i - 491520; }
    else                 { src = m3_w2; off = i - 557056; }
    Wb[i] = f2b(src[off]);
}

// ---------------------------------------------------------------------------
// edge2node: X[b,v,t,h] = (1/15)*sum_{e:RECV==v} EA[b,e,t,h] + rel@res_w.T + res_b
// Output bf16 (feeds MFMA mlp3).
// ---------------------------------------------------------------------------
__global__ __launch_bounds__(256) void e2n_k(
    const ushort_t* __restrict__ EA, const float* __restrict__ rel,
    const float* __restrict__ res_w, const float* __restrict__ res_b,
    ushort_t* __restrict__ X)
{
    const int idx = blockIdx.x;            // (b*V+v)*T + t
    const int t = idx & (T_ - 1);
    const int bv = idx >> 6;
    const int v = bv & (V_ - 1);
    const int b = bv >> 4;
    const int h = threadIdx.x;
    float sum = 0.f;
    #pragma unroll
    for (int i = 0; i < V_; ++i) {
        if (i == v) continue;
        int jj = (v < i) ? v : v - 1;
        int e = i * (V_ - 1) + jj;
        sum += b2f(EA[(((size_t)(b * E_ + e)) * T_ + t) * H_ + h]);
    }
    const float* rp = rel + ((size_t)bv * T_ + t) * DIN_;
    float res = res_b[h];
    #pragma unroll
    for (int d = 0; d < DIN_; ++d) res += rp[d] * res_w[h * DIN_ + d];
    X[((size_t)bv * T_ + t) * H_ + h] = f2b(sum * (1.f / 15.f) + res);
}

// ===========================================================================
// MFMA LSTM scan, both directions in one dispatch (blockIdx.y = dir).
// ===========================================================================
__global__ __launch_bounds__(256) void lstm_mfma4_k(
    const ushort_t* __restrict__ Gf, const ushort_t* __restrict__ Gr,
    const float* __restrict__ whh_f, const float* __restrict__ whh_r,
    ushort_t* __restrict__ COMB)
{
    __shared__ ushort_t hlds[2][1024];   // 2 x 2KB: h[seq][j] bf16, XOR-swizzled
    const int dir = blockIdx.y;
    const ushort_t* G = dir ? Gr : Gf;
    const float* whh = dir ? whh_r : whh_f;
    const int tid = threadIdx.x;
    const int lane = tid & 63;
    const int w = tid >> 6;              // wave id = j-block
    const int seq = lane & 15, kq = lane >> 4;
    const int be0 = blockIdx.x * 16;
    const int swz = (seq & 7) << 4;

    bf16x8 wf[4][2];
    #pragma unroll
    for (int a = 0; a < 4; ++a) {
        #pragma unroll
        for (int ks = 0; ks < 2; ++ks) {
            const float* p = whh + (size_t)((a * 4 + w) * 16 + seq) * 64 + ks * 32 + kq * 8;
            float4 x0 = *(const float4*)p;
            float4 x1 = *(const float4*)(p + 4);
            bf16x8 v;
            v[0] = (short)f2b(x0.x); v[1] = (short)f2b(x0.y);
            v[2] = (short)f2b(x0.z); v[3] = (short)f2b(x0.w);
            v[4] = (short)f2b(x1.x); v[5] = (short)f2b(x1.y);
            v[6] = (short)f2b(x1.z); v[7] = (short)f2b(x1.w);
            wf[a][ks] = v;
        }
    }

    const ushort_t* grow = G + ((size_t)(be0 + seq) * T_) * 256 + kq * 4;
    ushort_t* crow = COMB + ((size_t)(be0 + seq) * T_) * 128 + (dir ? 64 : 0) + 16 * w + 4 * kq;

    float c[4] = {};
    ushort4 gx[4];
    const int t0 = dir ? (T_ - 1) : 0;
    #pragma unroll
    for (int a = 0; a < 4; ++a)
        gx[a] = *(const ushort4*)(grow + (size_t)t0 * 256 + (a * 4 + w) * 16);

    for (int s = 0; s < T_; ++s) {
        const int t = dir ? (T_ - 1 - s) : s;
        f32x4 acc[4];
        #pragma unroll
        for (int a = 0; a < 4; ++a) {
            ushort4 g = gx[a];
            acc[a] = (f32x4){b2f(g.x), b2f(g.y), b2f(g.z), b2f(g.w)};
        }
        if (s < T_ - 1) {
            const int tn = dir ? (T_ - 2 - s) : (s + 1);
            #pragma unroll
            for (int a = 0; a < 4; ++a)
                gx[a] = *(const ushort4*)(grow + (size_t)tn * 256 + (a * 4 + w) * 16);
        }
        if (s) {
            bf16x8 af[2];
            #pragma unroll
            for (int ks = 0; ks < 2; ++ks) {
                int boff = (seq * 128 + ks * 64 + kq * 16) ^ swz;
                af[ks] = *(const bf16x8*)((const char*)hlds[(s - 1) & 1] + boff);
            }
            #pragma unroll
            for (int a = 0; a < 4; ++a) {
                acc[a] = __builtin_amdgcn_mfma_f32_16x16x32_bf16(wf[a][0], af[0], acc[a], 0, 0, 0);
                acc[a] = __builtin_amdgcn_mfma_f32_16x16x32_bf16(wf[a][1], af[1], acc[a], 0, 0, 0);
            }
        }
        float hh[4];
        #pragma unroll
        for (int r = 0; r < 4; ++r) {
            float zi = acc[0][r], zf = acc[1][r], zg = acc[2][r], zo = acc[3][r];
            float cc = fsig(zf) * c[r] + fsig(zi) * ftanh_(zg);
            c[r] = cc;
            hh[r] = fsig(zo) * ftanh_(cc);
        }
        ushort4 hv;
        hv.x = f2b(hh[0]); hv.y = f2b(hh[1]); hv.z = f2b(hh[2]); hv.w = f2b(hh[3]);
        int wb = (seq * 128 + 32 * w + 8 * kq) ^ swz;
        *(ushort4*)((char*)hlds[s & 1] + wb) = hv;
        *(ushort4*)(crow + (size_t)t * 128) = hv;
        asm volatile("s_waitcnt lgkmcnt(0)" ::: "memory");
        __builtin_amdgcn_sched_barrier(0);
        __builtin_amdgcn_s_barrier();
    }
}

// ---------------------------------------------------------------------------
// prior head: reads fwd hidden from comb[:, 0:64] (row stride 128)
// ---------------------------------------------------------------------------
__global__ __launch_bounds__(256) void prior_k(
    const ushort_t* __restrict__ COMB, const float* __restrict__ p_w,
    const float* __restrict__ p_b, float* __restrict__ out)
{
    const int row = blockIdx.x * 4 + (threadIdx.x >> 6);  // [0, BET)
    const int lane = threadIdx.x & 63;
    float hf = b2f(COMB[(size_t)row * 128 + lane]);
    float v0 = hf * p_w[lane];
    float v1 = hf * p_w[64 + lane];
    #pragma unroll
    for (int off = 32; off > 0; off >>= 1) {
        v0 += __shfl_down(v0, off, 64);
        v1 += __shfl_down(v1, off, 64);
    }
    if (lane == 0) {
        int t = row & (T_ - 1);
        int be = row >> 6;
        int e = be % E_, b = be / E_;
        size_t o = (((size_t)b * T_ + t) * E_ + e) * K_;
        out[o] = v0 + p_b[0];
        out[o + 1] = v1 + p_b[1];
    }
}

// ===========================================================================
// FUSED: ENCH = elu(COMB@e_w1.T + e_b1) in regs, then out = ENCH@e_w2.T + e_b2
// (unchanged from round 9/10/11)
// ===========================================================================
__global__ __launch_bounds__(512) void fused_enc_k(
    const ushort_t* __restrict__ COMB, const ushort_t* __restrict__ w_e1,
    const float* __restrict__ e_b1, const float* __restrict__ e_w2,
    const float* __restrict__ e_b2, float* __restrict__ out)
{
    __shared__ ushort_t sA[2][8][512];    // 16 KB
    __shared__ ushort_t sW[2][16][512];   // 32 KB
    __shared__ float part[128][4][2];     // 4 KB
    const int tid = threadIdx.x;
    const int lane = tid & 63;
    const int w = tid >> 6;
    const int wr = w >> 2, wc = w & 3;
    const int m0 = blockIdx.x * 128;
    const int r16 = lane & 15, kq = lane >> 4;

    const ushort_t* Asrc = COMB + (size_t)(m0 + w * 16 + r16) * 128 + kq * 8;
    const size_t woffA = (size_t)((2 * w) * 16 + r16) * 128 + kq * 8;
    const size_t woffB = (size_t)((2 * w + 1) * 16 + r16) * 128 + kq * 8;

    float4 w2v[2][4];
    #pragma unroll
    for (int j = 0; j < 2; ++j)
        #pragma unroll
        for (int nf = 0; nf < 4; ++nf)
            w2v[j][nf] = *(const float4*)&e_w2[j * 256 + wc * 64 + nf * 16 + kq * 4];

    f32x4 acc[4][4];
    #pragma unroll
    for (int i = 0; i < 4; ++i)
        #pragma unroll
        for (int j = 0; j < 4; ++j)
            acc[i][j] = (f32x4){0.f, 0.f, 0.f, 0.f};

#define FE_STAGE(bufi, kt_) do {                                             \
    gll16(Asrc + (kt_) * 32, &sA[bufi][w][0]);                               \
    gll16(w_e1 + woffA + (kt_) * 32, &sW[bufi][2 * w][0]);                   \
    gll16(w_e1 + woffB + (kt_) * 32, &sW[bufi][2 * w + 1][0]);               \
} while (0)

    FE_STAGE(0, 0);
    asm volatile("s_waitcnt vmcnt(0)" ::: "memory");
    __builtin_amdgcn_s_barrier();

    for (int s = 0; s < 4; ++s) {
        const int buf = s & 1;
        if (s < 3) FE_STAGE(buf ^ 1, s + 1);
        bf16x8 af[4], bfr[4];
        #pragma unroll
        for (int mf = 0; mf < 4; ++mf)
            af[mf] = *(const bf16x8*)&sA[buf][wr * 4 + mf][lane * 8];
        #pragma unroll
        for (int nf = 0; nf < 4; ++nf)
            bfr[nf] = *(const bf16x8*)&sW[buf][wc * 4 + nf][lane * 8];
        #pragma unroll
        for (int mf = 0; mf < 4; ++mf)
            #pragma unroll
            for (int nf = 0; nf < 4; ++nf)
                acc[mf][nf] = __builtin_amdgcn_mfma_f32_16x16x32_bf16(bfr[nf], af[mf], acc[mf][nf], 0, 0, 0);
        asm volatile("s_waitcnt vmcnt(0)" ::: "memory");
        __builtin_amdgcn_s_barrier();
    }

    #pragma unroll
    for (int mf = 0; mf < 4; ++mf) {
        float s0 = 0.f, s1 = 0.f;
        #pragma unroll
        for (int nf = 0; nf < 4; ++nf) {
            int col = wc * 64 + nf * 16 + kq * 4;
            float4 bb = *(const float4*)&e_b1[col];
            float v0 = eluf(acc[mf][nf][0] + bb.x);
            float v1 = eluf(acc[mf][nf][1] + bb.y);
            float v2 = eluf(acc[mf][nf][2] + bb.z);
            float v3 = eluf(acc[mf][nf][3] + bb.w);
            s0 += v0 * w2v[0][nf].x + v1 * w2v[0][nf].y + v2 * w2v[0][nf].z + v3 * w2v[0][nf].w;
            s1 += v0 * w2v[1][nf].x + v1 * w2v[1][nf].y + v2 * w2v[1][nf].z + v3 * w2v[1][nf].w;
        }
        s0 += __shfl_xor(s0, 16, 64); s0 += __shfl_xor(s0, 32, 64);
        s1 += __shfl_xor(s1, 16, 64); s1 += __shfl_xor(s1, 32, 64);
        if (kq == 0) {
            part[wr * 64 + mf * 16 + r16][wc][0] = s0;
            part[wr * 64 + mf * 16 + r16][wc][1] = s1;
        }
    }
    __syncthreads();
    if (tid < 256) {
        int row = tid >> 1, k = tid & 1;
        float v = part[row][0][k] + part[row][1][k] + part[row][2][k] + part[row][3][k] + e_b2[k];
        int gr = m0 + row;
        int be = gr >> 6, t = gr & 63;
        int e = be % E_, b = be / E_;
        out[(size_t)(B_ * T_ * E_ * K_) + (((size_t)b * T_ + t) * E_ + e) * K_ + k] = v;
    }
#undef FE_STAGE
}

// ---------------------------------------------------------------------------
extern "C" void kernel_launch(void* const* d_in, const int* in_sizes, int n_in,
                              void* d_out, int out_size, void* d_ws, size_t ws_size,
                              hipStream_t stream)
{
    const float* rel    = (const float*)d_in[0];
    const float* ear    = (const float*)d_in[1];
    const float* epos   = (const float*)d_in[2];
    const float* ef_w1  = (const float*)d_in[3];
    const float* ef_b1  = (const float*)d_in[4];
    const float* ef_w2  = (const float*)d_in[5];
    const float* ef_b2  = (const float*)d_in[6];
    const float* res_w  = (const float*)d_in[7];
    const float* res_b  = (const float*)d_in[8];
    const float* m3_w1  = (const float*)d_in[9];
    const float* m3_b1  = (const float*)d_in[10];
    const float* m3_w2  = (const float*)d_in[11];
    const float* m3_b2  = (const float*)d_in[12];
    const float* m4_w1  = (const float*)d_in[13];
    const float* m4_b1  = (const float*)d_in[14];
    const float* m4_w2  = (const float*)d_in[15];
    const float* m4_b2  = (const float*)d_in[16];
    const float* f_wih  = (const float*)d_in[17];
    const float* f_whh  = (const float*)d_in[18];
    const float* f_bih  = (const float*)d_in[19];
    const float* f_bhh  = (const float*)d_in[20];
    const float* r_wih  = (const float*)d_in[21];
    const float* r_whh  = (const float*)d_in[22];
    const float* r_bih  = (const float*)d_in[23];
    const float* r_bhh  = (const float*)d_in[24];
    const float* p_w    = (const float*)d_in[25];
    const float* p_b    = (const float*)d_in[26];
    const float* e_w1   = (const float*)d_in[27];
    const float* e_b1   = (const float*)d_in[28];
    const float* e_w2   = (const float*)d_in[29];
    const float* e_b2   = (const float*)d_in[30];
    float* out = (float*)d_out;

    // workspace layout (bytes), total ~163 MB
    char* ws = (char*)d_ws;
    const size_t BIGB  = (size_t)BET_ * H_ * sizeof(ushort_t);   // 62,914,560
    const size_t COMBB = (size_t)BET_ * 128 * sizeof(ushort_t);  // 31,457,280
    const size_t X2BB  = (size_t)BVT_ * H_ * sizeof(ushort_t);   //  4,194,304
    ushort_t* R1   = (ushort_t*)(ws);
    ushort_t* R2   = (ushort_t*)(ws + BIGB);
    ushort_t* COMB = (ushort_t*)(ws + 2 * BIGB);
    ushort_t* X2b  = (ushort_t*)(ws + 2 * BIGB + COMBB);
    ushort_t* Wb   = (ushort_t*)(ws + 2 * BIGB + COMBB + X2BB);
    // node-stage bf16 X lives inside (dead) R1 region
    ushort_t* Xbf = (ushort_t*)(ws);
    // packed bf16 weight offsets (elements)
    const ushort_t* wb_ef2  = Wb + 0;
    const ushort_t* wb_m41  = Wb + 65536;
    const ushort_t* wb_m42  = Wb + 262144;
    const ushort_t* wb_fwih = Wb + 327680;
    const ushort_t* wb_rwih = Wb + 393216;
    const ushort_t* wb_ew1  = Wb + 458752;
    const ushort_t* wb_m31  = Wb + 491520;
    const ushort_t* wb_m32  = Wb + 557056;

    dim3 blk(256);
    dim3 blk8(512);
    dim3 g128(BET_ / 128);     // 960 blocks (BM=128 kernels)
    dim3 g256(BET_ / 256);     // 480 blocks (BM=256 kernels)
    dim3 gE64(BET_ / 64, 4);   // VALU ein GEMM

    // 0. weights -> bf16 (incl. mlp3)
    wconv_k<<<2432, blk, 0, stream>>>(ef_w2, m4_w1, m4_w2, f_wih, r_wih, e_w1, m3_w1, m3_w2, Wb);
    // 1. edge-filter MLP: VALU ein (K=16) -> R1, then MFMA ef2 -> R2 (EA)
    gemm_ein_k<<<gE64, blk, 0, stream>>>(ear, epos, ef_w1, ef_b1, R1);
    gemm8_k<256, 1><<<g256, blk8, 0, stream>>>(R1, wb_ef2, ef_b2, nullptr, R2);
    // 2. edge2node + residual -> bf16 X (aliases R1; H1 dead)
    e2n_k<<<BVT_, blk, 0, stream>>>(R2, rel, res_w, res_b, Xbf);
    // 3. fused mlp3 (both layers, MFMA) -> X2b
    gemm8_mlp3_k<<<BVT_ / 128, blk8, 0, stream>>>(Xbf, wb_m31, m3_b1, wb_m32, m3_b2, X2b);
    // 4. node2edge gather + mlp4 layer 1 -> T1 (R1)
    gemm8_mlp4_k<<<g256, blk8, 0, stream>>>(X2b, R2, wb_m41, m4_b1, R1);
    // 5. m4l2 -> M2 (R2; EA dead), then merged gates: GF -> R1, GR -> R2 in-place
    gemm8_k<256, 1><<<g256, blk8, 0, stream>>>(R1, wb_m42, m4_b2, nullptr, R2);
    gemm8_gates_k<<<g128, blk8, 0, stream>>>(R2, wb_fwih, wb_rwih,
                                             f_bih, f_bhh, r_bih, r_bhh, R1, R2);
    // 6. LSTM scans, both directions in one dispatch (Gf=R1, Gr=R2)
    lstm_mfma4_k<<<dim3(BE_ / 16, 2), blk, 0, stream>>>(R1, R2, f_whh, r_whh, COMB);
    // 7. heads
    prior_k<<<BET_ / 4, blk, 0, stream>>>(COMB, p_w, p_b, out);
    fused_enc_k<<<g128, blk8, 0, stream>>>(COMB, wb_ew1, e_b1, e_w2, e_b2, out);
}